// Round 1
// baseline (4696.394 us; speedup 1.0000x reference)
//
#include <hip/hip_runtime.h>
#include <math.h>

// ---------------------------------------------------------------------------
// EATN forward, fp32 reference-accurate implementation.
// Layout convention: all activation tensors are (B, C, N) with N = 32*32 = 1024
// contiguous (identical memory layout to (B, C, H, W)).
// B=32, C=128 (144 for stem), HEADS=16, HD=8.
// ---------------------------------------------------------------------------

static constexpr int NPIX = 1024;

static __device__ __forceinline__ float dot4f(float4 a, float4 b) {
    return a.x * b.x + a.y * b.y + a.z * b.z + a.w * b.w;
}

// ------------------------- conv3x3 + scale/bias/relu (+res) ----------------
// in: (B,CIN,32,32)  wgt: (Cout,CIN,3,3)  out[b,co,n] = relu(conv*g+b) [+res]
template <int CIN>
__global__ __launch_bounds__(256) void conv3x3_kernel(
    const float* __restrict__ in, const float* __restrict__ wgt,
    const float* __restrict__ g, const float* __restrict__ bb,
    const float* __restrict__ res, float* __restrict__ out, int Cout)
{
    const int tid = threadIdx.x;
    const int b = blockIdx.x >> 2;
    const int n = ((blockIdx.x & 3) << 8) + tid;
    const int h = n >> 5, w = n & 31;
    const int co0 = blockIdx.y << 4;

    int off[9];
    bool ok[9];
#pragma unroll
    for (int dy = 0; dy < 3; ++dy)
#pragma unroll
        for (int dx = 0; dx < 3; ++dx) {
            int hh = h + dy - 1, ww = w + dx - 1;
            bool v = (hh >= 0) && (hh < 32) && (ww >= 0) && (ww < 32);
            ok[dy * 3 + dx] = v;
            off[dy * 3 + dx] = v ? hh * 32 + ww : 0;
        }
    const float* inb = in + (size_t)b * CIN * NPIX;
    float acc[16];
#pragma unroll
    for (int a = 0; a < 16; ++a) acc[a] = 0.f;

#pragma unroll 2
    for (int ci = 0; ci < CIN; ++ci) {
        const float* ip = inb + ci * NPIX;
        float xv[9];
#pragma unroll
        for (int tap = 0; tap < 9; ++tap) xv[tap] = ok[tap] ? ip[off[tap]] : 0.f;
        const float* wp = wgt + ((size_t)co0 * CIN + ci) * 9;
#pragma unroll
        for (int a = 0; a < 16; ++a) {
            const float* wa = wp + (size_t)a * CIN * 9;
            float s = acc[a];
#pragma unroll
            for (int tap = 0; tap < 9; ++tap) s = fmaf(wa[tap], xv[tap], s);
            acc[a] = s;
        }
    }
#pragma unroll
    for (int a = 0; a < 16; ++a) {
        int co = co0 + a;
        float v = fmaxf(acc[a] * g[co] + bb[co], 0.f);
        size_t oi = ((size_t)(b * Cout + co) << 10) + n;
        if (res) v += res[oi];
        out[oi] = v;
    }
}

// ------------------------- 1x1 conv, generic epilogue ----------------------
// out = [relu]((acc [+bias0]) [*g+b]) [+res]
__global__ __launch_bounds__(256) void conv1x1_kernel(
    const float* __restrict__ in, int Cin, const float* __restrict__ wgt,
    const float* __restrict__ bias0, const float* __restrict__ g,
    const float* __restrict__ bb, const float* __restrict__ res,
    float* __restrict__ out, int Cout, int do_relu)
{
    const int tid = threadIdx.x;
    const int b = blockIdx.x >> 2;
    const int n = ((blockIdx.x & 3) << 8) + tid;
    const int co0 = blockIdx.y << 4;
    const float* inb = in + (size_t)b * Cin * NPIX + n;
    float acc[16];
#pragma unroll
    for (int a = 0; a < 16; ++a) acc[a] = 0.f;
#pragma unroll 4
    for (int ci = 0; ci < Cin; ++ci) {
        float v = inb[(size_t)ci << 10];
        const float* wp = wgt + (size_t)co0 * Cin + ci;
#pragma unroll
        for (int a = 0; a < 16; ++a) acc[a] = fmaf(wp[(size_t)a * Cin], v, acc[a]);
    }
#pragma unroll
    for (int a = 0; a < 16; ++a) {
        int co = co0 + a;
        float v = acc[a];
        if (bias0) v += bias0[co];
        if (g) v = v * g[co] + bb[co];
        if (do_relu) v = fmaxf(v, 0.f);
        size_t oi = ((size_t)(b * Cout + co) << 10) + n;
        if (res) v += res[oi];
        out[oi] = v;
    }
}

// ------------------------- grouped 1x1 (GISSA qkv projections) -------------
// out[b,ch,n] = sum_{c<CPG} wgt[ch*CPG+c] * maybe_relu(in[b,(ch/GDIV)*CPG+c,n]) + bias[ch]
__global__ __launch_bounds__(256) void gconv_kernel(
    const float* __restrict__ in, const float* __restrict__ wgt,
    const float* __restrict__ bias, float* __restrict__ out,
    int CPG, int GDIV, int in_relu)
{
    const int tid = threadIdx.x;
    const int b = blockIdx.x >> 2;
    const int n = ((blockIdx.x & 3) << 8) + tid;
    const int ch0 = blockIdx.y << 4;
    const float* inb = in + ((size_t)b << 17) + n;  // b*128*1024
#pragma unroll
    for (int a = 0; a < 16; ++a) {
        int ch = ch0 + a;
        int cbase = (ch / GDIV) * CPG;
        float s = 0.f;
        for (int c = 0; c < CPG; ++c) {
            float v = inb[(size_t)(cbase + c) << 10];
            if (in_relu) v = fmaxf(v, 0.f);
            s = fmaf(wgt[(size_t)ch * CPG + c], v, s);
        }
        out[((size_t)(b * 384 + ch) << 10) + n] = s + bias[ch];
    }
}

// ------------------------- LayerNorm over C=128 -----------------------------
__global__ __launch_bounds__(256) void ln_kernel(
    const float* __restrict__ in, const float* __restrict__ g,
    const float* __restrict__ bb, float* __restrict__ out)
{
    const int tid = threadIdx.x;
    const int b = blockIdx.x >> 2;
    const int n = ((blockIdx.x & 3) << 8) + tid;
    const float* ib = in + ((size_t)b << 17) + n;
    float s = 0.f, sq = 0.f;
#pragma unroll 8
    for (int c = 0; c < 128; ++c) {
        float v = ib[(size_t)c << 10];
        s += v;
        sq += v * v;
    }
    const float mu = s * 0.0078125f;
    const float r = rsqrtf(sq * 0.0078125f - mu * mu + 1e-5f);
    float* ob = out + ((size_t)b << 17) + n;
#pragma unroll 8
    for (int c = 0; c < 128; ++c) {
        float v = ib[(size_t)c << 10];
        ob[(size_t)c << 10] = (v - mu) * r * g[c] + bb[c];
    }
}

// ------------------------- GISSA attention 1 (8x8 per (b,h)) ---------------
// ybuf[b, d*16+h, n] = (sum_e P[d][e] v[e,n] + cur[b,h*8+d,n]) * g + b
__global__ __launch_bounds__(64) void gissa1_kernel(
    const float* __restrict__ qkv, const float* __restrict__ cur,
    const float* __restrict__ g, const float* __restrict__ bb,
    float* __restrict__ ybuf)
{
    const int lane = threadIdx.x;
    const int b = blockIdx.x >> 4;
    const int h = blockIdx.x & 15;
    const int d = lane >> 3, e = lane & 7;
    const float* qp = qkv + ((size_t)(b * 384 + h * 8 + d) << 10);
    const float* kp = qkv + ((size_t)(b * 384 + 128 + h * 8 + e) << 10);
    float s = 0.f;
#pragma unroll 4
    for (int n = 0; n < 1024; n += 4) {
        float4 q4 = *(const float4*)(qp + n);
        float4 k4 = *(const float4*)(kp + n);
        s += dot4f(q4, k4);
    }
    s *= 0.35355339059327373f;  // 8^-0.5
    float a = (s > 0.f) ? sqrtf(s + 1e-5f) : ((s < 0.f) ? -sqrtf(1e-5f - s) : 0.f);
    float mx = a;
    mx = fmaxf(mx, __shfl_xor(mx, 1));
    mx = fmaxf(mx, __shfl_xor(mx, 2));
    mx = fmaxf(mx, __shfl_xor(mx, 4));
    float pp = __expf(a - mx);
    float dn = pp;
    dn += __shfl_xor(dn, 1);
    dn += __shfl_xor(dn, 2);
    dn += __shfl_xor(dn, 4);
    pp /= dn;
    const float* vp = qkv + ((size_t)(b * 384 + 256 + h * 8 + e) << 10);
    const int cp = d * 16 + h;
    const float gg = g[cp], gb = bb[cp];
    const float* rp = cur + ((size_t)(b * 128 + h * 8 + d) << 10);
    float* op = ybuf + ((size_t)(b * 128 + cp) << 10);
    for (int n = 0; n < 1024; n += 4) {
        float4 v4 = *(const float4*)(vp + n);
        float px = pp * v4.x, py = pp * v4.y, pz = pp * v4.z, pw = pp * v4.w;
        px += __shfl_xor(px, 1); px += __shfl_xor(px, 2); px += __shfl_xor(px, 4);
        py += __shfl_xor(py, 1); py += __shfl_xor(py, 2); py += __shfl_xor(py, 4);
        pz += __shfl_xor(pz, 1); pz += __shfl_xor(pz, 2); pz += __shfl_xor(pz, 4);
        pw += __shfl_xor(pw, 1); pw += __shfl_xor(pw, 2); pw += __shfl_xor(pw, 4);
        if (e == 0) {
            float4 r4 = *(const float4*)(rp + n);
            float4 o;
            o.x = (px + r4.x) * gg + gb;
            o.y = (py + r4.y) * gg + gb;
            o.z = (pz + r4.z) * gg + gb;
            o.w = (pw + r4.w) * gg + gb;
            *(float4*)(op + n) = o;
        }
    }
}

// ------------------------- GISSA attention 2 (16x16 per (b,d)) -------------
// t[b, h*8+d, n] += sum_g P[h][g] v2[g,n] + ybuf[b, h*8+d, n]
__global__ __launch_bounds__(256) void gissa2_kernel(
    const float* __restrict__ qkv2, const float* __restrict__ ybuf,
    float* __restrict__ t)
{
    const int tid = threadIdx.x;
    const int b = blockIdx.x >> 3;
    const int d = blockIdx.x & 7;
    const int h = tid >> 4, gi = tid & 15;
    const float* qp = qkv2 + ((size_t)(b * 384 + d * 16 + h) << 10);
    const float* kp = qkv2 + ((size_t)(b * 384 + 128 + d * 16 + gi) << 10);
    float s = 0.f;
#pragma unroll 4
    for (int n = 0; n < 1024; n += 4) {
        float4 q4 = *(const float4*)(qp + n);
        float4 k4 = *(const float4*)(kp + n);
        s += dot4f(q4, k4);
    }
    s *= 0.25f;  // 16^-0.5
    float a = (s > 0.f) ? sqrtf(s + 1e-5f) : ((s < 0.f) ? -sqrtf(1e-5f - s) : 0.f);
    float mx = a;
#pragma unroll
    for (int o = 1; o < 16; o <<= 1) mx = fmaxf(mx, __shfl_xor(mx, o));
    float pp = __expf(a - mx);
    float dn = pp;
#pragma unroll
    for (int o = 1; o < 16; o <<= 1) dn += __shfl_xor(dn, o);
    pp /= dn;
    const float* vp = qkv2 + ((size_t)(b * 384 + 256 + d * 16 + gi) << 10);
    const int ch = h * 8 + d;
    const float* yp = ybuf + ((size_t)(b * 128 + ch) << 10);
    float* tp = t + ((size_t)(b * 128 + ch) << 10);
    for (int n = 0; n < 1024; n += 4) {
        float4 v4 = *(const float4*)(vp + n);
        float px = pp * v4.x, py = pp * v4.y, pz = pp * v4.z, pw = pp * v4.w;
#pragma unroll
        for (int o = 1; o < 16; o <<= 1) {
            px += __shfl_xor(px, o);
            py += __shfl_xor(py, o);
            pz += __shfl_xor(pz, o);
            pw += __shfl_xor(pw, o);
        }
        if (gi == 0) {
            float4 tv = *(const float4*)(tp + n);
            float4 yv = *(const float4*)(yp + n);
            tv.x += px + yv.x;
            tv.y += py + yv.y;
            tv.z += pz + yv.z;
            tv.w += pw + yv.w;
            *(float4*)(tp + n) = tv;
        }
    }
}

// ------------------------- fused LN2 + MLP (t += mlp(ln(t))) ---------------
__global__ __launch_bounds__(256) void mlp_kernel(
    float* __restrict__ t, const float* __restrict__ ln_g,
    const float* __restrict__ ln_b, const float* __restrict__ w1,
    const float* __restrict__ b1, const float* __restrict__ w2,
    const float* __restrict__ b2)
{
    __shared__ float rows[64][132];
    const int tid = threadIdx.x;
    const int b = blockIdx.x >> 4;
    const int n0 = (blockIdx.x & 15) << 6;
    float* tb = t + ((size_t)b << 17);
    for (int idx = tid; idx < 64 * 128; idx += 256) {
        int c = idx & 127, rr = idx >> 7;
        rows[rr][c] = tb[((size_t)c << 10) + n0 + rr];
    }
    __syncthreads();
    const int row = tid >> 2, p = tid & 3;
    const int c0 = p << 5;
    float4 xr[8];
#pragma unroll
    for (int k = 0; k < 8; ++k) xr[k] = *(const float4*)&rows[row][c0 + (k << 2)];
    float s = 0.f, sq = 0.f;
#pragma unroll
    for (int k = 0; k < 8; ++k) {
        s += xr[k].x + xr[k].y + xr[k].z + xr[k].w;
        sq += xr[k].x * xr[k].x + xr[k].y * xr[k].y + xr[k].z * xr[k].z + xr[k].w * xr[k].w;
    }
    s += __shfl_xor(s, 1);
    s += __shfl_xor(s, 2);
    sq += __shfl_xor(sq, 1);
    sq += __shfl_xor(sq, 2);
    const float mu = s * 0.0078125f;
    const float rstd = rsqrtf(sq * 0.0078125f - mu * mu + 1e-5f);
#pragma unroll
    for (int k = 0; k < 8; ++k) {
        float4 g4 = *(const float4*)&ln_g[c0 + (k << 2)];
        float4 b4 = *(const float4*)&ln_b[c0 + (k << 2)];
        xr[k].x = (xr[k].x - mu) * rstd * g4.x + b4.x;
        xr[k].y = (xr[k].y - mu) * rstd * g4.y + b4.y;
        xr[k].z = (xr[k].z - mu) * rstd * g4.z + b4.z;
        xr[k].w = (xr[k].w - mu) * rstd * g4.w + b4.w;
    }
    float acc[32];
#pragma unroll
    for (int k = 0; k < 32; ++k) acc[k] = 0.f;
    for (int j4 = 0; j4 < 512; j4 += 4) {
        float hh[4];
#pragma unroll
        for (int jj = 0; jj < 4; ++jj) {
            const float4* wp = (const float4*)(w1 + (size_t)(j4 + jj) * 128 + c0);
            float dsum = 0.f;
#pragma unroll
            for (int k = 0; k < 8; ++k) dsum += dot4f(xr[k], wp[k]);
            dsum += __shfl_xor(dsum, 1);
            dsum += __shfl_xor(dsum, 2);
            dsum += b1[j4 + jj];
            hh[jj] = 0.5f * dsum * (1.f + erff(dsum * 0.70710678118654752f));
        }
#pragma unroll
        for (int k = 0; k < 32; ++k) {
            float4 wv = *(const float4*)(w2 + (size_t)(c0 + k) * 512 + j4);
            acc[k] = fmaf(hh[0], wv.x, fmaf(hh[1], wv.y, fmaf(hh[2], wv.z, fmaf(hh[3], wv.w, acc[k]))));
        }
    }
    float* tw = tb + n0 + row;
#pragma unroll
    for (int k = 0; k < 32; ++k) {
        size_t off = (size_t)(c0 + k) << 10;
        tw[off] += acc[k] + b2[c0 + k];
    }
}

// ------------------------- flash SWSA (softmax(q q^T/sqrt(128)) @ v) -------
// out[b,c,n] = fscale * sum_m softmax_m(q_n.q_m / sqrt(128)) * v[b,c,m]
// q channel c at qb + b*qstride + c*1024; v channel c at vb + b*vstride + c*1024
__global__ __launch_bounds__(256) void swsa_kernel(
    const float* __restrict__ qb, const float* __restrict__ vb,
    float* __restrict__ outp, int qstride, int vstride, float fscale)
{
    __shared__ float Qs[64][128];
    __shared__ float KV[64][128];
    const int tid = threadIdx.x;
    const int b = blockIdx.x >> 4;
    const int n0 = (blockIdx.x & 15) << 6;
    const float* q = qb + (size_t)b * qstride;
    const float* v = vb + (size_t)b * vstride;

    // stage Q rows (pre-scaled by 128^-0.5), XOR-swizzled columns
    for (int idx = tid; idx < 64 * 128; idx += 256) {
        int mm = idx & 63, c = idx >> 6;
        Qs[mm][c ^ ((mm & 7) << 2)] =
            q[((size_t)c << 10) + n0 + mm] * 0.08838834764831845f;
    }
    __syncthreads();

    const int rp = tid >> 3, p = tid & 7;
    const int lane = tid & 63;
    const int lbase = lane & ~7;
    const int r0 = rp * 2, r1 = r0 + 1;
    const int swq0 = (r0 & 7) << 2, swq1 = (r1 & 7) << 2;
    const int swp = p << 2;

    float mr0 = -INFINITY, mr1 = -INFINITY, l0 = 0.f, l1 = 0.f;
    float y0[16], y1[16];
#pragma unroll
    for (int k = 0; k < 16; ++k) { y0[k] = 0.f; y1[k] = 0.f; }

#pragma unroll 1
    for (int mt = 0; mt < 16; ++mt) {
        const int m0 = mt << 6;
        for (int idx = tid; idx < 64 * 128; idx += 256) {
            int mm = idx & 63, c = idx >> 6;
            KV[mm][c ^ ((mm & 7) << 2)] = q[((size_t)c << 10) + m0 + mm];
        }
        __syncthreads();

        float s0[8], s1[8];
#pragma unroll
        for (int jj = 0; jj < 8; ++jj) { s0[jj] = 0.f; s1[jj] = 0.f; }
#pragma unroll 4
        for (int c4 = 0; c4 < 128; c4 += 4) {
            float4 qa = *(const float4*)&Qs[r0][c4 ^ swq0];
            float4 qc = *(const float4*)&Qs[r1][c4 ^ swq1];
#pragma unroll
            for (int jj = 0; jj < 8; ++jj) {
                float4 kv = *(const float4*)&KV[p + 8 * jj][c4 ^ swp];
                s0[jj] += dot4f(qa, kv);
                s1[jj] += dot4f(qc, kv);
            }
        }
        float tm0 = s0[0], tm1 = s1[0];
#pragma unroll
        for (int jj = 1; jj < 8; ++jj) {
            tm0 = fmaxf(tm0, s0[jj]);
            tm1 = fmaxf(tm1, s1[jj]);
        }
        tm0 = fmaxf(tm0, __shfl_xor(tm0, 1));
        tm0 = fmaxf(tm0, __shfl_xor(tm0, 2));
        tm0 = fmaxf(tm0, __shfl_xor(tm0, 4));
        tm1 = fmaxf(tm1, __shfl_xor(tm1, 1));
        tm1 = fmaxf(tm1, __shfl_xor(tm1, 2));
        tm1 = fmaxf(tm1, __shfl_xor(tm1, 4));
        const float mn0 = fmaxf(mr0, tm0), mn1 = fmaxf(mr1, tm1);
        const float al0 = __expf(mr0 - mn0), al1 = __expf(mr1 - mn1);
        float p0[8], p1[8];
        float ps0 = 0.f, ps1 = 0.f;
#pragma unroll
        for (int jj = 0; jj < 8; ++jj) {
            p0[jj] = __expf(s0[jj] - mn0);
            ps0 += p0[jj];
            p1[jj] = __expf(s1[jj] - mn1);
            ps1 += p1[jj];
        }
        ps0 += __shfl_xor(ps0, 1); ps0 += __shfl_xor(ps0, 2); ps0 += __shfl_xor(ps0, 4);
        ps1 += __shfl_xor(ps1, 1); ps1 += __shfl_xor(ps1, 2); ps1 += __shfl_xor(ps1, 4);
        l0 = l0 * al0 + ps0;
        l1 = l1 * al1 + ps1;
        mr0 = mn0;
        mr1 = mn1;
#pragma unroll
        for (int k = 0; k < 16; ++k) { y0[k] *= al0; y1[k] *= al1; }

        __syncthreads();
        for (int idx = tid; idx < 64 * 128; idx += 256) {
            int mm = idx & 63, c = idx >> 6;
            KV[mm][c ^ ((mm & 7) << 2)] = v[((size_t)c << 10) + m0 + mm];
        }
        __syncthreads();

#pragma unroll
        for (int jj = 0; jj < 8; ++jj) {
#pragma unroll
            for (int sp = 0; sp < 8; ++sp) {
                const int mm = sp + 8 * jj;       // owner lane has p == sp
                const int swm = (mm & 7) << 2;
                float pa = __shfl(p0[jj], lbase + sp, 64);
                float pb = __shfl(p1[jj], lbase + sp, 64);
                const float* vrow = &KV[mm][0];
#pragma unroll
                for (int k4 = 0; k4 < 4; ++k4) {
                    float4 vv = *(const float4*)(vrow + (((p << 4) + (k4 << 2)) ^ swm));
                    y0[4 * k4 + 0] = fmaf(pa, vv.x, y0[4 * k4 + 0]);
                    y0[4 * k4 + 1] = fmaf(pa, vv.y, y0[4 * k4 + 1]);
                    y0[4 * k4 + 2] = fmaf(pa, vv.z, y0[4 * k4 + 2]);
                    y0[4 * k4 + 3] = fmaf(pa, vv.w, y0[4 * k4 + 3]);
                    y1[4 * k4 + 0] = fmaf(pb, vv.x, y1[4 * k4 + 0]);
                    y1[4 * k4 + 1] = fmaf(pb, vv.y, y1[4 * k4 + 1]);
                    y1[4 * k4 + 2] = fmaf(pb, vv.z, y1[4 * k4 + 2]);
                    y1[4 * k4 + 3] = fmaf(pb, vv.w, y1[4 * k4 + 3]);
                }
            }
        }
        __syncthreads();
    }

    const float i0 = fscale / l0, i1 = fscale / l1;
    float* ob = outp + ((size_t)b << 17) + n0;
#pragma unroll
    for (int k = 0; k < 16; ++k) {
        const int c = (p << 4) + k;
        ob[((size_t)c << 10) + r0] = y0[k] * i0;
        ob[((size_t)c << 10) + r1] = y1[k] * i1;
    }
}

// ------------------------- final mix + mean + fc ----------------------------
__global__ __launch_bounds__(256) void final_kernel(
    const float* __restrict__ xc, const float* __restrict__ xp,
    const float* __restrict__ lamuda, const float* __restrict__ fc_w,
    float* __restrict__ outp)
{
    __shared__ float meanb[128];
    __shared__ float red[4];
    const int tid = threadIdx.x;
    const int b = blockIdx.x;
    const float lmd = 1.f / (1.f + __expf(-lamuda[0]));
    const float* xcb = xc + ((size_t)b << 17);
    const float* xpb = xp + ((size_t)b << 17);
    for (int c = 0; c < 128; ++c) {
        float4 a = *(const float4*)(xcb + ((size_t)c << 10) + tid * 4);
        float4 d = *(const float4*)(xpb + ((size_t)c << 10) + tid * 4);
        float s = lmd * (a.x + a.y + a.z + a.w) + (1.f - lmd) * (d.x + d.y + d.z + d.w);
#pragma unroll
        for (int o = 1; o < 64; o <<= 1) s += __shfl_xor(s, o);
        if ((tid & 63) == 0) red[tid >> 6] = s;
        __syncthreads();
        if (tid == 0) meanb[c] = (red[0] + red[1] + red[2] + red[3]) * (1.f / 1024.f);
        __syncthreads();
    }
    if (tid < 16) {
        float s = 0.f;
        for (int c = 0; c < 128; ++c) s += fc_w[tid * 128 + c] * meanb[c];
        outp[b * 16 + tid] = s;
    }
}

// ---------------------------------------------------------------------------
extern "C" void kernel_launch(void* const* d_in, const int* in_sizes, int n_in,
                              void* d_out, int out_size, void* d_ws, size_t ws_size,
                              hipStream_t stream)
{
    (void)in_sizes; (void)n_in; (void)out_size; (void)ws_size;

    const float* x       = (const float*)d_in[0];
    const float* ssfe_w  = (const float*)d_in[1];
    const float* ssfe_g  = (const float*)d_in[2];
    const float* ssfe_b  = (const float*)d_in[3];
    const float* cc_w    = (const float*)d_in[4];
    const float* cc_g    = (const float*)d_in[5];
    const float* cc_b    = (const float*)d_in[6];
    const float* ln1_g   = (const float*)d_in[7];
    const float* ln1_b   = (const float*)d_in[8];
    const float* qkv_w   = (const float*)d_in[9];
    const float* qkv_b   = (const float*)d_in[10];
    const float* gbn_g   = (const float*)d_in[11];
    const float* gbn_b   = (const float*)d_in[12];
    const float* qkv2_w  = (const float*)d_in[13];
    const float* qkv2_b  = (const float*)d_in[14];
    const float* ln2_g   = (const float*)d_in[15];
    const float* ln2_b   = (const float*)d_in[16];
    const float* mlp_w1  = (const float*)d_in[17];
    const float* mlp_b1  = (const float*)d_in[18];
    const float* mlp_w2  = (const float*)d_in[19];
    const float* mlp_b2  = (const float*)d_in[20];
    const float* cs_w    = (const float*)d_in[21];
    const float* cs_g    = (const float*)d_in[22];
    const float* cs_b    = (const float*)d_in[23];
    const float* lfe0_w  = (const float*)d_in[24];
    const float* lfe0_g  = (const float*)d_in[25];
    const float* lfe0_b  = (const float*)d_in[26];
    const float* s0_pi_w = (const float*)d_in[27];
    const float* s0_pi_b = (const float*)d_in[28];
    const float* s0_bn_g = (const float*)d_in[29];
    const float* s0_bn_b = (const float*)d_in[30];
    const float* s0_po_w = (const float*)d_in[31];
    const float* s0_po_b = (const float*)d_in[32];
    const float* lfe1_w  = (const float*)d_in[33];
    const float* lfe1_g  = (const float*)d_in[34];
    const float* lfe1_b  = (const float*)d_in[35];
    const float* s1_pi_w = (const float*)d_in[36];
    const float* s1_pi_b = (const float*)d_in[37];
    const float* s1_bn_g = (const float*)d_in[38];
    const float* s1_bn_b = (const float*)d_in[39];
    const float* s1_po_w = (const float*)d_in[40];
    const float* s1_po_b = (const float*)d_in[41];
    const float* lamuda  = (const float*)d_in[42];
    const float* fc_w    = (const float*)d_in[43];
    float* out = (float*)d_out;
    float* ws = (float*)d_ws;

    // workspace layout (floats); total = 34,078,720 floats = 136.3 MB
    float* xs = ws;                    // (B,144,N)  stem features
    float* t  = ws + 4718592;          // (B,128,N)  transformer residual stream / xc
    float* P1 = ws + 8912896;          // (B,128,N)  cur / xp / yv / xp4
    float* Q  = ws + 13107200;         // (B,384,N)  qkv / qkv2 / tbuf(256ch)
    float* P2 = ws + 25690112;         // (B,128,N)  ybuf / xp2 / yv2
    float* P3 = ws + 29884416;         // (B,128,N)  xp3 / t1 / xp5

    const dim3 blk(256);

    // xs = cbr3(x, ssfe)                               (B,144,N)
    conv3x3_kernel<144><<<dim3(128, 9), blk, 0, stream>>>(x, ssfe_w, ssfe_g, ssfe_b, nullptr, xs, 144);
    // t = cbr1(xs, cc)                                 (B,128,N)
    conv1x1_kernel<<<dim3(128, 8), blk, 0, stream>>>(xs, 144, cc_w, nullptr, cc_g, cc_b, nullptr, t, 128, 1);
    // cur = LN1(t)
    ln_kernel<<<dim3(128), blk, 0, stream>>>(t, ln1_g, ln1_b, P1);
    // GISSA: qkv = gconv(cur)
    gconv_kernel<<<dim3(128, 24), blk, 0, stream>>>(P1, qkv_w, qkv_b, Q, 8, 24, 0);
    // GISSA attn1 -> ybuf (y, post-affine, pre-relu)
    gissa1_kernel<<<dim3(512), dim3(64), 0, stream>>>(Q, P1, gbn_g, gbn_b, P2);
    // GISSA: qkv2 = gconv(relu(y))
    gconv_kernel<<<dim3(128, 24), blk, 0, stream>>>(P2, qkv2_w, qkv2_b, Q, 16, 48, 1);
    // GISSA attn2 + residuals: t += PV2 + y
    gissa2_kernel<<<dim3(256), blk, 0, stream>>>(Q, P2, t);
    // t += MLP(LN2(t))
    mlp_kernel<<<dim3(512), blk, 0, stream>>>(t, ln2_g, ln2_b, mlp_w1, mlp_b1, mlp_w2, mlp_b2);
    // xp = cbr3(xs, cs)
    conv3x3_kernel<144><<<dim3(128, 8), blk, 0, stream>>>(xs, cs_w, cs_g, cs_b, nullptr, P1, 128);
    // xp2 = cbr3(xp, lfe0) + xp
    conv3x3_kernel<128><<<dim3(128, 8), blk, 0, stream>>>(P1, lfe0_w, lfe0_g, lfe0_b, P1, P2, 128);
    // tbuf = (pi0(xp2)+pib)*g+b                        (B,256,N)
    conv1x1_kernel<<<dim3(128, 16), blk, 0, stream>>>(P2, 128, s0_pi_w, s0_pi_b, s0_bn_g, s0_bn_b, nullptr, Q, 256, 0);
    // yv = softmax(q q^T/sqrt(128)) @ v                (flash, recompute)
    swsa_kernel<<<dim3(512), blk, 0, stream>>>(Q, Q + 131072, P1, 262144, 262144, 1.0f);
    // xp3 = po0(yv) + po_b + xp2
    conv1x1_kernel<<<dim3(128, 8), blk, 0, stream>>>(P1, 128, s0_po_w, s0_po_b, nullptr, nullptr, P2, P3, 128, 0);
    // xp4 = cbr3(xp3, lfe1) + xp3
    conv3x3_kernel<128><<<dim3(128, 8), blk, 0, stream>>>(P3, lfe1_w, lfe1_g, lfe1_b, P3, P1, 128);
    // t1 = (pi1(xp4)+pib)*g+b
    conv1x1_kernel<<<dim3(128, 8), blk, 0, stream>>>(P1, 128, s1_pi_w, s1_pi_b, s1_bn_g, s1_bn_b, nullptr, P3, 128, 0);
    // yv2 = (atn @ t1) * 128^-0.5   (same atn: q from tbuf, recomputed)
    swsa_kernel<<<dim3(512), blk, 0, stream>>>(Q, P3, P2, 262144, 131072, 0.08838834764831845f);
    // xp5 = po1(yv2) + po_b + xp4
    conv1x1_kernel<<<dim3(128, 8), blk, 0, stream>>>(P2, 128, s1_po_w, s1_po_b, nullptr, nullptr, P1, P3, 128, 0);
    // out = (lmd*t + (1-lmd)*xp5).mean(n) @ fc_w.T
    final_kernel<<<dim3(32), blk, 0, stream>>>(t, P3, lamuda, fc_w, out);
}

// Round 2
// 2867.061 us; speedup vs baseline: 1.6381x; 1.6381x over previous
//
#include <hip/hip_runtime.h>
#include <math.h>

// ---------------------------------------------------------------------------
// EATN forward. Layout: activations (B, C, N), N = 1024 contiguous.
// B=32, C=128 (144 stem), HEADS=16, HD=8.
// Round 2: MLP rewritten as fused LN + bf16-MFMA dual GEMM.
// ---------------------------------------------------------------------------

static constexpr int NPIX = 1024;

typedef __attribute__((ext_vector_type(8))) short bf16x8;
typedef __attribute__((ext_vector_type(4))) float f32x4;
typedef __attribute__((ext_vector_type(8))) unsigned short u16x8;
typedef __attribute__((ext_vector_type(4))) unsigned short u16x4;

static __device__ __forceinline__ float dot4f(float4 a, float4 b) {
    return a.x * b.x + a.y * b.y + a.z * b.z + a.w * b.w;
}

static __device__ __forceinline__ unsigned short f2bf(float f) {
    unsigned u = __builtin_bit_cast(unsigned, f);
    unsigned r = (u + 0x7fffu + ((u >> 16) & 1u)) >> 16;
    return (unsigned short)r;
}

// ------------------------- conv3x3 + scale/bias/relu (+res) ----------------
template <int CIN>
__global__ __launch_bounds__(256) void conv3x3_kernel(
    const float* __restrict__ in, const float* __restrict__ wgt,
    const float* __restrict__ g, const float* __restrict__ bb,
    const float* __restrict__ res, float* __restrict__ out, int Cout)
{
    const int tid = threadIdx.x;
    const int b = blockIdx.x >> 2;
    const int n = ((blockIdx.x & 3) << 8) + tid;
    const int h = n >> 5, w = n & 31;
    const int co0 = blockIdx.y << 4;

    int off[9];
    bool ok[9];
#pragma unroll
    for (int dy = 0; dy < 3; ++dy)
#pragma unroll
        for (int dx = 0; dx < 3; ++dx) {
            int hh = h + dy - 1, ww = w + dx - 1;
            bool v = (hh >= 0) && (hh < 32) && (ww >= 0) && (ww < 32);
            ok[dy * 3 + dx] = v;
            off[dy * 3 + dx] = v ? hh * 32 + ww : 0;
        }
    const float* inb = in + (size_t)b * CIN * NPIX;
    float acc[16];
#pragma unroll
    for (int a = 0; a < 16; ++a) acc[a] = 0.f;

#pragma unroll 2
    for (int ci = 0; ci < CIN; ++ci) {
        const float* ip = inb + ci * NPIX;
        float xv[9];
#pragma unroll
        for (int tap = 0; tap < 9; ++tap) xv[tap] = ok[tap] ? ip[off[tap]] : 0.f;
        const float* wp = wgt + ((size_t)co0 * CIN + ci) * 9;
#pragma unroll
        for (int a = 0; a < 16; ++a) {
            const float* wa = wp + (size_t)a * CIN * 9;
            float s = acc[a];
#pragma unroll
            for (int tap = 0; tap < 9; ++tap) s = fmaf(wa[tap], xv[tap], s);
            acc[a] = s;
        }
    }
#pragma unroll
    for (int a = 0; a < 16; ++a) {
        int co = co0 + a;
        float v = fmaxf(acc[a] * g[co] + bb[co], 0.f);
        size_t oi = ((size_t)(b * Cout + co) << 10) + n;
        if (res) v += res[oi];
        out[oi] = v;
    }
}

// ------------------------- 1x1 conv, generic epilogue ----------------------
__global__ __launch_bounds__(256) void conv1x1_kernel(
    const float* __restrict__ in, int Cin, const float* __restrict__ wgt,
    const float* __restrict__ bias0, const float* __restrict__ g,
    const float* __restrict__ bb, const float* __restrict__ res,
    float* __restrict__ out, int Cout, int do_relu)
{
    const int tid = threadIdx.x;
    const int b = blockIdx.x >> 2;
    const int n = ((blockIdx.x & 3) << 8) + tid;
    const int co0 = blockIdx.y << 4;
    const float* inb = in + (size_t)b * Cin * NPIX + n;
    float acc[16];
#pragma unroll
    for (int a = 0; a < 16; ++a) acc[a] = 0.f;
#pragma unroll 4
    for (int ci = 0; ci < Cin; ++ci) {
        float v = inb[(size_t)ci << 10];
        const float* wp = wgt + (size_t)co0 * Cin + ci;
#pragma unroll
        for (int a = 0; a < 16; ++a) acc[a] = fmaf(wp[(size_t)a * Cin], v, acc[a]);
    }
#pragma unroll
    for (int a = 0; a < 16; ++a) {
        int co = co0 + a;
        float v = acc[a];
        if (bias0) v += bias0[co];
        if (g) v = v * g[co] + bb[co];
        if (do_relu) v = fmaxf(v, 0.f);
        size_t oi = ((size_t)(b * Cout + co) << 10) + n;
        if (res) v += res[oi];
        out[oi] = v;
    }
}

// ------------------------- grouped 1x1 (GISSA qkv projections) -------------
__global__ __launch_bounds__(256) void gconv_kernel(
    const float* __restrict__ in, const float* __restrict__ wgt,
    const float* __restrict__ bias, float* __restrict__ out,
    int CPG, int GDIV, int in_relu)
{
    const int tid = threadIdx.x;
    const int b = blockIdx.x >> 2;
    const int n = ((blockIdx.x & 3) << 8) + tid;
    const int ch0 = blockIdx.y << 4;
    const float* inb = in + ((size_t)b << 17) + n;
#pragma unroll
    for (int a = 0; a < 16; ++a) {
        int ch = ch0 + a;
        int cbase = (ch / GDIV) * CPG;
        float s = 0.f;
        for (int c = 0; c < CPG; ++c) {
            float v = inb[(size_t)(cbase + c) << 10];
            if (in_relu) v = fmaxf(v, 0.f);
            s = fmaf(wgt[(size_t)ch * CPG + c], v, s);
        }
        out[((size_t)(b * 384 + ch) << 10) + n] = s + bias[ch];
    }
}

// ------------------------- LayerNorm over C=128 -----------------------------
__global__ __launch_bounds__(256) void ln_kernel(
    const float* __restrict__ in, const float* __restrict__ g,
    const float* __restrict__ bb, float* __restrict__ out)
{
    const int tid = threadIdx.x;
    const int b = blockIdx.x >> 2;
    const int n = ((blockIdx.x & 3) << 8) + tid;
    const float* ib = in + ((size_t)b << 17) + n;
    float s = 0.f, sq = 0.f;
#pragma unroll 8
    for (int c = 0; c < 128; ++c) {
        float v = ib[(size_t)c << 10];
        s += v;
        sq += v * v;
    }
    const float mu = s * 0.0078125f;
    const float r = rsqrtf(sq * 0.0078125f - mu * mu + 1e-5f);
    float* ob = out + ((size_t)b << 17) + n;
#pragma unroll 8
    for (int c = 0; c < 128; ++c) {
        float v = ib[(size_t)c << 10];
        ob[(size_t)c << 10] = (v - mu) * r * g[c] + bb[c];
    }
}

// ------------------------- GISSA attention 1 (8x8 per (b,h)) ---------------
__global__ __launch_bounds__(64) void gissa1_kernel(
    const float* __restrict__ qkv, const float* __restrict__ cur,
    const float* __restrict__ g, const float* __restrict__ bb,
    float* __restrict__ ybuf)
{
    const int lane = threadIdx.x;
    const int b = blockIdx.x >> 4;
    const int h = blockIdx.x & 15;
    const int d = lane >> 3, e = lane & 7;
    const float* qp = qkv + ((size_t)(b * 384 + h * 8 + d) << 10);
    const float* kp = qkv + ((size_t)(b * 384 + 128 + h * 8 + e) << 10);
    float s = 0.f;
#pragma unroll 4
    for (int n = 0; n < 1024; n += 4) {
        float4 q4 = *(const float4*)(qp + n);
        float4 k4 = *(const float4*)(kp + n);
        s += dot4f(q4, k4);
    }
    s *= 0.35355339059327373f;
    float a = (s > 0.f) ? sqrtf(s + 1e-5f) : ((s < 0.f) ? -sqrtf(1e-5f - s) : 0.f);
    float mx = a;
    mx = fmaxf(mx, __shfl_xor(mx, 1));
    mx = fmaxf(mx, __shfl_xor(mx, 2));
    mx = fmaxf(mx, __shfl_xor(mx, 4));
    float pp = __expf(a - mx);
    float dn = pp;
    dn += __shfl_xor(dn, 1);
    dn += __shfl_xor(dn, 2);
    dn += __shfl_xor(dn, 4);
    pp /= dn;
    const float* vp = qkv + ((size_t)(b * 384 + 256 + h * 8 + e) << 10);
    const int cp = d * 16 + h;
    const float gg = g[cp], gb = bb[cp];
    const float* rp = cur + ((size_t)(b * 128 + h * 8 + d) << 10);
    float* op = ybuf + ((size_t)(b * 128 + cp) << 10);
    for (int n = 0; n < 1024; n += 4) {
        float4 v4 = *(const float4*)(vp + n);
        float px = pp * v4.x, py = pp * v4.y, pz = pp * v4.z, pw = pp * v4.w;
        px += __shfl_xor(px, 1); px += __shfl_xor(px, 2); px += __shfl_xor(px, 4);
        py += __shfl_xor(py, 1); py += __shfl_xor(py, 2); py += __shfl_xor(py, 4);
        pz += __shfl_xor(pz, 1); pz += __shfl_xor(pz, 2); pz += __shfl_xor(pz, 4);
        pw += __shfl_xor(pw, 1); pw += __shfl_xor(pw, 2); pw += __shfl_xor(pw, 4);
        if (e == 0) {
            float4 r4 = *(const float4*)(rp + n);
            float4 o;
            o.x = (px + r4.x) * gg + gb;
            o.y = (py + r4.y) * gg + gb;
            o.z = (pz + r4.z) * gg + gb;
            o.w = (pw + r4.w) * gg + gb;
            *(float4*)(op + n) = o;
        }
    }
}

// ------------------------- GISSA attention 2 (16x16 per (b,d)) -------------
__global__ __launch_bounds__(256) void gissa2_kernel(
    const float* __restrict__ qkv2, const float* __restrict__ ybuf,
    float* __restrict__ t)
{
    const int tid = threadIdx.x;
    const int b = blockIdx.x >> 3;
    const int d = blockIdx.x & 7;
    const int h = tid >> 4, gi = tid & 15;
    const float* qp = qkv2 + ((size_t)(b * 384 + d * 16 + h) << 10);
    const float* kp = qkv2 + ((size_t)(b * 384 + 128 + d * 16 + gi) << 10);
    float s = 0.f;
#pragma unroll 4
    for (int n = 0; n < 1024; n += 4) {
        float4 q4 = *(const float4*)(qp + n);
        float4 k4 = *(const float4*)(kp + n);
        s += dot4f(q4, k4);
    }
    s *= 0.25f;
    float a = (s > 0.f) ? sqrtf(s + 1e-5f) : ((s < 0.f) ? -sqrtf(1e-5f - s) : 0.f);
    float mx = a;
#pragma unroll
    for (int o = 1; o < 16; o <<= 1) mx = fmaxf(mx, __shfl_xor(mx, o));
    float pp = __expf(a - mx);
    float dn = pp;
#pragma unroll
    for (int o = 1; o < 16; o <<= 1) dn += __shfl_xor(dn, o);
    pp /= dn;
    const float* vp = qkv2 + ((size_t)(b * 384 + 256 + d * 16 + gi) << 10);
    const int ch = h * 8 + d;
    const float* yp = ybuf + ((size_t)(b * 128 + ch) << 10);
    float* tp = t + ((size_t)(b * 128 + ch) << 10);
    for (int n = 0; n < 1024; n += 4) {
        float4 v4 = *(const float4*)(vp + n);
        float px = pp * v4.x, py = pp * v4.y, pz = pp * v4.z, pw = pp * v4.w;
#pragma unroll
        for (int o = 1; o < 16; o <<= 1) {
            px += __shfl_xor(px, o);
            py += __shfl_xor(py, o);
            pz += __shfl_xor(pz, o);
            pw += __shfl_xor(pw, o);
        }
        if (gi == 0) {
            float4 tv = *(const float4*)(tp + n);
            float4 yv = *(const float4*)(yp + n);
            tv.x += px + yv.x;
            tv.y += py + yv.y;
            tv.z += pz + yv.z;
            tv.w += pw + yv.w;
            *(float4*)(tp + n) = tv;
        }
    }
}

// ------------------------- f32 -> bf16 conversion --------------------------
__global__ __launch_bounds__(256) void cvt_bf16_kernel(
    const float* __restrict__ a, unsigned short* __restrict__ o, int n)
{
    int i = blockIdx.x * 256 + threadIdx.x;
    if (i < n) o[i] = f2bf(a[i]);
}

// ------------------------- fused LN2 + MLP via bf16 MFMA -------------------
// Per block: 64 pixels of one batch. t[b,:,n0+px] += W2 @ gelu(W1 @ ln(t) + b1) + b2
__global__ __launch_bounds__(256) void mlp_mfma_kernel(
    float* __restrict__ t, const float* __restrict__ ln_g,
    const float* __restrict__ ln_b, const unsigned short* __restrict__ w1bf,
    const float* __restrict__ b1, const unsigned short* __restrict__ w2bf,
    const float* __restrict__ b2)
{
    // LDS: xn [64 px][128 c] bf16 swizzled (16 KB) | h [64 px][512 hid] bf16 swizzled (64 KB)
    __shared__ unsigned char lds[16384 + 65536];
    unsigned char* xnb = lds;
    unsigned char* hb = lds + 16384;

    const int tid = threadIdx.x;
    const int b = blockIdx.x >> 4;
    const int n0 = (blockIdx.x & 15) << 6;
    float* tb = t + ((size_t)b << 17) + n0;

    // ---- LN: thread (px = tid>>2, q = tid&3) owns 32 channels of one pixel
    {
        const int px = tid >> 2, q = tid & 3;
        float v[32];
        float s = 0.f, sq = 0.f;
#pragma unroll
        for (int k = 0; k < 32; ++k) {
            float x = tb[((size_t)(q * 32 + k) << 10) + px];
            v[k] = x;
            s += x;
            sq += x * x;
        }
        s += __shfl_xor(s, 1); s += __shfl_xor(s, 2);
        sq += __shfl_xor(sq, 1); sq += __shfl_xor(sq, 2);
        const float mu = s * 0.0078125f;
        const float rstd = rsqrtf(sq * 0.0078125f - mu * mu + 1e-5f);
        const int sw = (px & 7) << 4;
#pragma unroll
        for (int cc = 0; cc < 4; ++cc) {
            u16x8 pk;
#pragma unroll
            for (int e = 0; e < 8; ++e) {
                int c = q * 32 + cc * 8 + e;
                float xv = (v[cc * 8 + e] - mu) * rstd * ln_g[c] + ln_b[c];
                pk[e] = f2bf(xv);
            }
            *(u16x8*)(xnb + px * 256 + ((q * 64 + cc * 16) ^ sw)) = pk;
        }
    }
    __syncthreads();

    const int wid = tid >> 6, lane = tid & 63;
    const int lr = lane & 15, lk = lane >> 4;

    // ---- GEMM1: h[hid, px] = gelu(sum_c w1[hid,c] * xn[px,c] + b1[hid])
    // wave wid covers hid [wid*128, wid*128+128) in 2 passes of 64
#pragma unroll 1
    for (int pass = 0; pass < 2; ++pass) {
        const int hidbase = (wid << 7) + (pass << 6);
        f32x4 acc[4][4];
#pragma unroll
        for (int i = 0; i < 4; ++i)
#pragma unroll
            for (int j = 0; j < 4; ++j)
#pragma unroll
                for (int r = 0; r < 4; ++r) acc[i][j][r] = 0.f;
#pragma unroll
        for (int kk = 0; kk < 4; ++kk) {
            bf16x8 af[4], bfr[4];
#pragma unroll
            for (int i = 0; i < 4; ++i)
                af[i] = *(const bf16x8*)(w1bf + (size_t)(hidbase + i * 16 + lr) * 128 + kk * 32 + lk * 8);
#pragma unroll
            for (int j = 0; j < 4; ++j) {
                const int px = j * 16 + lr;
                bfr[j] = *(const bf16x8*)(xnb + px * 256 + ((kk * 64 + lk * 16) ^ ((px & 7) << 4)));
            }
#pragma unroll
            for (int i = 0; i < 4; ++i)
#pragma unroll
                for (int j = 0; j < 4; ++j)
                    acc[i][j] = __builtin_amdgcn_mfma_f32_16x16x32_bf16(af[i], bfr[j], acc[i][j], 0, 0, 0);
        }
        // gelu (tanh form) + pack to h LDS
#pragma unroll
        for (int i = 0; i < 4; ++i) {
            const int hid0 = hidbase + i * 16 + lk * 4;
            float bi[4];
#pragma unroll
            for (int r = 0; r < 4; ++r) bi[r] = b1[hid0 + r];
#pragma unroll
            for (int j = 0; j < 4; ++j) {
                const int px = j * 16 + lr;
                u16x4 pk;
#pragma unroll
                for (int r = 0; r < 4; ++r) {
                    float x = acc[i][j][r] + bi[r];
                    float u = 1.5957691f * x * (1.f + 0.044715f * x * x);
                    float gv = x / (1.f + __expf(-u));
                    pk[r] = f2bf(gv);
                }
                *(u16x4*)(hb + px * 1024 + ((hid0 * 2) ^ ((px & 7) << 4))) = pk;
            }
        }
    }
    __syncthreads();

    // ---- GEMM2: out[c, px] = sum_hid w2[c,hid] * h[px,hid]; t += out + b2
    f32x4 acc2[2][4];
#pragma unroll
    for (int i = 0; i < 2; ++i)
#pragma unroll
        for (int j = 0; j < 4; ++j)
#pragma unroll
            for (int r = 0; r < 4; ++r) acc2[i][j][r] = 0.f;
#pragma unroll 2
    for (int ks = 0; ks < 16; ++ks) {
        bf16x8 af[2], bfr[4];
#pragma unroll
        for (int i = 0; i < 2; ++i)
            af[i] = *(const bf16x8*)(w2bf + (size_t)((wid << 5) + i * 16 + lr) * 512 + ks * 32 + lk * 8);
#pragma unroll
        for (int j = 0; j < 4; ++j) {
            const int px = j * 16 + lr;
            bfr[j] = *(const bf16x8*)(hb + px * 1024 + ((ks * 64 + lk * 16) ^ ((px & 7) << 4)));
        }
#pragma unroll
        for (int i = 0; i < 2; ++i)
#pragma unroll
            for (int j = 0; j < 4; ++j)
                acc2[i][j] = __builtin_amdgcn_mfma_f32_16x16x32_bf16(af[i], bfr[j], acc2[i][j], 0, 0, 0);
    }
#pragma unroll
    for (int i = 0; i < 2; ++i) {
        const int cb = (wid << 5) + i * 16 + lk * 4;
        float b2v[4];
#pragma unroll
        for (int r = 0; r < 4; ++r) b2v[r] = b2[cb + r];
#pragma unroll
        for (int j = 0; j < 4; ++j) {
            const int px = j * 16 + lr;
#pragma unroll
            for (int r = 0; r < 4; ++r) {
                const size_t off = ((size_t)(cb + r) << 10) + px;
                tb[off] += acc2[i][j][r] + b2v[r];
            }
        }
    }
}

// ------------------------- flash SWSA (softmax(q q^T/sqrt(128)) @ v) -------
__global__ __launch_bounds__(256) void swsa_kernel(
    const float* __restrict__ qb, const float* __restrict__ vb,
    float* __restrict__ outp, int qstride, int vstride, float fscale)
{
    __shared__ float Qs[64][128];
    __shared__ float KV[64][128];
    const int tid = threadIdx.x;
    const int b = blockIdx.x >> 4;
    const int n0 = (blockIdx.x & 15) << 6;
    const float* q = qb + (size_t)b * qstride;
    const float* v = vb + (size_t)b * vstride;

    for (int idx = tid; idx < 64 * 128; idx += 256) {
        int mm = idx & 63, c = idx >> 6;
        Qs[mm][c ^ ((mm & 7) << 2)] =
            q[((size_t)c << 10) + n0 + mm] * 0.08838834764831845f;
    }
    __syncthreads();

    const int rp = tid >> 3, p = tid & 7;
    const int lane = tid & 63;
    const int lbase = lane & ~7;
    const int r0 = rp * 2, r1 = r0 + 1;
    const int swq0 = (r0 & 7) << 2, swq1 = (r1 & 7) << 2;
    const int swp = p << 2;

    float mr0 = -INFINITY, mr1 = -INFINITY, l0 = 0.f, l1 = 0.f;
    float y0[16], y1[16];
#pragma unroll
    for (int k = 0; k < 16; ++k) { y0[k] = 0.f; y1[k] = 0.f; }

#pragma unroll 1
    for (int mt = 0; mt < 16; ++mt) {
        const int m0 = mt << 6;
        for (int idx = tid; idx < 64 * 128; idx += 256) {
            int mm = idx & 63, c = idx >> 6;
            KV[mm][c ^ ((mm & 7) << 2)] = q[((size_t)c << 10) + m0 + mm];
        }
        __syncthreads();

        float s0[8], s1[8];
#pragma unroll
        for (int jj = 0; jj < 8; ++jj) { s0[jj] = 0.f; s1[jj] = 0.f; }
#pragma unroll 4
        for (int c4 = 0; c4 < 128; c4 += 4) {
            float4 qa = *(const float4*)&Qs[r0][c4 ^ swq0];
            float4 qc = *(const float4*)&Qs[r1][c4 ^ swq1];
#pragma unroll
            for (int jj = 0; jj < 8; ++jj) {
                float4 kv = *(const float4*)&KV[p + 8 * jj][c4 ^ swp];
                s0[jj] += dot4f(qa, kv);
                s1[jj] += dot4f(qc, kv);
            }
        }
        float tm0 = s0[0], tm1 = s1[0];
#pragma unroll
        for (int jj = 1; jj < 8; ++jj) {
            tm0 = fmaxf(tm0, s0[jj]);
            tm1 = fmaxf(tm1, s1[jj]);
        }
        tm0 = fmaxf(tm0, __shfl_xor(tm0, 1));
        tm0 = fmaxf(tm0, __shfl_xor(tm0, 2));
        tm0 = fmaxf(tm0, __shfl_xor(tm0, 4));
        tm1 = fmaxf(tm1, __shfl_xor(tm1, 1));
        tm1 = fmaxf(tm1, __shfl_xor(tm1, 2));
        tm1 = fmaxf(tm1, __shfl_xor(tm1, 4));
        const float mn0 = fmaxf(mr0, tm0), mn1 = fmaxf(mr1, tm1);
        const float al0 = __expf(mr0 - mn0), al1 = __expf(mr1 - mn1);
        float p0[8], p1[8];
        float ps0 = 0.f, ps1 = 0.f;
#pragma unroll
        for (int jj = 0; jj < 8; ++jj) {
            p0[jj] = __expf(s0[jj] - mn0);
            ps0 += p0[jj];
            p1[jj] = __expf(s1[jj] - mn1);
            ps1 += p1[jj];
        }
        ps0 += __shfl_xor(ps0, 1); ps0 += __shfl_xor(ps0, 2); ps0 += __shfl_xor(ps0, 4);
        ps1 += __shfl_xor(ps1, 1); ps1 += __shfl_xor(ps1, 2); ps1 += __shfl_xor(ps1, 4);
        l0 = l0 * al0 + ps0;
        l1 = l1 * al1 + ps1;
        mr0 = mn0;
        mr1 = mn1;
#pragma unroll
        for (int k = 0; k < 16; ++k) { y0[k] *= al0; y1[k] *= al1; }

        __syncthreads();
        for (int idx = tid; idx < 64 * 128; idx += 256) {
            int mm = idx & 63, c = idx >> 6;
            KV[mm][c ^ ((mm & 7) << 2)] = v[((size_t)c << 10) + m0 + mm];
        }
        __syncthreads();

#pragma unroll
        for (int jj = 0; jj < 8; ++jj) {
#pragma unroll
            for (int sp = 0; sp < 8; ++sp) {
                const int mm = sp + 8 * jj;
                const int swm = (mm & 7) << 2;
                float pa = __shfl(p0[jj], lbase + sp, 64);
                float pb = __shfl(p1[jj], lbase + sp, 64);
                const float* vrow = &KV[mm][0];
#pragma unroll
                for (int k4 = 0; k4 < 4; ++k4) {
                    float4 vv = *(const float4*)(vrow + (((p << 4) + (k4 << 2)) ^ swm));
                    y0[4 * k4 + 0] = fmaf(pa, vv.x, y0[4 * k4 + 0]);
                    y0[4 * k4 + 1] = fmaf(pa, vv.y, y0[4 * k4 + 1]);
                    y0[4 * k4 + 2] = fmaf(pa, vv.z, y0[4 * k4 + 2]);
                    y0[4 * k4 + 3] = fmaf(pa, vv.w, y0[4 * k4 + 3]);
                    y1[4 * k4 + 0] = fmaf(pb, vv.x, y1[4 * k4 + 0]);
                    y1[4 * k4 + 1] = fmaf(pb, vv.y, y1[4 * k4 + 1]);
                    y1[4 * k4 + 2] = fmaf(pb, vv.z, y1[4 * k4 + 2]);
                    y1[4 * k4 + 3] = fmaf(pb, vv.w, y1[4 * k4 + 3]);
                }
            }
        }
        __syncthreads();
    }

    const float i0 = fscale / l0, i1 = fscale / l1;
    float* ob = outp + ((size_t)b << 17) + n0;
#pragma unroll
    for (int k = 0; k < 16; ++k) {
        const int c = (p << 4) + k;
        ob[((size_t)c << 10) + r0] = y0[k] * i0;
        ob[((size_t)c << 10) + r1] = y1[k] * i1;
    }
}

// ------------------------- final mix + mean + fc ----------------------------
__global__ __launch_bounds__(256) void final_kernel(
    const float* __restrict__ xc, const float* __restrict__ xp,
    const float* __restrict__ lamuda, const float* __restrict__ fc_w,
    float* __restrict__ outp)
{
    __shared__ float meanb[128];
    __shared__ float red[4];
    const int tid = threadIdx.x;
    const int b = blockIdx.x;
    const float lmd = 1.f / (1.f + __expf(-lamuda[0]));
    const float* xcb = xc + ((size_t)b << 17);
    const float* xpb = xp + ((size_t)b << 17);
    for (int c = 0; c < 128; ++c) {
        float4 a = *(const float4*)(xcb + ((size_t)c << 10) + tid * 4);
        float4 d = *(const float4*)(xpb + ((size_t)c << 10) + tid * 4);
        float s = lmd * (a.x + a.y + a.z + a.w) + (1.f - lmd) * (d.x + d.y + d.z + d.w);
#pragma unroll
        for (int o = 1; o < 64; o <<= 1) s += __shfl_xor(s, o);
        if ((tid & 63) == 0) red[tid >> 6] = s;
        __syncthreads();
        if (tid == 0) meanb[c] = (red[0] + red[1] + red[2] + red[3]) * (1.f / 1024.f);
        __syncthreads();
    }
    if (tid < 16) {
        float s = 0.f;
        for (int c = 0; c < 128; ++c) s += fc_w[tid * 128 + c] * meanb[c];
        outp[b * 16 + tid] = s;
    }
}

// ---------------------------------------------------------------------------
extern "C" void kernel_launch(void* const* d_in, const int* in_sizes, int n_in,
                              void* d_out, int out_size, void* d_ws, size_t ws_size,
                              hipStream_t stream)
{
    (void)in_sizes; (void)n_in; (void)out_size; (void)ws_size;

    const float* x       = (const float*)d_in[0];
    const float* ssfe_w  = (const float*)d_in[1];
    const float* ssfe_g  = (const float*)d_in[2];
    const float* ssfe_b  = (const float*)d_in[3];
    const float* cc_w    = (const float*)d_in[4];
    const float* cc_g    = (const float*)d_in[5];
    const float* cc_b    = (const float*)d_in[6];
    const float* ln1_g   = (const float*)d_in[7];
    const float* ln1_b   = (const float*)d_in[8];
    const float* qkv_w   = (const float*)d_in[9];
    const float* qkv_b   = (const float*)d_in[10];
    const float* gbn_g   = (const float*)d_in[11];
    const float* gbn_b   = (const float*)d_in[12];
    const float* qkv2_w  = (const float*)d_in[13];
    const float* qkv2_b  = (const float*)d_in[14];
    const float* ln2_g   = (const float*)d_in[15];
    const float* ln2_b   = (const float*)d_in[16];
    const float* mlp_w1  = (const float*)d_in[17];
    const float* mlp_b1  = (const float*)d_in[18];
    const float* mlp_w2  = (const float*)d_in[19];
    const float* mlp_b2  = (const float*)d_in[20];
    const float* cs_w    = (const float*)d_in[21];
    const float* cs_g    = (const float*)d_in[22];
    const float* cs_b    = (const float*)d_in[23];
    const float* lfe0_w  = (const float*)d_in[24];
    const float* lfe0_g  = (const float*)d_in[25];
    const float* lfe0_b  = (const float*)d_in[26];
    const float* s0_pi_w = (const float*)d_in[27];
    const float* s0_pi_b = (const float*)d_in[28];
    const float* s0_bn_g = (const float*)d_in[29];
    const float* s0_bn_b = (const float*)d_in[30];
    const float* s0_po_w = (const float*)d_in[31];
    const float* s0_po_b = (const float*)d_in[32];
    const float* lfe1_w  = (const float*)d_in[33];
    const float* lfe1_g  = (const float*)d_in[34];
    const float* lfe1_b  = (const float*)d_in[35];
    const float* s1_pi_w = (const float*)d_in[36];
    const float* s1_pi_b = (const float*)d_in[37];
    const float* s1_bn_g = (const float*)d_in[38];
    const float* s1_bn_b = (const float*)d_in[39];
    const float* s1_po_w = (const float*)d_in[40];
    const float* s1_po_b = (const float*)d_in[41];
    const float* lamuda  = (const float*)d_in[42];
    const float* fc_w    = (const float*)d_in[43];
    float* out = (float*)d_out;
    float* ws = (float*)d_ws;

    // workspace layout (floats); total = 34,078,720 floats = 136.3 MB
    float* xs = ws;                    // (B,144,N)
    float* t  = ws + 4718592;          // (B,128,N)  residual stream / xc
    float* P1 = ws + 8912896;          // (B,128,N)
    float* Q  = ws + 13107200;         // (B,384,N)
    float* P2 = ws + 25690112;         // (B,128,N)  ybuf / bf16 weights / xp2 / yv2
    float* P3 = ws + 29884416;         // (B,128,N)

    unsigned short* w1bf = (unsigned short*)P2;
    unsigned short* w2bf = w1bf + 65536;

    const dim3 blk(256);

    conv3x3_kernel<144><<<dim3(128, 9), blk, 0, stream>>>(x, ssfe_w, ssfe_g, ssfe_b, nullptr, xs, 144);
    conv1x1_kernel<<<dim3(128, 8), blk, 0, stream>>>(xs, 144, cc_w, nullptr, cc_g, cc_b, nullptr, t, 128, 1);
    ln_kernel<<<dim3(128), blk, 0, stream>>>(t, ln1_g, ln1_b, P1);
    gconv_kernel<<<dim3(128, 24), blk, 0, stream>>>(P1, qkv_w, qkv_b, Q, 8, 24, 0);
    gissa1_kernel<<<dim3(512), dim3(64), 0, stream>>>(Q, P1, gbn_g, gbn_b, P2);
    gconv_kernel<<<dim3(128, 24), blk, 0, stream>>>(P2, qkv2_w, qkv2_b, Q, 16, 48, 1);
    gissa2_kernel<<<dim3(256), blk, 0, stream>>>(Q, P2, t);
    // MLP (bf16 MFMA): convert weights into P2 (free after gissa2), then fused kernel
    cvt_bf16_kernel<<<dim3(256), blk, 0, stream>>>(mlp_w1, w1bf, 65536);
    cvt_bf16_kernel<<<dim3(256), blk, 0, stream>>>(mlp_w2, w2bf, 65536);
    mlp_mfma_kernel<<<dim3(512), blk, 0, stream>>>(t, ln2_g, ln2_b, w1bf, mlp_b1, w2bf, mlp_b2);
    conv3x3_kernel<144><<<dim3(128, 8), blk, 0, stream>>>(xs, cs_w, cs_g, cs_b, nullptr, P1, 128);
    conv3x3_kernel<128><<<dim3(128, 8), blk, 0, stream>>>(P1, lfe0_w, lfe0_g, lfe0_b, P1, P2, 128);
    conv1x1_kernel<<<dim3(128, 16), blk, 0, stream>>>(P2, 128, s0_pi_w, s0_pi_b, s0_bn_g, s0_bn_b, nullptr, Q, 256, 0);
    swsa_kernel<<<dim3(512), blk, 0, stream>>>(Q, Q + 131072, P1, 262144, 262144, 1.0f);
    conv1x1_kernel<<<dim3(128, 8), blk, 0, stream>>>(P1, 128, s0_po_w, s0_po_b, nullptr, nullptr, P2, P3, 128, 0);
    conv3x3_kernel<128><<<dim3(128, 8), blk, 0, stream>>>(P3, lfe1_w, lfe1_g, lfe1_b, P3, P1, 128);
    conv1x1_kernel<<<dim3(128, 8), blk, 0, stream>>>(P1, 128, s1_pi_w, s1_pi_b, s1_bn_g, s1_bn_b, nullptr, P3, 128, 0);
    swsa_kernel<<<dim3(512), blk, 0, stream>>>(Q, P3, P2, 262144, 131072, 0.08838834764831845f);
    conv1x1_kernel<<<dim3(128, 8), blk, 0, stream>>>(P2, 128, s1_po_w, s1_po_b, nullptr, nullptr, P1, P3, 128, 0);
    final_kernel<<<dim3(32), blk, 0, stream>>>(t, P3, lamuda, fc_w, out);
}

// Round 3
// 2153.045 us; speedup vs baseline: 2.1813x; 1.3316x over previous
//
#include <hip/hip_runtime.h>
#include <math.h>

// ---------------------------------------------------------------------------
// EATN forward. Layout: activations (B, C, N), N = 1024 contiguous.
// B=32, C=128 (144 stem), HEADS=16, HD=8.
// Round 3: SWSA rewritten as flash bf16-MFMA; pi convs emit bf16 qT/v.
// ---------------------------------------------------------------------------

static constexpr int NPIX = 1024;

typedef __attribute__((ext_vector_type(8))) short bf16x8;
typedef __attribute__((ext_vector_type(4))) float f32x4;
typedef __attribute__((ext_vector_type(8))) unsigned short u16x8;
typedef __attribute__((ext_vector_type(4))) unsigned short u16x4;

static __device__ __forceinline__ float dot4f(float4 a, float4 b) {
    return a.x * b.x + a.y * b.y + a.z * b.z + a.w * b.w;
}

static __device__ __forceinline__ unsigned short f2bf(float f) {
    unsigned u = __builtin_bit_cast(unsigned, f);
    unsigned r = (u + 0x7fffu + ((u >> 16) & 1u)) >> 16;
    return (unsigned short)r;
}

// ------------------------- conv3x3 + scale/bias/relu (+res) ----------------
template <int CIN>
__global__ __launch_bounds__(256) void conv3x3_kernel(
    const float* __restrict__ in, const float* __restrict__ wgt,
    const float* __restrict__ g, const float* __restrict__ bb,
    const float* __restrict__ res, float* __restrict__ out, int Cout)
{
    const int tid = threadIdx.x;
    const int b = blockIdx.x >> 2;
    const int n = ((blockIdx.x & 3) << 8) + tid;
    const int h = n >> 5, w = n & 31;
    const int co0 = blockIdx.y << 4;

    int off[9];
    bool ok[9];
#pragma unroll
    for (int dy = 0; dy < 3; ++dy)
#pragma unroll
        for (int dx = 0; dx < 3; ++dx) {
            int hh = h + dy - 1, ww = w + dx - 1;
            bool v = (hh >= 0) && (hh < 32) && (ww >= 0) && (ww < 32);
            ok[dy * 3 + dx] = v;
            off[dy * 3 + dx] = v ? hh * 32 + ww : 0;
        }
    const float* inb = in + (size_t)b * CIN * NPIX;
    float acc[16];
#pragma unroll
    for (int a = 0; a < 16; ++a) acc[a] = 0.f;

#pragma unroll 2
    for (int ci = 0; ci < CIN; ++ci) {
        const float* ip = inb + ci * NPIX;
        float xv[9];
#pragma unroll
        for (int tap = 0; tap < 9; ++tap) xv[tap] = ok[tap] ? ip[off[tap]] : 0.f;
        const float* wp = wgt + ((size_t)co0 * CIN + ci) * 9;
#pragma unroll
        for (int a = 0; a < 16; ++a) {
            const float* wa = wp + (size_t)a * CIN * 9;
            float s = acc[a];
#pragma unroll
            for (int tap = 0; tap < 9; ++tap) s = fmaf(wa[tap], xv[tap], s);
            acc[a] = s;
        }
    }
#pragma unroll
    for (int a = 0; a < 16; ++a) {
        int co = co0 + a;
        float v = fmaxf(acc[a] * g[co] + bb[co], 0.f);
        size_t oi = ((size_t)(b * Cout + co) << 10) + n;
        if (res) v += res[oi];
        out[oi] = v;
    }
}

// ------------------------- 1x1 conv, generic epilogue ----------------------
__global__ __launch_bounds__(256) void conv1x1_kernel(
    const float* __restrict__ in, int Cin, const float* __restrict__ wgt,
    const float* __restrict__ bias0, const float* __restrict__ g,
    const float* __restrict__ bb, const float* __restrict__ res,
    float* __restrict__ out, int Cout, int do_relu)
{
    const int tid = threadIdx.x;
    const int b = blockIdx.x >> 2;
    const int n = ((blockIdx.x & 3) << 8) + tid;
    const int co0 = blockIdx.y << 4;
    const float* inb = in + (size_t)b * Cin * NPIX + n;
    float acc[16];
#pragma unroll
    for (int a = 0; a < 16; ++a) acc[a] = 0.f;
#pragma unroll 4
    for (int ci = 0; ci < Cin; ++ci) {
        float v = inb[(size_t)ci << 10];
        const float* wp = wgt + (size_t)co0 * Cin + ci;
#pragma unroll
        for (int a = 0; a < 16; ++a) acc[a] = fmaf(wp[(size_t)a * Cin], v, acc[a]);
    }
#pragma unroll
    for (int a = 0; a < 16; ++a) {
        int co = co0 + a;
        float v = acc[a];
        if (bias0) v += bias0[co];
        if (g) v = v * g[co] + bb[co];
        if (do_relu) v = fmaxf(v, 0.f);
        size_t oi = ((size_t)(b * Cout + co) << 10) + n;
        if (res) v += res[oi];
        out[oi] = v;
    }
}

// ------------------------- pi conv: 1x1 + affine -> bf16 qT / v ------------
// y = (W x + b0) * g + bb.  co < qn  -> qTout[b][n][co] (bf16, transposed)
//                           co >= qn -> vout[b][co-qn][n] (bf16, natural)
__global__ __launch_bounds__(256) void pi_kernel(
    const float* __restrict__ in, const float* __restrict__ wgt,
    const float* __restrict__ b0, const float* __restrict__ g,
    const float* __restrict__ bb, unsigned short* __restrict__ qTout,
    unsigned short* __restrict__ vout, int Cout, int qn)
{
    const int tid = threadIdx.x;
    const int b = blockIdx.x >> 2;
    const int n = ((blockIdx.x & 3) << 8) + tid;
    const int co0 = blockIdx.y << 4;
    const float* inb = in + ((size_t)b << 17) + n;
    float acc[16];
#pragma unroll
    for (int a = 0; a < 16; ++a) acc[a] = 0.f;
#pragma unroll 4
    for (int ci = 0; ci < 128; ++ci) {
        float v = inb[(size_t)ci << 10];
        const float* wp = wgt + (size_t)co0 * 128 + ci;
#pragma unroll
        for (int a = 0; a < 16; ++a) acc[a] = fmaf(wp[(size_t)a * 128], v, acc[a]);
    }
#pragma unroll
    for (int a = 0; a < 16; ++a) {
        int co = co0 + a;
        acc[a] = (acc[a] + b0[co]) * g[co] + bb[co];
    }
    if (co0 < qn) {
        // transposed bf16: qT[b][n][co0..co0+15]
        u16x8 p0, p1;
#pragma unroll
        for (int e = 0; e < 8; ++e) { p0[e] = f2bf(acc[e]); p1[e] = f2bf(acc[8 + e]); }
        unsigned short* qp = qTout + ((((size_t)b << 10) + n) << 7) + co0;
        *(u16x8*)qp = p0;
        *(u16x8*)(qp + 8) = p1;
    } else {
#pragma unroll
        for (int a = 0; a < 16; ++a)
            vout[((size_t)(b * (Cout - qn) + (co0 - qn + a)) << 10) + n] = f2bf(acc[a]);
    }
}

// ------------------------- grouped 1x1 (GISSA qkv projections) -------------
__global__ __launch_bounds__(256) void gconv_kernel(
    const float* __restrict__ in, const float* __restrict__ wgt,
    const float* __restrict__ bias, float* __restrict__ out,
    int CPG, int GDIV, int in_relu)
{
    const int tid = threadIdx.x;
    const int b = blockIdx.x >> 2;
    const int n = ((blockIdx.x & 3) << 8) + tid;
    const int ch0 = blockIdx.y << 4;
    const float* inb = in + ((size_t)b << 17) + n;
#pragma unroll
    for (int a = 0; a < 16; ++a) {
        int ch = ch0 + a;
        int cbase = (ch / GDIV) * CPG;
        float s = 0.f;
        for (int c = 0; c < CPG; ++c) {
            float v = inb[(size_t)(cbase + c) << 10];
            if (in_relu) v = fmaxf(v, 0.f);
            s = fmaf(wgt[(size_t)ch * CPG + c], v, s);
        }
        out[((size_t)(b * 384 + ch) << 10) + n] = s + bias[ch];
    }
}

// ------------------------- LayerNorm over C=128 -----------------------------
__global__ __launch_bounds__(256) void ln_kernel(
    const float* __restrict__ in, const float* __restrict__ g,
    const float* __restrict__ bb, float* __restrict__ out)
{
    const int tid = threadIdx.x;
    const int b = blockIdx.x >> 2;
    const int n = ((blockIdx.x & 3) << 8) + tid;
    const float* ib = in + ((size_t)b << 17) + n;
    float s = 0.f, sq = 0.f;
#pragma unroll 8
    for (int c = 0; c < 128; ++c) {
        float v = ib[(size_t)c << 10];
        s += v;
        sq += v * v;
    }
    const float mu = s * 0.0078125f;
    const float r = rsqrtf(sq * 0.0078125f - mu * mu + 1e-5f);
    float* ob = out + ((size_t)b << 17) + n;
#pragma unroll 8
    for (int c = 0; c < 128; ++c) {
        float v = ib[(size_t)c << 10];
        ob[(size_t)c << 10] = (v - mu) * r * g[c] + bb[c];
    }
}

// ------------------------- GISSA attention 1 (8x8 per (b,h)) ---------------
__global__ __launch_bounds__(64) void gissa1_kernel(
    const float* __restrict__ qkv, const float* __restrict__ cur,
    const float* __restrict__ g, const float* __restrict__ bb,
    float* __restrict__ ybuf)
{
    const int lane = threadIdx.x;
    const int b = blockIdx.x >> 4;
    const int h = blockIdx.x & 15;
    const int d = lane >> 3, e = lane & 7;
    const float* qp = qkv + ((size_t)(b * 384 + h * 8 + d) << 10);
    const float* kp = qkv + ((size_t)(b * 384 + 128 + h * 8 + e) << 10);
    float s = 0.f;
#pragma unroll 4
    for (int n = 0; n < 1024; n += 4) {
        float4 q4 = *(const float4*)(qp + n);
        float4 k4 = *(const float4*)(kp + n);
        s += dot4f(q4, k4);
    }
    s *= 0.35355339059327373f;
    float a = (s > 0.f) ? sqrtf(s + 1e-5f) : ((s < 0.f) ? -sqrtf(1e-5f - s) : 0.f);
    float mx = a;
    mx = fmaxf(mx, __shfl_xor(mx, 1));
    mx = fmaxf(mx, __shfl_xor(mx, 2));
    mx = fmaxf(mx, __shfl_xor(mx, 4));
    float pp = __expf(a - mx);
    float dn = pp;
    dn += __shfl_xor(dn, 1);
    dn += __shfl_xor(dn, 2);
    dn += __shfl_xor(dn, 4);
    pp /= dn;
    const float* vp = qkv + ((size_t)(b * 384 + 256 + h * 8 + e) << 10);
    const int cp = d * 16 + h;
    const float gg = g[cp], gb = bb[cp];
    const float* rp = cur + ((size_t)(b * 128 + h * 8 + d) << 10);
    float* op = ybuf + ((size_t)(b * 128 + cp) << 10);
    for (int n = 0; n < 1024; n += 4) {
        float4 v4 = *(const float4*)(vp + n);
        float px = pp * v4.x, py = pp * v4.y, pz = pp * v4.z, pw = pp * v4.w;
        px += __shfl_xor(px, 1); px += __shfl_xor(px, 2); px += __shfl_xor(px, 4);
        py += __shfl_xor(py, 1); py += __shfl_xor(py, 2); py += __shfl_xor(py, 4);
        pz += __shfl_xor(pz, 1); pz += __shfl_xor(pz, 2); pz += __shfl_xor(pz, 4);
        pw += __shfl_xor(pw, 1); pw += __shfl_xor(pw, 2); pw += __shfl_xor(pw, 4);
        if (e == 0) {
            float4 r4 = *(const float4*)(rp + n);
            float4 o;
            o.x = (px + r4.x) * gg + gb;
            o.y = (py + r4.y) * gg + gb;
            o.z = (pz + r4.z) * gg + gb;
            o.w = (pw + r4.w) * gg + gb;
            *(float4*)(op + n) = o;
        }
    }
}

// ------------------------- GISSA attention 2 (16x16 per (b,d)) -------------
__global__ __launch_bounds__(256) void gissa2_kernel(
    const float* __restrict__ qkv2, const float* __restrict__ ybuf,
    float* __restrict__ t)
{
    const int tid = threadIdx.x;
    const int b = blockIdx.x >> 3;
    const int d = blockIdx.x & 7;
    const int h = tid >> 4, gi = tid & 15;
    const float* qp = qkv2 + ((size_t)(b * 384 + d * 16 + h) << 10);
    const float* kp = qkv2 + ((size_t)(b * 384 + 128 + d * 16 + gi) << 10);
    float s = 0.f;
#pragma unroll 4
    for (int n = 0; n < 1024; n += 4) {
        float4 q4 = *(const float4*)(qp + n);
        float4 k4 = *(const float4*)(kp + n);
        s += dot4f(q4, k4);
    }
    s *= 0.25f;
    float a = (s > 0.f) ? sqrtf(s + 1e-5f) : ((s < 0.f) ? -sqrtf(1e-5f - s) : 0.f);
    float mx = a;
#pragma unroll
    for (int o = 1; o < 16; o <<= 1) mx = fmaxf(mx, __shfl_xor(mx, o));
    float pp = __expf(a - mx);
    float dn = pp;
#pragma unroll
    for (int o = 1; o < 16; o <<= 1) dn += __shfl_xor(dn, o);
    pp /= dn;
    const float* vp = qkv2 + ((size_t)(b * 384 + 256 + d * 16 + gi) << 10);
    const int ch = h * 8 + d;
    const float* yp = ybuf + ((size_t)(b * 128 + ch) << 10);
    float* tp = t + ((size_t)(b * 128 + ch) << 10);
    for (int n = 0; n < 1024; n += 4) {
        float4 v4 = *(const float4*)(vp + n);
        float px = pp * v4.x, py = pp * v4.y, pz = pp * v4.z, pw = pp * v4.w;
#pragma unroll
        for (int o = 1; o < 16; o <<= 1) {
            px += __shfl_xor(px, o);
            py += __shfl_xor(py, o);
            pz += __shfl_xor(pz, o);
            pw += __shfl_xor(pw, o);
        }
        if (gi == 0) {
            float4 tv = *(const float4*)(tp + n);
            float4 yv = *(const float4*)(yp + n);
            tv.x += px + yv.x;
            tv.y += py + yv.y;
            tv.z += pz + yv.z;
            tv.w += pw + yv.w;
            *(float4*)(tp + n) = tv;
        }
    }
}

// ------------------------- f32 -> bf16 conversion --------------------------
__global__ __launch_bounds__(256) void cvt_bf16_kernel(
    const float* __restrict__ a, unsigned short* __restrict__ o, int n)
{
    int i = blockIdx.x * 256 + threadIdx.x;
    if (i < n) o[i] = f2bf(a[i]);
}

// ------------------------- fused LN2 + MLP via bf16 MFMA -------------------
__global__ __launch_bounds__(256) void mlp_mfma_kernel(
    float* __restrict__ t, const float* __restrict__ ln_g,
    const float* __restrict__ ln_b, const unsigned short* __restrict__ w1bf,
    const float* __restrict__ b1, const unsigned short* __restrict__ w2bf,
    const float* __restrict__ b2)
{
    __shared__ unsigned char lds[16384 + 65536];
    unsigned char* xnb = lds;
    unsigned char* hb = lds + 16384;

    const int tid = threadIdx.x;
    const int b = blockIdx.x >> 4;
    const int n0 = (blockIdx.x & 15) << 6;
    float* tb = t + ((size_t)b << 17) + n0;

    {
        const int px = tid >> 2, q = tid & 3;
        float v[32];
        float s = 0.f, sq = 0.f;
#pragma unroll
        for (int k = 0; k < 32; ++k) {
            float x = tb[((size_t)(q * 32 + k) << 10) + px];
            v[k] = x;
            s += x;
            sq += x * x;
        }
        s += __shfl_xor(s, 1); s += __shfl_xor(s, 2);
        sq += __shfl_xor(sq, 1); sq += __shfl_xor(sq, 2);
        const float mu = s * 0.0078125f;
        const float rstd = rsqrtf(sq * 0.0078125f - mu * mu + 1e-5f);
        const int sw = (px & 7) << 4;
#pragma unroll
        for (int cc = 0; cc < 4; ++cc) {
            u16x8 pk;
#pragma unroll
            for (int e = 0; e < 8; ++e) {
                int c = q * 32 + cc * 8 + e;
                float xv = (v[cc * 8 + e] - mu) * rstd * ln_g[c] + ln_b[c];
                pk[e] = f2bf(xv);
            }
            *(u16x8*)(xnb + px * 256 + ((q * 64 + cc * 16) ^ sw)) = pk;
        }
    }
    __syncthreads();

    const int wid = tid >> 6, lane = tid & 63;
    const int lr = lane & 15, lk = lane >> 4;

#pragma unroll 1
    for (int pass = 0; pass < 2; ++pass) {
        const int hidbase = (wid << 7) + (pass << 6);
        f32x4 acc[4][4];
#pragma unroll
        for (int i = 0; i < 4; ++i)
#pragma unroll
            for (int j = 0; j < 4; ++j)
#pragma unroll
                for (int r = 0; r < 4; ++r) acc[i][j][r] = 0.f;
#pragma unroll
        for (int kk = 0; kk < 4; ++kk) {
            bf16x8 af[4], bfr[4];
#pragma unroll
            for (int i = 0; i < 4; ++i)
                af[i] = *(const bf16x8*)(w1bf + (size_t)(hidbase + i * 16 + lr) * 128 + kk * 32 + lk * 8);
#pragma unroll
            for (int j = 0; j < 4; ++j) {
                const int px = j * 16 + lr;
                bfr[j] = *(const bf16x8*)(xnb + px * 256 + ((kk * 64 + lk * 16) ^ ((px & 7) << 4)));
            }
#pragma unroll
            for (int i = 0; i < 4; ++i)
#pragma unroll
                for (int j = 0; j < 4; ++j)
                    acc[i][j] = __builtin_amdgcn_mfma_f32_16x16x32_bf16(af[i], bfr[j], acc[i][j], 0, 0, 0);
        }
#pragma unroll
        for (int i = 0; i < 4; ++i) {
            const int hid0 = hidbase + i * 16 + lk * 4;
            float bi[4];
#pragma unroll
            for (int r = 0; r < 4; ++r) bi[r] = b1[hid0 + r];
#pragma unroll
            for (int j = 0; j < 4; ++j) {
                const int px = j * 16 + lr;
                u16x4 pk;
#pragma unroll
                for (int r = 0; r < 4; ++r) {
                    float x = acc[i][j][r] + bi[r];
                    float u = 1.5957691f * x * (1.f + 0.044715f * x * x);
                    float gv = x / (1.f + __expf(-u));
                    pk[r] = f2bf(gv);
                }
                *(u16x4*)(hb + px * 1024 + ((hid0 * 2) ^ ((px & 7) << 4))) = pk;
            }
        }
    }
    __syncthreads();

    f32x4 acc2[2][4];
#pragma unroll
    for (int i = 0; i < 2; ++i)
#pragma unroll
        for (int j = 0; j < 4; ++j)
#pragma unroll
            for (int r = 0; r < 4; ++r) acc2[i][j][r] = 0.f;
#pragma unroll 2
    for (int ks = 0; ks < 16; ++ks) {
        bf16x8 af[2], bfr[4];
#pragma unroll
        for (int i = 0; i < 2; ++i)
            af[i] = *(const bf16x8*)(w2bf + (size_t)((wid << 5) + i * 16 + lr) * 512 + ks * 32 + lk * 8);
#pragma unroll
        for (int j = 0; j < 4; ++j) {
            const int px = j * 16 + lr;
            bfr[j] = *(const bf16x8*)(hb + px * 1024 + ((ks * 64 + lk * 16) ^ ((px & 7) << 4)));
        }
#pragma unroll
        for (int i = 0; i < 2; ++i)
#pragma unroll
            for (int j = 0; j < 4; ++j)
                acc2[i][j] = __builtin_amdgcn_mfma_f32_16x16x32_bf16(af[i], bfr[j], acc2[i][j], 0, 0, 0);
    }
#pragma unroll
    for (int i = 0; i < 2; ++i) {
        const int cb = (wid << 5) + i * 16 + lk * 4;
        float b2v[4];
#pragma unroll
        for (int r = 0; r < 4; ++r) b2v[r] = b2[cb + r];
#pragma unroll
        for (int j = 0; j < 4; ++j) {
            const int px = j * 16 + lr;
#pragma unroll
            for (int r = 0; r < 4; ++r) {
                const size_t off = ((size_t)(cb + r) << 10) + px;
                tb[off] += acc2[i][j][r] + b2v[r];
            }
        }
    }
}

// ------------------------- flash SWSA via bf16 MFMA ------------------------
// out[b,c,n] = fscale * sum_m softmax_m(qT[n,:].qT[m,:] * 128^-0.5) * v[c,m]
// qT: (B,1024,128) bf16 row-major; v: (B,128,1024) bf16.
// Block: 128 query rows (n0..n0+127), 4 waves x 32 rows, 8 K-tiles of 128.
__global__ __launch_bounds__(256) void swsa_mfma_kernel(
    const unsigned short* __restrict__ qT, const unsigned short* __restrict__ vbf,
    float* __restrict__ outp, float fscale)
{
    __shared__ unsigned short K_lds[128 * 128];   // K-tile, then P-tile
    __shared__ unsigned short V_lds[128 * 128];
    const int tid = threadIdx.x;
    const int b = blockIdx.x >> 3;
    const int n0 = (blockIdx.x & 7) << 7;
    const int wid = tid >> 6, lane = tid & 63;
    const int lq = lane >> 4, ll = lane & 15;
    const unsigned short* qTb = qT + ((size_t)b << 17);
    const unsigned short* vb = vbf + ((size_t)b << 17);

    // Q A-fragments (wave rows n0 + wid*32 + ...)
    bf16x8 aq[2][4];
#pragma unroll
    for (int mi = 0; mi < 2; ++mi) {
        const int row = n0 + wid * 32 + mi * 16 + ll;
#pragma unroll
        for (int kk = 0; kk < 4; ++kk)
            aq[mi][kk] = *(const bf16x8*)(qTb + ((size_t)row << 7) + kk * 32 + lq * 8);
    }

    float mrun[8], lrun[8];
#pragma unroll
    for (int i = 0; i < 8; ++i) { mrun[i] = -INFINITY; lrun[i] = 0.f; }
    f32x4 yacc[2][8];
#pragma unroll
    for (int mi = 0; mi < 2; ++mi)
#pragma unroll
        for (int cj = 0; cj < 8; ++cj)
#pragma unroll
            for (int r = 0; r < 4; ++r) yacc[mi][cj][r] = 0.f;

#pragma unroll 1
    for (int mt = 0; mt < 8; ++mt) {
        const int m0 = mt << 7;
        // stage K (qT rows m0..m0+127) and V (v cols m0..m0+127), XOR-swizzled
        for (int ch = tid; ch < 2048; ch += 256) {
            const int rr = ch >> 4, e0 = (ch & 15) << 3;
            const int sw = (rr & 7) << 3;
            *(u16x8*)&K_lds[rr * 128 + (e0 ^ sw)] =
                *(const u16x8*)(qTb + ((size_t)(m0 + rr) << 7) + e0);
            *(u16x8*)&V_lds[rr * 128 + (e0 ^ sw)] =
                *(const u16x8*)(vb + ((size_t)rr << 10) + m0 + e0);
        }
        __syncthreads();

        // QK^T: sacc[mi][j] = D[n][m] (row n, col m)
        f32x4 sacc[2][8];
#pragma unroll
        for (int mi = 0; mi < 2; ++mi)
#pragma unroll
            for (int j = 0; j < 8; ++j)
#pragma unroll
                for (int r = 0; r < 4; ++r) sacc[mi][j][r] = 0.f;
#pragma unroll
        for (int j = 0; j < 8; ++j) {
            const int ml = j * 16 + ll;
            const int swk = (ml & 7) << 3;
            bf16x8 bk[4];
#pragma unroll
            for (int kk = 0; kk < 4; ++kk)
                bk[kk] = *(const bf16x8*)&K_lds[ml * 128 + ((kk * 32 + lq * 8) ^ swk)];
#pragma unroll
            for (int mi = 0; mi < 2; ++mi)
#pragma unroll
                for (int kk = 0; kk < 4; ++kk)
                    sacc[mi][j] = __builtin_amdgcn_mfma_f32_16x16x32_bf16(aq[mi][kk], bk[kk], sacc[mi][j], 0, 0, 0);
        }
        __syncthreads();   // all K_lds reads complete; region becomes P

        // online softmax (lane rows: n = mi*16 + lq*4 + r, ri = mi*4+r)
        float pmax[8];
#pragma unroll
        for (int i = 0; i < 8; ++i) pmax[i] = -INFINITY;
#pragma unroll
        for (int mi = 0; mi < 2; ++mi)
#pragma unroll
            for (int j = 0; j < 8; ++j)
#pragma unroll
                for (int r = 0; r < 4; ++r) {
                    float s = sacc[mi][j][r] * 0.08838834764831845f;
                    sacc[mi][j][r] = s;
                    pmax[mi * 4 + r] = fmaxf(pmax[mi * 4 + r], s);
                }
        float alpha[8], psum[8];
#pragma unroll
        for (int i = 0; i < 8; ++i) {
            float m = pmax[i];
            m = fmaxf(m, __shfl_xor(m, 1));
            m = fmaxf(m, __shfl_xor(m, 2));
            m = fmaxf(m, __shfl_xor(m, 4));
            m = fmaxf(m, __shfl_xor(m, 8));
            const float mn = fmaxf(mrun[i], m);
            alpha[i] = __expf(mrun[i] - mn);
            mrun[i] = mn;
            psum[i] = 0.f;
        }
        // p = exp(s - m), write bf16 P into K_lds region (own wave rows only)
#pragma unroll
        for (int mi = 0; mi < 2; ++mi)
#pragma unroll
            for (int r = 0; r < 4; ++r) {
                const int nbw = wid * 32 + mi * 16 + lq * 4 + r;
                const int sw = (nbw & 7) << 3;
                const float mn = mrun[mi * 4 + r];
                float ps = 0.f;
#pragma unroll
                for (int j = 0; j < 8; ++j) {
                    float p = __expf(sacc[mi][j][r] - mn);
                    ps += p;
                    K_lds[nbw * 128 + ((j * 16 + ll) ^ sw)] = f2bf(p);
                }
                psum[mi * 4 + r] += ps;
            }
#pragma unroll
        for (int i = 0; i < 8; ++i) {
            float s = psum[i];
            s += __shfl_xor(s, 1);
            s += __shfl_xor(s, 2);
            s += __shfl_xor(s, 4);
            s += __shfl_xor(s, 8);
            lrun[i] = lrun[i] * alpha[i] + s;
        }
#pragma unroll
        for (int mi = 0; mi < 2; ++mi)
#pragma unroll
            for (int cj = 0; cj < 8; ++cj)
#pragma unroll
                for (int r = 0; r < 4; ++r) yacc[mi][cj][r] *= alpha[mi * 4 + r];

        // PV: A = P (own rows), B = V^T from v natural layout
        bf16x8 ap[2][4];
#pragma unroll
        for (int mi = 0; mi < 2; ++mi) {
            const int nb = wid * 32 + mi * 16 + ll;
            const int sw = (nb & 7) << 3;
#pragma unroll
            for (int mk = 0; mk < 4; ++mk)
                ap[mi][mk] = *(const bf16x8*)&K_lds[nb * 128 + ((mk * 32 + lq * 8) ^ sw)];
        }
#pragma unroll
        for (int cj = 0; cj < 8; ++cj) {
            const int cl = cj * 16 + ll;
            const int sw = (cl & 7) << 3;
            bf16x8 bv[4];
#pragma unroll
            for (int mk = 0; mk < 4; ++mk)
                bv[mk] = *(const bf16x8*)&V_lds[cl * 128 + ((mk * 32 + lq * 8) ^ sw)];
#pragma unroll
            for (int mi = 0; mi < 2; ++mi)
#pragma unroll
                for (int mk = 0; mk < 4; ++mk)
                    yacc[mi][cj] = __builtin_amdgcn_mfma_f32_16x16x32_bf16(ap[mi][mk], bv[mk], yacc[mi][cj], 0, 0, 0);
        }
        __syncthreads();   // PV reads done; safe to restage
    }

    // epilogue: out[c][n] = yacc * fscale / l_row
#pragma unroll
    for (int mi = 0; mi < 2; ++mi) {
        const int nbase = n0 + wid * 32 + mi * 16 + lq * 4;
        float inv[4];
#pragma unroll
        for (int r = 0; r < 4; ++r) inv[r] = fscale / lrun[mi * 4 + r];
#pragma unroll
        for (int cj = 0; cj < 8; ++cj) {
            const int c = cj * 16 + ll;
            float4 o;
            o.x = yacc[mi][cj][0] * inv[0];
            o.y = yacc[mi][cj][1] * inv[1];
            o.z = yacc[mi][cj][2] * inv[2];
            o.w = yacc[mi][cj][3] * inv[3];
            *(float4*)(outp + ((size_t)(b * 128 + c) << 10) + nbase) = o;
        }
    }
}

// ------------------------- final mix + mean + fc ----------------------------
__global__ __launch_bounds__(256) void final_kernel(
    const float* __restrict__ xc, const float* __restrict__ xp,
    const float* __restrict__ lamuda, const float* __restrict__ fc_w,
    float* __restrict__ outp)
{
    __shared__ float meanb[128];
    __shared__ float red[4];
    const int tid = threadIdx.x;
    const int b = blockIdx.x;
    const float lmd = 1.f / (1.f + __expf(-lamuda[0]));
    const float* xcb = xc + ((size_t)b << 17);
    const float* xpb = xp + ((size_t)b << 17);
    for (int c = 0; c < 128; ++c) {
        float4 a = *(const float4*)(xcb + ((size_t)c << 10) + tid * 4);
        float4 d = *(const float4*)(xpb + ((size_t)c << 10) + tid * 4);
        float s = lmd * (a.x + a.y + a.z + a.w) + (1.f - lmd) * (d.x + d.y + d.z + d.w);
#pragma unroll
        for (int o = 1; o < 64; o <<= 1) s += __shfl_xor(s, o);
        if ((tid & 63) == 0) red[tid >> 6] = s;
        __syncthreads();
        if (tid == 0) meanb[c] = (red[0] + red[1] + red[2] + red[3]) * (1.f / 1024.f);
        __syncthreads();
    }
    if (tid < 16) {
        float s = 0.f;
        for (int c = 0; c < 128; ++c) s += fc_w[tid * 128 + c] * meanb[c];
        outp[b * 16 + tid] = s;
    }
}

// ---------------------------------------------------------------------------
extern "C" void kernel_launch(void* const* d_in, const int* in_sizes, int n_in,
                              void* d_out, int out_size, void* d_ws, size_t ws_size,
                              hipStream_t stream)
{
    (void)in_sizes; (void)n_in; (void)out_size; (void)ws_size;

    const float* x       = (const float*)d_in[0];
    const float* ssfe_w  = (const float*)d_in[1];
    const float* ssfe_g  = (const float*)d_in[2];
    const float* ssfe_b  = (const float*)d_in[3];
    const float* cc_w    = (const float*)d_in[4];
    const float* cc_g    = (const float*)d_in[5];
    const float* cc_b    = (const float*)d_in[6];
    const float* ln1_g   = (const float*)d_in[7];
    const float* ln1_b   = (const float*)d_in[8];
    const float* qkv_w   = (const float*)d_in[9];
    const float* qkv_b   = (const float*)d_in[10];
    const float* gbn_g   = (const float*)d_in[11];
    const float* gbn_b   = (const float*)d_in[12];
    const float* qkv2_w  = (const float*)d_in[13];
    const float* qkv2_b  = (const float*)d_in[14];
    const float* ln2_g   = (const float*)d_in[15];
    const float* ln2_b   = (const float*)d_in[16];
    const float* mlp_w1  = (const float*)d_in[17];
    const float* mlp_b1  = (const float*)d_in[18];
    const float* mlp_w2  = (const float*)d_in[19];
    const float* mlp_b2  = (const float*)d_in[20];
    const float* cs_w    = (const float*)d_in[21];
    const float* cs_g    = (const float*)d_in[22];
    const float* cs_b    = (const float*)d_in[23];
    const float* lfe0_w  = (const float*)d_in[24];
    const float* lfe0_g  = (const float*)d_in[25];
    const float* lfe0_b  = (const float*)d_in[26];
    const float* s0_pi_w = (const float*)d_in[27];
    const float* s0_pi_b = (const float*)d_in[28];
    const float* s0_bn_g = (const float*)d_in[29];
    const float* s0_bn_b = (const float*)d_in[30];
    const float* s0_po_w = (const float*)d_in[31];
    const float* s0_po_b = (const float*)d_in[32];
    const float* lfe1_w  = (const float*)d_in[33];
    const float* lfe1_g  = (const float*)d_in[34];
    const float* lfe1_b  = (const float*)d_in[35];
    const float* s1_pi_w = (const float*)d_in[36];
    const float* s1_pi_b = (const float*)d_in[37];
    const float* s1_bn_g = (const float*)d_in[38];
    const float* s1_bn_b = (const float*)d_in[39];
    const float* s1_po_w = (const float*)d_in[40];
    const float* s1_po_b = (const float*)d_in[41];
    const float* lamuda  = (const float*)d_in[42];
    const float* fc_w    = (const float*)d_in[43];
    float* out = (float*)d_out;
    float* ws = (float*)d_ws;

    // workspace layout (floats); total = 34,078,720 floats = 136.3 MB
    float* xs = ws;                    // (B,144,N)
    float* t  = ws + 4718592;          // (B,128,N)  residual stream / xc
    float* P1 = ws + 8912896;          // (B,128,N)
    float* Q  = ws + 13107200;         // (B,384,N) fp32 (gissa) / bf16 qT,v (swsa)
    float* P2 = ws + 25690112;         // (B,128,N)  ybuf / bf16 weights / xp2 / yv2
    float* P3 = ws + 29884416;         // (B,128,N)

    unsigned short* w1bf = (unsigned short*)P2;
    unsigned short* w2bf = w1bf + 65536;

    // bf16 attention buffers inside the Q region (fp32 Q dead after gissa)
    unsigned short* qT0 = (unsigned short*)Q;      // (B,1024,128) 4.19M elems
    unsigned short* v0  = qT0 + 4194304;           // (B,128,1024)
    unsigned short* v1  = v0 + 4194304;            // (B,128,1024)

    const dim3 blk(256);

    conv3x3_kernel<144><<<dim3(128, 9), blk, 0, stream>>>(x, ssfe_w, ssfe_g, ssfe_b, nullptr, xs, 144);
    conv1x1_kernel<<<dim3(128, 8), blk, 0, stream>>>(xs, 144, cc_w, nullptr, cc_g, cc_b, nullptr, t, 128, 1);
    ln_kernel<<<dim3(128), blk, 0, stream>>>(t, ln1_g, ln1_b, P1);
    gconv_kernel<<<dim3(128, 24), blk, 0, stream>>>(P1, qkv_w, qkv_b, Q, 8, 24, 0);
    gissa1_kernel<<<dim3(512), dim3(64), 0, stream>>>(Q, P1, gbn_g, gbn_b, P2);
    gconv_kernel<<<dim3(128, 24), blk, 0, stream>>>(P2, qkv2_w, qkv2_b, Q, 16, 48, 1);
    gissa2_kernel<<<dim3(256), blk, 0, stream>>>(Q, P2, t);
    cvt_bf16_kernel<<<dim3(256), blk, 0, stream>>>(mlp_w1, w1bf, 65536);
    cvt_bf16_kernel<<<dim3(256), blk, 0, stream>>>(mlp_w2, w2bf, 65536);
    mlp_mfma_kernel<<<dim3(512), blk, 0, stream>>>(t, ln2_g, ln2_b, w1bf, mlp_b1, w2bf, mlp_b2);
    conv3x3_kernel<144><<<dim3(128, 8), blk, 0, stream>>>(xs, cs_w, cs_g, cs_b, nullptr, P1, 128);
    conv3x3_kernel<128><<<dim3(128, 8), blk, 0, stream>>>(P1, lfe0_w, lfe0_g, lfe0_b, P1, P2, 128);
    // pi0: q -> qT0 (bf16 T), v -> v0 (bf16)
    pi_kernel<<<dim3(128, 16), blk, 0, stream>>>(P2, s0_pi_w, s0_pi_b, s0_bn_g, s0_bn_b, qT0, v0, 256, 128);
    swsa_mfma_kernel<<<dim3(256), blk, 0, stream>>>(qT0, v0, P1, 1.0f);
    conv1x1_kernel<<<dim3(128, 8), blk, 0, stream>>>(P1, 128, s0_po_w, s0_po_b, nullptr, nullptr, P2, P3, 128, 0);
    conv3x3_kernel<128><<<dim3(128, 8), blk, 0, stream>>>(P3, lfe1_w, lfe1_g, lfe1_b, P3, P1, 128);
    // pi1: all channels -> v1 (bf16 natural)
    pi_kernel<<<dim3(128, 8), blk, 0, stream>>>(P1, s1_pi_w, s1_pi_b, s1_bn_g, s1_bn_b, nullptr, v1, 128, 0);
    swsa_mfma_kernel<<<dim3(256), blk, 0, stream>>>(qT0, v1, P2, 0.08838834764831845f);
    conv1x1_kernel<<<dim3(128, 8), blk, 0, stream>>>(P2, 128, s1_po_w, s1_po_b, nullptr, nullptr, P1, P3, 128, 0);
    final_kernel<<<dim3(32), blk, 0, stream>>>(t, P3, lamuda, fc_w, out);
}

// Round 4
// 1217.578 us; speedup vs baseline: 3.8572x; 1.7683x over previous
//
#include <hip/hip_runtime.h>
#include <math.h>

// ---------------------------------------------------------------------------
// EATN forward. Layout: activations (B, C, N), N = 1024 contiguous.
// B=32, C=128 (144 stem), HEADS=16, HD=8.
// Round 4: conv3x3 -> implicit-GEMM bf16 MFMA (weights prepacked per call).
// ---------------------------------------------------------------------------

static constexpr int NPIX = 1024;

typedef __attribute__((ext_vector_type(8))) short bf16x8;
typedef __attribute__((ext_vector_type(4))) float f32x4;
typedef __attribute__((ext_vector_type(8))) unsigned short u16x8;
typedef __attribute__((ext_vector_type(4))) unsigned short u16x4;

static __device__ __forceinline__ float dot4f(float4 a, float4 b) {
    return a.x * b.x + a.y * b.y + a.z * b.z + a.w * b.w;
}

static __device__ __forceinline__ unsigned short f2bf(float f) {
    unsigned u = __builtin_bit_cast(unsigned, f);
    unsigned r = (u + 0x7fffu + ((u >> 16) & 1u)) >> 16;
    return (unsigned short)r;
}

// ------------------------- conv3x3 weight prepack --------------------------
// w (Cout,CIN,3,3) fp32 -> o[tap][co][ci_pad] bf16 (ci>=CIN zero)
__global__ __launch_bounds__(256) void prepack_conv_w(
    const float* __restrict__ w, unsigned short* __restrict__ o,
    int Cout, int CIN, int CINP)
{
    int idx = blockIdx.x * 256 + threadIdx.x;
    if (idx >= 9 * Cout * CINP) return;
    int ci = idx % CINP;
    int rem = idx / CINP;
    int co = rem % Cout;
    int tap = rem / Cout;
    float v = (ci < CIN) ? w[((size_t)co * CIN + ci) * 9 + tap] : 0.f;
    o[idx] = f2bf(v);
}

// ------------------------- conv3x3 via bf16 MFMA ---------------------------
// Block: image b x 8 output rows (256 px) x M*16 output channels.
// LDS: input chunk transposed [sp 324][ci 32] bf16, stride 40 (16B-aligned).
template <int CINP, int NCH, int M>
__global__ __launch_bounds__(256) void conv3x3_mfma_kernel(
    const float* __restrict__ in, int CIN,
    const unsigned short* __restrict__ wrep,  // [9][Cout][CINP] bf16
    const float* __restrict__ g, const float* __restrict__ bb,
    const float* __restrict__ res, float* __restrict__ out, int Cout)
{
    __shared__ unsigned short X[324 * 40];
    const int tid = threadIdx.x;
    const int b = blockIdx.x;
    const int gr = blockIdx.y;
    const int cg = blockIdx.z;
    const int co0 = cg * (M * 16);
    const int pbase = gr << 8;
    const int gbase = pbase - 33;      // staged global px = gbase + sp
    const int wv = tid >> 6, lane = tid & 63;
    const int ll = lane & 15, lk = lane >> 4;

    const float* inb = in + ((size_t)b * CIN << 10);

    f32x4 acc[M][4];
#pragma unroll
    for (int i = 0; i < M; ++i)
#pragma unroll
        for (int j = 0; j < 4; ++j)
#pragma unroll
            for (int r = 0; r < 4; ++r) acc[i][j][r] = 0.f;

#pragma unroll 1
    for (int ch = 0; ch < NCH; ++ch) {
        const int c0 = ch << 5;
        // ---- stage transposed bf16 tile with zero halo
#pragma unroll 1
        for (int ci2 = 0; ci2 < 16; ++ci2) {
            const int ci = c0 + ci2 * 2;
            const float* p0 = inb + ((size_t)ci << 10);
            const float* p1 = p0 + NPIX;
            const bool ok0 = ci < CIN, ok1 = (ci + 1) < CIN;
#pragma unroll 1
            for (int sp = tid; sp < 324; sp += 256) {
                const int gp = gbase + sp;
                const bool inr = (gp >= 0) & (gp < 1024);
                float a = (inr && ok0) ? p0[gp] : 0.f;
                float c = (inr && ok1) ? p1[gp] : 0.f;
                *(unsigned*)&X[sp * 40 + ci2 * 2] =
                    (unsigned)f2bf(a) | ((unsigned)f2bf(c) << 16);
            }
        }
        __syncthreads();
        // ---- 9 taps: A = weights (global, cached), B = patches (LDS)
#pragma unroll
        for (int tap = 0; tap < 9; ++tap) {
            const int soff = (tap / 3) * 32 + (tap % 3);  // dy*32 + dx
            const int dx = tap % 3;
            bf16x8 bfrag[4];
#pragma unroll
            for (int j = 0; j < 4; ++j) {
                const int p = (wv << 6) + (j << 4) + ll;   // local out px
                bf16x8 v = *(const bf16x8*)&X[(p + soff) * 40 + lk * 8];
                const bool zedge = (dx == 0 && (j & 1) == 0 && ll == 0) ||
                                   (dx == 2 && (j & 1) == 1 && ll == 15);
                if (zedge) { bf16x8 z = {}; v = z; }
                bfrag[j] = v;
            }
            const unsigned short* wb =
                wrep + ((size_t)tap * Cout + co0) * CINP + c0 + lk * 8;
#pragma unroll
            for (int i = 0; i < M; ++i) {
                bf16x8 afr = *(const bf16x8*)(wb + (size_t)(i * 16 + ll) * CINP);
#pragma unroll
                for (int j = 0; j < 4; ++j)
                    acc[i][j] = __builtin_amdgcn_mfma_f32_16x16x32_bf16(
                        afr, bfrag[j], acc[i][j], 0, 0, 0);
            }
        }
        __syncthreads();
    }

    // ---- epilogue: relu(acc*g + b) [+ res]
#pragma unroll
    for (int i = 0; i < M; ++i) {
#pragma unroll
        for (int r = 0; r < 4; ++r) {
            const int co = co0 + i * 16 + lk * 4 + r;
            const float gg = g[co], gb = bb[co];
            const size_t rowoff =
                ((size_t)(b * Cout + co) << 10) + pbase + (wv << 6) + ll;
#pragma unroll
            for (int j = 0; j < 4; ++j) {
                float v = fmaxf(acc[i][j][r] * gg + gb, 0.f);
                if (res) v += res[rowoff + (j << 4)];
                out[rowoff + (j << 4)] = v;
            }
        }
    }
}

// ------------------------- 1x1 conv, generic epilogue ----------------------
__global__ __launch_bounds__(256) void conv1x1_kernel(
    const float* __restrict__ in, int Cin, const float* __restrict__ wgt,
    const float* __restrict__ bias0, const float* __restrict__ g,
    const float* __restrict__ bb, const float* __restrict__ res,
    float* __restrict__ out, int Cout, int do_relu)
{
    const int tid = threadIdx.x;
    const int b = blockIdx.x >> 2;
    const int n = ((blockIdx.x & 3) << 8) + tid;
    const int co0 = blockIdx.y << 4;
    const float* inb = in + (size_t)b * Cin * NPIX + n;
    float acc[16];
#pragma unroll
    for (int a = 0; a < 16; ++a) acc[a] = 0.f;
#pragma unroll 4
    for (int ci = 0; ci < Cin; ++ci) {
        float v = inb[(size_t)ci << 10];
        const float* wp = wgt + (size_t)co0 * Cin + ci;
#pragma unroll
        for (int a = 0; a < 16; ++a) acc[a] = fmaf(wp[(size_t)a * Cin], v, acc[a]);
    }
#pragma unroll
    for (int a = 0; a < 16; ++a) {
        int co = co0 + a;
        float v = acc[a];
        if (bias0) v += bias0[co];
        if (g) v = v * g[co] + bb[co];
        if (do_relu) v = fmaxf(v, 0.f);
        size_t oi = ((size_t)(b * Cout + co) << 10) + n;
        if (res) v += res[oi];
        out[oi] = v;
    }
}

// ------------------------- pi conv: 1x1 + affine -> bf16 qT / v ------------
__global__ __launch_bounds__(256) void pi_kernel(
    const float* __restrict__ in, const float* __restrict__ wgt,
    const float* __restrict__ b0, const float* __restrict__ g,
    const float* __restrict__ bb, unsigned short* __restrict__ qTout,
    unsigned short* __restrict__ vout, int Cout, int qn)
{
    const int tid = threadIdx.x;
    const int b = blockIdx.x >> 2;
    const int n = ((blockIdx.x & 3) << 8) + tid;
    const int co0 = blockIdx.y << 4;
    const float* inb = in + ((size_t)b << 17) + n;
    float acc[16];
#pragma unroll
    for (int a = 0; a < 16; ++a) acc[a] = 0.f;
#pragma unroll 4
    for (int ci = 0; ci < 128; ++ci) {
        float v = inb[(size_t)ci << 10];
        const float* wp = wgt + (size_t)co0 * 128 + ci;
#pragma unroll
        for (int a = 0; a < 16; ++a) acc[a] = fmaf(wp[(size_t)a * 128], v, acc[a]);
    }
#pragma unroll
    for (int a = 0; a < 16; ++a) {
        int co = co0 + a;
        acc[a] = (acc[a] + b0[co]) * g[co] + bb[co];
    }
    if (co0 < qn) {
        u16x8 p0, p1;
#pragma unroll
        for (int e = 0; e < 8; ++e) { p0[e] = f2bf(acc[e]); p1[e] = f2bf(acc[8 + e]); }
        unsigned short* qp = qTout + ((((size_t)b << 10) + n) << 7) + co0;
        *(u16x8*)qp = p0;
        *(u16x8*)(qp + 8) = p1;
    } else {
#pragma unroll
        for (int a = 0; a < 16; ++a)
            vout[((size_t)(b * (Cout - qn) + (co0 - qn + a)) << 10) + n] = f2bf(acc[a]);
    }
}

// ------------------------- grouped 1x1 (GISSA qkv projections) -------------
__global__ __launch_bounds__(256) void gconv_kernel(
    const float* __restrict__ in, const float* __restrict__ wgt,
    const float* __restrict__ bias, float* __restrict__ out,
    int CPG, int GDIV, int in_relu)
{
    const int tid = threadIdx.x;
    const int b = blockIdx.x >> 2;
    const int n = ((blockIdx.x & 3) << 8) + tid;
    const int ch0 = blockIdx.y << 4;
    const float* inb = in + ((size_t)b << 17) + n;
#pragma unroll
    for (int a = 0; a < 16; ++a) {
        int ch = ch0 + a;
        int cbase = (ch / GDIV) * CPG;
        float s = 0.f;
        for (int c = 0; c < CPG; ++c) {
            float v = inb[(size_t)(cbase + c) << 10];
            if (in_relu) v = fmaxf(v, 0.f);
            s = fmaf(wgt[(size_t)ch * CPG + c], v, s);
        }
        out[((size_t)(b * 384 + ch) << 10) + n] = s + bias[ch];
    }
}

// ------------------------- LayerNorm over C=128 -----------------------------
__global__ __launch_bounds__(256) void ln_kernel(
    const float* __restrict__ in, const float* __restrict__ g,
    const float* __restrict__ bb, float* __restrict__ out)
{
    const int tid = threadIdx.x;
    const int b = blockIdx.x >> 2;
    const int n = ((blockIdx.x & 3) << 8) + tid;
    const float* ib = in + ((size_t)b << 17) + n;
    float s = 0.f, sq = 0.f;
#pragma unroll 8
    for (int c = 0; c < 128; ++c) {
        float v = ib[(size_t)c << 10];
        s += v;
        sq += v * v;
    }
    const float mu = s * 0.0078125f;
    const float r = rsqrtf(sq * 0.0078125f - mu * mu + 1e-5f);
    float* ob = out + ((size_t)b << 17) + n;
#pragma unroll 8
    for (int c = 0; c < 128; ++c) {
        float v = ib[(size_t)c << 10];
        ob[(size_t)c << 10] = (v - mu) * r * g[c] + bb[c];
    }
}

// ------------------------- GISSA attention 1 (8x8 per (b,h)) ---------------
__global__ __launch_bounds__(64) void gissa1_kernel(
    const float* __restrict__ qkv, const float* __restrict__ cur,
    const float* __restrict__ g, const float* __restrict__ bb,
    float* __restrict__ ybuf)
{
    const int lane = threadIdx.x;
    const int b = blockIdx.x >> 4;
    const int h = blockIdx.x & 15;
    const int d = lane >> 3, e = lane & 7;
    const float* qp = qkv + ((size_t)(b * 384 + h * 8 + d) << 10);
    const float* kp = qkv + ((size_t)(b * 384 + 128 + h * 8 + e) << 10);
    float s = 0.f;
#pragma unroll 4
    for (int n = 0; n < 1024; n += 4) {
        float4 q4 = *(const float4*)(qp + n);
        float4 k4 = *(const float4*)(kp + n);
        s += dot4f(q4, k4);
    }
    s *= 0.35355339059327373f;
    float a = (s > 0.f) ? sqrtf(s + 1e-5f) : ((s < 0.f) ? -sqrtf(1e-5f - s) : 0.f);
    float mx = a;
    mx = fmaxf(mx, __shfl_xor(mx, 1));
    mx = fmaxf(mx, __shfl_xor(mx, 2));
    mx = fmaxf(mx, __shfl_xor(mx, 4));
    float pp = __expf(a - mx);
    float dn = pp;
    dn += __shfl_xor(dn, 1);
    dn += __shfl_xor(dn, 2);
    dn += __shfl_xor(dn, 4);
    pp /= dn;
    const float* vp = qkv + ((size_t)(b * 384 + 256 + h * 8 + e) << 10);
    const int cp = d * 16 + h;
    const float gg = g[cp], gb = bb[cp];
    const float* rp = cur + ((size_t)(b * 128 + h * 8 + d) << 10);
    float* op = ybuf + ((size_t)(b * 128 + cp) << 10);
    for (int n = 0; n < 1024; n += 4) {
        float4 v4 = *(const float4*)(vp + n);
        float px = pp * v4.x, py = pp * v4.y, pz = pp * v4.z, pw = pp * v4.w;
        px += __shfl_xor(px, 1); px += __shfl_xor(px, 2); px += __shfl_xor(px, 4);
        py += __shfl_xor(py, 1); py += __shfl_xor(py, 2); py += __shfl_xor(py, 4);
        pz += __shfl_xor(pz, 1); pz += __shfl_xor(pz, 2); pz += __shfl_xor(pz, 4);
        pw += __shfl_xor(pw, 1); pw += __shfl_xor(pw, 2); pw += __shfl_xor(pw, 4);
        if (e == 0) {
            float4 r4 = *(const float4*)(rp + n);
            float4 o;
            o.x = (px + r4.x) * gg + gb;
            o.y = (py + r4.y) * gg + gb;
            o.z = (pz + r4.z) * gg + gb;
            o.w = (pw + r4.w) * gg + gb;
            *(float4*)(op + n) = o;
        }
    }
}

// ------------------------- GISSA attention 2 (16x16 per (b,d)) -------------
__global__ __launch_bounds__(256) void gissa2_kernel(
    const float* __restrict__ qkv2, const float* __restrict__ ybuf,
    float* __restrict__ t)
{
    const int tid = threadIdx.x;
    const int b = blockIdx.x >> 3;
    const int d = blockIdx.x & 7;
    const int h = tid >> 4, gi = tid & 15;
    const float* qp = qkv2 + ((size_t)(b * 384 + d * 16 + h) << 10);
    const float* kp = qkv2 + ((size_t)(b * 384 + 128 + d * 16 + gi) << 10);
    float s = 0.f;
#pragma unroll 4
    for (int n = 0; n < 1024; n += 4) {
        float4 q4 = *(const float4*)(qp + n);
        float4 k4 = *(const float4*)(kp + n);
        s += dot4f(q4, k4);
    }
    s *= 0.25f;
    float a = (s > 0.f) ? sqrtf(s + 1e-5f) : ((s < 0.f) ? -sqrtf(1e-5f - s) : 0.f);
    float mx = a;
#pragma unroll
    for (int o = 1; o < 16; o <<= 1) mx = fmaxf(mx, __shfl_xor(mx, o));
    float pp = __expf(a - mx);
    float dn = pp;
#pragma unroll
    for (int o = 1; o < 16; o <<= 1) dn += __shfl_xor(dn, o);
    pp /= dn;
    const float* vp = qkv2 + ((size_t)(b * 384 + 256 + d * 16 + gi) << 10);
    const int ch = h * 8 + d;
    const float* yp = ybuf + ((size_t)(b * 128 + ch) << 10);
    float* tp = t + ((size_t)(b * 128 + ch) << 10);
    for (int n = 0; n < 1024; n += 4) {
        float4 v4 = *(const float4*)(vp + n);
        float px = pp * v4.x, py = pp * v4.y, pz = pp * v4.z, pw = pp * v4.w;
#pragma unroll
        for (int o = 1; o < 16; o <<= 1) {
            px += __shfl_xor(px, o);
            py += __shfl_xor(py, o);
            pz += __shfl_xor(pz, o);
            pw += __shfl_xor(pw, o);
        }
        if (gi == 0) {
            float4 tv = *(const float4*)(tp + n);
            float4 yv = *(const float4*)(yp + n);
            tv.x += px + yv.x;
            tv.y += py + yv.y;
            tv.z += pz + yv.z;
            tv.w += pw + yv.w;
            *(float4*)(tp + n) = tv;
        }
    }
}

// ------------------------- f32 -> bf16 conversion --------------------------
__global__ __launch_bounds__(256) void cvt_bf16_kernel(
    const float* __restrict__ a, unsigned short* __restrict__ o, int n)
{
    int i = blockIdx.x * 256 + threadIdx.x;
    if (i < n) o[i] = f2bf(a[i]);
}

// ------------------------- fused LN2 + MLP via bf16 MFMA -------------------
__global__ __launch_bounds__(256) void mlp_mfma_kernel(
    float* __restrict__ t, const float* __restrict__ ln_g,
    const float* __restrict__ ln_b, const unsigned short* __restrict__ w1bf,
    const float* __restrict__ b1, const unsigned short* __restrict__ w2bf,
    const float* __restrict__ b2)
{
    __shared__ unsigned char lds[16384 + 65536];
    unsigned char* xnb = lds;
    unsigned char* hb = lds + 16384;

    const int tid = threadIdx.x;
    const int b = blockIdx.x >> 4;
    const int n0 = (blockIdx.x & 15) << 6;
    float* tb = t + ((size_t)b << 17) + n0;

    {
        const int px = tid >> 2, q = tid & 3;
        float v[32];
        float s = 0.f, sq = 0.f;
#pragma unroll
        for (int k = 0; k < 32; ++k) {
            float x = tb[((size_t)(q * 32 + k) << 10) + px];
            v[k] = x;
            s += x;
            sq += x * x;
        }
        s += __shfl_xor(s, 1); s += __shfl_xor(s, 2);
        sq += __shfl_xor(sq, 1); sq += __shfl_xor(sq, 2);
        const float mu = s * 0.0078125f;
        const float rstd = rsqrtf(sq * 0.0078125f - mu * mu + 1e-5f);
        const int sw = (px & 7) << 4;
#pragma unroll
        for (int cc = 0; cc < 4; ++cc) {
            u16x8 pk;
#pragma unroll
            for (int e = 0; e < 8; ++e) {
                int c = q * 32 + cc * 8 + e;
                float xv = (v[cc * 8 + e] - mu) * rstd * ln_g[c] + ln_b[c];
                pk[e] = f2bf(xv);
            }
            *(u16x8*)(xnb + px * 256 + ((q * 64 + cc * 16) ^ sw)) = pk;
        }
    }
    __syncthreads();

    const int wid = tid >> 6, lane = tid & 63;
    const int lr = lane & 15, lk = lane >> 4;

#pragma unroll 1
    for (int pass = 0; pass < 2; ++pass) {
        const int hidbase = (wid << 7) + (pass << 6);
        f32x4 acc[4][4];
#pragma unroll
        for (int i = 0; i < 4; ++i)
#pragma unroll
            for (int j = 0; j < 4; ++j)
#pragma unroll
                for (int r = 0; r < 4; ++r) acc[i][j][r] = 0.f;
#pragma unroll
        for (int kk = 0; kk < 4; ++kk) {
            bf16x8 af[4], bfr[4];
#pragma unroll
            for (int i = 0; i < 4; ++i)
                af[i] = *(const bf16x8*)(w1bf + (size_t)(hidbase + i * 16 + lr) * 128 + kk * 32 + lk * 8);
#pragma unroll
            for (int j = 0; j < 4; ++j) {
                const int px = j * 16 + lr;
                bfr[j] = *(const bf16x8*)(xnb + px * 256 + ((kk * 64 + lk * 16) ^ ((px & 7) << 4)));
            }
#pragma unroll
            for (int i = 0; i < 4; ++i)
#pragma unroll
                for (int j = 0; j < 4; ++j)
                    acc[i][j] = __builtin_amdgcn_mfma_f32_16x16x32_bf16(af[i], bfr[j], acc[i][j], 0, 0, 0);
        }
#pragma unroll
        for (int i = 0; i < 4; ++i) {
            const int hid0 = hidbase + i * 16 + lk * 4;
            float bi[4];
#pragma unroll
            for (int r = 0; r < 4; ++r) bi[r] = b1[hid0 + r];
#pragma unroll
            for (int j = 0; j < 4; ++j) {
                const int px = j * 16 + lr;
                u16x4 pk;
#pragma unroll
                for (int r = 0; r < 4; ++r) {
                    float x = acc[i][j][r] + bi[r];
                    float u = 1.5957691f * x * (1.f + 0.044715f * x * x);
                    float gv = x / (1.f + __expf(-u));
                    pk[r] = f2bf(gv);
                }
                *(u16x4*)(hb + px * 1024 + ((hid0 * 2) ^ ((px & 7) << 4))) = pk;
            }
        }
    }
    __syncthreads();

    f32x4 acc2[2][4];
#pragma unroll
    for (int i = 0; i < 2; ++i)
#pragma unroll
        for (int j = 0; j < 4; ++j)
#pragma unroll
            for (int r = 0; r < 4; ++r) acc2[i][j][r] = 0.f;
#pragma unroll 2
    for (int ks = 0; ks < 16; ++ks) {
        bf16x8 af[2], bfr[4];
#pragma unroll
        for (int i = 0; i < 2; ++i)
            af[i] = *(const bf16x8*)(w2bf + (size_t)((wid << 5) + i * 16 + lr) * 512 + ks * 32 + lk * 8);
#pragma unroll
        for (int j = 0; j < 4; ++j) {
            const int px = j * 16 + lr;
            bfr[j] = *(const bf16x8*)(hb + px * 1024 + ((ks * 64 + lk * 16) ^ ((px & 7) << 4)));
        }
#pragma unroll
        for (int i = 0; i < 2; ++i)
#pragma unroll
            for (int j = 0; j < 4; ++j)
                acc2[i][j] = __builtin_amdgcn_mfma_f32_16x16x32_bf16(af[i], bfr[j], acc2[i][j], 0, 0, 0);
    }
#pragma unroll
    for (int i = 0; i < 2; ++i) {
        const int cb = (wid << 5) + i * 16 + lk * 4;
        float b2v[4];
#pragma unroll
        for (int r = 0; r < 4; ++r) b2v[r] = b2[cb + r];
#pragma unroll
        for (int j = 0; j < 4; ++j) {
            const int px = j * 16 + lr;
#pragma unroll
            for (int r = 0; r < 4; ++r) {
                const size_t off = ((size_t)(cb + r) << 10) + px;
                tb[off] += acc2[i][j][r] + b2v[r];
            }
        }
    }
}

// ------------------------- flash SWSA via bf16 MFMA ------------------------
__global__ __launch_bounds__(256) void swsa_mfma_kernel(
    const unsigned short* __restrict__ qT, const unsigned short* __restrict__ vbf,
    float* __restrict__ outp, float fscale)
{
    __shared__ unsigned short K_lds[128 * 128];
    __shared__ unsigned short V_lds[128 * 128];
    const int tid = threadIdx.x;
    const int b = blockIdx.x >> 3;
    const int n0 = (blockIdx.x & 7) << 7;
    const int wid = tid >> 6, lane = tid & 63;
    const int lq = lane >> 4, ll = lane & 15;
    const unsigned short* qTb = qT + ((size_t)b << 17);
    const unsigned short* vb = vbf + ((size_t)b << 17);

    bf16x8 aq[2][4];
#pragma unroll
    for (int mi = 0; mi < 2; ++mi) {
        const int row = n0 + wid * 32 + mi * 16 + ll;
#pragma unroll
        for (int kk = 0; kk < 4; ++kk)
            aq[mi][kk] = *(const bf16x8*)(qTb + ((size_t)row << 7) + kk * 32 + lq * 8);
    }

    float mrun[8], lrun[8];
#pragma unroll
    for (int i = 0; i < 8; ++i) { mrun[i] = -INFINITY; lrun[i] = 0.f; }
    f32x4 yacc[2][8];
#pragma unroll
    for (int mi = 0; mi < 2; ++mi)
#pragma unroll
        for (int cj = 0; cj < 8; ++cj)
#pragma unroll
            for (int r = 0; r < 4; ++r) yacc[mi][cj][r] = 0.f;

#pragma unroll 1
    for (int mt = 0; mt < 8; ++mt) {
        const int m0 = mt << 7;
        for (int ch = tid; ch < 2048; ch += 256) {
            const int rr = ch >> 4, e0 = (ch & 15) << 3;
            const int sw = (rr & 7) << 3;
            *(u16x8*)&K_lds[rr * 128 + (e0 ^ sw)] =
                *(const u16x8*)(qTb + ((size_t)(m0 + rr) << 7) + e0);
            *(u16x8*)&V_lds[rr * 128 + (e0 ^ sw)] =
                *(const u16x8*)(vb + ((size_t)rr << 10) + m0 + e0);
        }
        __syncthreads();

        f32x4 sacc[2][8];
#pragma unroll
        for (int mi = 0; mi < 2; ++mi)
#pragma unroll
            for (int j = 0; j < 8; ++j)
#pragma unroll
                for (int r = 0; r < 4; ++r) sacc[mi][j][r] = 0.f;
#pragma unroll
        for (int j = 0; j < 8; ++j) {
            const int ml = j * 16 + ll;
            const int swk = (ml & 7) << 3;
            bf16x8 bk[4];
#pragma unroll
            for (int kk = 0; kk < 4; ++kk)
                bk[kk] = *(const bf16x8*)&K_lds[ml * 128 + ((kk * 32 + lq * 8) ^ swk)];
#pragma unroll
            for (int mi = 0; mi < 2; ++mi)
#pragma unroll
                for (int kk = 0; kk < 4; ++kk)
                    sacc[mi][j] = __builtin_amdgcn_mfma_f32_16x16x32_bf16(aq[mi][kk], bk[kk], sacc[mi][j], 0, 0, 0);
        }
        __syncthreads();

        float pmax[8];
#pragma unroll
        for (int i = 0; i < 8; ++i) pmax[i] = -INFINITY;
#pragma unroll
        for (int mi = 0; mi < 2; ++mi)
#pragma unroll
            for (int j = 0; j < 8; ++j)
#pragma unroll
                for (int r = 0; r < 4; ++r) {
                    float s = sacc[mi][j][r] * 0.08838834764831845f;
                    sacc[mi][j][r] = s;
                    pmax[mi * 4 + r] = fmaxf(pmax[mi * 4 + r], s);
                }
        float alpha[8], psum[8];
#pragma unroll
        for (int i = 0; i < 8; ++i) {
            float m = pmax[i];
            m = fmaxf(m, __shfl_xor(m, 1));
            m = fmaxf(m, __shfl_xor(m, 2));
            m = fmaxf(m, __shfl_xor(m, 4));
            m = fmaxf(m, __shfl_xor(m, 8));
            const float mn = fmaxf(mrun[i], m);
            alpha[i] = __expf(mrun[i] - mn);
            mrun[i] = mn;
            psum[i] = 0.f;
        }
#pragma unroll
        for (int mi = 0; mi < 2; ++mi)
#pragma unroll
            for (int r = 0; r < 4; ++r) {
                const int nbw = wid * 32 + mi * 16 + lq * 4 + r;
                const int sw = (nbw & 7) << 3;
                const float mn = mrun[mi * 4 + r];
                float ps = 0.f;
#pragma unroll
                for (int j = 0; j < 8; ++j) {
                    float p = __expf(sacc[mi][j][r] - mn);
                    ps += p;
                    K_lds[nbw * 128 + ((j * 16 + ll) ^ sw)] = f2bf(p);
                }
                psum[mi * 4 + r] += ps;
            }
#pragma unroll
        for (int i = 0; i < 8; ++i) {
            float s = psum[i];
            s += __shfl_xor(s, 1);
            s += __shfl_xor(s, 2);
            s += __shfl_xor(s, 4);
            s += __shfl_xor(s, 8);
            lrun[i] = lrun[i] * alpha[i] + s;
        }
#pragma unroll
        for (int mi = 0; mi < 2; ++mi)
#pragma unroll
            for (int cj = 0; cj < 8; ++cj)
#pragma unroll
                for (int r = 0; r < 4; ++r) yacc[mi][cj][r] *= alpha[mi * 4 + r];

        bf16x8 ap[2][4];
#pragma unroll
        for (int mi = 0; mi < 2; ++mi) {
            const int nb = wid * 32 + mi * 16 + ll;
            const int sw = (nb & 7) << 3;
#pragma unroll
            for (int mk = 0; mk < 4; ++mk)
                ap[mi][mk] = *(const bf16x8*)&K_lds[nb * 128 + ((mk * 32 + lq * 8) ^ sw)];
        }
#pragma unroll
        for (int cj = 0; cj < 8; ++cj) {
            const int cl = cj * 16 + ll;
            const int sw = (cl & 7) << 3;
            bf16x8 bv[4];
#pragma unroll
            for (int mk = 0; mk < 4; ++mk)
                bv[mk] = *(const bf16x8*)&V_lds[cl * 128 + ((mk * 32 + lq * 8) ^ sw)];
#pragma unroll
            for (int mi = 0; mi < 2; ++mi)
#pragma unroll
                for (int mk = 0; mk < 4; ++mk)
                    yacc[mi][cj] = __builtin_amdgcn_mfma_f32_16x16x32_bf16(ap[mi][mk], bv[mk], yacc[mi][cj], 0, 0, 0);
        }
        __syncthreads();
    }

#pragma unroll
    for (int mi = 0; mi < 2; ++mi) {
        const int nbase = n0 + wid * 32 + mi * 16 + lq * 4;
        float inv[4];
#pragma unroll
        for (int r = 0; r < 4; ++r) inv[r] = fscale / lrun[mi * 4 + r];
#pragma unroll
        for (int cj = 0; cj < 8; ++cj) {
            const int c = cj * 16 + ll;
            float4 o;
            o.x = yacc[mi][cj][0] * inv[0];
            o.y = yacc[mi][cj][1] * inv[1];
            o.z = yacc[mi][cj][2] * inv[2];
            o.w = yacc[mi][cj][3] * inv[3];
            *(float4*)(outp + ((size_t)(b * 128 + c) << 10) + nbase) = o;
        }
    }
}

// ------------------------- final mix + mean + fc ----------------------------
__global__ __launch_bounds__(256) void final_kernel(
    const float* __restrict__ xc, const float* __restrict__ xp,
    const float* __restrict__ lamuda, const float* __restrict__ fc_w,
    float* __restrict__ outp)
{
    __shared__ float meanb[128];
    __shared__ float red[4];
    const int tid = threadIdx.x;
    const int b = blockIdx.x;
    const float lmd = 1.f / (1.f + __expf(-lamuda[0]));
    const float* xcb = xc + ((size_t)b << 17);
    const float* xpb = xp + ((size_t)b << 17);
    for (int c = 0; c < 128; ++c) {
        float4 a = *(const float4*)(xcb + ((size_t)c << 10) + tid * 4);
        float4 d = *(const float4*)(xpb + ((size_t)c << 10) + tid * 4);
        float s = lmd * (a.x + a.y + a.z + a.w) + (1.f - lmd) * (d.x + d.y + d.z + d.w);
#pragma unroll
        for (int o = 1; o < 64; o <<= 1) s += __shfl_xor(s, o);
        if ((tid & 63) == 0) red[tid >> 6] = s;
        __syncthreads();
        if (tid == 0) meanb[c] = (red[0] + red[1] + red[2] + red[3]) * (1.f / 1024.f);
        __syncthreads();
    }
    if (tid < 16) {
        float s = 0.f;
        for (int c = 0; c < 128; ++c) s += fc_w[tid * 128 + c] * meanb[c];
        outp[b * 16 + tid] = s;
    }
}

// ---------------------------------------------------------------------------
extern "C" void kernel_launch(void* const* d_in, const int* in_sizes, int n_in,
                              void* d_out, int out_size, void* d_ws, size_t ws_size,
                              hipStream_t stream)
{
    (void)in_sizes; (void)n_in; (void)out_size; (void)ws_size;

    const float* x       = (const float*)d_in[0];
    const float* ssfe_w  = (const float*)d_in[1];
    const float* ssfe_g  = (const float*)d_in[2];
    const float* ssfe_b  = (const float*)d_in[3];
    const float* cc_w    = (const float*)d_in[4];
    const float* cc_g    = (const float*)d_in[5];
    const float* cc_b    = (const float*)d_in[6];
    const float* ln1_g   = (const float*)d_in[7];
    const float* ln1_b   = (const float*)d_in[8];
    const float* qkv_w   = (const float*)d_in[9];
    const float* qkv_b   = (const float*)d_in[10];
    const float* gbn_g   = (const float*)d_in[11];
    const float* gbn_b   = (const float*)d_in[12];
    const float* qkv2_w  = (const float*)d_in[13];
    const float* qkv2_b  = (const float*)d_in[14];
    const float* ln2_g   = (const float*)d_in[15];
    const float* ln2_b   = (const float*)d_in[16];
    const float* mlp_w1  = (const float*)d_in[17];
    const float* mlp_b1  = (const float*)d_in[18];
    const float* mlp_w2  = (const float*)d_in[19];
    const float* mlp_b2  = (const float*)d_in[20];
    const float* cs_w    = (const float*)d_in[21];
    const float* cs_g    = (const float*)d_in[22];
    const float* cs_b    = (const float*)d_in[23];
    const float* lfe0_w  = (const float*)d_in[24];
    const float* lfe0_g  = (const float*)d_in[25];
    const float* lfe0_b  = (const float*)d_in[26];
    const float* s0_pi_w = (const float*)d_in[27];
    const float* s0_pi_b = (const float*)d_in[28];
    const float* s0_bn_g = (const float*)d_in[29];
    const float* s0_bn_b = (const float*)d_in[30];
    const float* s0_po_w = (const float*)d_in[31];
    const float* s0_po_b = (const float*)d_in[32];
    const float* lfe1_w  = (const float*)d_in[33];
    const float* lfe1_g  = (const float*)d_in[34];
    const float* lfe1_b  = (const float*)d_in[35];
    const float* s1_pi_w = (const float*)d_in[36];
    const float* s1_pi_b = (const float*)d_in[37];
    const float* s1_bn_g = (const float*)d_in[38];
    const float* s1_bn_b = (const float*)d_in[39];
    const float* s1_po_w = (const float*)d_in[40];
    const float* s1_po_b = (const float*)d_in[41];
    const float* lamuda  = (const float*)d_in[42];
    const float* fc_w    = (const float*)d_in[43];
    float* out = (float*)d_out;
    float* ws = (float*)d_ws;

    // workspace layout (floats); total = 34,078,720 floats = 136.3 MB
    float* xs = ws;                    // (B,144,N); tail reused for wlfe1 after cs conv
    float* t  = ws + 4718592;          // (B,128,N)  residual stream / xc
    float* P1 = ws + 8912896;          // (B,128,N)
    float* Q  = ws + 13107200;         // (B,384,N) fp32 (gissa) / bf16 qT,v (swsa)
    float* P2 = ws + 25690112;         // (B,128,N)  ybuf / bf16 weights / xp2 / yv2
    float* P3 = ws + 29884416;         // (B,128,N); head reused for conv wreps early

    unsigned short* w1bf = (unsigned short*)P2;
    unsigned short* w2bf = w1bf + 65536;

    unsigned short* qT0 = (unsigned short*)Q;      // (B,1024,128) bf16
    unsigned short* v0  = qT0 + 4194304;           // (B,128,1024) bf16
    unsigned short* v1  = v0 + 4194304;            // (B,128,1024) bf16

    // conv3x3 prepacked weights (bf16): early ones in P3 head (P3 first
    // written at po0, after all three are consumed); lfe1's in xs (dead
    // after the cs conv reads it).
    unsigned short* wssfe = (unsigned short*)P3;                 // 9*144*160
    unsigned short* wcs   = (unsigned short*)(P3 + 131072);      // 9*128*160
    unsigned short* wlfe0 = (unsigned short*)(P3 + 262144);      // 9*128*128
    unsigned short* wlfe1 = (unsigned short*)xs;                 // 9*128*128

    const dim3 blk(256);

    prepack_conv_w<<<dim3((9 * 144 * 160 + 255) / 256), blk, 0, stream>>>(ssfe_w, wssfe, 144, 144, 160);
    prepack_conv_w<<<dim3((9 * 128 * 160 + 255) / 256), blk, 0, stream>>>(cs_w, wcs, 128, 144, 160);
    prepack_conv_w<<<dim3((9 * 128 * 128 + 255) / 256), blk, 0, stream>>>(lfe0_w, wlfe0, 128, 128, 128);

    // xs = cbr3(x, ssfe)
    conv3x3_mfma_kernel<160, 5, 3><<<dim3(32, 4, 3), blk, 0, stream>>>(x, 144, wssfe, ssfe_g, ssfe_b, nullptr, xs, 144);
    conv1x1_kernel<<<dim3(128, 8), blk, 0, stream>>>(xs, 144, cc_w, nullptr, cc_g, cc_b, nullptr, t, 128, 1);
    ln_kernel<<<dim3(128), blk, 0, stream>>>(t, ln1_g, ln1_b, P1);
    gconv_kernel<<<dim3(128, 24), blk, 0, stream>>>(P1, qkv_w, qkv_b, Q, 8, 24, 0);
    gissa1_kernel<<<dim3(512), dim3(64), 0, stream>>>(Q, P1, gbn_g, gbn_b, P2);
    gconv_kernel<<<dim3(128, 24), blk, 0, stream>>>(P2, qkv2_w, qkv2_b, Q, 16, 48, 1);
    gissa2_kernel<<<dim3(256), blk, 0, stream>>>(Q, P2, t);
    cvt_bf16_kernel<<<dim3(256), blk, 0, stream>>>(mlp_w1, w1bf, 65536);
    cvt_bf16_kernel<<<dim3(256), blk, 0, stream>>>(mlp_w2, w2bf, 65536);
    mlp_mfma_kernel<<<dim3(512), blk, 0, stream>>>(t, ln2_g, ln2_b, w1bf, mlp_b1, w2bf, mlp_b2);
    // xp = cbr3(xs, cs)
    conv3x3_mfma_kernel<160, 5, 2><<<dim3(32, 4, 4), blk, 0, stream>>>(xs, 144, wcs, cs_g, cs_b, nullptr, P1, 128);
    // xs dead now -> prepack lfe1 weights into it
    prepack_conv_w<<<dim3((9 * 128 * 128 + 255) / 256), blk, 0, stream>>>(lfe1_w, wlfe1, 128, 128, 128);
    // xp2 = cbr3(xp, lfe0) + xp
    conv3x3_mfma_kernel<128, 4, 2><<<dim3(32, 4, 4), blk, 0, stream>>>(P1, 128, wlfe0, lfe0_g, lfe0_b, P1, P2, 128);
    pi_kernel<<<dim3(128, 16), blk, 0, stream>>>(P2, s0_pi_w, s0_pi_b, s0_bn_g, s0_bn_b, qT0, v0, 256, 128);
    swsa_mfma_kernel<<<dim3(256), blk, 0, stream>>>(qT0, v0, P1, 1.0f);
    conv1x1_kernel<<<dim3(128, 8), blk, 0, stream>>>(P1, 128, s0_po_w, s0_po_b, nullptr, nullptr, P2, P3, 128, 0);
    // xp4 = cbr3(xp3, lfe1) + xp3
    conv3x3_mfma_kernel<128, 4, 2><<<dim3(32, 4, 4), blk, 0, stream>>>(P3, 128, wlfe1, lfe1_g, lfe1_b, P3, P1, 128);
    pi_kernel<<<dim3(128, 8), blk, 0, stream>>>(P1, s1_pi_w, s1_pi_b, s1_bn_g, s1_bn_b, nullptr, v1, 128, 0);
    swsa_mfma_kernel<<<dim3(256), blk, 0, stream>>>(qT0, v1, P2, 0.08838834764831845f);
    conv1x1_kernel<<<dim3(128, 8), blk, 0, stream>>>(P2, 128, s1_po_w, s1_po_b, nullptr, nullptr, P1, P3, 128, 0);
    final_kernel<<<dim3(32), blk, 0, stream>>>(t, P3, lamuda, fc_w, out);
}

// Round 5
// 1013.112 us; speedup vs baseline: 4.6356x; 1.2018x over previous
//
#include <hip/hip_runtime.h>
#include <math.h>

// ---------------------------------------------------------------------------
// EATN forward. Layout: activations (B, C, N), N = 1024 contiguous.
// B=32, C=128 (144 stem), HEADS=16, HD=8.
// Round 5: GISSA restructured via Gram-matrix trick (no qkv materialization).
// ---------------------------------------------------------------------------

static constexpr int NPIX = 1024;

typedef __attribute__((ext_vector_type(8))) short bf16x8;
typedef __attribute__((ext_vector_type(4))) float f32x4;
typedef __attribute__((ext_vector_type(8))) unsigned short u16x8;
typedef __attribute__((ext_vector_type(4))) unsigned short u16x4;

static __device__ __forceinline__ unsigned short f2bf(float f) {
    unsigned u = __builtin_bit_cast(unsigned, f);
    unsigned r = (u + 0x7fffu + ((u >> 16) & 1u)) >> 16;
    return (unsigned short)r;
}
static __device__ __forceinline__ float bf2f(unsigned short u) {
    unsigned v = ((unsigned)u) << 16;
    return __builtin_bit_cast(float, v);
}

// ------------------------- conv3x3 weight prepack --------------------------
__global__ __launch_bounds__(256) void prepack_conv_w(
    const float* __restrict__ w, unsigned short* __restrict__ o,
    int Cout, int CIN, int CINP)
{
    int idx = blockIdx.x * 256 + threadIdx.x;
    if (idx >= 9 * Cout * CINP) return;
    int ci = idx % CINP;
    int rem = idx / CINP;
    int co = rem % Cout;
    int tap = rem / Cout;
    float v = (ci < CIN) ? w[((size_t)co * CIN + ci) * 9 + tap] : 0.f;
    o[idx] = f2bf(v);
}

// ------------------------- conv3x3 via bf16 MFMA ---------------------------
template <int CINP, int NCH, int M>
__global__ __launch_bounds__(256) void conv3x3_mfma_kernel(
    const float* __restrict__ in, int CIN,
    const unsigned short* __restrict__ wrep,
    const float* __restrict__ g, const float* __restrict__ bb,
    const float* __restrict__ res, float* __restrict__ out, int Cout)
{
    __shared__ unsigned short X[324 * 40];
    const int tid = threadIdx.x;
    const int b = blockIdx.x;
    const int gr = blockIdx.y;
    const int cg = blockIdx.z;
    const int co0 = cg * (M * 16);
    const int pbase = gr << 8;
    const int gbase = pbase - 33;
    const int wv = tid >> 6, lane = tid & 63;
    const int ll = lane & 15, lk = lane >> 4;

    const float* inb = in + ((size_t)b * CIN << 10);

    f32x4 acc[M][4];
#pragma unroll
    for (int i = 0; i < M; ++i)
#pragma unroll
        for (int j = 0; j < 4; ++j)
#pragma unroll
            for (int r = 0; r < 4; ++r) acc[i][j][r] = 0.f;

#pragma unroll 1
    for (int ch = 0; ch < NCH; ++ch) {
        const int c0 = ch << 5;
#pragma unroll 1
        for (int ci2 = 0; ci2 < 16; ++ci2) {
            const int ci = c0 + ci2 * 2;
            const float* p0 = inb + ((size_t)ci << 10);
            const float* p1 = p0 + NPIX;
            const bool ok0 = ci < CIN, ok1 = (ci + 1) < CIN;
#pragma unroll 1
            for (int sp = tid; sp < 324; sp += 256) {
                const int gp = gbase + sp;
                const bool inr = (gp >= 0) & (gp < 1024);
                float a = (inr && ok0) ? p0[gp] : 0.f;
                float c = (inr && ok1) ? p1[gp] : 0.f;
                *(unsigned*)&X[sp * 40 + ci2 * 2] =
                    (unsigned)f2bf(a) | ((unsigned)f2bf(c) << 16);
            }
        }
        __syncthreads();
#pragma unroll
        for (int tap = 0; tap < 9; ++tap) {
            const int soff = (tap / 3) * 32 + (tap % 3);
            const int dx = tap % 3;
            bf16x8 bfrag[4];
#pragma unroll
            for (int j = 0; j < 4; ++j) {
                const int p = (wv << 6) + (j << 4) + ll;
                bf16x8 v = *(const bf16x8*)&X[(p + soff) * 40 + lk * 8];
                const bool zedge = (dx == 0 && (j & 1) == 0 && ll == 0) ||
                                   (dx == 2 && (j & 1) == 1 && ll == 15);
                if (zedge) { bf16x8 z = {}; v = z; }
                bfrag[j] = v;
            }
            const unsigned short* wb =
                wrep + ((size_t)tap * Cout + co0) * CINP + c0 + lk * 8;
#pragma unroll
            for (int i = 0; i < M; ++i) {
                bf16x8 afr = *(const bf16x8*)(wb + (size_t)(i * 16 + ll) * CINP);
#pragma unroll
                for (int j = 0; j < 4; ++j)
                    acc[i][j] = __builtin_amdgcn_mfma_f32_16x16x32_bf16(
                        afr, bfrag[j], acc[i][j], 0, 0, 0);
            }
        }
        __syncthreads();
    }

#pragma unroll
    for (int i = 0; i < M; ++i) {
#pragma unroll
        for (int r = 0; r < 4; ++r) {
            const int co = co0 + i * 16 + lk * 4 + r;
            const float gg = g[co], gb = bb[co];
            const size_t rowoff =
                ((size_t)(b * Cout + co) << 10) + pbase + (wv << 6) + ll;
#pragma unroll
            for (int j = 0; j < 4; ++j) {
                float v = fmaxf(acc[i][j][r] * gg + gb, 0.f);
                if (res) v += res[rowoff + (j << 4)];
                out[rowoff + (j << 4)] = v;
            }
        }
    }
}

// ------------------------- 1x1 conv, generic epilogue ----------------------
__global__ __launch_bounds__(256) void conv1x1_kernel(
    const float* __restrict__ in, int Cin, const float* __restrict__ wgt,
    const float* __restrict__ bias0, const float* __restrict__ g,
    const float* __restrict__ bb, const float* __restrict__ res,
    float* __restrict__ out, int Cout, int do_relu)
{
    const int tid = threadIdx.x;
    const int b = blockIdx.x >> 2;
    const int n = ((blockIdx.x & 3) << 8) + tid;
    const int co0 = blockIdx.y << 4;
    const float* inb = in + (size_t)b * Cin * NPIX + n;
    float acc[16];
#pragma unroll
    for (int a = 0; a < 16; ++a) acc[a] = 0.f;
#pragma unroll 4
    for (int ci = 0; ci < Cin; ++ci) {
        float v = inb[(size_t)ci << 10];
        const float* wp = wgt + (size_t)co0 * Cin + ci;
#pragma unroll
        for (int a = 0; a < 16; ++a) acc[a] = fmaf(wp[(size_t)a * Cin], v, acc[a]);
    }
#pragma unroll
    for (int a = 0; a < 16; ++a) {
        int co = co0 + a;
        float v = acc[a];
        if (bias0) v += bias0[co];
        if (g) v = v * g[co] + bb[co];
        if (do_relu) v = fmaxf(v, 0.f);
        size_t oi = ((size_t)(b * Cout + co) << 10) + n;
        if (res) v += res[oi];
        out[oi] = v;
    }
}

// ------------------------- pi conv: 1x1 + affine -> bf16 qT / v ------------
__global__ __launch_bounds__(256) void pi_kernel(
    const float* __restrict__ in, const float* __restrict__ wgt,
    const float* __restrict__ b0, const float* __restrict__ g,
    const float* __restrict__ bb, unsigned short* __restrict__ qTout,
    unsigned short* __restrict__ vout, int Cout, int qn)
{
    const int tid = threadIdx.x;
    const int b = blockIdx.x >> 2;
    const int n = ((blockIdx.x & 3) << 8) + tid;
    const int co0 = blockIdx.y << 4;
    const float* inb = in + ((size_t)b << 17) + n;
    float acc[16];
#pragma unroll
    for (int a = 0; a < 16; ++a) acc[a] = 0.f;
#pragma unroll 4
    for (int ci = 0; ci < 128; ++ci) {
        float v = inb[(size_t)ci << 10];
        const float* wp = wgt + (size_t)co0 * 128 + ci;
#pragma unroll
        for (int a = 0; a < 16; ++a) acc[a] = fmaf(wp[(size_t)a * 128], v, acc[a]);
    }
#pragma unroll
    for (int a = 0; a < 16; ++a) {
        int co = co0 + a;
        acc[a] = (acc[a] + b0[co]) * g[co] + bb[co];
    }
    if (co0 < qn) {
        u16x8 p0, p1;
#pragma unroll
        for (int e = 0; e < 8; ++e) { p0[e] = f2bf(acc[e]); p1[e] = f2bf(acc[8 + e]); }
        unsigned short* qp = qTout + ((((size_t)b << 10) + n) << 7) + co0;
        *(u16x8*)qp = p0;
        *(u16x8*)(qp + 8) = p1;
    } else {
#pragma unroll
        for (int a = 0; a < 16; ++a)
            vout[((size_t)(b * (Cout - qn) + (co0 - qn + a)) << 10) + n] = f2bf(acc[a]);
    }
}

// ------------------------- LayerNorm over C=128 (+ bf16 copy) --------------
__global__ __launch_bounds__(256) void ln_kernel(
    const float* __restrict__ in, const float* __restrict__ g,
    const float* __restrict__ bb, float* __restrict__ out,
    unsigned short* __restrict__ out_bf)
{
    const int tid = threadIdx.x;
    const int b = blockIdx.x >> 2;
    const int n = ((blockIdx.x & 3) << 8) + tid;
    const float* ib = in + ((size_t)b << 17) + n;
    float s = 0.f, sq = 0.f;
#pragma unroll 8
    for (int c = 0; c < 128; ++c) {
        float v = ib[(size_t)c << 10];
        s += v;
        sq += v * v;
    }
    const float mu = s * 0.0078125f;
    const float r = rsqrtf(sq * 0.0078125f - mu * mu + 1e-5f);
    float* ob = out + ((size_t)b << 17) + n;
    unsigned short* obf = out_bf + ((size_t)b << 17) + n;
#pragma unroll 8
    for (int c = 0; c < 128; ++c) {
        float v = ib[(size_t)c << 10];
        float y = (v - mu) * r * g[c] + bb[c];
        ob[(size_t)c << 10] = y;
        obf[(size_t)c << 10] = f2bf(y);
    }
}

// ------------------------- Gram matrix via bf16 MFMA -----------------------
// G[b][i][j] = sum_n X[b][i][n] X[b][j][n]; X bf16 (B,128,1024).
__global__ __launch_bounds__(256) void gram_kernel(
    const unsigned short* __restrict__ Xbf, float* __restrict__ G)
{
    __shared__ unsigned short Xs[128 * 128];
    const int tid = threadIdx.x;
    const int b = blockIdx.x >> 2;
    const int rg = blockIdx.x & 3;
    const int wid = tid >> 6, lane = tid & 63;
    const int lq = lane >> 4, ll = lane & 15;
    const unsigned short* Xb = Xbf + ((size_t)b << 17);

    f32x4 acc[2][2];
#pragma unroll
    for (int mi = 0; mi < 2; ++mi)
#pragma unroll
        for (int ci = 0; ci < 2; ++ci)
#pragma unroll
            for (int r = 0; r < 4; ++r) acc[mi][ci][r] = 0.f;

#pragma unroll 1
    for (int nt = 0; nt < 8; ++nt) {
        const int n0 = nt << 7;
#pragma unroll
        for (int p = 0; p < 8; ++p) {
            const int ch = (p << 4) + (tid >> 4);
            const int seg = (tid & 15) << 3;
            *(u16x8*)&Xs[ch * 128 + (seg ^ ((ch & 7) << 3))] =
                *(const u16x8*)(Xb + ((size_t)ch << 10) + n0 + seg);
        }
        __syncthreads();
#pragma unroll
        for (int ks = 0; ks < 4; ++ks) {
            bf16x8 af[2], bf_[2];
#pragma unroll
            for (int mi = 0; mi < 2; ++mi) {
                const int ar = (rg << 5) + mi * 16 + ll;
                af[mi] = *(const bf16x8*)&Xs[ar * 128 + ((ks * 32 + lq * 8) ^ ((ar & 7) << 3))];
            }
#pragma unroll
            for (int ci = 0; ci < 2; ++ci) {
                const int br = (wid << 5) + ci * 16 + ll;
                bf_[ci] = *(const bf16x8*)&Xs[br * 128 + ((ks * 32 + lq * 8) ^ ((br & 7) << 3))];
            }
#pragma unroll
            for (int mi = 0; mi < 2; ++mi)
#pragma unroll
                for (int ci = 0; ci < 2; ++ci)
                    acc[mi][ci] = __builtin_amdgcn_mfma_f32_16x16x32_bf16(
                        af[mi], bf_[ci], acc[mi][ci], 0, 0, 0);
        }
        __syncthreads();
    }
    float* Gb = G + ((size_t)b << 14);
#pragma unroll
    for (int mi = 0; mi < 2; ++mi)
#pragma unroll
        for (int ci = 0; ci < 2; ++ci)
#pragma unroll
            for (int r = 0; r < 4; ++r) {
                const int row = (rg << 5) + mi * 16 + lq * 4 + r;
                const int col = (wid << 5) + ci * 16 + ll;
                Gb[row * 128 + col] = acc[mi][ci][r];
            }
}

// ------------------------- channel row-sums of bf16 tensor -----------------
__global__ __launch_bounds__(256) void sums_kernel(
    const unsigned short* __restrict__ Xbf, float* __restrict__ S)
{
    const int tid = threadIdx.x;
    const int b = blockIdx.x;
    const int ch = tid >> 1, half = tid & 1;
    const unsigned short* p = Xbf + ((size_t)b << 17) + ((size_t)ch << 10) + half * 512;
    float s = 0.f;
#pragma unroll 4
    for (int i = 0; i < 64; ++i) {
        u16x8 v = *(const u16x8*)(p + i * 8);
#pragma unroll
        for (int e = 0; e < 8; ++e) s += bf2f(v[e]);
    }
    s += __shfl_xor(s, 1);
    if (half == 0) S[(b << 7) + ch] = s;
}

// ------------------------- GISSA stage-1 matrices --------------------------
// Per (b,h): 8x8 logits from Gram, ss_softmax, fold attn+Wv+identity+affine
// into M1 rows (cp = d*16+h) and c1.
__global__ __launch_bounds__(64) void mats1_kernel(
    const float* __restrict__ G, const float* __restrict__ S,
    const float* __restrict__ qkv_w, const float* __restrict__ qkv_b,
    const float* __restrict__ g, const float* __restrict__ bb,
    float* __restrict__ M1, float* __restrict__ c1)
{
    const int lane = threadIdx.x;
    const int b = blockIdx.x >> 4, h = blockIdx.x & 15;
    const float* Gb = G + ((size_t)b << 14);
    const float* Sb = S + (b << 7);
    const int d = lane >> 3, e = lane & 7;
    const int qch = h * 8 + d, kch = 128 + h * 8 + e;
    const int qoff = (qch / 24) * 8, koff = (kch / 24) * 8;
    float wq[8], wk[8];
#pragma unroll
    for (int i = 0; i < 8; ++i) {
        wq[i] = qkv_w[qch * 8 + i];
        wk[i] = qkv_w[kch * 8 + i];
    }
    float s = 0.f;
#pragma unroll
    for (int i = 0; i < 8; ++i) {
        float gu = 0.f;
#pragma unroll
        for (int j = 0; j < 8; ++j) gu += Gb[(qoff + i) * 128 + koff + j] * wk[j];
        s += wq[i] * gu;
    }
    const float bq = qkv_b[qch], bk = qkv_b[kch];
    float swk = 0.f, swq = 0.f;
#pragma unroll
    for (int j = 0; j < 8; ++j) { swk += wk[j] * Sb[koff + j]; swq += wq[j] * Sb[qoff + j]; }
    s += bq * swk + bk * swq + 1024.f * bq * bk;
    s *= 0.35355339059327373f;
    float a = (s > 0.f) ? sqrtf(s + 1e-5f) : ((s < 0.f) ? -sqrtf(1e-5f - s) : 0.f);
    float mx = a;
    mx = fmaxf(mx, __shfl_xor(mx, 1));
    mx = fmaxf(mx, __shfl_xor(mx, 2));
    mx = fmaxf(mx, __shfl_xor(mx, 4));
    float p = __expf(a - mx);
    float den = p;
    den += __shfl_xor(den, 1);
    den += __shfl_xor(den, 2);
    den += __shfl_xor(den, 4);
    const float A = p / den;

    // build: lane = d*8 + l, row cp = d*16+h, cols l*16..l*16+16
    const int l = e;
    const int cp = d * 16 + h;
    float row[16];
#pragma unroll
    for (int j = 0; j < 16; ++j) row[j] = 0.f;
    float cacc = 0.f;
#pragma unroll
    for (int e2 = 0; e2 < 8; ++e2) {
        const float Ae = __shfl(A, d * 8 + e2);
        const int vch = 256 + h * 8 + e2;
        const int voff = (vch / 24) * 8;
        cacc += Ae * qkv_b[vch];
        if ((voff >> 4) == l) {
            const int base = voff & 15;
#pragma unroll
            for (int j = 0; j < 8; ++j) row[base + j] += Ae * qkv_w[vch * 8 + j];
        }
    }
    const int idc = h * 8 + d;
    if ((idc >> 4) == l) row[idc & 15] += 1.f;
    const float gg = g[cp];
    float* mrow = M1 + ((size_t)b << 14) + cp * 128 + l * 16;
#pragma unroll
    for (int j = 0; j < 16; ++j) mrow[j] = gg * row[j];
    if (l == 0) c1[(b << 7) + cp] = gg * cacc + bb[cp];
}

// ------------------------- GISSA stage-2 matrices --------------------------
// Per (b,d): 16x16 logits from Gram(relu y), ss_softmax, fold into M2/c2.
__global__ __launch_bounds__(256) void mats2_kernel(
    const float* __restrict__ G, const float* __restrict__ S,
    const float* __restrict__ qkv2_w, const float* __restrict__ qkv2_b,
    float* __restrict__ M2, float* __restrict__ c2)
{
    const int tid = threadIdx.x;
    const int b = blockIdx.x >> 3, d = blockIdx.x & 7;
    const float* Gb = G + ((size_t)b << 14);
    const float* Sb = S + (b << 7);
    const int h = tid >> 4, gq = tid & 15;
    const int q2ch = d * 16 + h, k2ch = 128 + d * 16 + gq;
    const int qoff = (q2ch / 48) * 16, koff = (k2ch / 48) * 16;
    float wq[16], wk[16];
#pragma unroll
    for (int i = 0; i < 16; ++i) {
        wq[i] = qkv2_w[q2ch * 16 + i];
        wk[i] = qkv2_w[k2ch * 16 + i];
    }
    float s = 0.f;
#pragma unroll
    for (int i = 0; i < 16; ++i) {
        float gu = 0.f;
#pragma unroll
        for (int j = 0; j < 16; ++j) gu += Gb[(qoff + i) * 128 + koff + j] * wk[j];
        s += wq[i] * gu;
    }
    const float bq = qkv2_b[q2ch], bk = qkv2_b[k2ch];
    float swk = 0.f, swq = 0.f;
#pragma unroll
    for (int j = 0; j < 16; ++j) { swk += wk[j] * Sb[koff + j]; swq += wq[j] * Sb[qoff + j]; }
    s += bq * swk + bk * swq + 1024.f * bq * bk;
    s *= 0.25f;
    float a = (s > 0.f) ? sqrtf(s + 1e-5f) : ((s < 0.f) ? -sqrtf(1e-5f - s) : 0.f);
    float mx = a;
    mx = fmaxf(mx, __shfl_xor(mx, 1));
    mx = fmaxf(mx, __shfl_xor(mx, 2));
    mx = fmaxf(mx, __shfl_xor(mx, 4));
    mx = fmaxf(mx, __shfl_xor(mx, 8));
    float p = __expf(a - mx);
    float den = p;
    den += __shfl_xor(den, 1);
    den += __shfl_xor(den, 2);
    den += __shfl_xor(den, 4);
    den += __shfl_xor(den, 8);
    const float A2 = p / den;

    // build: lane (h, l=gq): row c = h*8+d, cols l*8..l*8+8
    const int l = gq;
    float row[8];
#pragma unroll
    for (int j = 0; j < 8; ++j) row[j] = 0.f;
    float cacc = 0.f;
#pragma unroll
    for (int g2 = 0; g2 < 16; ++g2) {
        const float Ag = __shfl(A2, (tid & 48) + g2);
        const int v2ch = 256 + d * 16 + g2;
        const int voff = (v2ch / 48) * 16;
        cacc += Ag * qkv2_b[v2ch];
        if ((l >> 1) == (voff >> 4)) {
            const int base = (l & 1) * 8;
#pragma unroll
            for (int j = 0; j < 8; ++j) row[j] += Ag * qkv2_w[v2ch * 16 + base + j];
        }
    }
    const int c = h * 8 + d;
    float* mrow = M2 + ((size_t)b << 14) + c * 128 + l * 8;
#pragma unroll
    for (int j = 0; j < 8; ++j) mrow[j] = row[j];
    if (l == 0) c2[(b << 7) + c] = cacc;
}

// ------------------------- apply1: y = M1 x + c1 ---------------------------
// Writes fp32 y and bf16 relu(y).
__global__ __launch_bounds__(256) void apply1_kernel(
    const float* __restrict__ x, const float* __restrict__ M1,
    const float* __restrict__ c1, float* __restrict__ ybuf,
    unsigned short* __restrict__ yrbf)
{
    __shared__ float Xs[128][128];
    const int tid = threadIdx.x;
    const int b = blockIdx.x >> 3;
    const int n0 = (blockIdx.x & 7) << 7;
    const float* xb = x + ((size_t)b << 17) + n0;
#pragma unroll
    for (int p = 0; p < 16; ++p) {
        const int lin = p * 1024 + tid * 4;
        const int ch = lin >> 7, px = lin & 127;
        *(float4*)&Xs[ch][px] = *(const float4*)(xb + ((size_t)ch << 10) + px);
    }
    __syncthreads();
    const int px = tid & 127, half = tid >> 7;
    const int co0 = half << 6;
    float acc[64];
#pragma unroll
    for (int o = 0; o < 64; ++o) acc[o] = 0.f;
    const float* Mb = M1 + ((size_t)b << 14);
#pragma unroll 1
    for (int i0 = 0; i0 < 128; i0 += 8) {
        float xv[8];
#pragma unroll
        for (int j = 0; j < 8; ++j) xv[j] = Xs[i0 + j][px];
#pragma unroll
        for (int o = 0; o < 64; ++o) {
            const float* mr = Mb + (co0 + o) * 128 + i0;
            float t = acc[o];
#pragma unroll
            for (int j = 0; j < 8; ++j) t = fmaf(mr[j], xv[j], t);
            acc[o] = t;
        }
    }
#pragma unroll
    for (int o = 0; o < 64; ++o) {
        const int cp = co0 + o;
        const float v = acc[o] + c1[(b << 7) + cp];
        const size_t oi = ((size_t)(b * 128 + cp) << 10) + n0 + px;
        ybuf[oi] = v;
        yrbf[oi] = f2bf(fmaxf(v, 0.f));
    }
}

// ------------------------- apply2: t += M2 relu(y) + c2 + y ----------------
__global__ __launch_bounds__(256) void apply2_kernel(
    const float* __restrict__ ybuf, const float* __restrict__ M2,
    const float* __restrict__ c2, float* __restrict__ t)
{
    __shared__ float Ys[128][128];
    const int tid = threadIdx.x;
    const int b = blockIdx.x >> 3;
    const int n0 = (blockIdx.x & 7) << 7;
    const float* yb = ybuf + ((size_t)b << 17) + n0;
#pragma unroll
    for (int p = 0; p < 16; ++p) {
        const int lin = p * 1024 + tid * 4;
        const int ch = lin >> 7, px = lin & 127;
        *(float4*)&Ys[ch][px] = *(const float4*)(yb + ((size_t)ch << 10) + px);
    }
    __syncthreads();
    const int px = tid & 127, half = tid >> 7;
    const int co0 = half << 6;
    float acc[64];
#pragma unroll
    for (int o = 0; o < 64; ++o) acc[o] = 0.f;
    const float* Mb = M2 + ((size_t)b << 14);
#pragma unroll 1
    for (int i0 = 0; i0 < 128; i0 += 8) {
        float xv[8];
#pragma unroll
        for (int j = 0; j < 8; ++j) xv[j] = fmaxf(Ys[i0 + j][px], 0.f);
#pragma unroll
        for (int o = 0; o < 64; ++o) {
            const float* mr = Mb + (co0 + o) * 128 + i0;
            float tt = acc[o];
#pragma unroll
            for (int j = 0; j < 8; ++j) tt = fmaf(mr[j], xv[j], tt);
            acc[o] = tt;
        }
    }
#pragma unroll
    for (int o = 0; o < 64; ++o) {
        const int c = co0 + o;
        const float v = acc[o] + c2[(b << 7) + c] + Ys[c][px];
        const size_t oi = ((size_t)(b * 128 + c) << 10) + n0 + px;
        t[oi] += v;
    }
}

// ------------------------- f32 -> bf16 conversion --------------------------
__global__ __launch_bounds__(256) void cvt_bf16_kernel(
    const float* __restrict__ a, unsigned short* __restrict__ o, int n)
{
    int i = blockIdx.x * 256 + threadIdx.x;
    if (i < n) o[i] = f2bf(a[i]);
}

// ------------------------- fused LN2 + MLP via bf16 MFMA -------------------
__global__ __launch_bounds__(256) void mlp_mfma_kernel(
    float* __restrict__ t, const float* __restrict__ ln_g,
    const float* __restrict__ ln_b, const unsigned short* __restrict__ w1bf,
    const float* __restrict__ b1, const unsigned short* __restrict__ w2bf,
    const float* __restrict__ b2)
{
    __shared__ unsigned char lds[16384 + 65536];
    unsigned char* xnb = lds;
    unsigned char* hb = lds + 16384;

    const int tid = threadIdx.x;
    const int b = blockIdx.x >> 4;
    const int n0 = (blockIdx.x & 15) << 6;
    float* tb = t + ((size_t)b << 17) + n0;

    {
        const int px = tid >> 2, q = tid & 3;
        float v[32];
        float s = 0.f, sq = 0.f;
#pragma unroll
        for (int k = 0; k < 32; ++k) {
            float x = tb[((size_t)(q * 32 + k) << 10) + px];
            v[k] = x;
            s += x;
            sq += x * x;
        }
        s += __shfl_xor(s, 1); s += __shfl_xor(s, 2);
        sq += __shfl_xor(sq, 1); sq += __shfl_xor(sq, 2);
        const float mu = s * 0.0078125f;
        const float rstd = rsqrtf(sq * 0.0078125f - mu * mu + 1e-5f);
        const int sw = (px & 7) << 4;
#pragma unroll
        for (int cc = 0; cc < 4; ++cc) {
            u16x8 pk;
#pragma unroll
            for (int e = 0; e < 8; ++e) {
                int c = q * 32 + cc * 8 + e;
                float xv = (v[cc * 8 + e] - mu) * rstd * ln_g[c] + ln_b[c];
                pk[e] = f2bf(xv);
            }
            *(u16x8*)(xnb + px * 256 + ((q * 64 + cc * 16) ^ sw)) = pk;
        }
    }
    __syncthreads();

    const int wid = tid >> 6, lane = tid & 63;
    const int lr = lane & 15, lk = lane >> 4;

#pragma unroll 1
    for (int pass = 0; pass < 2; ++pass) {
        const int hidbase = (wid << 7) + (pass << 6);
        f32x4 acc[4][4];
#pragma unroll
        for (int i = 0; i < 4; ++i)
#pragma unroll
            for (int j = 0; j < 4; ++j)
#pragma unroll
                for (int r = 0; r < 4; ++r) acc[i][j][r] = 0.f;
#pragma unroll
        for (int kk = 0; kk < 4; ++kk) {
            bf16x8 af[4], bfr[4];
#pragma unroll
            for (int i = 0; i < 4; ++i)
                af[i] = *(const bf16x8*)(w1bf + (size_t)(hidbase + i * 16 + lr) * 128 + kk * 32 + lk * 8);
#pragma unroll
            for (int j = 0; j < 4; ++j) {
                const int px = j * 16 + lr;
                bfr[j] = *(const bf16x8*)(xnb + px * 256 + ((kk * 64 + lk * 16) ^ ((px & 7) << 4)));
            }
#pragma unroll
            for (int i = 0; i < 4; ++i)
#pragma unroll
                for (int j = 0; j < 4; ++j)
                    acc[i][j] = __builtin_amdgcn_mfma_f32_16x16x32_bf16(af[i], bfr[j], acc[i][j], 0, 0, 0);
        }
#pragma unroll
        for (int i = 0; i < 4; ++i) {
            const int hid0 = hidbase + i * 16 + lk * 4;
            float bi[4];
#pragma unroll
            for (int r = 0; r < 4; ++r) bi[r] = b1[hid0 + r];
#pragma unroll
            for (int j = 0; j < 4; ++j) {
                const int px = j * 16 + lr;
                u16x4 pk;
#pragma unroll
                for (int r = 0; r < 4; ++r) {
                    float x = acc[i][j][r] + bi[r];
                    float u = 1.5957691f * x * (1.f + 0.044715f * x * x);
                    float gv = x / (1.f + __expf(-u));
                    pk[r] = f2bf(gv);
                }
                *(u16x4*)(hb + px * 1024 + ((hid0 * 2) ^ ((px & 7) << 4))) = pk;
            }
        }
    }
    __syncthreads();

    f32x4 acc2[2][4];
#pragma unroll
    for (int i = 0; i < 2; ++i)
#pragma unroll
        for (int j = 0; j < 4; ++j)
#pragma unroll
            for (int r = 0; r < 4; ++r) acc2[i][j][r] = 0.f;
#pragma unroll 2
    for (int ks = 0; ks < 16; ++ks) {
        bf16x8 af[2], bfr[4];
#pragma unroll
        for (int i = 0; i < 2; ++i)
            af[i] = *(const bf16x8*)(w2bf + (size_t)((wid << 5) + i * 16 + lr) * 512 + ks * 32 + lk * 8);
#pragma unroll
        for (int j = 0; j < 4; ++j) {
            const int px = j * 16 + lr;
            bfr[j] = *(const bf16x8*)(hb + px * 1024 + ((ks * 64 + lk * 16) ^ ((px & 7) << 4)));
        }
#pragma unroll
        for (int i = 0; i < 2; ++i)
#pragma unroll
            for (int j = 0; j < 4; ++j)
                acc2[i][j] = __builtin_amdgcn_mfma_f32_16x16x32_bf16(af[i], bfr[j], acc2[i][j], 0, 0, 0);
    }
#pragma unroll
    for (int i = 0; i < 2; ++i) {
        const int cb = (wid << 5) + i * 16 + lk * 4;
        float b2v[4];
#pragma unroll
        for (int r = 0; r < 4; ++r) b2v[r] = b2[cb + r];
#pragma unroll
        for (int j = 0; j < 4; ++j) {
            const int px = j * 16 + lr;
#pragma unroll
            for (int r = 0; r < 4; ++r) {
                const size_t off = ((size_t)(cb + r) << 10) + px;
                tb[off] += acc2[i][j][r] + b2v[r];
            }
        }
    }
}

// ------------------------- flash SWSA via bf16 MFMA ------------------------
__global__ __launch_bounds__(256) void swsa_mfma_kernel(
    const unsigned short* __restrict__ qT, const unsigned short* __restrict__ vbf,
    float* __restrict__ outp, float fscale)
{
    __shared__ unsigned short K_lds[128 * 128];
    __shared__ unsigned short V_lds[128 * 128];
    const int tid = threadIdx.x;
    const int b = blockIdx.x >> 3;
    const int n0 = (blockIdx.x & 7) << 7;
    const int wid = tid >> 6, lane = tid & 63;
    const int lq = lane >> 4, ll = lane & 15;
    const unsigned short* qTb = qT + ((size_t)b << 17);
    const unsigned short* vb = vbf + ((size_t)b << 17);

    bf16x8 aq[2][4];
#pragma unroll
    for (int mi = 0; mi < 2; ++mi) {
        const int row = n0 + wid * 32 + mi * 16 + ll;
#pragma unroll
        for (int kk = 0; kk < 4; ++kk)
            aq[mi][kk] = *(const bf16x8*)(qTb + ((size_t)row << 7) + kk * 32 + lq * 8);
    }

    float mrun[8], lrun[8];
#pragma unroll
    for (int i = 0; i < 8; ++i) { mrun[i] = -INFINITY; lrun[i] = 0.f; }
    f32x4 yacc[2][8];
#pragma unroll
    for (int mi = 0; mi < 2; ++mi)
#pragma unroll
        for (int cj = 0; cj < 8; ++cj)
#pragma unroll
            for (int r = 0; r < 4; ++r) yacc[mi][cj][r] = 0.f;

#pragma unroll 1
    for (int mt = 0; mt < 8; ++mt) {
        const int m0 = mt << 7;
        for (int ch = tid; ch < 2048; ch += 256) {
            const int rr = ch >> 4, e0 = (ch & 15) << 3;
            const int sw = (rr & 7) << 3;
            *(u16x8*)&K_lds[rr * 128 + (e0 ^ sw)] =
                *(const u16x8*)(qTb + ((size_t)(m0 + rr) << 7) + e0);
            *(u16x8*)&V_lds[rr * 128 + (e0 ^ sw)] =
                *(const u16x8*)(vb + ((size_t)rr << 10) + m0 + e0);
        }
        __syncthreads();

        f32x4 sacc[2][8];
#pragma unroll
        for (int mi = 0; mi < 2; ++mi)
#pragma unroll
            for (int j = 0; j < 8; ++j)
#pragma unroll
                for (int r = 0; r < 4; ++r) sacc[mi][j][r] = 0.f;
#pragma unroll
        for (int j = 0; j < 8; ++j) {
            const int ml = j * 16 + ll;
            const int swk = (ml & 7) << 3;
            bf16x8 bk[4];
#pragma unroll
            for (int kk = 0; kk < 4; ++kk)
                bk[kk] = *(const bf16x8*)&K_lds[ml * 128 + ((kk * 32 + lq * 8) ^ swk)];
#pragma unroll
            for (int mi = 0; mi < 2; ++mi)
#pragma unroll
                for (int kk = 0; kk < 4; ++kk)
                    sacc[mi][j] = __builtin_amdgcn_mfma_f32_16x16x32_bf16(aq[mi][kk], bk[kk], sacc[mi][j], 0, 0, 0);
        }
        __syncthreads();

        float pmax[8];
#pragma unroll
        for (int i = 0; i < 8; ++i) pmax[i] = -INFINITY;
#pragma unroll
        for (int mi = 0; mi < 2; ++mi)
#pragma unroll
            for (int j = 0; j < 8; ++j)
#pragma unroll
                for (int r = 0; r < 4; ++r) {
                    float s = sacc[mi][j][r] * 0.08838834764831845f;
                    sacc[mi][j][r] = s;
                    pmax[mi * 4 + r] = fmaxf(pmax[mi * 4 + r], s);
                }
        float alpha[8], psum[8];
#pragma unroll
        for (int i = 0; i < 8; ++i) {
            float m = pmax[i];
            m = fmaxf(m, __shfl_xor(m, 1));
            m = fmaxf(m, __shfl_xor(m, 2));
            m = fmaxf(m, __shfl_xor(m, 4));
            m = fmaxf(m, __shfl_xor(m, 8));
            const float mn = fmaxf(mrun[i], m);
            alpha[i] = __expf(mrun[i] - mn);
            mrun[i] = mn;
            psum[i] = 0.f;
        }
#pragma unroll
        for (int mi = 0; mi < 2; ++mi)
#pragma unroll
            for (int r = 0; r < 4; ++r) {
                const int nbw = wid * 32 + mi * 16 + lq * 4 + r;
                const int sw = (nbw & 7) << 3;
                const float mn = mrun[mi * 4 + r];
                float ps = 0.f;
#pragma unroll
                for (int j = 0; j < 8; ++j) {
                    float p = __expf(sacc[mi][j][r] - mn);
                    ps += p;
                    K_lds[nbw * 128 + ((j * 16 + ll) ^ sw)] = f2bf(p);
                }
                psum[mi * 4 + r] += ps;
            }
#pragma unroll
        for (int i = 0; i < 8; ++i) {
            float s = psum[i];
            s += __shfl_xor(s, 1);
            s += __shfl_xor(s, 2);
            s += __shfl_xor(s, 4);
            s += __shfl_xor(s, 8);
            lrun[i] = lrun[i] * alpha[i] + s;
        }
#pragma unroll
        for (int mi = 0; mi < 2; ++mi)
#pragma unroll
            for (int cj = 0; cj < 8; ++cj)
#pragma unroll
                for (int r = 0; r < 4; ++r) yacc[mi][cj][r] *= alpha[mi * 4 + r];

        bf16x8 ap[2][4];
#pragma unroll
        for (int mi = 0; mi < 2; ++mi) {
            const int nb = wid * 32 + mi * 16 + ll;
            const int sw = (nb & 7) << 3;
#pragma unroll
            for (int mk = 0; mk < 4; ++mk)
                ap[mi][mk] = *(const bf16x8*)&K_lds[nb * 128 + ((mk * 32 + lq * 8) ^ sw)];
        }
#pragma unroll
        for (int cj = 0; cj < 8; ++cj) {
            const int cl = cj * 16 + ll;
            const int sw = (cl & 7) << 3;
            bf16x8 bv[4];
#pragma unroll
            for (int mk = 0; mk < 4; ++mk)
                bv[mk] = *(const bf16x8*)&V_lds[cl * 128 + ((mk * 32 + lq * 8) ^ sw)];
#pragma unroll
            for (int mi = 0; mi < 2; ++mi)
#pragma unroll
                for (int mk = 0; mk < 4; ++mk)
                    yacc[mi][cj] = __builtin_amdgcn_mfma_f32_16x16x32_bf16(ap[mi][mk], bv[mk], yacc[mi][cj], 0, 0, 0);
        }
        __syncthreads();
    }

#pragma unroll
    for (int mi = 0; mi < 2; ++mi) {
        const int nbase = n0 + wid * 32 + mi * 16 + lq * 4;
        float inv[4];
#pragma unroll
        for (int r = 0; r < 4; ++r) inv[r] = fscale / lrun[mi * 4 + r];
#pragma unroll
        for (int cj = 0; cj < 8; ++cj) {
            const int c = cj * 16 + ll;
            float4 o;
            o.x = yacc[mi][cj][0] * inv[0];
            o.y = yacc[mi][cj][1] * inv[1];
            o.z = yacc[mi][cj][2] * inv[2];
            o.w = yacc[mi][cj][3] * inv[3];
            *(float4*)(outp + ((size_t)(b * 128 + c) << 10) + nbase) = o;
        }
    }
}

// ------------------------- final mix + mean + fc ----------------------------
__global__ __launch_bounds__(256) void final_kernel(
    const float* __restrict__ xc, const float* __restrict__ xp,
    const float* __restrict__ lamuda, const float* __restrict__ fc_w,
    float* __restrict__ outp)
{
    __shared__ float meanb[128];
    __shared__ float red[4];
    const int tid = threadIdx.x;
    const int b = blockIdx.x;
    const float lmd = 1.f / (1.f + __expf(-lamuda[0]));
    const float* xcb = xc + ((size_t)b << 17);
    const float* xpb = xp + ((size_t)b << 17);
    for (int c = 0; c < 128; ++c) {
        float4 a = *(const float4*)(xcb + ((size_t)c << 10) + tid * 4);
        float4 d = *(const float4*)(xpb + ((size_t)c << 10) + tid * 4);
        float s = lmd * (a.x + a.y + a.z + a.w) + (1.f - lmd) * (d.x + d.y + d.z + d.w);
#pragma unroll
        for (int o = 1; o < 64; o <<= 1) s += __shfl_xor(s, o);
        if ((tid & 63) == 0) red[tid >> 6] = s;
        __syncthreads();
        if (tid == 0) meanb[c] = (red[0] + red[1] + red[2] + red[3]) * (1.f / 1024.f);
        __syncthreads();
    }
    if (tid < 16) {
        float s = 0.f;
        for (int c = 0; c < 128; ++c) s += fc_w[tid * 128 + c] * meanb[c];
        outp[b * 16 + tid] = s;
    }
}

// ---------------------------------------------------------------------------
extern "C" void kernel_launch(void* const* d_in, const int* in_sizes, int n_in,
                              void* d_out, int out_size, void* d_ws, size_t ws_size,
                              hipStream_t stream)
{
    (void)in_sizes; (void)n_in; (void)out_size; (void)ws_size;

    const float* x       = (const float*)d_in[0];
    const float* ssfe_w  = (const float*)d_in[1];
    const float* ssfe_g  = (const float*)d_in[2];
    const float* ssfe_b  = (const float*)d_in[3];
    const float* cc_w    = (const float*)d_in[4];
    const float* cc_g    = (const float*)d_in[5];
    const float* cc_b    = (const float*)d_in[6];
    const float* ln1_g   = (const float*)d_in[7];
    const float* ln1_b   = (const float*)d_in[8];
    const float* qkv_w   = (const float*)d_in[9];
    const float* qkv_b   = (const float*)d_in[10];
    const float* gbn_g   = (const float*)d_in[11];
    const float* gbn_b   = (const float*)d_in[12];
    const float* qkv2_w  = (const float*)d_in[13];
    const float* qkv2_b  = (const float*)d_in[14];
    const float* ln2_g   = (const float*)d_in[15];
    const float* ln2_b   = (const float*)d_in[16];
    const float* mlp_w1  = (const float*)d_in[17];
    const float* mlp_b1  = (const float*)d_in[18];
    const float* mlp_w2  = (const float*)d_in[19];
    const float* mlp_b2  = (const float*)d_in[20];
    const float* cs_w    = (const float*)d_in[21];
    const float* cs_g    = (const float*)d_in[22];
    const float* cs_b    = (const float*)d_in[23];
    const float* lfe0_w  = (const float*)d_in[24];
    const float* lfe0_g  = (const float*)d_in[25];
    const float* lfe0_b  = (const float*)d_in[26];
    const float* s0_pi_w = (const float*)d_in[27];
    const float* s0_pi_b = (const float*)d_in[28];
    const float* s0_bn_g = (const float*)d_in[29];
    const float* s0_bn_b = (const float*)d_in[30];
    const float* s0_po_w = (const float*)d_in[31];
    const float* s0_po_b = (const float*)d_in[32];
    const float* lfe1_w  = (const float*)d_in[33];
    const float* lfe1_g  = (const float*)d_in[34];
    const float* lfe1_b  = (const float*)d_in[35];
    const float* s1_pi_w = (const float*)d_in[36];
    const float* s1_pi_b = (const float*)d_in[37];
    const float* s1_bn_g = (const float*)d_in[38];
    const float* s1_bn_b = (const float*)d_in[39];
    const float* s1_po_w = (const float*)d_in[40];
    const float* s1_po_b = (const float*)d_in[41];
    const float* lamuda  = (const float*)d_in[42];
    const float* fc_w    = (const float*)d_in[43];
    float* out = (float*)d_out;
    float* ws = (float*)d_ws;

    // workspace layout (floats); total = 34,078,720 floats = 136.3 MB
    float* xs = ws;                    // (B,144,N); tail reused for wlfe1 later
    float* t  = ws + 4718592;          // (B,128,N)  residual stream / xc
    float* P1 = ws + 8912896;          // (B,128,N)  cur / xp / yv / xp4
    float* Qr = ws + 13107200;         // 12.58M floats: GISSA scratch then swsa bufs
    float* P2 = ws + 25690112;         // (B,128,N)
    float* P3 = ws + 29884416;         // (B,128,N)

    // GISSA-phase buffers (inside Qr; all dead before pi/swsa phase)
    unsigned short* curbf = (unsigned short*)Qr;             // (B,128,1024) bf16
    float* ybuf  = Qr + 2097152;                             // (B,128,1024) f32
    unsigned short* yrbf = (unsigned short*)(Qr + 6291456);  // (B,128,1024) bf16
    float* Gbuf  = Qr + 8388608;                             // (B,128,128)
    float* Sbuf  = Qr + 8912896;                             // (B,128)
    float* M1buf = Qr + 8916992;                             // (B,128,128)
    float* c1buf = Qr + 9441280;                             // (B,128)
    float* M2buf = Qr + 9445376;                             // (B,128,128)
    float* c2buf = Qr + 9969664;                             // (B,128)

    // swsa-phase buffers (inside Qr)
    unsigned short* qT0 = (unsigned short*)Qr;     // (B,1024,128) bf16
    unsigned short* v0  = qT0 + 4194304;           // (B,128,1024) bf16
    unsigned short* v1  = v0 + 4194304;            // (B,128,1024) bf16

    unsigned short* w1bf = (unsigned short*)P2;
    unsigned short* w2bf = w1bf + 65536;

    unsigned short* wssfe = (unsigned short*)P3;                 // 9*144*160
    unsigned short* wcs   = (unsigned short*)(P3 + 131072);      // 9*128*160
    unsigned short* wlfe0 = (unsigned short*)(P3 + 262144);      // 9*128*128
    unsigned short* wlfe1 = (unsigned short*)xs;                 // 9*128*128

    const dim3 blk(256);

    prepack_conv_w<<<dim3((9 * 144 * 160 + 255) / 256), blk, 0, stream>>>(ssfe_w, wssfe, 144, 144, 160);
    prepack_conv_w<<<dim3((9 * 128 * 160 + 255) / 256), blk, 0, stream>>>(cs_w, wcs, 128, 144, 160);
    prepack_conv_w<<<dim3((9 * 128 * 128 + 255) / 256), blk, 0, stream>>>(lfe0_w, wlfe0, 128, 128, 128);

    conv3x3_mfma_kernel<160, 5, 3><<<dim3(32, 4, 3), blk, 0, stream>>>(x, 144, wssfe, ssfe_g, ssfe_b, nullptr, xs, 144);
    conv1x1_kernel<<<dim3(128, 8), blk, 0, stream>>>(xs, 144, cc_w, nullptr, cc_g, cc_b, nullptr, t, 128, 1);

    // ---- GISSA via Gram trick ----
    ln_kernel<<<dim3(128), blk, 0, stream>>>(t, ln1_g, ln1_b, P1, curbf);
    gram_kernel<<<dim3(128), blk, 0, stream>>>(curbf, Gbuf);
    sums_kernel<<<dim3(32), blk, 0, stream>>>(curbf, Sbuf);
    mats1_kernel<<<dim3(512), dim3(64), 0, stream>>>(Gbuf, Sbuf, qkv_w, qkv_b, gbn_g, gbn_b, M1buf, c1buf);
    apply1_kernel<<<dim3(256), blk, 0, stream>>>(P1, M1buf, c1buf, ybuf, yrbf);
    gram_kernel<<<dim3(128), blk, 0, stream>>>(yrbf, Gbuf);
    sums_kernel<<<dim3(32), blk, 0, stream>>>(yrbf, Sbuf);
    mats2_kernel<<<dim3(256), blk, 0, stream>>>(Gbuf, Sbuf, qkv2_w, qkv2_b, M2buf, c2buf);
    apply2_kernel<<<dim3(256), blk, 0, stream>>>(ybuf, M2buf, c2buf, t);

    cvt_bf16_kernel<<<dim3(256), blk, 0, stream>>>(mlp_w1, w1bf, 65536);
    cvt_bf16_kernel<<<dim3(256), blk, 0, stream>>>(mlp_w2, w2bf, 65536);
    mlp_mfma_kernel<<<dim3(512), blk, 0, stream>>>(t, ln2_g, ln2_b, w1bf, mlp_b1, w2bf, mlp_b2);

    conv3x3_mfma_kernel<160, 5, 2><<<dim3(32, 4, 4), blk, 0, stream>>>(xs, 144, wcs, cs_g, cs_b, nullptr, P1, 128);
    prepack_conv_w<<<dim3((9 * 128 * 128 + 255) / 256), blk, 0, stream>>>(lfe1_w, wlfe1, 128, 128, 128);
    conv3x3_mfma_kernel<128, 4, 2><<<dim3(32, 4, 4), blk, 0, stream>>>(P1, 128, wlfe0, lfe0_g, lfe0_b, P1, P2, 128);
    pi_kernel<<<dim3(128, 16), blk, 0, stream>>>(P2, s0_pi_w, s0_pi_b, s0_bn_g, s0_bn_b, qT0, v0, 256, 128);
    swsa_mfma_kernel<<<dim3(256), blk, 0, stream>>>(qT0, v0, P1, 1.0f);
    conv1x1_kernel<<<dim3(128, 8), blk, 0, stream>>>(P1, 128, s0_po_w, s0_po_b, nullptr, nullptr, P2, P3, 128, 0);
    conv3x3_mfma_kernel<128, 4, 2><<<dim3(32, 4, 4), blk, 0, stream>>>(P3, 128, wlfe1, lfe1_g, lfe1_b, P3, P1, 128);
    pi_kernel<<<dim3(128, 8), blk, 0, stream>>>(P1, s1_pi_w, s1_pi_b, s1_bn_g, s1_bn_b, nullptr, v1, 128, 0);
    swsa_mfma_kernel<<<dim3(256), blk, 0, stream>>>(qT0, v1, P2, 0.08838834764831845f);
    conv1x1_kernel<<<dim3(128, 8), blk, 0, stream>>>(P2, 128, s1_po_w, s1_po_b, nullptr, nullptr, P1, P3, 128, 0);
    final_kernel<<<dim3(32), blk, 0, stream>>>(t, P3, lamuda, fc_w, out);
}

// Round 6
// 823.149 us; speedup vs baseline: 5.7054x; 1.2308x over previous
//
#include <hip/hip_runtime.h>
#include <math.h>

// ---------------------------------------------------------------------------
// EATN forward. Layout: activations (B, C, N), N = 1024 contiguous.
// B=32, C=128 (144 stem), HEADS=16, HD=8.
// Round 6: apply1/2 -> MFMA GEMMs (transposed bf16 operands from producers);
//          cs/lfe0/lfe1 convs -> direct-global implicit GEMM (no LDS);
//          ssfe staged conv: 2x grid, flattened staging.
// ---------------------------------------------------------------------------

static constexpr int NPIX = 1024;

typedef __attribute__((ext_vector_type(8))) short bf16x8;
typedef __attribute__((ext_vector_type(4))) float f32x4;
typedef __attribute__((ext_vector_type(8))) unsigned short u16x8;
typedef __attribute__((ext_vector_type(4))) unsigned short u16x4;

static __device__ __forceinline__ unsigned short f2bf(float f) {
    unsigned u = __builtin_bit_cast(unsigned, f);
    unsigned r = (u + 0x7fffu + ((u >> 16) & 1u)) >> 16;
    return (unsigned short)r;
}
static __device__ __forceinline__ float bf2f(unsigned short u) {
    unsigned v = ((unsigned)u) << 16;
    return __builtin_bit_cast(float, v);
}

// ------------------------- conv3x3 weight prepack --------------------------
__global__ __launch_bounds__(256) void prepack_conv_w(
    const float* __restrict__ w, unsigned short* __restrict__ o,
    int Cout, int CIN, int CINP)
{
    int idx = blockIdx.x * 256 + threadIdx.x;
    if (idx >= 9 * Cout * CINP) return;
    int ci = idx % CINP;
    int rem = idx / CINP;
    int co = rem % Cout;
    int tap = rem / Cout;
    float v = (ci < CIN) ? w[((size_t)co * CIN + ci) * 9 + tap] : 0.f;
    o[idx] = f2bf(v);
}

// ------------------------- conv3x3, LDS-staged (ssfe) ----------------------
// Block: (b, 128 px, M*16 co). Also emits transposed bf16 output (pitch CINP)
// with zero tail columns [zcol, CINP) written by the last cg.
template <int CINP, int NCH, int M>
__global__ __launch_bounds__(256) void conv3x3_stg_kernel(
    const float* __restrict__ in, int CIN,
    const unsigned short* __restrict__ wrep,
    const float* __restrict__ g, const float* __restrict__ bb,
    float* __restrict__ out, unsigned short* __restrict__ outT,
    int Cout, int zcol)
{
    __shared__ unsigned short X[194 * 40];
    const int tid = threadIdx.x;
    const int b = blockIdx.x, gr = blockIdx.y, cg = blockIdx.z;
    const int co0 = cg * (M * 16);
    const int pbase = gr << 7;
    const int gbase = pbase - 33;
    const int wv = tid >> 6, lane = tid & 63;
    const int ll = lane & 15, lk = lane >> 4;
    const float* inb = in + ((size_t)b * CIN << 10);

    f32x4 acc[M][2];
#pragma unroll
    for (int i = 0; i < M; ++i)
#pragma unroll
        for (int j = 0; j < 2; ++j)
#pragma unroll
            for (int r = 0; r < 4; ++r) acc[i][j][r] = 0.f;

#pragma unroll 1
    for (int ch = 0; ch < NCH; ++ch) {
        const int c0 = ch << 5;
#pragma unroll 1
        for (int idx = tid; idx < 16 * 194; idx += 256) {
            const int ci2 = idx / 194;
            const int sp = idx - ci2 * 194;
            const int ci = c0 + ci2 * 2;
            const int gp = gbase + sp;
            const bool inr = (gp >= 0) & (gp < 1024);
            const float* p0 = inb + ((size_t)ci << 10);
            float a = (inr && ci < CIN) ? p0[gp] : 0.f;
            float c = (inr && (ci + 1) < CIN) ? p0[gp + 1024] : 0.f;
            *(unsigned*)&X[sp * 40 + ci2 * 2] =
                (unsigned)f2bf(a) | ((unsigned)f2bf(c) << 16);
        }
        __syncthreads();
#pragma unroll
        for (int tap = 0; tap < 9; ++tap) {
            const int soff = (tap / 3) * 32 + (tap % 3);
            const int dx = tap % 3;
            bf16x8 bfrag[2];
#pragma unroll
            for (int j = 0; j < 2; ++j) {
                const int p = wv * 32 + j * 16 + ll;
                bf16x8 v = *(const bf16x8*)&X[(p + soff) * 40 + lk * 8];
                const bool zed = (dx == 0 && j == 0 && ll == 0) ||
                                 (dx == 2 && j == 1 && ll == 15);
                if (zed) { bf16x8 z = {}; v = z; }
                bfrag[j] = v;
            }
            const unsigned short* wb =
                wrep + ((size_t)tap * Cout + co0) * CINP + c0 + lk * 8;
#pragma unroll
            for (int i = 0; i < M; ++i) {
                bf16x8 afr = *(const bf16x8*)(wb + (size_t)(i * 16 + ll) * CINP);
#pragma unroll
                for (int j = 0; j < 2; ++j)
                    acc[i][j] = __builtin_amdgcn_mfma_f32_16x16x32_bf16(
                        afr, bfrag[j], acc[i][j], 0, 0, 0);
            }
        }
        __syncthreads();
    }

#pragma unroll
    for (int i = 0; i < M; ++i) {
#pragma unroll
        for (int j = 0; j < 2; ++j) {
            const int px = pbase + wv * 32 + j * 16 + ll;
            u16x4 tp;
#pragma unroll
            for (int r = 0; r < 4; ++r) {
                const int co = co0 + i * 16 + lk * 4 + r;
                float v = fmaxf(acc[i][j][r] * g[co] + bb[co], 0.f);
                out[((size_t)(b * Cout + co) << 10) + px] = v;
                tp[r] = f2bf(v);
            }
            *(u16x4*)(outT + (((size_t)b << 10) + px) * CINP + co0 + i * 16 + lk * 4) = tp;
            if (cg == (int)gridDim.z - 1 && i == 0) {
                u16x4 z = {};
                *(u16x4*)(outT + (((size_t)b << 10) + px) * CINP + zcol + lk * 4) = z;
            }
        }
    }
}

// ------------------------- conv3x3, direct-global implicit GEMM ------------
// xT: (B,1024,CINP) bf16 px-major. No LDS. Block: (b, 128 px, M*16 co).
template <int CINP, int M>
__global__ __launch_bounds__(256) void conv3x3_dir_kernel(
    const unsigned short* __restrict__ xT,
    const unsigned short* __restrict__ wrep,
    const float* __restrict__ g, const float* __restrict__ bb,
    const float* __restrict__ res, float* __restrict__ out,
    unsigned short* __restrict__ outT, int Cout)
{
    const int tid = threadIdx.x;
    const int b = blockIdx.x, gr = blockIdx.y, cg = blockIdx.z;
    const int co0 = cg * (M * 16);
    const int pbase = gr << 7;
    const int wv = tid >> 6, lane = tid & 63;
    const int ll = lane & 15, lq = lane >> 4;
    const unsigned short* xb = xT + ((size_t)b << 10) * CINP;

    f32x4 acc[M][2];
#pragma unroll
    for (int i = 0; i < M; ++i)
#pragma unroll
        for (int j = 0; j < 2; ++j)
#pragma unroll
            for (int r = 0; r < 4; ++r) acc[i][j][r] = 0.f;

#pragma unroll
    for (int tap = 0; tap < 9; ++tap) {
        const int dy = tap / 3, dx = tap % 3;
        const int off = (dy - 1) * 32 + (dx - 1);
        int gpc[2];
        bool val[2];
#pragma unroll
        for (int j = 0; j < 2; ++j) {
            const int px = pbase + wv * 32 + j * 16 + ll;
            const int gp = px + off;
            const bool zed = (dx == 0 && j == 0 && ll == 0) ||
                             (dx == 2 && j == 1 && ll == 15);
            val[j] = (gp >= 0) && (gp < 1024) && !zed;
            gpc[j] = min(max(gp, 0), 1023);
        }
#pragma unroll
        for (int kc = 0; kc < CINP / 32; ++kc) {
            bf16x8 bfv[2];
#pragma unroll
            for (int j = 0; j < 2; ++j) {
                bf16x8 v = *(const bf16x8*)(xb + (size_t)gpc[j] * CINP + kc * 32 + lq * 8);
                if (!val[j]) { bf16x8 z = {}; v = z; }
                bfv[j] = v;
            }
            const unsigned short* wb =
                wrep + ((size_t)tap * Cout + co0) * CINP + kc * 32 + lq * 8;
#pragma unroll
            for (int i = 0; i < M; ++i) {
                bf16x8 af = *(const bf16x8*)(wb + (size_t)(i * 16 + ll) * CINP);
#pragma unroll
                for (int j = 0; j < 2; ++j)
                    acc[i][j] = __builtin_amdgcn_mfma_f32_16x16x32_bf16(
                        af, bfv[j], acc[i][j], 0, 0, 0);
            }
        }
    }

#pragma unroll
    for (int i = 0; i < M; ++i) {
#pragma unroll
        for (int j = 0; j < 2; ++j) {
            const int px = pbase + wv * 32 + j * 16 + ll;
            u16x4 tp;
#pragma unroll
            for (int r = 0; r < 4; ++r) {
                const int co = co0 + i * 16 + lq * 4 + r;
                float v = fmaxf(acc[i][j][r] * g[co] + bb[co], 0.f);
                const size_t oi = ((size_t)(b * Cout + co) << 10) + px;
                if (res) v += res[oi];
                out[oi] = v;
                tp[r] = f2bf(v);
            }
            if (outT)
                *(u16x4*)(outT + (((size_t)b << 10) + px) * 128 + co0 + i * 16 + lq * 4) = tp;
        }
    }
}

// ------------------------- 1x1 conv, generic epilogue (+opt bf16 T out) ----
__global__ __launch_bounds__(256) void conv1x1_kernel(
    const float* __restrict__ in, int Cin, const float* __restrict__ wgt,
    const float* __restrict__ bias0, const float* __restrict__ g,
    const float* __restrict__ bb, const float* __restrict__ res,
    float* __restrict__ out, unsigned short* __restrict__ outT,
    int Cout, int do_relu)
{
    const int tid = threadIdx.x;
    const int b = blockIdx.x >> 2;
    const int n = ((blockIdx.x & 3) << 8) + tid;
    const int co0 = blockIdx.y << 4;
    const float* inb = in + (size_t)b * Cin * NPIX + n;
    float acc[16];
#pragma unroll
    for (int a = 0; a < 16; ++a) acc[a] = 0.f;
#pragma unroll 4
    for (int ci = 0; ci < Cin; ++ci) {
        float v = inb[(size_t)ci << 10];
        const float* wp = wgt + (size_t)co0 * Cin + ci;
#pragma unroll
        for (int a = 0; a < 16; ++a) acc[a] = fmaf(wp[(size_t)a * Cin], v, acc[a]);
    }
#pragma unroll
    for (int a = 0; a < 16; ++a) {
        int co = co0 + a;
        float v = acc[a];
        if (bias0) v += bias0[co];
        if (g) v = v * g[co] + bb[co];
        if (do_relu) v = fmaxf(v, 0.f);
        size_t oi = ((size_t)(b * Cout + co) << 10) + n;
        if (res) v += res[oi];
        out[oi] = v;
        acc[a] = v;
    }
    if (outT) {
        u16x8 t0, t1;
#pragma unroll
        for (int e = 0; e < 8; ++e) { t0[e] = f2bf(acc[e]); t1[e] = f2bf(acc[8 + e]); }
        unsigned short* tp = outT + (((size_t)b << 10) + n) * 128 + co0;
        *(u16x8*)tp = t0;
        *(u16x8*)(tp + 8) = t1;
    }
}

// ------------------------- pi conv: 1x1 + affine -> bf16 qT / v ------------
__global__ __launch_bounds__(256) void pi_kernel(
    const float* __restrict__ in, const float* __restrict__ wgt,
    const float* __restrict__ b0, const float* __restrict__ g,
    const float* __restrict__ bb, unsigned short* __restrict__ qTout,
    unsigned short* __restrict__ vout, int Cout, int qn)
{
    const int tid = threadIdx.x;
    const int b = blockIdx.x >> 2;
    const int n = ((blockIdx.x & 3) << 8) + tid;
    const int co0 = blockIdx.y << 4;
    const float* inb = in + ((size_t)b << 17) + n;
    float acc[16];
#pragma unroll
    for (int a = 0; a < 16; ++a) acc[a] = 0.f;
#pragma unroll 4
    for (int ci = 0; ci < 128; ++ci) {
        float v = inb[(size_t)ci << 10];
        const float* wp = wgt + (size_t)co0 * 128 + ci;
#pragma unroll
        for (int a = 0; a < 16; ++a) acc[a] = fmaf(wp[(size_t)a * 128], v, acc[a]);
    }
#pragma unroll
    for (int a = 0; a < 16; ++a) {
        int co = co0 + a;
        acc[a] = (acc[a] + b0[co]) * g[co] + bb[co];
    }
    if (co0 < qn) {
        u16x8 p0, p1;
#pragma unroll
        for (int e = 0; e < 8; ++e) { p0[e] = f2bf(acc[e]); p1[e] = f2bf(acc[8 + e]); }
        unsigned short* qp = qTout + ((((size_t)b << 10) + n) << 7) + co0;
        *(u16x8*)qp = p0;
        *(u16x8*)(qp + 8) = p1;
    } else {
#pragma unroll
        for (int a = 0; a < 16; ++a)
            vout[((size_t)(b * (Cout - qn) + (co0 - qn + a)) << 10) + n] = f2bf(acc[a]);
    }
}

// ------------------------- LayerNorm -> bf16 (ch-major + px-major) ---------
__global__ __launch_bounds__(256) void ln_kernel(
    const float* __restrict__ in, const float* __restrict__ g,
    const float* __restrict__ bb, unsigned short* __restrict__ out_bf,
    unsigned short* __restrict__ outT)
{
    const int tid = threadIdx.x;
    const int b = blockIdx.x >> 2;
    const int n = ((blockIdx.x & 3) << 8) + tid;
    const float* ib = in + ((size_t)b << 17) + n;
    float s = 0.f, sq = 0.f;
#pragma unroll 8
    for (int c = 0; c < 128; ++c) {
        float v = ib[(size_t)c << 10];
        s += v;
        sq += v * v;
    }
    const float mu = s * 0.0078125f;
    const float r = rsqrtf(sq * 0.0078125f - mu * mu + 1e-5f);
    unsigned short* obf = out_bf + ((size_t)b << 17) + n;
    unsigned short* oT = outT + (((size_t)b << 10) + n) * 128;
#pragma unroll 2
    for (int c0 = 0; c0 < 128; c0 += 8) {
        u16x8 pk;
#pragma unroll
        for (int e = 0; e < 8; ++e) {
            const int c = c0 + e;
            float v = ib[(size_t)c << 10];
            float y = (v - mu) * r * g[c] + bb[c];
            unsigned short h = f2bf(y);
            obf[(size_t)c << 10] = h;
            pk[e] = h;
        }
        *(u16x8*)(oT + c0) = pk;
    }
}

// ------------------------- Gram matrix via bf16 MFMA -----------------------
__global__ __launch_bounds__(256) void gram_kernel(
    const unsigned short* __restrict__ Xbf, float* __restrict__ G)
{
    __shared__ unsigned short Xs[128 * 128];
    const int tid = threadIdx.x;
    const int b = blockIdx.x >> 2;
    const int rg = blockIdx.x & 3;
    const int wid = tid >> 6, lane = tid & 63;
    const int lq = lane >> 4, ll = lane & 15;
    const unsigned short* Xb = Xbf + ((size_t)b << 17);

    f32x4 acc[2][2];
#pragma unroll
    for (int mi = 0; mi < 2; ++mi)
#pragma unroll
        for (int ci = 0; ci < 2; ++ci)
#pragma unroll
            for (int r = 0; r < 4; ++r) acc[mi][ci][r] = 0.f;

#pragma unroll 1
    for (int nt = 0; nt < 8; ++nt) {
        const int n0 = nt << 7;
#pragma unroll
        for (int p = 0; p < 8; ++p) {
            const int ch = (p << 4) + (tid >> 4);
            const int seg = (tid & 15) << 3;
            *(u16x8*)&Xs[ch * 128 + (seg ^ ((ch & 7) << 3))] =
                *(const u16x8*)(Xb + ((size_t)ch << 10) + n0 + seg);
        }
        __syncthreads();
#pragma unroll
        for (int ks = 0; ks < 4; ++ks) {
            bf16x8 af[2], bf_[2];
#pragma unroll
            for (int mi = 0; mi < 2; ++mi) {
                const int ar = (rg << 5) + mi * 16 + ll;
                af[mi] = *(const bf16x8*)&Xs[ar * 128 + ((ks * 32 + lq * 8) ^ ((ar & 7) << 3))];
            }
#pragma unroll
            for (int ci = 0; ci < 2; ++ci) {
                const int br = (wid << 5) + ci * 16 + ll;
                bf_[ci] = *(const bf16x8*)&Xs[br * 128 + ((ks * 32 + lq * 8) ^ ((br & 7) << 3))];
            }
#pragma unroll
            for (int mi = 0; mi < 2; ++mi)
#pragma unroll
                for (int ci = 0; ci < 2; ++ci)
                    acc[mi][ci] = __builtin_amdgcn_mfma_f32_16x16x32_bf16(
                        af[mi], bf_[ci], acc[mi][ci], 0, 0, 0);
        }
        __syncthreads();
    }
    float* Gb = G + ((size_t)b << 14);
#pragma unroll
    for (int mi = 0; mi < 2; ++mi)
#pragma unroll
        for (int ci = 0; ci < 2; ++ci)
#pragma unroll
            for (int r = 0; r < 4; ++r) {
                const int row = (rg << 5) + mi * 16 + lq * 4 + r;
                const int col = (wid << 5) + ci * 16 + ll;
                Gb[row * 128 + col] = acc[mi][ci][r];
            }
}

// ------------------------- channel row-sums of bf16 tensor -----------------
__global__ __launch_bounds__(256) void sums_kernel(
    const unsigned short* __restrict__ Xbf, float* __restrict__ S)
{
    const int tid = threadIdx.x;
    const int b = blockIdx.x;
    const int ch = tid >> 1, half = tid & 1;
    const unsigned short* p = Xbf + ((size_t)b << 17) + ((size_t)ch << 10) + half * 512;
    float s = 0.f;
#pragma unroll 4
    for (int i = 0; i < 64; ++i) {
        u16x8 v = *(const u16x8*)(p + i * 8);
#pragma unroll
        for (int e = 0; e < 8; ++e) s += bf2f(v[e]);
    }
    s += __shfl_xor(s, 1);
    if (half == 0) S[(b << 7) + ch] = s;
}

// ------------------------- GISSA stage-1 matrices (bf16 M1) ----------------
__global__ __launch_bounds__(64) void mats1_kernel(
    const float* __restrict__ G, const float* __restrict__ S,
    const float* __restrict__ qkv_w, const float* __restrict__ qkv_b,
    const float* __restrict__ g, const float* __restrict__ bb,
    unsigned short* __restrict__ M1, float* __restrict__ c1)
{
    const int lane = threadIdx.x;
    const int b = blockIdx.x >> 4, h = blockIdx.x & 15;
    const float* Gb = G + ((size_t)b << 14);
    const float* Sb = S + (b << 7);
    const int d = lane >> 3, e = lane & 7;
    const int qch = h * 8 + d, kch = 128 + h * 8 + e;
    const int qoff = (qch / 24) * 8, koff = (kch / 24) * 8;
    float wq[8], wk[8];
#pragma unroll
    for (int i = 0; i < 8; ++i) {
        wq[i] = qkv_w[qch * 8 + i];
        wk[i] = qkv_w[kch * 8 + i];
    }
    float s = 0.f;
#pragma unroll
    for (int i = 0; i < 8; ++i) {
        float gu = 0.f;
#pragma unroll
        for (int j = 0; j < 8; ++j) gu += Gb[(qoff + i) * 128 + koff + j] * wk[j];
        s += wq[i] * gu;
    }
    const float bq = qkv_b[qch], bk = qkv_b[kch];
    float swk = 0.f, swq = 0.f;
#pragma unroll
    for (int j = 0; j < 8; ++j) { swk += wk[j] * Sb[koff + j]; swq += wq[j] * Sb[qoff + j]; }
    s += bq * swk + bk * swq + 1024.f * bq * bk;
    s *= 0.35355339059327373f;
    float a = (s > 0.f) ? sqrtf(s + 1e-5f) : ((s < 0.f) ? -sqrtf(1e-5f - s) : 0.f);
    float mx = a;
    mx = fmaxf(mx, __shfl_xor(mx, 1));
    mx = fmaxf(mx, __shfl_xor(mx, 2));
    mx = fmaxf(mx, __shfl_xor(mx, 4));
    float p = __expf(a - mx);
    float den = p;
    den += __shfl_xor(den, 1);
    den += __shfl_xor(den, 2);
    den += __shfl_xor(den, 4);
    const float A = p / den;

    const int l = e;
    const int cp = d * 16 + h;
    float row[16];
#pragma unroll
    for (int j = 0; j < 16; ++j) row[j] = 0.f;
    float cacc = 0.f;
#pragma unroll
    for (int e2 = 0; e2 < 8; ++e2) {
        const float Ae = __shfl(A, d * 8 + e2);
        const int vch = 256 + h * 8 + e2;
        const int voff = (vch / 24) * 8;
        cacc += Ae * qkv_b[vch];
        if ((voff >> 4) == l) {
            const int base = voff & 15;
#pragma unroll
            for (int j = 0; j < 8; ++j) row[base + j] += Ae * qkv_w[vch * 8 + j];
        }
    }
    const int idc = h * 8 + d;
    if ((idc >> 4) == l) row[idc & 15] += 1.f;
    const float gg = g[cp];
    unsigned short* mrow = M1 + ((size_t)b << 14) + cp * 128 + l * 16;
#pragma unroll
    for (int j = 0; j < 16; ++j) mrow[j] = f2bf(gg * row[j]);
    if (l == 0) c1[(b << 7) + cp] = gg * cacc + bb[cp];
}

// ------------------------- GISSA stage-2 matrices (bf16 M2) ----------------
__global__ __launch_bounds__(256) void mats2_kernel(
    const float* __restrict__ G, const float* __restrict__ S,
    const float* __restrict__ qkv2_w, const float* __restrict__ qkv2_b,
    unsigned short* __restrict__ M2, float* __restrict__ c2)
{
    const int tid = threadIdx.x;
    const int b = blockIdx.x >> 3, d = blockIdx.x & 7;
    const float* Gb = G + ((size_t)b << 14);
    const float* Sb = S + (b << 7);
    const int h = tid >> 4, gq = tid & 15;
    const int q2ch = d * 16 + h, k2ch = 128 + d * 16 + gq;
    const int qoff = (q2ch / 48) * 16, koff = (k2ch / 48) * 16;
    float wq[16], wk[16];
#pragma unroll
    for (int i = 0; i < 16; ++i) {
        wq[i] = qkv2_w[q2ch * 16 + i];
        wk[i] = qkv2_w[k2ch * 16 + i];
    }
    float s = 0.f;
#pragma unroll
    for (int i = 0; i < 16; ++i) {
        float gu = 0.f;
#pragma unroll
        for (int j = 0; j < 16; ++j) gu += Gb[(qoff + i) * 128 + koff + j] * wk[j];
        s += wq[i] * gu;
    }
    const float bq = qkv2_b[q2ch], bk = qkv2_b[k2ch];
    float swk = 0.f, swq = 0.f;
#pragma unroll
    for (int j = 0; j < 16; ++j) { swk += wk[j] * Sb[koff + j]; swq += wq[j] * Sb[qoff + j]; }
    s += bq * swk + bk * swq + 1024.f * bq * bk;
    s *= 0.25f;
    float a = (s > 0.f) ? sqrtf(s + 1e-5f) : ((s < 0.f) ? -sqrtf(1e-5f - s) : 0.f);
    float mx = a;
    mx = fmaxf(mx, __shfl_xor(mx, 1));
    mx = fmaxf(mx, __shfl_xor(mx, 2));
    mx = fmaxf(mx, __shfl_xor(mx, 4));
    mx = fmaxf(mx, __shfl_xor(mx, 8));
    float p = __expf(a - mx);
    float den = p;
    den += __shfl_xor(den, 1);
    den += __shfl_xor(den, 2);
    den += __shfl_xor(den, 4);
    den += __shfl_xor(den, 8);
    const float A2 = p / den;

    const int l = gq;
    float row[8];
#pragma unroll
    for (int j = 0; j < 8; ++j) row[j] = 0.f;
    float cacc = 0.f;
#pragma unroll
    for (int g2 = 0; g2 < 16; ++g2) {
        const float Ag = __shfl(A2, (tid & 48) + g2);
        const int v2ch = 256 + d * 16 + g2;
        const int voff = (v2ch / 48) * 16;
        cacc += Ag * qkv2_b[v2ch];
        if ((l >> 1) == (voff >> 4)) {
            const int base = (l & 1) * 8;
#pragma unroll
            for (int j = 0; j < 8; ++j) row[j] += Ag * qkv2_w[v2ch * 16 + base + j];
        }
    }
    const int c = h * 8 + d;
    unsigned short* mrow = M2 + ((size_t)b << 14) + c * 128 + l * 8;
#pragma unroll
    for (int j = 0; j < 8; ++j) mrow[j] = f2bf(row[j]);
    if (l == 0) c2[(b << 7) + c] = cacc;
}

// ------------------------- apply1: y = M1 x + c1 (MFMA) --------------------
// A = M1bf (128x128), B = curT (px-major). Outputs: ybuf fp32, yr bf16
// ch-major (for gram/sums), yrT bf16 px-major (for apply2's B operand).
__global__ __launch_bounds__(256) void apply1_mfma_kernel(
    const unsigned short* __restrict__ curT, const unsigned short* __restrict__ M1bf,
    const float* __restrict__ c1, float* __restrict__ ybuf,
    unsigned short* __restrict__ yrbf, unsigned short* __restrict__ yrT)
{
    const int tid = threadIdx.x;
    const int b = blockIdx.x >> 3;
    const int n0 = (blockIdx.x & 7) << 7;
    const int wid = tid >> 6, lane = tid & 63;
    const int wr = wid >> 1, wc = wid & 1;
    const int ll = lane & 15, lq = lane >> 4;
    const unsigned short* Mb = M1bf + ((size_t)b << 14);
    const unsigned short* xb = curT + (((size_t)b << 10) + n0 + wc * 64) * 128;

    f32x4 acc[4][4];
#pragma unroll
    for (int i = 0; i < 4; ++i)
#pragma unroll
        for (int j = 0; j < 4; ++j)
#pragma unroll
            for (int r = 0; r < 4; ++r) acc[i][j][r] = 0.f;

#pragma unroll
    for (int kk = 0; kk < 4; ++kk) {
        bf16x8 af[4], bfv[4];
#pragma unroll
        for (int i = 0; i < 4; ++i)
            af[i] = *(const bf16x8*)(Mb + (size_t)(wr * 64 + i * 16 + ll) * 128 + kk * 32 + lq * 8);
#pragma unroll
        for (int j = 0; j < 4; ++j)
            bfv[j] = *(const bf16x8*)(xb + (size_t)(j * 16 + ll) * 128 + kk * 32 + lq * 8);
#pragma unroll
        for (int i = 0; i < 4; ++i)
#pragma unroll
            for (int j = 0; j < 4; ++j)
                acc[i][j] = __builtin_amdgcn_mfma_f32_16x16x32_bf16(af[i], bfv[j], acc[i][j], 0, 0, 0);
    }

#pragma unroll
    for (int i = 0; i < 4; ++i) {
        const int cob = wr * 64 + i * 16 + lq * 4;
        float c1v[4];
#pragma unroll
        for (int r = 0; r < 4; ++r) c1v[r] = c1[(b << 7) + cob + r];
#pragma unroll
        for (int j = 0; j < 4; ++j) {
            const int px = n0 + wc * 64 + j * 16 + ll;
            u16x4 tp;
#pragma unroll
            for (int r = 0; r < 4; ++r) {
                const int co = cob + r;
                const float v = acc[i][j][r] + c1v[r];
                const size_t oi = ((size_t)(b * 128 + co) << 10) + px;
                ybuf[oi] = v;
                const unsigned short h = f2bf(fmaxf(v, 0.f));
                yrbf[oi] = h;
                tp[r] = h;
            }
            *(u16x4*)(yrT + (((size_t)b << 10) + px) * 128 + cob) = tp;
        }
    }
}

// ------------------------- apply2: t += M2 relu(y) + c2 + y (MFMA) ---------
__global__ __launch_bounds__(256) void apply2_mfma_kernel(
    const unsigned short* __restrict__ yrT, const unsigned short* __restrict__ M2bf,
    const float* __restrict__ c2, const float* __restrict__ ybuf,
    float* __restrict__ t)
{
    const int tid = threadIdx.x;
    const int b = blockIdx.x >> 3;
    const int n0 = (blockIdx.x & 7) << 7;
    const int wid = tid >> 6, lane = tid & 63;
    const int wr = wid >> 1, wc = wid & 1;
    const int ll = lane & 15, lq = lane >> 4;
    const unsigned short* Mb = M2bf + ((size_t)b << 14);
    const unsigned short* xb = yrT + (((size_t)b << 10) + n0 + wc * 64) * 128;

    f32x4 acc[4][4];
#pragma unroll
    for (int i = 0; i < 4; ++i)
#pragma unroll
        for (int j = 0; j < 4; ++j)
#pragma unroll
            for (int r = 0; r < 4; ++r) acc[i][j][r] = 0.f;

#pragma unroll
    for (int kk = 0; kk < 4; ++kk) {
        bf16x8 af[4], bfv[4];
#pragma unroll
        for (int i = 0; i < 4; ++i)
            af[i] = *(const bf16x8*)(Mb + (size_t)(wr * 64 + i * 16 + ll) * 128 + kk * 32 + lq * 8);
#pragma unroll
        for (int j = 0; j < 4; ++j)
            bfv[j] = *(const bf16x8*)(xb + (size_t)(j * 16 + ll) * 128 + kk * 32 + lq * 8);
#pragma unroll
        for (int i = 0; i < 4; ++i)
#pragma unroll
            for (int j = 0; j < 4; ++j)
                acc[i][j] = __builtin_amdgcn_mfma_f32_16x16x32_bf16(af[i], bfv[j], acc[i][j], 0, 0, 0);
    }

#pragma unroll
    for (int i = 0; i < 4; ++i) {
        const int cob = wr * 64 + i * 16 + lq * 4;
        float c2v[4];
#pragma unroll
        for (int r = 0; r < 4; ++r) c2v[r] = c2[(b << 7) + cob + r];
#pragma unroll
        for (int j = 0; j < 4; ++j) {
            const int px = n0 + wc * 64 + j * 16 + ll;
#pragma unroll
            for (int r = 0; r < 4; ++r) {
                const size_t oi = ((size_t)(b * 128 + cob + r) << 10) + px;
                t[oi] += acc[i][j][r] + c2v[r] + ybuf[oi];
            }
        }
    }
}

// ------------------------- f32 -> bf16 conversion --------------------------
__global__ __launch_bounds__(256) void cvt_bf16_kernel(
    const float* __restrict__ a, unsigned short* __restrict__ o, int n)
{
    int i = blockIdx.x * 256 + threadIdx.x;
    if (i < n) o[i] = f2bf(a[i]);
}

// ------------------------- fused LN2 + MLP via bf16 MFMA -------------------
__global__ __launch_bounds__(256) void mlp_mfma_kernel(
    float* __restrict__ t, const float* __restrict__ ln_g,
    const float* __restrict__ ln_b, const unsigned short* __restrict__ w1bf,
    const float* __restrict__ b1, const unsigned short* __restrict__ w2bf,
    const float* __restrict__ b2)
{
    __shared__ unsigned char lds[16384 + 65536];
    unsigned char* xnb = lds;
    unsigned char* hb = lds + 16384;

    const int tid = threadIdx.x;
    const int b = blockIdx.x >> 4;
    const int n0 = (blockIdx.x & 15) << 6;
    float* tb = t + ((size_t)b << 17) + n0;

    {
        const int px = tid >> 2, q = tid & 3;
        float v[32];
        float s = 0.f, sq = 0.f;
#pragma unroll
        for (int k = 0; k < 32; ++k) {
            float x = tb[((size_t)(q * 32 + k) << 10) + px];
            v[k] = x;
            s += x;
            sq += x * x;
        }
        s += __shfl_xor(s, 1); s += __shfl_xor(s, 2);
        sq += __shfl_xor(sq, 1); sq += __shfl_xor(sq, 2);
        const float mu = s * 0.0078125f;
        const float rstd = rsqrtf(sq * 0.0078125f - mu * mu + 1e-5f);
        const int sw = (px & 7) << 4;
#pragma unroll
        for (int cc = 0; cc < 4; ++cc) {
            u16x8 pk;
#pragma unroll
            for (int e = 0; e < 8; ++e) {
                int c = q * 32 + cc * 8 + e;
                float xv = (v[cc * 8 + e] - mu) * rstd * ln_g[c] + ln_b[c];
                pk[e] = f2bf(xv);
            }
            *(u16x8*)(xnb + px * 256 + ((q * 64 + cc * 16) ^ sw)) = pk;
        }
    }
    __syncthreads();

    const int wid = tid >> 6, lane = tid & 63;
    const int lr = lane & 15, lk = lane >> 4;

#pragma unroll 1
    for (int pass = 0; pass < 2; ++pass) {
        const int hidbase = (wid << 7) + (pass << 6);
        f32x4 acc[4][4];
#pragma unroll
        for (int i = 0; i < 4; ++i)
#pragma unroll
            for (int j = 0; j < 4; ++j)
#pragma unroll
                for (int r = 0; r < 4; ++r) acc[i][j][r] = 0.f;
#pragma unroll
        for (int kk = 0; kk < 4; ++kk) {
            bf16x8 af[4], bfr[4];
#pragma unroll
            for (int i = 0; i < 4; ++i)
                af[i] = *(const bf16x8*)(w1bf + (size_t)(hidbase + i * 16 + lr) * 128 + kk * 32 + lk * 8);
#pragma unroll
            for (int j = 0; j < 4; ++j) {
                const int px = j * 16 + lr;
                bfr[j] = *(const bf16x8*)(xnb + px * 256 + ((kk * 64 + lk * 16) ^ ((px & 7) << 4)));
            }
#pragma unroll
            for (int i = 0; i < 4; ++i)
#pragma unroll
                for (int j = 0; j < 4; ++j)
                    acc[i][j] = __builtin_amdgcn_mfma_f32_16x16x32_bf16(af[i], bfr[j], acc[i][j], 0, 0, 0);
        }
#pragma unroll
        for (int i = 0; i < 4; ++i) {
            const int hid0 = hidbase + i * 16 + lk * 4;
            float bi[4];
#pragma unroll
            for (int r = 0; r < 4; ++r) bi[r] = b1[hid0 + r];
#pragma unroll
            for (int j = 0; j < 4; ++j) {
                const int px = j * 16 + lr;
                u16x4 pk;
#pragma unroll
                for (int r = 0; r < 4; ++r) {
                    float x = acc[i][j][r] + bi[r];
                    float u = 1.5957691f * x * (1.f + 0.044715f * x * x);
                    float gv = x / (1.f + __expf(-u));
                    pk[r] = f2bf(gv);
                }
                *(u16x4*)(hb + px * 1024 + ((hid0 * 2) ^ ((px & 7) << 4))) = pk;
            }
        }
    }
    __syncthreads();

    f32x4 acc2[2][4];
#pragma unroll
    for (int i = 0; i < 2; ++i)
#pragma unroll
        for (int j = 0; j < 4; ++j)
#pragma unroll
            for (int r = 0; r < 4; ++r) acc2[i][j][r] = 0.f;
#pragma unroll 2
    for (int ks = 0; ks < 16; ++ks) {
        bf16x8 af[2], bfr[4];
#pragma unroll
        for (int i = 0; i < 2; ++i)
            af[i] = *(const bf16x8*)(w2bf + (size_t)((wid << 5) + i * 16 + lr) * 512 + ks * 32 + lk * 8);
#pragma unroll
        for (int j = 0; j < 4; ++j) {
            const int px = j * 16 + lr;
            bfr[j] = *(const bf16x8*)(hb + px * 1024 + ((ks * 64 + lk * 16) ^ ((px & 7) << 4)));
        }
#pragma unroll
        for (int i = 0; i < 2; ++i)
#pragma unroll
            for (int j = 0; j < 4; ++j)
                acc2[i][j] = __builtin_amdgcn_mfma_f32_16x16x32_bf16(af[i], bfr[j], acc2[i][j], 0, 0, 0);
    }
#pragma unroll
    for (int i = 0; i < 2; ++i) {
        const int cb = (wid << 5) + i * 16 + lk * 4;
        float b2v[4];
#pragma unroll
        for (int r = 0; r < 4; ++r) b2v[r] = b2[cb + r];
#pragma unroll
        for (int j = 0; j < 4; ++j) {
            const int px = j * 16 + lr;
#pragma unroll
            for (int r = 0; r < 4; ++r) {
                const size_t off = ((size_t)(cb + r) << 10) + px;
                tb[off] += acc2[i][j][r] + b2v[r];
            }
        }
    }
}

// ------------------------- flash SWSA via bf16 MFMA ------------------------
__global__ __launch_bounds__(256) void swsa_mfma_kernel(
    const unsigned short* __restrict__ qT, const unsigned short* __restrict__ vbf,
    float* __restrict__ outp, float fscale)
{
    __shared__ unsigned short K_lds[128 * 128];
    __shared__ unsigned short V_lds[128 * 128];
    const int tid = threadIdx.x;
    const int b = blockIdx.x >> 3;
    const int n0 = (blockIdx.x & 7) << 7;
    const int wid = tid >> 6, lane = tid & 63;
    const int lq = lane >> 4, ll = lane & 15;
    const unsigned short* qTb = qT + ((size_t)b << 17);
    const unsigned short* vb = vbf + ((size_t)b << 17);

    bf16x8 aq[2][4];
#pragma unroll
    for (int mi = 0; mi < 2; ++mi) {
        const int row = n0 + wid * 32 + mi * 16 + ll;
#pragma unroll
        for (int kk = 0; kk < 4; ++kk)
            aq[mi][kk] = *(const bf16x8*)(qTb + ((size_t)row << 7) + kk * 32 + lq * 8);
    }

    float mrun[8], lrun[8];
#pragma unroll
    for (int i = 0; i < 8; ++i) { mrun[i] = -INFINITY; lrun[i] = 0.f; }
    f32x4 yacc[2][8];
#pragma unroll
    for (int mi = 0; mi < 2; ++mi)
#pragma unroll
        for (int cj = 0; cj < 8; ++cj)
#pragma unroll
            for (int r = 0; r < 4; ++r) yacc[mi][cj][r] = 0.f;

#pragma unroll 1
    for (int mt = 0; mt < 8; ++mt) {
        const int m0 = mt << 7;
        for (int ch = tid; ch < 2048; ch += 256) {
            const int rr = ch >> 4, e0 = (ch & 15) << 3;
            const int sw = (rr & 7) << 3;
            *(u16x8*)&K_lds[rr * 128 + (e0 ^ sw)] =
                *(const u16x8*)(qTb + ((size_t)(m0 + rr) << 7) + e0);
            *(u16x8*)&V_lds[rr * 128 + (e0 ^ sw)] =
                *(const u16x8*)(vb + ((size_t)rr << 10) + m0 + e0);
        }
        __syncthreads();

        f32x4 sacc[2][8];
#pragma unroll
        for (int mi = 0; mi < 2; ++mi)
#pragma unroll
            for (int j = 0; j < 8; ++j)
#pragma unroll
                for (int r = 0; r < 4; ++r) sacc[mi][j][r] = 0.f;
#pragma unroll
        for (int j = 0; j < 8; ++j) {
            const int ml = j * 16 + ll;
            const int swk = (ml & 7) << 3;
            bf16x8 bk[4];
#pragma unroll
            for (int kk = 0; kk < 4; ++kk)
                bk[kk] = *(const bf16x8*)&K_lds[ml * 128 + ((kk * 32 + lq * 8) ^ swk)];
#pragma unroll
            for (int mi = 0; mi < 2; ++mi)
#pragma unroll
                for (int kk = 0; kk < 4; ++kk)
                    sacc[mi][j] = __builtin_amdgcn_mfma_f32_16x16x32_bf16(aq[mi][kk], bk[kk], sacc[mi][j], 0, 0, 0);
        }
        __syncthreads();

        float pmax[8];
#pragma unroll
        for (int i = 0; i < 8; ++i) pmax[i] = -INFINITY;
#pragma unroll
        for (int mi = 0; mi < 2; ++mi)
#pragma unroll
            for (int j = 0; j < 8; ++j)
#pragma unroll
                for (int r = 0; r < 4; ++r) {
                    float s = sacc[mi][j][r] * 0.08838834764831845f;
                    sacc[mi][j][r] = s;
                    pmax[mi * 4 + r] = fmaxf(pmax[mi * 4 + r], s);
                }
        float alpha[8], psum[8];
#pragma unroll
        for (int i = 0; i < 8; ++i) {
            float m = pmax[i];
            m = fmaxf(m, __shfl_xor(m, 1));
            m = fmaxf(m, __shfl_xor(m, 2));
            m = fmaxf(m, __shfl_xor(m, 4));
            m = fmaxf(m, __shfl_xor(m, 8));
            const float mn = fmaxf(mrun[i], m);
            alpha[i] = __expf(mrun[i] - mn);
            mrun[i] = mn;
            psum[i] = 0.f;
        }
#pragma unroll
        for (int mi = 0; mi < 2; ++mi)
#pragma unroll
            for (int r = 0; r < 4; ++r) {
                const int nbw = wid * 32 + mi * 16 + lq * 4 + r;
                const int sw = (nbw & 7) << 3;
                const float mn = mrun[mi * 4 + r];
                float ps = 0.f;
#pragma unroll
                for (int j = 0; j < 8; ++j) {
                    float p = __expf(sacc[mi][j][r] - mn);
                    ps += p;
                    K_lds[nbw * 128 + ((j * 16 + ll) ^ sw)] = f2bf(p);
                }
                psum[mi * 4 + r] += ps;
            }
#pragma unroll
        for (int i = 0; i < 8; ++i) {
            float s = psum[i];
            s += __shfl_xor(s, 1);
            s += __shfl_xor(s, 2);
            s += __shfl_xor(s, 4);
            s += __shfl_xor(s, 8);
            lrun[i] = lrun[i] * alpha[i] + s;
        }
#pragma unroll
        for (int mi = 0; mi < 2; ++mi)
#pragma unroll
            for (int cj = 0; cj < 8; ++cj)
#pragma unroll
                for (int r = 0; r < 4; ++r) yacc[mi][cj][r] *= alpha[mi * 4 + r];

        bf16x8 ap[2][4];
#pragma unroll
        for (int mi = 0; mi < 2; ++mi) {
            const int nb = wid * 32 + mi * 16 + ll;
            const int sw = (nb & 7) << 3;
#pragma unroll
            for (int mk = 0; mk < 4; ++mk)
                ap[mi][mk] = *(const bf16x8*)&K_lds[nb * 128 + ((mk * 32 + lq * 8) ^ sw)];
        }
#pragma unroll
        for (int cj = 0; cj < 8; ++cj) {
            const int cl = cj * 16 + ll;
            const int sw = (cl & 7) << 3;
            bf16x8 bv[4];
#pragma unroll
            for (int mk = 0; mk < 4; ++mk)
                bv[mk] = *(const bf16x8*)&V_lds[cl * 128 + ((mk * 32 + lq * 8) ^ sw)];
#pragma unroll
            for (int mi = 0; mi < 2; ++mi)
#pragma unroll
                for (int mk = 0; mk < 4; ++mk)
                    yacc[mi][cj] = __builtin_amdgcn_mfma_f32_16x16x32_bf16(ap[mi][mk], bv[mk], yacc[mi][cj], 0, 0, 0);
        }
        __syncthreads();
    }

#pragma unroll
    for (int mi = 0; mi < 2; ++mi) {
        const int nbase = n0 + wid * 32 + mi * 16 + lq * 4;
        float inv[4];
#pragma unroll
        for (int r = 0; r < 4; ++r) inv[r] = fscale / lrun[mi * 4 + r];
#pragma unroll
        for (int cj = 0; cj < 8; ++cj) {
            const int c = cj * 16 + ll;
            float4 o;
            o.x = yacc[mi][cj][0] * inv[0];
            o.y = yacc[mi][cj][1] * inv[1];
            o.z = yacc[mi][cj][2] * inv[2];
            o.w = yacc[mi][cj][3] * inv[3];
            *(float4*)(outp + ((size_t)(b * 128 + c) << 10) + nbase) = o;
        }
    }
}

// ------------------------- final mix + mean + fc ----------------------------
__global__ __launch_bounds__(256) void final_kernel(
    const float* __restrict__ xc, const float* __restrict__ xp,
    const float* __restrict__ lamuda, const float* __restrict__ fc_w,
    float* __restrict__ outp)
{
    __shared__ float meanb[128];
    __shared__ float red[4];
    const int tid = threadIdx.x;
    const int b = blockIdx.x;
    const float lmd = 1.f / (1.f + __expf(-lamuda[0]));
    const float* xcb = xc + ((size_t)b << 17);
    const float* xpb = xp + ((size_t)b << 17);
    for (int c = 0; c < 128; ++c) {
        float4 a = *(const float4*)(xcb + ((size_t)c << 10) + tid * 4);
        float4 d = *(const float4*)(xpb + ((size_t)c << 10) + tid * 4);
        float s = lmd * (a.x + a.y + a.z + a.w) + (1.f - lmd) * (d.x + d.y + d.z + d.w);
#pragma unroll
        for (int o = 1; o < 64; o <<= 1) s += __shfl_xor(s, o);
        if ((tid & 63) == 0) red[tid >> 6] = s;
        __syncthreads();
        if (tid == 0) meanb[c] = (red[0] + red[1] + red[2] + red[3]) * (1.f / 1024.f);
        __syncthreads();
    }
    if (tid < 16) {
        float s = 0.f;
        for (int c = 0; c < 128; ++c) s += fc_w[tid * 128 + c] * meanb[c];
        outp[b * 16 + tid] = s;
    }
}

// ---------------------------------------------------------------------------
extern "C" void kernel_launch(void* const* d_in, const int* in_sizes, int n_in,
                              void* d_out, int out_size, void* d_ws, size_t ws_size,
                              hipStream_t stream)
{
    (void)in_sizes; (void)n_in; (void)out_size; (void)ws_size;

    const float* x       = (const float*)d_in[0];
    const float* ssfe_w  = (const float*)d_in[1];
    const float* ssfe_g  = (const float*)d_in[2];
    const float* ssfe_b  = (const float*)d_in[3];
    const float* cc_w    = (const float*)d_in[4];
    const float* cc_g    = (const float*)d_in[5];
    const float* cc_b    = (const float*)d_in[6];
    const float* ln1_g   = (const float*)d_in[7];
    const float* ln1_b   = (const float*)d_in[8];
    const float* qkv_w   = (const float*)d_in[9];
    const float* qkv_b   = (const float*)d_in[10];
    const float* gbn_g   = (const float*)d_in[11];
    const float* gbn_b   = (const float*)d_in[12];
    const float* qkv2_w  = (const float*)d_in[13];
    const float* qkv2_b  = (const float*)d_in[14];
    const float* ln2_g   = (const float*)d_in[15];
    const float* ln2_b   = (const float*)d_in[16];
    const float* mlp_w1  = (const float*)d_in[17];
    const float* mlp_b1  = (const float*)d_in[18];
    const float* mlp_w2  = (const float*)d_in[19];
    const float* mlp_b2  = (const float*)d_in[20];
    const float* cs_w    = (const float*)d_in[21];
    const float* cs_g    = (const float*)d_in[22];
    const float* cs_b    = (const float*)d_in[23];
    const float* lfe0_w  = (const float*)d_in[24];
    const float* lfe0_g  = (const float*)d_in[25];
    const float* lfe0_b  = (const float*)d_in[26];
    const float* s0_pi_w = (const float*)d_in[27];
    const float* s0_pi_b = (const float*)d_in[28];
    const float* s0_bn_g = (const float*)d_in[29];
    const float* s0_bn_b = (const float*)d_in[30];
    const float* s0_po_w = (const float*)d_in[31];
    const float* s0_po_b = (const float*)d_in[32];
    const float* lfe1_w  = (const float*)d_in[33];
    const float* lfe1_g  = (const float*)d_in[34];
    const float* lfe1_b  = (const float*)d_in[35];
    const float* s1_pi_w = (const float*)d_in[36];
    const float* s1_pi_b = (const float*)d_in[37];
    const float* s1_bn_g = (const float*)d_in[38];
    const float* s1_bn_b = (const float*)d_in[39];
    const float* s1_po_w = (const float*)d_in[40];
    const float* s1_po_b = (const float*)d_in[41];
    const float* lamuda  = (const float*)d_in[42];
    const float* fc_w    = (const float*)d_in[43];
    float* out = (float*)d_out;
    float* ws = (float*)d_ws;

    // workspace regions (floats)
    float* xs = ws;                    // (B,144,N) fp32; tail reused for wlfe1
    float* t  = ws + 4718592;          // (B,128,N)  residual stream / xc
    float* P1 = ws + 8912896;          // (B,128,N)
    float* Qr = ws + 13107200;         // 12.58M floats, phase-overlaid
    float* P2 = ws + 25690112;         // (B,128,N): ybuf -> mlp weights -> xp2 -> yv2
    float* P3 = ws + 29884416;         // (B,128,N): wreps + G/S/M bufs -> xp3/xp5

    // GISSA phase (Qr)
    unsigned short* curbf = (unsigned short*)Qr;               // (B,128,1024)
    unsigned short* curT  = (unsigned short*)(Qr + 2097152);   // (B,1024,128)
    unsigned short* yrbf  = (unsigned short*)(Qr + 4194304);   // (B,128,1024)
    unsigned short* yrT   = (unsigned short*)(Qr + 6291456);   // (B,1024,128)
    unsigned short* xsT   = (unsigned short*)(Qr + 8388608);   // (B,1024,160) ssfe->cs
    float* ybuf = P2;                                          // (B,128,1024) fp32

    // swsa phase (Qr overlay; GISSA bufs dead)
    unsigned short* xpT  = (unsigned short*)Qr;                // (B,1024,128) cs->lfe0
    unsigned short* qT0  = (unsigned short*)Qr;                // (B,1024,128) pi0->swsa
    unsigned short* v0   = (unsigned short*)(Qr + 2097152);    // (B,128,1024)
    unsigned short* v1   = (unsigned short*)(Qr + 4194304);    // (B,128,1024)
    unsigned short* xp3T = (unsigned short*)(Qr + 6291456);    // (B,1024,128) po0->lfe1

    // small mats in P3 (past wreps at head; consumed before po0 writes P3)
    float* Gbuf  = P3 + 1048576;
    float* Sbuf  = P3 + 1572864;
    unsigned short* M1bf = (unsigned short*)(P3 + 1576960);
    float* c1buf = P3 + 1839104;
    unsigned short* M2bf = (unsigned short*)(P3 + 1843200);
    float* c2buf = P3 + 2105344;

    unsigned short* w1bf = (unsigned short*)P2;
    unsigned short* w2bf = w1bf + 65536;

    unsigned short* wssfe = (unsigned short*)P3;             // 9*144*160
    unsigned short* wcs   = (unsigned short*)(P3 + 131072);  // 9*128*160
    unsigned short* wlfe0 = (unsigned short*)(P3 + 262144);  // 9*128*128
    unsigned short* wlfe1 = (unsigned short*)xs;             // 9*128*128

    const dim3 blk(256);

    prepack_conv_w<<<dim3((9 * 144 * 160 + 255) / 256), blk, 0, stream>>>(ssfe_w, wssfe, 144, 144, 160);
    prepack_conv_w<<<dim3((9 * 128 * 160 + 255) / 256), blk, 0, stream>>>(cs_w, wcs, 128, 144, 160);
    prepack_conv_w<<<dim3((9 * 128 * 128 + 255) / 256), blk, 0, stream>>>(lfe0_w, wlfe0, 128, 128, 128);

    // xs = cbr3(x, ssfe): fp32 + transposed bf16 (pitch 160, zero tail)
    conv3x3_stg_kernel<160, 5, 3><<<dim3(32, 8, 3), blk, 0, stream>>>(
        x, 144, wssfe, ssfe_g, ssfe_b, xs, xsT, 144, 144);
    conv1x1_kernel<<<dim3(128, 8), blk, 0, stream>>>(xs, 144, cc_w, nullptr, cc_g, cc_b, nullptr, t, nullptr, 128, 1);

    // ---- GISSA via Gram trick (MFMA applies) ----
    ln_kernel<<<dim3(128), blk, 0, stream>>>(t, ln1_g, ln1_b, curbf, curT);
    prepack_conv_w<<<dim3((9 * 128 * 128 + 255) / 256), blk, 0, stream>>>(lfe1_w, wlfe1, 128, 128, 128);
    gram_kernel<<<dim3(128), blk, 0, stream>>>(curbf, Gbuf);
    sums_kernel<<<dim3(32), blk, 0, stream>>>(curbf, Sbuf);
    mats1_kernel<<<dim3(512), dim3(64), 0, stream>>>(Gbuf, Sbuf, qkv_w, qkv_b, gbn_g, gbn_b, M1bf, c1buf);
    apply1_mfma_kernel<<<dim3(256), blk, 0, stream>>>(curT, M1bf, c1buf, ybuf, yrbf, yrT);
    gram_kernel<<<dim3(128), blk, 0, stream>>>(yrbf, Gbuf);
    sums_kernel<<<dim3(32), blk, 0, stream>>>(yrbf, Sbuf);
    mats2_kernel<<<dim3(256), blk, 0, stream>>>(Gbuf, Sbuf, qkv2_w, qkv2_b, M2bf, c2buf);
    apply2_mfma_kernel<<<dim3(256), blk, 0, stream>>>(yrT, M2bf, c2buf, ybuf, t);

    cvt_bf16_kernel<<<dim3(256), blk, 0, stream>>>(mlp_w1, w1bf, 65536);
    cvt_bf16_kernel<<<dim3(256), blk, 0, stream>>>(mlp_w2, w2bf, 65536);
    mlp_mfma_kernel<<<dim3(512), blk, 0, stream>>>(t, ln2_g, ln2_b, w1bf, mlp_b1, w2bf, mlp_b2);

    // xp = cbr3(xs, cs): direct conv from xsT -> P1 fp32 + xpT bf16
    conv3x3_dir_kernel<160, 2><<<dim3(32, 8, 4), blk, 0, stream>>>(
        xsT, wcs, cs_g, cs_b, nullptr, P1, xpT, 128);
    // xp2 = cbr3(xp, lfe0) + xp: direct conv from xpT -> P2 fp32
    conv3x3_dir_kernel<128, 2><<<dim3(32, 8, 4), blk, 0, stream>>>(
        xpT, wlfe0, lfe0_g, lfe0_b, P1, P2, nullptr, 128);
    pi_kernel<<<dim3(128, 16), blk, 0, stream>>>(P2, s0_pi_w, s0_pi_b, s0_bn_g, s0_bn_b, qT0, v0, 256, 128);
    swsa_mfma_kernel<<<dim3(256), blk, 0, stream>>>(qT0, v0, P1, 1.0f);
    // xp3 = po0(yv) + xp2 -> P3 fp32 + xp3T bf16
    conv1x1_kernel<<<dim3(128, 8), blk, 0, stream>>>(P1, 128, s0_po_w, s0_po_b, nullptr, nullptr, P2, P3, xp3T, 128, 0);
    // xp4 = cbr3(xp3, lfe1) + xp3: direct conv from xp3T -> P1 fp32
    conv3x3_dir_kernel<128, 2><<<dim3(32, 8, 4), blk, 0, stream>>>(
        xp3T, wlfe1, lfe1_g, lfe1_b, P3, P1, nullptr, 128);
    pi_kernel<<<dim3(128, 8), blk, 0, stream>>>(P1, s1_pi_w, s1_pi_b, s1_bn_g, s1_bn_b, nullptr, v1, 128, 0);
    swsa_mfma_kernel<<<dim3(256), blk, 0, stream>>>(qT0, v1, P2, 0.08838834764831845f);
    conv1x1_kernel<<<dim3(128, 8), blk, 0, stream>>>(P2, 128, s1_po_w, s1_po_b, nullptr, nullptr, P1, P3, nullptr, 128, 0);
    final_kernel<<<dim3(32), blk, 0, stream>>>(t, P3, lamuda, fc_w, out);
}

// Round 7
// 656.566 us; speedup vs baseline: 7.1530x; 1.2537x over previous
//
#include <hip/hip_runtime.h>
#include <math.h>

// ---------------------------------------------------------------------------
// EATN forward. Layout: activations (B, C, N), N = 1024 contiguous.
// B=32, C=128 (144 stem), HEADS=16, HD=8.
// Round 7: all 1x1 convs -> unified bf16 MFMA GEMM (lin_mfma); final -> 2-stage
// reduction; swsa emits bf16-T output for po; ssfe drops fp32 output.
// ---------------------------------------------------------------------------

static constexpr int NPIX = 1024;

typedef __attribute__((ext_vector_type(8))) short bf16x8;
typedef __attribute__((ext_vector_type(4))) float f32x4;
typedef __attribute__((ext_vector_type(8))) unsigned short u16x8;
typedef __attribute__((ext_vector_type(4))) unsigned short u16x4;

static __device__ __forceinline__ unsigned short f2bf(float f) {
    unsigned u = __builtin_bit_cast(unsigned, f);
    unsigned r = (u + 0x7fffu + ((u >> 16) & 1u)) >> 16;
    return (unsigned short)r;
}
static __device__ __forceinline__ float bf2f(unsigned short u) {
    unsigned v = ((unsigned)u) << 16;
    return __builtin_bit_cast(float, v);
}

// ------------------------- conv3x3 weight prepack --------------------------
__global__ __launch_bounds__(256) void prepack_conv_w(
    const float* __restrict__ w, unsigned short* __restrict__ o,
    int Cout, int CIN, int CINP)
{
    int idx = blockIdx.x * 256 + threadIdx.x;
    if (idx >= 9 * Cout * CINP) return;
    int ci = idx % CINP;
    int rem = idx / CINP;
    int co = rem % Cout;
    int tap = rem / Cout;
    float v = (ci < CIN) ? w[((size_t)co * CIN + ci) * 9 + tap] : 0.f;
    o[idx] = f2bf(v);
}

// ------------------------- all 1x1 weights prepack (one launch) ------------
// Packed layout (u16): cc[128][160] | pi0[256][128] | pi1[128][128]
//                      | po0[128][128] | po1[128][128]
__global__ __launch_bounds__(256) void prepack_all_lin(
    const float* __restrict__ cc_w, const float* __restrict__ pi0_w,
    const float* __restrict__ pi1_w, const float* __restrict__ po0_w,
    const float* __restrict__ po1_w, unsigned short* __restrict__ o)
{
    int idx = blockIdx.x * 256 + threadIdx.x;
    if (idx >= 102400) return;
    float v;
    if (idx < 20480) {
        int ci = idx % 160, co = idx / 160;
        v = (ci < 144) ? cc_w[co * 144 + ci] : 0.f;
    } else if (idx < 53248) {
        int k = idx - 20480;
        v = pi0_w[k];
    } else if (idx < 69632) {
        v = pi1_w[idx - 53248];
    } else if (idx < 86016) {
        v = po0_w[idx - 69632];
    } else {
        v = po1_w[idx - 86016];
    }
    o[idx] = f2bf(v);
}

// ------------------------- conv3x3, LDS-staged (ssfe) ----------------------
template <int CINP, int NCH, int M>
__global__ __launch_bounds__(256) void conv3x3_stg_kernel(
    const float* __restrict__ in, int CIN,
    const unsigned short* __restrict__ wrep,
    const float* __restrict__ g, const float* __restrict__ bb,
    float* __restrict__ out, unsigned short* __restrict__ outT,
    int Cout, int zcol)
{
    __shared__ unsigned short X[194 * 40];
    const int tid = threadIdx.x;
    const int b = blockIdx.x, gr = blockIdx.y, cg = blockIdx.z;
    const int co0 = cg * (M * 16);
    const int pbase = gr << 7;
    const int gbase = pbase - 33;
    const int wv = tid >> 6, lane = tid & 63;
    const int ll = lane & 15, lk = lane >> 4;
    const float* inb = in + ((size_t)b * CIN << 10);

    f32x4 acc[M][2];
#pragma unroll
    for (int i = 0; i < M; ++i)
#pragma unroll
        for (int j = 0; j < 2; ++j)
#pragma unroll
            for (int r = 0; r < 4; ++r) acc[i][j][r] = 0.f;

#pragma unroll 1
    for (int ch = 0; ch < NCH; ++ch) {
        const int c0 = ch << 5;
#pragma unroll 1
        for (int idx = tid; idx < 16 * 194; idx += 256) {
            const int ci2 = idx / 194;
            const int sp = idx - ci2 * 194;
            const int ci = c0 + ci2 * 2;
            const int gp = gbase + sp;
            const bool inr = (gp >= 0) & (gp < 1024);
            const float* p0 = inb + ((size_t)ci << 10);
            float a = (inr && ci < CIN) ? p0[gp] : 0.f;
            float c = (inr && (ci + 1) < CIN) ? p0[gp + 1024] : 0.f;
            *(unsigned*)&X[sp * 40 + ci2 * 2] =
                (unsigned)f2bf(a) | ((unsigned)f2bf(c) << 16);
        }
        __syncthreads();
#pragma unroll
        for (int tap = 0; tap < 9; ++tap) {
            const int soff = (tap / 3) * 32 + (tap % 3);
            const int dx = tap % 3;
            bf16x8 bfrag[2];
#pragma unroll
            for (int j = 0; j < 2; ++j) {
                const int p = wv * 32 + j * 16 + ll;
                bf16x8 v = *(const bf16x8*)&X[(p + soff) * 40 + lk * 8];
                const bool zed = (dx == 0 && j == 0 && ll == 0) ||
                                 (dx == 2 && j == 1 && ll == 15);
                if (zed) { bf16x8 z = {}; v = z; }
                bfrag[j] = v;
            }
            const unsigned short* wb =
                wrep + ((size_t)tap * Cout + co0) * CINP + c0 + lk * 8;
#pragma unroll
            for (int i = 0; i < M; ++i) {
                bf16x8 afr = *(const bf16x8*)(wb + (size_t)(i * 16 + ll) * CINP);
#pragma unroll
                for (int j = 0; j < 2; ++j)
                    acc[i][j] = __builtin_amdgcn_mfma_f32_16x16x32_bf16(
                        afr, bfrag[j], acc[i][j], 0, 0, 0);
            }
        }
        __syncthreads();
    }

#pragma unroll
    for (int i = 0; i < M; ++i) {
#pragma unroll
        for (int j = 0; j < 2; ++j) {
            const int px = pbase + wv * 32 + j * 16 + ll;
            u16x4 tp;
#pragma unroll
            for (int r = 0; r < 4; ++r) {
                const int co = co0 + i * 16 + lk * 4 + r;
                float v = fmaxf(acc[i][j][r] * g[co] + bb[co], 0.f);
                if (out) out[((size_t)(b * Cout + co) << 10) + px] = v;
                tp[r] = f2bf(v);
            }
            *(u16x4*)(outT + (((size_t)b << 10) + px) * CINP + co0 + i * 16 + lk * 4) = tp;
            if (cg == (int)gridDim.z - 1 && i == 0) {
                u16x4 z = {};
                *(u16x4*)(outT + (((size_t)b << 10) + px) * CINP + zcol + lk * 4) = z;
            }
        }
    }
}

// ------------------------- conv3x3, direct-global implicit GEMM ------------
template <int CINP, int M>
__global__ __launch_bounds__(256) void conv3x3_dir_kernel(
    const unsigned short* __restrict__ xT,
    const unsigned short* __restrict__ wrep,
    const float* __restrict__ g, const float* __restrict__ bb,
    const float* __restrict__ res, float* __restrict__ out,
    unsigned short* __restrict__ outT, int Cout)
{
    const int tid = threadIdx.x;
    const int b = blockIdx.x, gr = blockIdx.y, cg = blockIdx.z;
    const int co0 = cg * (M * 16);
    const int pbase = gr << 7;
    const int wv = tid >> 6, lane = tid & 63;
    const int ll = lane & 15, lq = lane >> 4;
    const unsigned short* xb = xT + ((size_t)b << 10) * CINP;

    f32x4 acc[M][2];
#pragma unroll
    for (int i = 0; i < M; ++i)
#pragma unroll
        for (int j = 0; j < 2; ++j)
#pragma unroll
            for (int r = 0; r < 4; ++r) acc[i][j][r] = 0.f;

#pragma unroll
    for (int tap = 0; tap < 9; ++tap) {
        const int dy = tap / 3, dx = tap % 3;
        const int off = (dy - 1) * 32 + (dx - 1);
        int gpc[2];
        bool val[2];
#pragma unroll
        for (int j = 0; j < 2; ++j) {
            const int px = pbase + wv * 32 + j * 16 + ll;
            const int gp = px + off;
            const bool zed = (dx == 0 && j == 0 && ll == 0) ||
                             (dx == 2 && j == 1 && ll == 15);
            val[j] = (gp >= 0) && (gp < 1024) && !zed;
            gpc[j] = min(max(gp, 0), 1023);
        }
#pragma unroll
        for (int kc = 0; kc < CINP / 32; ++kc) {
            bf16x8 bfv[2];
#pragma unroll
            for (int j = 0; j < 2; ++j) {
                bf16x8 v = *(const bf16x8*)(xb + (size_t)gpc[j] * CINP + kc * 32 + lq * 8);
                if (!val[j]) { bf16x8 z = {}; v = z; }
                bfv[j] = v;
            }
            const unsigned short* wb =
                wrep + ((size_t)tap * Cout + co0) * CINP + kc * 32 + lq * 8;
#pragma unroll
            for (int i = 0; i < M; ++i) {
                bf16x8 af = *(const bf16x8*)(wb + (size_t)(i * 16 + ll) * CINP);
#pragma unroll
                for (int j = 0; j < 2; ++j)
                    acc[i][j] = __builtin_amdgcn_mfma_f32_16x16x32_bf16(
                        af, bfv[j], acc[i][j], 0, 0, 0);
            }
        }
    }

#pragma unroll
    for (int i = 0; i < M; ++i) {
#pragma unroll
        for (int j = 0; j < 2; ++j) {
            const int px = pbase + wv * 32 + j * 16 + ll;
            u16x4 tp;
#pragma unroll
            for (int r = 0; r < 4; ++r) {
                const int co = co0 + i * 16 + lq * 4 + r;
                float v = fmaxf(acc[i][j][r] * g[co] + bb[co], 0.f);
                const size_t oi = ((size_t)(b * Cout + co) << 10) + px;
                if (res) v += res[oi];
                out[oi] = v;
                tp[r] = f2bf(v);
            }
            if (outT)
                *(u16x4*)(outT + (((size_t)b << 10) + px) * 128 + co0 + i * 16 + lq * 4) = tp;
        }
    }
}

// ------------------------- unified 1x1 via bf16 MFMA -----------------------
// xT: (B,1024,KP) bf16 px-major. wbf: (128,KP) bf16 (caller offsets for >128).
// 128 output channels per launch; grid (B, 8). Epilogue:
//   v = acc [+bias0] [*g+bb] [relu] [+res]; writes any of outF/outBF/outT.
template <int KP>
__global__ __launch_bounds__(256) void lin_mfma_kernel(
    const unsigned short* __restrict__ xT, const unsigned short* __restrict__ wbf,
    const float* __restrict__ bias0, const float* __restrict__ g,
    const float* __restrict__ bb, const float* __restrict__ res,
    float* __restrict__ outF, unsigned short* __restrict__ outBF,
    unsigned short* __restrict__ outT, int do_relu)
{
    const int tid = threadIdx.x;
    const int b = blockIdx.x;
    const int n0 = blockIdx.y << 7;
    const int wid = tid >> 6, lane = tid & 63;
    const int wr = wid >> 1, wc = wid & 1;
    const int ll = lane & 15, lq = lane >> 4;
    const unsigned short* xb = xT + (size_t)((b << 10) + n0 + wc * 64) * KP;

    f32x4 acc[4][4];
#pragma unroll
    for (int i = 0; i < 4; ++i)
#pragma unroll
        for (int j = 0; j < 4; ++j)
#pragma unroll
            for (int r = 0; r < 4; ++r) acc[i][j][r] = 0.f;

#pragma unroll
    for (int kk = 0; kk < KP / 32; ++kk) {
        bf16x8 af[4], bfv[4];
#pragma unroll
        for (int i = 0; i < 4; ++i)
            af[i] = *(const bf16x8*)(wbf + (size_t)(wr * 64 + i * 16 + ll) * KP + kk * 32 + lq * 8);
#pragma unroll
        for (int j = 0; j < 4; ++j)
            bfv[j] = *(const bf16x8*)(xb + (size_t)(j * 16 + ll) * KP + kk * 32 + lq * 8);
#pragma unroll
        for (int i = 0; i < 4; ++i)
#pragma unroll
            for (int j = 0; j < 4; ++j)
                acc[i][j] = __builtin_amdgcn_mfma_f32_16x16x32_bf16(af[i], bfv[j], acc[i][j], 0, 0, 0);
    }

#pragma unroll
    for (int i = 0; i < 4; ++i) {
        const int cob = wr * 64 + i * 16 + lq * 4;
        float b0v[4], gv[4], bv[4];
#pragma unroll
        for (int r = 0; r < 4; ++r) {
            b0v[r] = bias0 ? bias0[cob + r] : 0.f;
            gv[r] = g ? g[cob + r] : 1.f;
            bv[r] = g ? bb[cob + r] : 0.f;
        }
#pragma unroll
        for (int j = 0; j < 4; ++j) {
            const int px = n0 + wc * 64 + j * 16 + ll;
            u16x4 tp;
#pragma unroll
            for (int r = 0; r < 4; ++r) {
                const int co = cob + r;
                float v = acc[i][j][r] + b0v[r];
                v = v * gv[r] + bv[r];
                if (do_relu) v = fmaxf(v, 0.f);
                const size_t oi = ((size_t)((b << 7) + co) << 10) + px;
                if (res) v += res[oi];
                if (outF) outF[oi] = v;
                unsigned short h = f2bf(v);
                if (outBF) outBF[oi] = h;
                tp[r] = h;
            }
            if (outT)
                *(u16x4*)(outT + ((size_t)((b << 10) + px)) * 128 + cob) = tp;
        }
    }
}

// ------------------------- LayerNorm -> bf16 (ch-major + px-major) ---------
__global__ __launch_bounds__(256) void ln_kernel(
    const float* __restrict__ in, const float* __restrict__ g,
    const float* __restrict__ bb, unsigned short* __restrict__ out_bf,
    unsigned short* __restrict__ outT)
{
    const int tid = threadIdx.x;
    const int b = blockIdx.x >> 2;
    const int n = ((blockIdx.x & 3) << 8) + tid;
    const float* ib = in + ((size_t)b << 17) + n;
    float s = 0.f, sq = 0.f;
#pragma unroll 8
    for (int c = 0; c < 128; ++c) {
        float v = ib[(size_t)c << 10];
        s += v;
        sq += v * v;
    }
    const float mu = s * 0.0078125f;
    const float r = rsqrtf(sq * 0.0078125f - mu * mu + 1e-5f);
    unsigned short* obf = out_bf + ((size_t)b << 17) + n;
    unsigned short* oT = outT + (((size_t)b << 10) + n) * 128;
#pragma unroll 2
    for (int c0 = 0; c0 < 128; c0 += 8) {
        u16x8 pk;
#pragma unroll
        for (int e = 0; e < 8; ++e) {
            const int c = c0 + e;
            float v = ib[(size_t)c << 10];
            float y = (v - mu) * r * g[c] + bb[c];
            unsigned short h = f2bf(y);
            obf[(size_t)c << 10] = h;
            pk[e] = h;
        }
        *(u16x8*)(oT + c0) = pk;
    }
}

// ------------------------- Gram matrix via bf16 MFMA -----------------------
__global__ __launch_bounds__(256) void gram_kernel(
    const unsigned short* __restrict__ Xbf, float* __restrict__ G)
{
    __shared__ unsigned short Xs[128 * 128];
    const int tid = threadIdx.x;
    const int b = blockIdx.x >> 2;
    const int rg = blockIdx.x & 3;
    const int wid = tid >> 6, lane = tid & 63;
    const int lq = lane >> 4, ll = lane & 15;
    const unsigned short* Xb = Xbf + ((size_t)b << 17);

    f32x4 acc[2][2];
#pragma unroll
    for (int mi = 0; mi < 2; ++mi)
#pragma unroll
        for (int ci = 0; ci < 2; ++ci)
#pragma unroll
            for (int r = 0; r < 4; ++r) acc[mi][ci][r] = 0.f;

#pragma unroll 1
    for (int nt = 0; nt < 8; ++nt) {
        const int n0 = nt << 7;
#pragma unroll
        for (int p = 0; p < 8; ++p) {
            const int ch = (p << 4) + (tid >> 4);
            const int seg = (tid & 15) << 3;
            *(u16x8*)&Xs[ch * 128 + (seg ^ ((ch & 7) << 3))] =
                *(const u16x8*)(Xb + ((size_t)ch << 10) + n0 + seg);
        }
        __syncthreads();
#pragma unroll
        for (int ks = 0; ks < 4; ++ks) {
            bf16x8 af[2], bf_[2];
#pragma unroll
            for (int mi = 0; mi < 2; ++mi) {
                const int ar = (rg << 5) + mi * 16 + ll;
                af[mi] = *(const bf16x8*)&Xs[ar * 128 + ((ks * 32 + lq * 8) ^ ((ar & 7) << 3))];
            }
#pragma unroll
            for (int ci = 0; ci < 2; ++ci) {
                const int br = (wid << 5) + ci * 16 + ll;
                bf_[ci] = *(const bf16x8*)&Xs[br * 128 + ((ks * 32 + lq * 8) ^ ((br & 7) << 3))];
            }
#pragma unroll
            for (int mi = 0; mi < 2; ++mi)
#pragma unroll
                for (int ci = 0; ci < 2; ++ci)
                    acc[mi][ci] = __builtin_amdgcn_mfma_f32_16x16x32_bf16(
                        af[mi], bf_[ci], acc[mi][ci], 0, 0, 0);
        }
        __syncthreads();
    }
    float* Gb = G + ((size_t)b << 14);
#pragma unroll
    for (int mi = 0; mi < 2; ++mi)
#pragma unroll
        for (int ci = 0; ci < 2; ++ci)
#pragma unroll
            for (int r = 0; r < 4; ++r) {
                const int row = (rg << 5) + mi * 16 + lq * 4 + r;
                const int col = (wid << 5) + ci * 16 + ll;
                Gb[row * 128 + col] = acc[mi][ci][r];
            }
}

// ------------------------- channel row-sums of bf16 tensor -----------------
__global__ __launch_bounds__(256) void sums_kernel(
    const unsigned short* __restrict__ Xbf, float* __restrict__ S)
{
    const int tid = threadIdx.x;
    const int b = blockIdx.x;
    const int ch = tid >> 1, half = tid & 1;
    const unsigned short* p = Xbf + ((size_t)b << 17) + ((size_t)ch << 10) + half * 512;
    float s = 0.f;
#pragma unroll 4
    for (int i = 0; i < 64; ++i) {
        u16x8 v = *(const u16x8*)(p + i * 8);
#pragma unroll
        for (int e = 0; e < 8; ++e) s += bf2f(v[e]);
    }
    s += __shfl_xor(s, 1);
    if (half == 0) S[(b << 7) + ch] = s;
}

// ------------------------- GISSA stage-1 matrices (bf16 M1) ----------------
__global__ __launch_bounds__(64) void mats1_kernel(
    const float* __restrict__ G, const float* __restrict__ S,
    const float* __restrict__ qkv_w, const float* __restrict__ qkv_b,
    const float* __restrict__ g, const float* __restrict__ bb,
    unsigned short* __restrict__ M1, float* __restrict__ c1)
{
    const int lane = threadIdx.x;
    const int b = blockIdx.x >> 4, h = blockIdx.x & 15;
    const float* Gb = G + ((size_t)b << 14);
    const float* Sb = S + (b << 7);
    const int d = lane >> 3, e = lane & 7;
    const int qch = h * 8 + d, kch = 128 + h * 8 + e;
    const int qoff = (qch / 24) * 8, koff = (kch / 24) * 8;
    float wq[8], wk[8];
#pragma unroll
    for (int i = 0; i < 8; ++i) {
        wq[i] = qkv_w[qch * 8 + i];
        wk[i] = qkv_w[kch * 8 + i];
    }
    float s = 0.f;
#pragma unroll
    for (int i = 0; i < 8; ++i) {
        float gu = 0.f;
#pragma unroll
        for (int j = 0; j < 8; ++j) gu += Gb[(qoff + i) * 128 + koff + j] * wk[j];
        s += wq[i] * gu;
    }
    const float bq = qkv_b[qch], bk = qkv_b[kch];
    float swk = 0.f, swq = 0.f;
#pragma unroll
    for (int j = 0; j < 8; ++j) { swk += wk[j] * Sb[koff + j]; swq += wq[j] * Sb[qoff + j]; }
    s += bq * swk + bk * swq + 1024.f * bq * bk;
    s *= 0.35355339059327373f;
    float a = (s > 0.f) ? sqrtf(s + 1e-5f) : ((s < 0.f) ? -sqrtf(1e-5f - s) : 0.f);
    float mx = a;
    mx = fmaxf(mx, __shfl_xor(mx, 1));
    mx = fmaxf(mx, __shfl_xor(mx, 2));
    mx = fmaxf(mx, __shfl_xor(mx, 4));
    float p = __expf(a - mx);
    float den = p;
    den += __shfl_xor(den, 1);
    den += __shfl_xor(den, 2);
    den += __shfl_xor(den, 4);
    const float A = p / den;

    const int l = e;
    const int cp = d * 16 + h;
    float row[16];
#pragma unroll
    for (int j = 0; j < 16; ++j) row[j] = 0.f;
    float cacc = 0.f;
#pragma unroll
    for (int e2 = 0; e2 < 8; ++e2) {
        const float Ae = __shfl(A, d * 8 + e2);
        const int vch = 256 + h * 8 + e2;
        const int voff = (vch / 24) * 8;
        cacc += Ae * qkv_b[vch];
        if ((voff >> 4) == l) {
            const int base = voff & 15;
#pragma unroll
            for (int j = 0; j < 8; ++j) row[base + j] += Ae * qkv_w[vch * 8 + j];
        }
    }
    const int idc = h * 8 + d;
    if ((idc >> 4) == l) row[idc & 15] += 1.f;
    const float gg = g[cp];
    unsigned short* mrow = M1 + ((size_t)b << 14) + cp * 128 + l * 16;
#pragma unroll
    for (int j = 0; j < 16; ++j) mrow[j] = f2bf(gg * row[j]);
    if (l == 0) c1[(b << 7) + cp] = gg * cacc + bb[cp];
}

// ------------------------- GISSA stage-2 matrices (bf16 M2) ----------------
__global__ __launch_bounds__(256) void mats2_kernel(
    const float* __restrict__ G, const float* __restrict__ S,
    const float* __restrict__ qkv2_w, const float* __restrict__ qkv2_b,
    unsigned short* __restrict__ M2, float* __restrict__ c2)
{
    const int tid = threadIdx.x;
    const int b = blockIdx.x >> 3, d = blockIdx.x & 7;
    const float* Gb = G + ((size_t)b << 14);
    const float* Sb = S + (b << 7);
    const int h = tid >> 4, gq = tid & 15;
    const int q2ch = d * 16 + h, k2ch = 128 + d * 16 + gq;
    const int qoff = (q2ch / 48) * 16, koff = (k2ch / 48) * 16;
    float wq[16], wk[16];
#pragma unroll
    for (int i = 0; i < 16; ++i) {
        wq[i] = qkv2_w[q2ch * 16 + i];
        wk[i] = qkv2_w[k2ch * 16 + i];
    }
    float s = 0.f;
#pragma unroll
    for (int i = 0; i < 16; ++i) {
        float gu = 0.f;
#pragma unroll
        for (int j = 0; j < 16; ++j) gu += Gb[(qoff + i) * 128 + koff + j] * wk[j];
        s += wq[i] * gu;
    }
    const float bq = qkv2_b[q2ch], bk = qkv2_b[k2ch];
    float swk = 0.f, swq = 0.f;
#pragma unroll
    for (int j = 0; j < 16; ++j) { swk += wk[j] * Sb[koff + j]; swq += wq[j] * Sb[qoff + j]; }
    s += bq * swk + bk * swq + 1024.f * bq * bk;
    s *= 0.25f;
    float a = (s > 0.f) ? sqrtf(s + 1e-5f) : ((s < 0.f) ? -sqrtf(1e-5f - s) : 0.f);
    float mx = a;
    mx = fmaxf(mx, __shfl_xor(mx, 1));
    mx = fmaxf(mx, __shfl_xor(mx, 2));
    mx = fmaxf(mx, __shfl_xor(mx, 4));
    mx = fmaxf(mx, __shfl_xor(mx, 8));
    float p = __expf(a - mx);
    float den = p;
    den += __shfl_xor(den, 1);
    den += __shfl_xor(den, 2);
    den += __shfl_xor(den, 4);
    den += __shfl_xor(den, 8);
    const float A2 = p / den;

    const int l = gq;
    float row[8];
#pragma unroll
    for (int j = 0; j < 8; ++j) row[j] = 0.f;
    float cacc = 0.f;
#pragma unroll
    for (int g2 = 0; g2 < 16; ++g2) {
        const float Ag = __shfl(A2, (tid & 48) + g2);
        const int v2ch = 256 + d * 16 + g2;
        const int voff = (v2ch / 48) * 16;
        cacc += Ag * qkv2_b[v2ch];
        if ((l >> 1) == (voff >> 4)) {
            const int base = (l & 1) * 8;
#pragma unroll
            for (int j = 0; j < 8; ++j) row[j] += Ag * qkv2_w[v2ch * 16 + base + j];
        }
    }
    const int c = h * 8 + d;
    unsigned short* mrow = M2 + ((size_t)b << 14) + c * 128 + l * 8;
#pragma unroll
    for (int j = 0; j < 8; ++j) mrow[j] = f2bf(row[j]);
    if (l == 0) c2[(b << 7) + c] = cacc;
}

// ------------------------- apply1: y = M1 x + c1 (MFMA) --------------------
__global__ __launch_bounds__(256) void apply1_mfma_kernel(
    const unsigned short* __restrict__ curT, const unsigned short* __restrict__ M1bf,
    const float* __restrict__ c1, float* __restrict__ ybuf,
    unsigned short* __restrict__ yrbf, unsigned short* __restrict__ yrT)
{
    const int tid = threadIdx.x;
    const int b = blockIdx.x >> 3;
    const int n0 = (blockIdx.x & 7) << 7;
    const int wid = tid >> 6, lane = tid & 63;
    const int wr = wid >> 1, wc = wid & 1;
    const int ll = lane & 15, lq = lane >> 4;
    const unsigned short* Mb = M1bf + ((size_t)b << 14);
    const unsigned short* xb = curT + (((size_t)b << 10) + n0 + wc * 64) * 128;

    f32x4 acc[4][4];
#pragma unroll
    for (int i = 0; i < 4; ++i)
#pragma unroll
        for (int j = 0; j < 4; ++j)
#pragma unroll
            for (int r = 0; r < 4; ++r) acc[i][j][r] = 0.f;

#pragma unroll
    for (int kk = 0; kk < 4; ++kk) {
        bf16x8 af[4], bfv[4];
#pragma unroll
        for (int i = 0; i < 4; ++i)
            af[i] = *(const bf16x8*)(Mb + (size_t)(wr * 64 + i * 16 + ll) * 128 + kk * 32 + lq * 8);
#pragma unroll
        for (int j = 0; j < 4; ++j)
            bfv[j] = *(const bf16x8*)(xb + (size_t)(j * 16 + ll) * 128 + kk * 32 + lq * 8);
#pragma unroll
        for (int i = 0; i < 4; ++i)
#pragma unroll
            for (int j = 0; j < 4; ++j)
                acc[i][j] = __builtin_amdgcn_mfma_f32_16x16x32_bf16(af[i], bfv[j], acc[i][j], 0, 0, 0);
    }

#pragma unroll
    for (int i = 0; i < 4; ++i) {
        const int cob = wr * 64 + i * 16 + lq * 4;
        float c1v[4];
#pragma unroll
        for (int r = 0; r < 4; ++r) c1v[r] = c1[(b << 7) + cob + r];
#pragma unroll
        for (int j = 0; j < 4; ++j) {
            const int px = n0 + wc * 64 + j * 16 + ll;
            u16x4 tp;
#pragma unroll
            for (int r = 0; r < 4; ++r) {
                const int co = cob + r;
                const float v = acc[i][j][r] + c1v[r];
                const size_t oi = ((size_t)(b * 128 + co) << 10) + px;
                ybuf[oi] = v;
                const unsigned short h = f2bf(fmaxf(v, 0.f));
                yrbf[oi] = h;
                tp[r] = h;
            }
            *(u16x4*)(yrT + (((size_t)b << 10) + px) * 128 + cob) = tp;
        }
    }
}

// ------------------------- apply2: t += M2 relu(y) + c2 + y (MFMA) ---------
__global__ __launch_bounds__(256) void apply2_mfma_kernel(
    const unsigned short* __restrict__ yrT, const unsigned short* __restrict__ M2bf,
    const float* __restrict__ c2, const float* __restrict__ ybuf,
    float* __restrict__ t)
{
    const int tid = threadIdx.x;
    const int b = blockIdx.x >> 3;
    const int n0 = (blockIdx.x & 7) << 7;
    const int wid = tid >> 6, lane = tid & 63;
    const int wr = wid >> 1, wc = wid & 1;
    const int ll = lane & 15, lq = lane >> 4;
    const unsigned short* Mb = M2bf + ((size_t)b << 14);
    const unsigned short* xb = yrT + (((size_t)b << 10) + n0 + wc * 64) * 128;

    f32x4 acc[4][4];
#pragma unroll
    for (int i = 0; i < 4; ++i)
#pragma unroll
        for (int j = 0; j < 4; ++j)
#pragma unroll
            for (int r = 0; r < 4; ++r) acc[i][j][r] = 0.f;

#pragma unroll
    for (int kk = 0; kk < 4; ++kk) {
        bf16x8 af[4], bfv[4];
#pragma unroll
        for (int i = 0; i < 4; ++i)
            af[i] = *(const bf16x8*)(Mb + (size_t)(wr * 64 + i * 16 + ll) * 128 + kk * 32 + lq * 8);
#pragma unroll
        for (int j = 0; j < 4; ++j)
            bfv[j] = *(const bf16x8*)(xb + (size_t)(j * 16 + ll) * 128 + kk * 32 + lq * 8);
#pragma unroll
        for (int i = 0; i < 4; ++i)
#pragma unroll
            for (int j = 0; j < 4; ++j)
                acc[i][j] = __builtin_amdgcn_mfma_f32_16x16x32_bf16(af[i], bfv[j], acc[i][j], 0, 0, 0);
    }

#pragma unroll
    for (int i = 0; i < 4; ++i) {
        const int cob = wr * 64 + i * 16 + lq * 4;
        float c2v[4];
#pragma unroll
        for (int r = 0; r < 4; ++r) c2v[r] = c2[(b << 7) + cob + r];
#pragma unroll
        for (int j = 0; j < 4; ++j) {
            const int px = n0 + wc * 64 + j * 16 + ll;
#pragma unroll
            for (int r = 0; r < 4; ++r) {
                const size_t oi = ((size_t)(b * 128 + cob + r) << 10) + px;
                t[oi] += acc[i][j][r] + c2v[r] + ybuf[oi];
            }
        }
    }
}

// ------------------------- f32 -> bf16 conversion --------------------------
__global__ __launch_bounds__(256) void cvt_bf16_kernel(
    const float* __restrict__ a, unsigned short* __restrict__ o, int n)
{
    int i = blockIdx.x * 256 + threadIdx.x;
    if (i < n) o[i] = f2bf(a[i]);
}

// ------------------------- fused LN2 + MLP via bf16 MFMA -------------------
__global__ __launch_bounds__(256) void mlp_mfma_kernel(
    float* __restrict__ t, const float* __restrict__ ln_g,
    const float* __restrict__ ln_b, const unsigned short* __restrict__ w1bf,
    const float* __restrict__ b1, const unsigned short* __restrict__ w2bf,
    const float* __restrict__ b2)
{
    __shared__ unsigned char lds[16384 + 65536];
    unsigned char* xnb = lds;
    unsigned char* hb = lds + 16384;

    const int tid = threadIdx.x;
    const int b = blockIdx.x >> 4;
    const int n0 = (blockIdx.x & 15) << 6;
    float* tb = t + ((size_t)b << 17) + n0;

    {
        const int px = tid >> 2, q = tid & 3;
        float v[32];
        float s = 0.f, sq = 0.f;
#pragma unroll
        for (int k = 0; k < 32; ++k) {
            float x = tb[((size_t)(q * 32 + k) << 10) + px];
            v[k] = x;
            s += x;
            sq += x * x;
        }
        s += __shfl_xor(s, 1); s += __shfl_xor(s, 2);
        sq += __shfl_xor(sq, 1); sq += __shfl_xor(sq, 2);
        const float mu = s * 0.0078125f;
        const float rstd = rsqrtf(sq * 0.0078125f - mu * mu + 1e-5f);
        const int sw = (px & 7) << 4;
#pragma unroll
        for (int cc = 0; cc < 4; ++cc) {
            u16x8 pk;
#pragma unroll
            for (int e = 0; e < 8; ++e) {
                int c = q * 32 + cc * 8 + e;
                float xv = (v[cc * 8 + e] - mu) * rstd * ln_g[c] + ln_b[c];
                pk[e] = f2bf(xv);
            }
            *(u16x8*)(xnb + px * 256 + ((q * 64 + cc * 16) ^ sw)) = pk;
        }
    }
    __syncthreads();

    const int wid = tid >> 6, lane = tid & 63;
    const int lr = lane & 15, lk = lane >> 4;

#pragma unroll 1
    for (int pass = 0; pass < 2; ++pass) {
        const int hidbase = (wid << 7) + (pass << 6);
        f32x4 acc[4][4];
#pragma unroll
        for (int i = 0; i < 4; ++i)
#pragma unroll
            for (int j = 0; j < 4; ++j)
#pragma unroll
                for (int r = 0; r < 4; ++r) acc[i][j][r] = 0.f;
#pragma unroll
        for (int kk = 0; kk < 4; ++kk) {
            bf16x8 af[4], bfr[4];
#pragma unroll
            for (int i = 0; i < 4; ++i)
                af[i] = *(const bf16x8*)(w1bf + (size_t)(hidbase + i * 16 + lr) * 128 + kk * 32 + lk * 8);
#pragma unroll
            for (int j = 0; j < 4; ++j) {
                const int px = j * 16 + lr;
                bfr[j] = *(const bf16x8*)(xnb + px * 256 + ((kk * 64 + lk * 16) ^ ((px & 7) << 4)));
            }
#pragma unroll
            for (int i = 0; i < 4; ++i)
#pragma unroll
                for (int j = 0; j < 4; ++j)
                    acc[i][j] = __builtin_amdgcn_mfma_f32_16x16x32_bf16(af[i], bfr[j], acc[i][j], 0, 0, 0);
        }
#pragma unroll
        for (int i = 0; i < 4; ++i) {
            const int hid0 = hidbase + i * 16 + lk * 4;
            float bi[4];
#pragma unroll
            for (int r = 0; r < 4; ++r) bi[r] = b1[hid0 + r];
#pragma unroll
            for (int j = 0; j < 4; ++j) {
                const int px = j * 16 + lr;
                u16x4 pk;
#pragma unroll
                for (int r = 0; r < 4; ++r) {
                    float x = acc[i][j][r] + bi[r];
                    float u = 1.5957691f * x * (1.f + 0.044715f * x * x);
                    float gv = x / (1.f + __expf(-u));
                    pk[r] = f2bf(gv);
                }
                *(u16x4*)(hb + px * 1024 + ((hid0 * 2) ^ ((px & 7) << 4))) = pk;
            }
        }
    }
    __syncthreads();

    f32x4 acc2[2][4];
#pragma unroll
    for (int i = 0; i < 2; ++i)
#pragma unroll
        for (int j = 0; j < 4; ++j)
#pragma unroll
            for (int r = 0; r < 4; ++r) acc2[i][j][r] = 0.f;
#pragma unroll 2
    for (int ks = 0; ks < 16; ++ks) {
        bf16x8 af[2], bfr[4];
#pragma unroll
        for (int i = 0; i < 2; ++i)
            af[i] = *(const bf16x8*)(w2bf + (size_t)((wid << 5) + i * 16 + lr) * 512 + ks * 32 + lk * 8);
#pragma unroll
        for (int j = 0; j < 4; ++j) {
            const int px = j * 16 + lr;
            bfr[j] = *(const bf16x8*)(hb + px * 1024 + ((ks * 64 + lk * 16) ^ ((px & 7) << 4)));
        }
#pragma unroll
        for (int i = 0; i < 2; ++i)
#pragma unroll
            for (int j = 0; j < 4; ++j)
                acc2[i][j] = __builtin_amdgcn_mfma_f32_16x16x32_bf16(af[i], bfr[j], acc2[i][j], 0, 0, 0);
    }
#pragma unroll
    for (int i = 0; i < 2; ++i) {
        const int cb = (wid << 5) + i * 16 + lk * 4;
        float b2v[4];
#pragma unroll
        for (int r = 0; r < 4; ++r) b2v[r] = b2[cb + r];
#pragma unroll
        for (int j = 0; j < 4; ++j) {
            const int px = j * 16 + lr;
#pragma unroll
            for (int r = 0; r < 4; ++r) {
                const size_t off = ((size_t)(cb + r) << 10) + px;
                tb[off] += acc2[i][j][r] + b2v[r];
            }
        }
    }
}

// ------------------------- flash SWSA via bf16 MFMA (+bf16 T out) ----------
__global__ __launch_bounds__(256) void swsa_mfma_kernel(
    const unsigned short* __restrict__ qT, const unsigned short* __restrict__ vbf,
    float* __restrict__ outp, unsigned short* __restrict__ outT, float fscale)
{
    __shared__ unsigned short K_lds[128 * 128];
    __shared__ unsigned short V_lds[128 * 128];
    const int tid = threadIdx.x;
    const int b = blockIdx.x >> 3;
    const int n0 = (blockIdx.x & 7) << 7;
    const int wid = tid >> 6, lane = tid & 63;
    const int lq = lane >> 4, ll = lane & 15;
    const unsigned short* qTb = qT + ((size_t)b << 17);
    const unsigned short* vb = vbf + ((size_t)b << 17);

    bf16x8 aq[2][4];
#pragma unroll
    for (int mi = 0; mi < 2; ++mi) {
        const int row = n0 + wid * 32 + mi * 16 + ll;
#pragma unroll
        for (int kk = 0; kk < 4; ++kk)
            aq[mi][kk] = *(const bf16x8*)(qTb + ((size_t)row << 7) + kk * 32 + lq * 8);
    }

    float mrun[8], lrun[8];
#pragma unroll
    for (int i = 0; i < 8; ++i) { mrun[i] = -INFINITY; lrun[i] = 0.f; }
    f32x4 yacc[2][8];
#pragma unroll
    for (int mi = 0; mi < 2; ++mi)
#pragma unroll
        for (int cj = 0; cj < 8; ++cj)
#pragma unroll
            for (int r = 0; r < 4; ++r) yacc[mi][cj][r] = 0.f;

#pragma unroll 1
    for (int mt = 0; mt < 8; ++mt) {
        const int m0 = mt << 7;
        for (int ch = tid; ch < 2048; ch += 256) {
            const int rr = ch >> 4, e0 = (ch & 15) << 3;
            const int sw = (rr & 7) << 3;
            *(u16x8*)&K_lds[rr * 128 + (e0 ^ sw)] =
                *(const u16x8*)(qTb + ((size_t)(m0 + rr) << 7) + e0);
            *(u16x8*)&V_lds[rr * 128 + (e0 ^ sw)] =
                *(const u16x8*)(vb + ((size_t)rr << 10) + m0 + e0);
        }
        __syncthreads();

        f32x4 sacc[2][8];
#pragma unroll
        for (int mi = 0; mi < 2; ++mi)
#pragma unroll
            for (int j = 0; j < 8; ++j)
#pragma unroll
                for (int r = 0; r < 4; ++r) sacc[mi][j][r] = 0.f;
#pragma unroll
        for (int j = 0; j < 8; ++j) {
            const int ml = j * 16 + ll;
            const int swk = (ml & 7) << 3;
            bf16x8 bk[4];
#pragma unroll
            for (int kk = 0; kk < 4; ++kk)
                bk[kk] = *(const bf16x8*)&K_lds[ml * 128 + ((kk * 32 + lq * 8) ^ swk)];
#pragma unroll
            for (int mi = 0; mi < 2; ++mi)
#pragma unroll
                for (int kk = 0; kk < 4; ++kk)
                    sacc[mi][j] = __builtin_amdgcn_mfma_f32_16x16x32_bf16(aq[mi][kk], bk[kk], sacc[mi][j], 0, 0, 0);
        }
        __syncthreads();

        float pmax[8];
#pragma unroll
        for (int i = 0; i < 8; ++i) pmax[i] = -INFINITY;
#pragma unroll
        for (int mi = 0; mi < 2; ++mi)
#pragma unroll
            for (int j = 0; j < 8; ++j)
#pragma unroll
                for (int r = 0; r < 4; ++r) {
                    float s = sacc[mi][j][r] * 0.08838834764831845f;
                    sacc[mi][j][r] = s;
                    pmax[mi * 4 + r] = fmaxf(pmax[mi * 4 + r], s);
                }
        float alpha[8], psum[8];
#pragma unroll
        for (int i = 0; i < 8; ++i) {
            float m = pmax[i];
            m = fmaxf(m, __shfl_xor(m, 1));
            m = fmaxf(m, __shfl_xor(m, 2));
            m = fmaxf(m, __shfl_xor(m, 4));
            m = fmaxf(m, __shfl_xor(m, 8));
            const float mn = fmaxf(mrun[i], m);
            alpha[i] = __expf(mrun[i] - mn);
            mrun[i] = mn;
            psum[i] = 0.f;
        }
#pragma unroll
        for (int mi = 0; mi < 2; ++mi)
#pragma unroll
            for (int r = 0; r < 4; ++r) {
                const int nbw = wid * 32 + mi * 16 + lq * 4 + r;
                const int sw = (nbw & 7) << 3;
                const float mn = mrun[mi * 4 + r];
                float ps = 0.f;
#pragma unroll
                for (int j = 0; j < 8; ++j) {
                    float p = __expf(sacc[mi][j][r] - mn);
                    ps += p;
                    K_lds[nbw * 128 + ((j * 16 + ll) ^ sw)] = f2bf(p);
                }
                psum[mi * 4 + r] += ps;
            }
#pragma unroll
        for (int i = 0; i < 8; ++i) {
            float s = psum[i];
            s += __shfl_xor(s, 1);
            s += __shfl_xor(s, 2);
            s += __shfl_xor(s, 4);
            s += __shfl_xor(s, 8);
            lrun[i] = lrun[i] * alpha[i] + s;
        }
#pragma unroll
        for (int mi = 0; mi < 2; ++mi)
#pragma unroll
            for (int cj = 0; cj < 8; ++cj)
#pragma unroll
                for (int r = 0; r < 4; ++r) yacc[mi][cj][r] *= alpha[mi * 4 + r];

        bf16x8 ap[2][4];
#pragma unroll
        for (int mi = 0; mi < 2; ++mi) {
            const int nb = wid * 32 + mi * 16 + ll;
            const int sw = (nb & 7) << 3;
#pragma unroll
            for (int mk = 0; mk < 4; ++mk)
                ap[mi][mk] = *(const bf16x8*)&K_lds[nb * 128 + ((mk * 32 + lq * 8) ^ sw)];
        }
#pragma unroll
        for (int cj = 0; cj < 8; ++cj) {
            const int cl = cj * 16 + ll;
            const int sw = (cl & 7) << 3;
            bf16x8 bv[4];
#pragma unroll
            for (int mk = 0; mk < 4; ++mk)
                bv[mk] = *(const bf16x8*)&V_lds[cl * 128 + ((mk * 32 + lq * 8) ^ sw)];
#pragma unroll
            for (int mi = 0; mi < 2; ++mi)
#pragma unroll
                for (int mk = 0; mk < 4; ++mk)
                    yacc[mi][cj] = __builtin_amdgcn_mfma_f32_16x16x32_bf16(ap[mi][mk], bv[mk], yacc[mi][cj], 0, 0, 0);
        }
        __syncthreads();
    }

#pragma unroll
    for (int mi = 0; mi < 2; ++mi) {
        const int nbase = n0 + wid * 32 + mi * 16 + lq * 4;
        float inv[4];
#pragma unroll
        for (int r = 0; r < 4; ++r) inv[r] = fscale / lrun[mi * 4 + r];
#pragma unroll
        for (int cj = 0; cj < 8; ++cj) {
            const int c = cj * 16 + ll;
            float4 o;
            o.x = yacc[mi][cj][0] * inv[0];
            o.y = yacc[mi][cj][1] * inv[1];
            o.z = yacc[mi][cj][2] * inv[2];
            o.w = yacc[mi][cj][3] * inv[3];
            *(float4*)(outp + ((size_t)(b * 128 + c) << 10) + nbase) = o;
            if (outT) {
                unsigned short* tb = outT + ((size_t)((b << 10) + nbase)) * 128 + c;
                tb[0] = f2bf(o.x);
                tb[128] = f2bf(o.y);
                tb[256] = f2bf(o.z);
                tb[384] = f2bf(o.w);
            }
        }
    }
}

// ------------------------- final: mean (stage 1) ---------------------------
__global__ __launch_bounds__(256) void mean_kernel(
    const float* __restrict__ xc, const float* __restrict__ xp,
    const float* __restrict__ lamuda, float* __restrict__ meanb)
{
    const int wid = threadIdx.x >> 6, lane = threadIdx.x & 63;
    const int row = (blockIdx.x << 2) + wid;     // row = b*128 + c, 4096 rows
    const float lmd = 1.f / (1.f + __expf(-lamuda[0]));
    const float* a = xc + ((size_t)row << 10) + (lane << 2);
    const float* d = xp + ((size_t)row << 10) + (lane << 2);
    float s = 0.f;
#pragma unroll
    for (int i = 0; i < 4; ++i) {
        float4 va = *(const float4*)(a + (i << 8));
        float4 vd = *(const float4*)(d + (i << 8));
        s += lmd * (va.x + va.y + va.z + va.w) +
             (1.f - lmd) * (vd.x + vd.y + vd.z + vd.w);
    }
#pragma unroll
    for (int o = 1; o < 64; o <<= 1) s += __shfl_xor(s, o);
    if (lane == 0) meanb[row] = s * (1.f / 1024.f);
}

// ------------------------- final: fc (stage 2) -----------------------------
__global__ __launch_bounds__(256) void fc_kernel(
    const float* __restrict__ meanb, const float* __restrict__ fc_w,
    float* __restrict__ outp)
{
    const int idx = blockIdx.x * 256 + threadIdx.x;   // 512 pairs
    if (idx >= 512) return;
    const int b = idx >> 4, o = idx & 15;
    float s = 0.f;
#pragma unroll 4
    for (int c = 0; c < 128; ++c) s += fc_w[o * 128 + c] * meanb[b * 128 + c];
    outp[b * 16 + o] = s;
}

// ---------------------------------------------------------------------------
extern "C" void kernel_launch(void* const* d_in, const int* in_sizes, int n_in,
                              void* d_out, int out_size, void* d_ws, size_t ws_size,
                              hipStream_t stream)
{
    (void)in_sizes; (void)n_in; (void)out_size; (void)ws_size;

    const float* x       = (const float*)d_in[0];
    const float* ssfe_w  = (const float*)d_in[1];
    const float* ssfe_g  = (const float*)d_in[2];
    const float* ssfe_b  = (const float*)d_in[3];
    const float* cc_w    = (const float*)d_in[4];
    const float* cc_g    = (const float*)d_in[5];
    const float* cc_b    = (const float*)d_in[6];
    const float* ln1_g   = (const float*)d_in[7];
    const float* ln1_b   = (const float*)d_in[8];
    const float* qkv_w   = (const float*)d_in[9];
    const float* qkv_b   = (const float*)d_in[10];
    const float* gbn_g   = (const float*)d_in[11];
    const float* gbn_b   = (const float*)d_in[12];
    const float* qkv2_w  = (const float*)d_in[13];
    const float* qkv2_b  = (const float*)d_in[14];
    const float* ln2_g   = (const float*)d_in[15];
    const float* ln2_b   = (const float*)d_in[16];
    const float* mlp_w1  = (const float*)d_in[17];
    const float* mlp_b1  = (const float*)d_in[18];
    const float* mlp_w2  = (const float*)d_in[19];
    const float* mlp_b2  = (const float*)d_in[20];
    const float* cs_w    = (const float*)d_in[21];
    const float* cs_g    = (const float*)d_in[22];
    const float* cs_b    = (const float*)d_in[23];
    const float* lfe0_w  = (const float*)d_in[24];
    const float* lfe0_g  = (const float*)d_in[25];
    const float* lfe0_b  = (const float*)d_in[26];
    const float* s0_pi_w = (const float*)d_in[27];
    const float* s0_pi_b = (const float*)d_in[28];
    const float* s0_bn_g = (const float*)d_in[29];
    const float* s0_bn_b = (const float*)d_in[30];
    const float* s0_po_w = (const float*)d_in[31];
    const float* s0_po_b = (const float*)d_in[32];
    const float* lfe1_w  = (const float*)d_in[33];
    const float* lfe1_g  = (const float*)d_in[34];
    const float* lfe1_b  = (const float*)d_in[35];
    const float* s1_pi_w = (const float*)d_in[36];
    const float* s1_pi_b = (const float*)d_in[37];
    const float* s1_bn_g = (const float*)d_in[38];
    const float* s1_bn_b = (const float*)d_in[39];
    const float* s1_po_w = (const float*)d_in[40];
    const float* s1_po_b = (const float*)d_in[41];
    const float* lamuda  = (const float*)d_in[42];
    const float* fc_w    = (const float*)d_in[43];
    float* out = (float*)d_out;
    float* ws = (float*)d_ws;

    // workspace regions (floats)
    float* xs = ws;                    // scratch (wlfe1 weights)
    float* t  = ws + 4718592;          // (B,128,N) residual stream / xc
    float* P1 = ws + 8912896;          // (B,128,N)
    float* Qr = ws + 13107200;         // 12.58M floats, phase-overlaid
    float* P2 = ws + 25690112;         // (B,128,N)
    float* P3 = ws + 29884416;         // (B,128,N)

    // GISSA phase (Qr)
    unsigned short* curbf = (unsigned short*)Qr;               // (B,128,1024)
    unsigned short* curT  = (unsigned short*)(Qr + 2097152);   // (B,1024,128)
    unsigned short* yrbf  = (unsigned short*)(Qr + 4194304);   // (B,128,1024)
    unsigned short* yrT   = (unsigned short*)(Qr + 6291456);   // (B,1024,128)
    unsigned short* xsT   = (unsigned short*)(Qr + 8388608);   // (B,1024,160)
    float* ybuf = P2;                                          // (B,128,1024) fp32

    // swsa phase (Qr overlay)
    unsigned short* xpT   = (unsigned short*)Qr;               // cs->lfe0
    unsigned short* qT0   = (unsigned short*)Qr;               // pi0->swsa0/1
    unsigned short* v0    = (unsigned short*)(Qr + 2097152);
    unsigned short* yvT   = (unsigned short*)(Qr + 4194304);   // swsa0->po0
    unsigned short* v1    = (unsigned short*)(Qr + 4194304);   // pi1->swsa1 (after yvT dead)
    unsigned short* xp3T  = (unsigned short*)(Qr + 6291456);   // po0->lfe1
    unsigned short* yv2T  = (unsigned short*)(Qr + 6291456);   // swsa1->po1 (after xp3T dead)
    unsigned short* xp2T  = (unsigned short*)(Qr + 8388608);   // lfe0->pi0 (over dead xsT)
    unsigned short* xp4T  = (unsigned short*)(Qr + 8388608);   // lfe1->pi1 (over dead xp2T)

    // permanently-free Qr tail: packed 1x1 weights + meanb
    unsigned short* linw  = (unsigned short*)(Qr + 11010048);  // 102400 u16
    unsigned short* wcc   = linw;                 // [128][160]
    unsigned short* wpi0  = linw + 20480;         // [256][128]
    unsigned short* wpi1  = linw + 53248;         // [128][128]
    unsigned short* wpo0  = linw + 69632;         // [128][128]
    unsigned short* wpo1  = linw + 86016;         // [128][128]
    float* meanb = Qr + 11061248;                 // 4096 floats

    // small mats in P3 (dead before po0 writes P3)
    float* Gbuf  = P3 + 1048576;
    float* Sbuf  = P3 + 1572864;
    unsigned short* M1bf = (unsigned short*)(P3 + 1576960);
    float* c1buf = P3 + 1839104;
    unsigned short* M2bf = (unsigned short*)(P3 + 1843200);
    float* c2buf = P3 + 2105344;

    unsigned short* w1bf = (unsigned short*)P2;   // after ybuf dead
    unsigned short* w2bf = w1bf + 65536;

    unsigned short* wssfe = (unsigned short*)P3;             // 9*144*160
    unsigned short* wcs   = (unsigned short*)(P3 + 131072);  // 9*128*160
    unsigned short* wlfe0 = (unsigned short*)(P3 + 262144);  // 9*128*128
    unsigned short* wlfe1 = (unsigned short*)xs;             // 9*128*128

    const dim3 blk(256);

    prepack_conv_w<<<dim3((9 * 144 * 160 + 255) / 256), blk, 0, stream>>>(ssfe_w, wssfe, 144, 144, 160);
    prepack_conv_w<<<dim3((9 * 128 * 160 + 255) / 256), blk, 0, stream>>>(cs_w, wcs, 128, 144, 160);
    prepack_conv_w<<<dim3((9 * 128 * 128 + 255) / 256), blk, 0, stream>>>(lfe0_w, wlfe0, 128, 128, 128);
    prepack_all_lin<<<dim3(400), blk, 0, stream>>>(cc_w, s0_pi_w, s1_pi_w, s0_po_w, s1_po_w, linw);

    // xsT = cbr3(x, ssfe) (bf16 T only, pitch 160 zero-tailed)
    conv3x3_stg_kernel<160, 5, 3><<<dim3(32, 8, 3), blk, 0, stream>>>(
        x, 144, wssfe, ssfe_g, ssfe_b, nullptr, xsT, 144, 144);
    // t = cbr1(xs, cc)  [MFMA]
    lin_mfma_kernel<160><<<dim3(32, 8), blk, 0, stream>>>(
        xsT, wcc, nullptr, cc_g, cc_b, nullptr, t, nullptr, nullptr, 1);

    // ---- GISSA via Gram trick ----
    ln_kernel<<<dim3(128), blk, 0, stream>>>(t, ln1_g, ln1_b, curbf, curT);
    prepack_conv_w<<<dim3((9 * 128 * 128 + 255) / 256), blk, 0, stream>>>(lfe1_w, wlfe1, 128, 128, 128);
    gram_kernel<<<dim3(128), blk, 0, stream>>>(curbf, Gbuf);
    sums_kernel<<<dim3(32), blk, 0, stream>>>(curbf, Sbuf);
    mats1_kernel<<<dim3(512), dim3(64), 0, stream>>>(Gbuf, Sbuf, qkv_w, qkv_b, gbn_g, gbn_b, M1bf, c1buf);
    apply1_mfma_kernel<<<dim3(256), blk, 0, stream>>>(curT, M1bf, c1buf, ybuf, yrbf, yrT);
    gram_kernel<<<dim3(128), blk, 0, stream>>>(yrbf, Gbuf);
    sums_kernel<<<dim3(32), blk, 0, stream>>>(yrbf, Sbuf);
    mats2_kernel<<<dim3(256), blk, 0, stream>>>(Gbuf, Sbuf, qkv2_w, qkv2_b, M2bf, c2buf);
    apply2_mfma_kernel<<<dim3(256), blk, 0, stream>>>(yrT, M2bf, c2buf, ybuf, t);

    cvt_bf16_kernel<<<dim3(256), blk, 0, stream>>>(mlp_w1, w1bf, 65536);
    cvt_bf16_kernel<<<dim3(256), blk, 0, stream>>>(mlp_w2, w2bf, 65536);
    mlp_mfma_kernel<<<dim3(512), blk, 0, stream>>>(t, ln2_g, ln2_b, w1bf, mlp_b1, w2bf, mlp_b2);

    // xp = cbr3(xs, cs): direct conv from xsT -> P1 fp32 + xpT bf16
    conv3x3_dir_kernel<160, 2><<<dim3(32, 8, 4), blk, 0, stream>>>(
        xsT, wcs, cs_g, cs_b, nullptr, P1, xpT, 128);
    // xp2 = cbr3(xp, lfe0) + xp -> P2 fp32 + xp2T bf16
    conv3x3_dir_kernel<128, 2><<<dim3(32, 8, 4), blk, 0, stream>>>(
        xpT, wlfe0, lfe0_g, lfe0_b, P1, P2, xp2T, 128);
    // pi0: q half -> qT0 (px-major), v half -> v0 (ch-major)  [MFMA x2]
    lin_mfma_kernel<128><<<dim3(32, 8), blk, 0, stream>>>(
        xp2T, wpi0, s0_pi_b, s0_bn_g, s0_bn_b, nullptr, nullptr, nullptr, qT0, 0);
    lin_mfma_kernel<128><<<dim3(32, 8), blk, 0, stream>>>(
        xp2T, wpi0 + (size_t)128 * 128, s0_pi_b + 128, s0_bn_g + 128, s0_bn_b + 128,
        nullptr, nullptr, v0, nullptr, 0);
    swsa_mfma_kernel<<<dim3(256), blk, 0, stream>>>(qT0, v0, P1, yvT, 1.0f);
    // xp3 = po0(yv) + xp2 -> P3 fp32 + xp3T bf16  [MFMA]
    lin_mfma_kernel<128><<<dim3(32, 8), blk, 0, stream>>>(
        yvT, wpo0, s0_po_b, nullptr, nullptr, P2, P3, nullptr, xp3T, 0);
    // xp4 = cbr3(xp3, lfe1) + xp3 -> P1 fp32 + xp4T bf16
    conv3x3_dir_kernel<128, 2><<<dim3(32, 8, 4), blk, 0, stream>>>(
        xp3T, wlfe1, lfe1_g, lfe1_b, P3, P1, xp4T, 128);
    // pi1 -> v1 (ch-major)  [MFMA]
    lin_mfma_kernel<128><<<dim3(32, 8), blk, 0, stream>>>(
        xp4T, wpi1, s1_pi_b, s1_bn_g, s1_bn_b, nullptr, nullptr, v1, nullptr, 0);
    swsa_mfma_kernel<<<dim3(256), blk, 0, stream>>>(qT0, v1, P2, yv2T, 0.08838834764831845f);
    // xp5 = po1(yv2) + xp4 -> P3  [MFMA]
    lin_mfma_kernel<128><<<dim3(32, 8), blk, 0, stream>>>(
        yv2T, wpo1, s1_po_b, nullptr, nullptr, P1, P3, nullptr, nullptr, 0);

    mean_kernel<<<dim3(1024), blk, 0, stream>>>(t, P3, lamuda, meanb);
    fc_kernel<<<dim3(2), blk, 0, stream>>>(meanb, fc_w, out);
}

// Round 8
// 634.635 us; speedup vs baseline: 7.4001x; 1.0346x over previous
//
#include <hip/hip_runtime.h>
#include <math.h>

// ---------------------------------------------------------------------------
// EATN forward. Layout: activations (B, C, N), N = 1024 contiguous.
// B=32, C=128 (144 stem), HEADS=16, HD=8.
// Round 8: conv3x3_dir -> LDS-staged B-fragments (conv3x3_lds); all weight
// prepacks fused into 2 head launches; mlp weights moved to Qr tail.
// ---------------------------------------------------------------------------

static constexpr int NPIX = 1024;

typedef __attribute__((ext_vector_type(8))) short bf16x8;
typedef __attribute__((ext_vector_type(4))) float f32x4;
typedef __attribute__((ext_vector_type(8))) unsigned short u16x8;
typedef __attribute__((ext_vector_type(4))) unsigned short u16x4;

static __device__ __forceinline__ unsigned short f2bf(float f) {
    unsigned u = __builtin_bit_cast(unsigned, f);
    unsigned r = (u + 0x7fffu + ((u >> 16) & 1u)) >> 16;
    return (unsigned short)r;
}
static __device__ __forceinline__ float bf2f(unsigned short u) {
    unsigned v = ((unsigned)u) << 16;
    return __builtin_bit_cast(float, v);
}

// ------------------------- conv weight prepack (all 4, one launch) ---------
// dst layouts: [tap][co][ci_pad] bf16
__global__ __launch_bounds__(256) void prepack_convs(
    const float* __restrict__ ssfe_w, const float* __restrict__ cs_w,
    const float* __restrict__ lfe0_w, const float* __restrict__ lfe1_w,
    unsigned short* __restrict__ wssfe, unsigned short* __restrict__ wcs,
    unsigned short* __restrict__ wlfe0, unsigned short* __restrict__ wlfe1)
{
    int idx = blockIdx.x * 256 + threadIdx.x;
    const float* src;
    unsigned short* dst;
    int k, Cout, CIN, CINP;
    if (idx < 207360) {                     // ssfe: 9*144*160
        src = ssfe_w; dst = wssfe; k = idx; Cout = 144; CIN = 144; CINP = 160;
    } else if (idx < 391680) {              // cs: 9*128*160
        src = cs_w; dst = wcs; k = idx - 207360; Cout = 128; CIN = 144; CINP = 160;
    } else if (idx < 539136) {              // lfe0: 9*128*128
        src = lfe0_w; dst = wlfe0; k = idx - 391680; Cout = 128; CIN = 128; CINP = 128;
    } else if (idx < 686592) {              // lfe1
        src = lfe1_w; dst = wlfe1; k = idx - 539136; Cout = 128; CIN = 128; CINP = 128;
    } else return;
    int ci = k % CINP;
    int rem = k / CINP;
    int co = rem % Cout;
    int tap = rem / Cout;
    float v = (ci < CIN) ? src[((size_t)co * CIN + ci) * 9 + tap] : 0.f;
    dst[k] = f2bf(v);
}

// ------------------------- 1x1 + mlp weights prepack (one launch) ----------
// dst contiguous: cc[128][160] | pi0[256][128] | pi1 | po0 | po1 | w1[512][128] | w2[128][512]
__global__ __launch_bounds__(256) void prepack_lins(
    const float* __restrict__ cc_w, const float* __restrict__ pi0_w,
    const float* __restrict__ pi1_w, const float* __restrict__ po0_w,
    const float* __restrict__ po1_w, const float* __restrict__ w1,
    const float* __restrict__ w2, unsigned short* __restrict__ o)
{
    int idx = blockIdx.x * 256 + threadIdx.x;
    if (idx >= 233472) return;
    float v;
    if (idx < 20480) {
        int ci = idx % 160, co = idx / 160;
        v = (ci < 144) ? cc_w[co * 144 + ci] : 0.f;
    } else if (idx < 53248) {
        v = pi0_w[idx - 20480];
    } else if (idx < 69632) {
        v = pi1_w[idx - 53248];
    } else if (idx < 86016) {
        v = po0_w[idx - 69632];
    } else if (idx < 102400) {
        v = po1_w[idx - 86016];
    } else if (idx < 167936) {
        v = w1[idx - 102400];
    } else {
        v = w2[idx - 167936];
    }
    o[idx] = f2bf(v);
}

// ------------------------- conv3x3, LDS-staged (ssfe, fp32 in) -------------
template <int CINP, int NCH, int M>
__global__ __launch_bounds__(256) void conv3x3_stg_kernel(
    const float* __restrict__ in, int CIN,
    const unsigned short* __restrict__ wrep,
    const float* __restrict__ g, const float* __restrict__ bb,
    float* __restrict__ out, unsigned short* __restrict__ outT,
    int Cout, int zcol)
{
    __shared__ unsigned short X[194 * 40];
    const int tid = threadIdx.x;
    const int b = blockIdx.x, gr = blockIdx.y, cg = blockIdx.z;
    const int co0 = cg * (M * 16);
    const int pbase = gr << 7;
    const int gbase = pbase - 33;
    const int wv = tid >> 6, lane = tid & 63;
    const int ll = lane & 15, lk = lane >> 4;
    const float* inb = in + ((size_t)b * CIN << 10);

    f32x4 acc[M][2];
#pragma unroll
    for (int i = 0; i < M; ++i)
#pragma unroll
        for (int j = 0; j < 2; ++j)
#pragma unroll
            for (int r = 0; r < 4; ++r) acc[i][j][r] = 0.f;

#pragma unroll 1
    for (int ch = 0; ch < NCH; ++ch) {
        const int c0 = ch << 5;
#pragma unroll 1
        for (int idx = tid; idx < 16 * 194; idx += 256) {
            const int ci2 = idx / 194;
            const int sp = idx - ci2 * 194;
            const int ci = c0 + ci2 * 2;
            const int gp = gbase + sp;
            const bool inr = (gp >= 0) & (gp < 1024);
            const float* p0 = inb + ((size_t)ci << 10);
            float a = (inr && ci < CIN) ? p0[gp] : 0.f;
            float c = (inr && (ci + 1) < CIN) ? p0[gp + 1024] : 0.f;
            *(unsigned*)&X[sp * 40 + ci2 * 2] =
                (unsigned)f2bf(a) | ((unsigned)f2bf(c) << 16);
        }
        __syncthreads();
#pragma unroll
        for (int tap = 0; tap < 9; ++tap) {
            const int soff = (tap / 3) * 32 + (tap % 3);
            const int dx = tap % 3;
            bf16x8 bfrag[2];
#pragma unroll
            for (int j = 0; j < 2; ++j) {
                const int p = wv * 32 + j * 16 + ll;
                bf16x8 v = *(const bf16x8*)&X[(p + soff) * 40 + lk * 8];
                const bool zed = (dx == 0 && j == 0 && ll == 0) ||
                                 (dx == 2 && j == 1 && ll == 15);
                if (zed) { bf16x8 z = {}; v = z; }
                bfrag[j] = v;
            }
            const unsigned short* wb =
                wrep + ((size_t)tap * Cout + co0) * CINP + c0 + lk * 8;
#pragma unroll
            for (int i = 0; i < M; ++i) {
                bf16x8 afr = *(const bf16x8*)(wb + (size_t)(i * 16 + ll) * CINP);
#pragma unroll
                for (int j = 0; j < 2; ++j)
                    acc[i][j] = __builtin_amdgcn_mfma_f32_16x16x32_bf16(
                        afr, bfrag[j], acc[i][j], 0, 0, 0);
            }
        }
        __syncthreads();
    }

#pragma unroll
    for (int i = 0; i < M; ++i) {
#pragma unroll
        for (int j = 0; j < 2; ++j) {
            const int px = pbase + wv * 32 + j * 16 + ll;
            u16x4 tp;
#pragma unroll
            for (int r = 0; r < 4; ++r) {
                const int co = co0 + i * 16 + lk * 4 + r;
                float v = fmaxf(acc[i][j][r] * g[co] + bb[co], 0.f);
                if (out) out[((size_t)(b * Cout + co) << 10) + px] = v;
                tp[r] = f2bf(v);
            }
            *(u16x4*)(outT + (((size_t)b << 10) + px) * CINP + co0 + i * 16 + lk * 4) = tp;
            if (cg == (int)gridDim.z - 1 && i == 0) {
                u16x4 z = {};
                *(u16x4*)(outT + (((size_t)b << 10) + px) * CINP + zcol + lk * 4) = z;
            }
        }
    }
}

// ------------------------- conv3x3, LDS-staged from bf16 xT ----------------
// xT: (B,1024,CINP) bf16 px-major. Stage [194][CINP+8] tile once; 9 taps read
// B-frags from LDS (pitch padding makes b128 reads bank-uniform).
template <int CINP, int M>
__global__ __launch_bounds__(256) void conv3x3_lds_kernel(
    const unsigned short* __restrict__ xT,
    const unsigned short* __restrict__ wrep,
    const float* __restrict__ g, const float* __restrict__ bb,
    const float* __restrict__ res, float* __restrict__ out,
    unsigned short* __restrict__ outT, int Cout)
{
    constexpr int PITCH = CINP + 8;
    constexpr int NCHK = CINP / 8;
    __shared__ unsigned short X[194 * PITCH];
    const int tid = threadIdx.x;
    const int b = blockIdx.x, gr = blockIdx.y, cg = blockIdx.z;
    const int co0 = cg * (M * 16);
    const int pbase = gr << 7;
    const int gbase = pbase - 33;
    const int wv = tid >> 6, lane = tid & 63;
    const int ll = lane & 15, lq = lane >> 4;
    const unsigned short* xb = xT + ((size_t)b << 10) * CINP;

    // ---- stage 194 rows (coalesced u16x8 row segments, zero halo)
#pragma unroll 1
    for (int idx = tid; idx < 194 * NCHK; idx += 256) {
        const int row = idx / NCHK;
        const int chunk = idx - row * NCHK;
        const int gp = gbase + row;
        u16x8 v = {};
        if (gp >= 0 && gp < 1024)
            v = *(const u16x8*)(xb + (size_t)gp * CINP + chunk * 8);
        *(u16x8*)&X[row * PITCH + chunk * 8] = v;
    }
    __syncthreads();

    f32x4 acc[M][2];
#pragma unroll
    for (int i = 0; i < M; ++i)
#pragma unroll
        for (int j = 0; j < 2; ++j)
#pragma unroll
            for (int r = 0; r < 4; ++r) acc[i][j][r] = 0.f;

#pragma unroll
    for (int tap = 0; tap < 9; ++tap) {
        const int soff = (tap / 3) * 32 + (tap % 3);
        const int dx = tap % 3;
#pragma unroll
        for (int kc = 0; kc < CINP / 32; ++kc) {
            bf16x8 bfv[2];
#pragma unroll
            for (int j = 0; j < 2; ++j) {
                const int p = wv * 32 + j * 16 + ll;
                bf16x8 v = *(const bf16x8*)&X[(p + soff) * PITCH + kc * 32 + lq * 8];
                const bool zed = (dx == 0 && j == 0 && ll == 0) ||
                                 (dx == 2 && j == 1 && ll == 15);
                if (zed) { bf16x8 z = {}; v = z; }
                bfv[j] = v;
            }
            const unsigned short* wb =
                wrep + ((size_t)tap * Cout + co0) * CINP + kc * 32 + lq * 8;
#pragma unroll
            for (int i = 0; i < M; ++i) {
                bf16x8 af = *(const bf16x8*)(wb + (size_t)(i * 16 + ll) * CINP);
#pragma unroll
                for (int j = 0; j < 2; ++j)
                    acc[i][j] = __builtin_amdgcn_mfma_f32_16x16x32_bf16(
                        af, bfv[j], acc[i][j], 0, 0, 0);
            }
        }
    }

#pragma unroll
    for (int i = 0; i < M; ++i) {
#pragma unroll
        for (int j = 0; j < 2; ++j) {
            const int px = pbase + wv * 32 + j * 16 + ll;
            u16x4 tp;
#pragma unroll
            for (int r = 0; r < 4; ++r) {
                const int co = co0 + i * 16 + lq * 4 + r;
                float v = fmaxf(acc[i][j][r] * g[co] + bb[co], 0.f);
                const size_t oi = ((size_t)(b * Cout + co) << 10) + px;
                if (res) v += res[oi];
                out[oi] = v;
                tp[r] = f2bf(v);
            }
            if (outT)
                *(u16x4*)(outT + (((size_t)b << 10) + px) * 128 + co0 + i * 16 + lq * 4) = tp;
        }
    }
}

// ------------------------- unified 1x1 via bf16 MFMA -----------------------
template <int KP>
__global__ __launch_bounds__(256) void lin_mfma_kernel(
    const unsigned short* __restrict__ xT, const unsigned short* __restrict__ wbf,
    const float* __restrict__ bias0, const float* __restrict__ g,
    const float* __restrict__ bb, const float* __restrict__ res,
    float* __restrict__ outF, unsigned short* __restrict__ outBF,
    unsigned short* __restrict__ outT, int do_relu)
{
    const int tid = threadIdx.x;
    const int b = blockIdx.x;
    const int n0 = blockIdx.y << 7;
    const int wid = tid >> 6, lane = tid & 63;
    const int wr = wid >> 1, wc = wid & 1;
    const int ll = lane & 15, lq = lane >> 4;
    const unsigned short* xb = xT + (size_t)((b << 10) + n0 + wc * 64) * KP;

    f32x4 acc[4][4];
#pragma unroll
    for (int i = 0; i < 4; ++i)
#pragma unroll
        for (int j = 0; j < 4; ++j)
#pragma unroll
            for (int r = 0; r < 4; ++r) acc[i][j][r] = 0.f;

#pragma unroll
    for (int kk = 0; kk < KP / 32; ++kk) {
        bf16x8 af[4], bfv[4];
#pragma unroll
        for (int i = 0; i < 4; ++i)
            af[i] = *(const bf16x8*)(wbf + (size_t)(wr * 64 + i * 16 + ll) * KP + kk * 32 + lq * 8);
#pragma unroll
        for (int j = 0; j < 4; ++j)
            bfv[j] = *(const bf16x8*)(xb + (size_t)(j * 16 + ll) * KP + kk * 32 + lq * 8);
#pragma unroll
        for (int i = 0; i < 4; ++i)
#pragma unroll
            for (int j = 0; j < 4; ++j)
                acc[i][j] = __builtin_amdgcn_mfma_f32_16x16x32_bf16(af[i], bfv[j], acc[i][j], 0, 0, 0);
    }

#pragma unroll
    for (int i = 0; i < 4; ++i) {
        const int cob = wr * 64 + i * 16 + lq * 4;
        float b0v[4], gv[4], bv[4];
#pragma unroll
        for (int r = 0; r < 4; ++r) {
            b0v[r] = bias0 ? bias0[cob + r] : 0.f;
            gv[r] = g ? g[cob + r] : 1.f;
            bv[r] = g ? bb[cob + r] : 0.f;
        }
#pragma unroll
        for (int j = 0; j < 4; ++j) {
            const int px = n0 + wc * 64 + j * 16 + ll;
            u16x4 tp;
#pragma unroll
            for (int r = 0; r < 4; ++r) {
                const int co = cob + r;
                float v = acc[i][j][r] + b0v[r];
                v = v * gv[r] + bv[r];
                if (do_relu) v = fmaxf(v, 0.f);
                const size_t oi = ((size_t)((b << 7) + co) << 10) + px;
                if (res) v += res[oi];
                if (outF) outF[oi] = v;
                unsigned short h = f2bf(v);
                if (outBF) outBF[oi] = h;
                tp[r] = h;
            }
            if (outT)
                *(u16x4*)(outT + ((size_t)((b << 10) + px)) * 128 + cob) = tp;
        }
    }
}

// ------------------------- LayerNorm -> bf16 (ch-major + px-major) ---------
__global__ __launch_bounds__(256) void ln_kernel(
    const float* __restrict__ in, const float* __restrict__ g,
    const float* __restrict__ bb, unsigned short* __restrict__ out_bf,
    unsigned short* __restrict__ outT)
{
    const int tid = threadIdx.x;
    const int b = blockIdx.x >> 2;
    const int n = ((blockIdx.x & 3) << 8) + tid;
    const float* ib = in + ((size_t)b << 17) + n;
    float s = 0.f, sq = 0.f;
#pragma unroll 8
    for (int c = 0; c < 128; ++c) {
        float v = ib[(size_t)c << 10];
        s += v;
        sq += v * v;
    }
    const float mu = s * 0.0078125f;
    const float r = rsqrtf(sq * 0.0078125f - mu * mu + 1e-5f);
    unsigned short* obf = out_bf + ((size_t)b << 17) + n;
    unsigned short* oT = outT + (((size_t)b << 10) + n) * 128;
#pragma unroll 2
    for (int c0 = 0; c0 < 128; c0 += 8) {
        u16x8 pk;
#pragma unroll
        for (int e = 0; e < 8; ++e) {
            const int c = c0 + e;
            float v = ib[(size_t)c << 10];
            float y = (v - mu) * r * g[c] + bb[c];
            unsigned short h = f2bf(y);
            obf[(size_t)c << 10] = h;
            pk[e] = h;
        }
        *(u16x8*)(oT + c0) = pk;
    }
}

// ------------------------- Gram matrix via bf16 MFMA -----------------------
__global__ __launch_bounds__(256) void gram_kernel(
    const unsigned short* __restrict__ Xbf, float* __restrict__ G)
{
    __shared__ unsigned short Xs[128 * 128];
    const int tid = threadIdx.x;
    const int b = blockIdx.x >> 2;
    const int rg = blockIdx.x & 3;
    const int wid = tid >> 6, lane = tid & 63;
    const int lq = lane >> 4, ll = lane & 15;
    const unsigned short* Xb = Xbf + ((size_t)b << 17);

    f32x4 acc[2][2];
#pragma unroll
    for (int mi = 0; mi < 2; ++mi)
#pragma unroll
        for (int ci = 0; ci < 2; ++ci)
#pragma unroll
            for (int r = 0; r < 4; ++r) acc[mi][ci][r] = 0.f;

#pragma unroll 1
    for (int nt = 0; nt < 8; ++nt) {
        const int n0 = nt << 7;
#pragma unroll
        for (int p = 0; p < 8; ++p) {
            const int ch = (p << 4) + (tid >> 4);
            const int seg = (tid & 15) << 3;
            *(u16x8*)&Xs[ch * 128 + (seg ^ ((ch & 7) << 3))] =
                *(const u16x8*)(Xb + ((size_t)ch << 10) + n0 + seg);
        }
        __syncthreads();
#pragma unroll
        for (int ks = 0; ks < 4; ++ks) {
            bf16x8 af[2], bf_[2];
#pragma unroll
            for (int mi = 0; mi < 2; ++mi) {
                const int ar = (rg << 5) + mi * 16 + ll;
                af[mi] = *(const bf16x8*)&Xs[ar * 128 + ((ks * 32 + lq * 8) ^ ((ar & 7) << 3))];
            }
#pragma unroll
            for (int ci = 0; ci < 2; ++ci) {
                const int br = (wid << 5) + ci * 16 + ll;
                bf_[ci] = *(const bf16x8*)&Xs[br * 128 + ((ks * 32 + lq * 8) ^ ((br & 7) << 3))];
            }
#pragma unroll
            for (int mi = 0; mi < 2; ++mi)
#pragma unroll
                for (int ci = 0; ci < 2; ++ci)
                    acc[mi][ci] = __builtin_amdgcn_mfma_f32_16x16x32_bf16(
                        af[mi], bf_[ci], acc[mi][ci], 0, 0, 0);
        }
        __syncthreads();
    }
    float* Gb = G + ((size_t)b << 14);
#pragma unroll
    for (int mi = 0; mi < 2; ++mi)
#pragma unroll
        for (int ci = 0; ci < 2; ++ci)
#pragma unroll
            for (int r = 0; r < 4; ++r) {
                const int row = (rg << 5) + mi * 16 + lq * 4 + r;
                const int col = (wid << 5) + ci * 16 + ll;
                Gb[row * 128 + col] = acc[mi][ci][r];
            }
}

// ------------------------- channel row-sums of bf16 tensor -----------------
__global__ __launch_bounds__(256) void sums_kernel(
    const unsigned short* __restrict__ Xbf, float* __restrict__ S)
{
    const int tid = threadIdx.x;
    const int b = blockIdx.x;
    const int ch = tid >> 1, half = tid & 1;
    const unsigned short* p = Xbf + ((size_t)b << 17) + ((size_t)ch << 10) + half * 512;
    float s = 0.f;
#pragma unroll 4
    for (int i = 0; i < 64; ++i) {
        u16x8 v = *(const u16x8*)(p + i * 8);
#pragma unroll
        for (int e = 0; e < 8; ++e) s += bf2f(v[e]);
    }
    s += __shfl_xor(s, 1);
    if (half == 0) S[(b << 7) + ch] = s;
}

// ------------------------- GISSA stage-1 matrices (bf16 M1) ----------------
__global__ __launch_bounds__(64) void mats1_kernel(
    const float* __restrict__ G, const float* __restrict__ S,
    const float* __restrict__ qkv_w, const float* __restrict__ qkv_b,
    const float* __restrict__ g, const float* __restrict__ bb,
    unsigned short* __restrict__ M1, float* __restrict__ c1)
{
    const int lane = threadIdx.x;
    const int b = blockIdx.x >> 4, h = blockIdx.x & 15;
    const float* Gb = G + ((size_t)b << 14);
    const float* Sb = S + (b << 7);
    const int d = lane >> 3, e = lane & 7;
    const int qch = h * 8 + d, kch = 128 + h * 8 + e;
    const int qoff = (qch / 24) * 8, koff = (kch / 24) * 8;
    float wq[8], wk[8];
#pragma unroll
    for (int i = 0; i < 8; ++i) {
        wq[i] = qkv_w[qch * 8 + i];
        wk[i] = qkv_w[kch * 8 + i];
    }
    float s = 0.f;
#pragma unroll
    for (int i = 0; i < 8; ++i) {
        float gu = 0.f;
#pragma unroll
        for (int j = 0; j < 8; ++j) gu += Gb[(qoff + i) * 128 + koff + j] * wk[j];
        s += wq[i] * gu;
    }
    const float bq = qkv_b[qch], bk = qkv_b[kch];
    float swk = 0.f, swq = 0.f;
#pragma unroll
    for (int j = 0; j < 8; ++j) { swk += wk[j] * Sb[koff + j]; swq += wq[j] * Sb[qoff + j]; }
    s += bq * swk + bk * swq + 1024.f * bq * bk;
    s *= 0.35355339059327373f;
    float a = (s > 0.f) ? sqrtf(s + 1e-5f) : ((s < 0.f) ? -sqrtf(1e-5f - s) : 0.f);
    float mx = a;
    mx = fmaxf(mx, __shfl_xor(mx, 1));
    mx = fmaxf(mx, __shfl_xor(mx, 2));
    mx = fmaxf(mx, __shfl_xor(mx, 4));
    float p = __expf(a - mx);
    float den = p;
    den += __shfl_xor(den, 1);
    den += __shfl_xor(den, 2);
    den += __shfl_xor(den, 4);
    const float A = p / den;

    const int l = e;
    const int cp = d * 16 + h;
    float row[16];
#pragma unroll
    for (int j = 0; j < 16; ++j) row[j] = 0.f;
    float cacc = 0.f;
#pragma unroll
    for (int e2 = 0; e2 < 8; ++e2) {
        const float Ae = __shfl(A, d * 8 + e2);
        const int vch = 256 + h * 8 + e2;
        const int voff = (vch / 24) * 8;
        cacc += Ae * qkv_b[vch];
        if ((voff >> 4) == l) {
            const int base = voff & 15;
#pragma unroll
            for (int j = 0; j < 8; ++j) row[base + j] += Ae * qkv_w[vch * 8 + j];
        }
    }
    const int idc = h * 8 + d;
    if ((idc >> 4) == l) row[idc & 15] += 1.f;
    const float gg = g[cp];
    unsigned short* mrow = M1 + ((size_t)b << 14) + cp * 128 + l * 16;
#pragma unroll
    for (int j = 0; j < 16; ++j) mrow[j] = f2bf(gg * row[j]);
    if (l == 0) c1[(b << 7) + cp] = gg * cacc + bb[cp];
}

// ------------------------- GISSA stage-2 matrices (bf16 M2) ----------------
__global__ __launch_bounds__(256) void mats2_kernel(
    const float* __restrict__ G, const float* __restrict__ S,
    const float* __restrict__ qkv2_w, const float* __restrict__ qkv2_b,
    unsigned short* __restrict__ M2, float* __restrict__ c2)
{
    const int tid = threadIdx.x;
    const int b = blockIdx.x >> 3, d = blockIdx.x & 7;
    const float* Gb = G + ((size_t)b << 14);
    const float* Sb = S + (b << 7);
    const int h = tid >> 4, gq = tid & 15;
    const int q2ch = d * 16 + h, k2ch = 128 + d * 16 + gq;
    const int qoff = (q2ch / 48) * 16, koff = (k2ch / 48) * 16;
    float wq[16], wk[16];
#pragma unroll
    for (int i = 0; i < 16; ++i) {
        wq[i] = qkv2_w[q2ch * 16 + i];
        wk[i] = qkv2_w[k2ch * 16 + i];
    }
    float s = 0.f;
#pragma unroll
    for (int i = 0; i < 16; ++i) {
        float gu = 0.f;
#pragma unroll
        for (int j = 0; j < 16; ++j) gu += Gb[(qoff + i) * 128 + koff + j] * wk[j];
        s += wq[i] * gu;
    }
    const float bq = qkv2_b[q2ch], bk = qkv2_b[k2ch];
    float swk = 0.f, swq = 0.f;
#pragma unroll
    for (int j = 0; j < 16; ++j) { swk += wk[j] * Sb[koff + j]; swq += wq[j] * Sb[qoff + j]; }
    s += bq * swk + bk * swq + 1024.f * bq * bk;
    s *= 0.25f;
    float a = (s > 0.f) ? sqrtf(s + 1e-5f) : ((s < 0.f) ? -sqrtf(1e-5f - s) : 0.f);
    float mx = a;
    mx = fmaxf(mx, __shfl_xor(mx, 1));
    mx = fmaxf(mx, __shfl_xor(mx, 2));
    mx = fmaxf(mx, __shfl_xor(mx, 4));
    mx = fmaxf(mx, __shfl_xor(mx, 8));
    float p = __expf(a - mx);
    float den = p;
    den += __shfl_xor(den, 1);
    den += __shfl_xor(den, 2);
    den += __shfl_xor(den, 4);
    den += __shfl_xor(den, 8);
    const float A2 = p / den;

    const int l = gq;
    float row[8];
#pragma unroll
    for (int j = 0; j < 8; ++j) row[j] = 0.f;
    float cacc = 0.f;
#pragma unroll
    for (int g2 = 0; g2 < 16; ++g2) {
        const float Ag = __shfl(A2, (tid & 48) + g2);
        const int v2ch = 256 + d * 16 + g2;
        const int voff = (v2ch / 48) * 16;
        cacc += Ag * qkv2_b[v2ch];
        if ((l >> 1) == (voff >> 4)) {
            const int base = (l & 1) * 8;
#pragma unroll
            for (int j = 0; j < 8; ++j) row[j] += Ag * qkv2_w[v2ch * 16 + base + j];
        }
    }
    const int c = h * 8 + d;
    unsigned short* mrow = M2 + ((size_t)b << 14) + c * 128 + l * 8;
#pragma unroll
    for (int j = 0; j < 8; ++j) mrow[j] = f2bf(row[j]);
    if (l == 0) c2[(b << 7) + c] = cacc;
}

// ------------------------- apply1: y = M1 x + c1 (MFMA) --------------------
__global__ __launch_bounds__(256) void apply1_mfma_kernel(
    const unsigned short* __restrict__ curT, const unsigned short* __restrict__ M1bf,
    const float* __restrict__ c1, float* __restrict__ ybuf,
    unsigned short* __restrict__ yrbf, unsigned short* __restrict__ yrT)
{
    const int tid = threadIdx.x;
    const int b = blockIdx.x >> 3;
    const int n0 = (blockIdx.x & 7) << 7;
    const int wid = tid >> 6, lane = tid & 63;
    const int wr = wid >> 1, wc = wid & 1;
    const int ll = lane & 15, lq = lane >> 4;
    const unsigned short* Mb = M1bf + ((size_t)b << 14);
    const unsigned short* xb = curT + (((size_t)b << 10) + n0 + wc * 64) * 128;

    f32x4 acc[4][4];
#pragma unroll
    for (int i = 0; i < 4; ++i)
#pragma unroll
        for (int j = 0; j < 4; ++j)
#pragma unroll
            for (int r = 0; r < 4; ++r) acc[i][j][r] = 0.f;

#pragma unroll
    for (int kk = 0; kk < 4; ++kk) {
        bf16x8 af[4], bfv[4];
#pragma unroll
        for (int i = 0; i < 4; ++i)
            af[i] = *(const bf16x8*)(Mb + (size_t)(wr * 64 + i * 16 + ll) * 128 + kk * 32 + lq * 8);
#pragma unroll
        for (int j = 0; j < 4; ++j)
            bfv[j] = *(const bf16x8*)(xb + (size_t)(j * 16 + ll) * 128 + kk * 32 + lq * 8);
#pragma unroll
        for (int i = 0; i < 4; ++i)
#pragma unroll
            for (int j = 0; j < 4; ++j)
                acc[i][j] = __builtin_amdgcn_mfma_f32_16x16x32_bf16(af[i], bfv[j], acc[i][j], 0, 0, 0);
    }

#pragma unroll
    for (int i = 0; i < 4; ++i) {
        const int cob = wr * 64 + i * 16 + lq * 4;
        float c1v[4];
#pragma unroll
        for (int r = 0; r < 4; ++r) c1v[r] = c1[(b << 7) + cob + r];
#pragma unroll
        for (int j = 0; j < 4; ++j) {
            const int px = n0 + wc * 64 + j * 16 + ll;
            u16x4 tp;
#pragma unroll
            for (int r = 0; r < 4; ++r) {
                const int co = cob + r;
                const float v = acc[i][j][r] + c1v[r];
                const size_t oi = ((size_t)(b * 128 + co) << 10) + px;
                ybuf[oi] = v;
                const unsigned short h = f2bf(fmaxf(v, 0.f));
                yrbf[oi] = h;
                tp[r] = h;
            }
            *(u16x4*)(yrT + (((size_t)b << 10) + px) * 128 + cob) = tp;
        }
    }
}

// ------------------------- apply2: t += M2 relu(y) + c2 + y (MFMA) ---------
__global__ __launch_bounds__(256) void apply2_mfma_kernel(
    const unsigned short* __restrict__ yrT, const unsigned short* __restrict__ M2bf,
    const float* __restrict__ c2, const float* __restrict__ ybuf,
    float* __restrict__ t)
{
    const int tid = threadIdx.x;
    const int b = blockIdx.x >> 3;
    const int n0 = (blockIdx.x & 7) << 7;
    const int wid = tid >> 6, lane = tid & 63;
    const int wr = wid >> 1, wc = wid & 1;
    const int ll = lane & 15, lq = lane >> 4;
    const unsigned short* Mb = M2bf + ((size_t)b << 14);
    const unsigned short* xb = yrT + (((size_t)b << 10) + n0 + wc * 64) * 128;

    f32x4 acc[4][4];
#pragma unroll
    for (int i = 0; i < 4; ++i)
#pragma unroll
        for (int j = 0; j < 4; ++j)
#pragma unroll
            for (int r = 0; r < 4; ++r) acc[i][j][r] = 0.f;

#pragma unroll
    for (int kk = 0; kk < 4; ++kk) {
        bf16x8 af[4], bfv[4];
#pragma unroll
        for (int i = 0; i < 4; ++i)
            af[i] = *(const bf16x8*)(Mb + (size_t)(wr * 64 + i * 16 + ll) * 128 + kk * 32 + lq * 8);
#pragma unroll
        for (int j = 0; j < 4; ++j)
            bfv[j] = *(const bf16x8*)(xb + (size_t)(j * 16 + ll) * 128 + kk * 32 + lq * 8);
#pragma unroll
        for (int i = 0; i < 4; ++i)
#pragma unroll
            for (int j = 0; j < 4; ++j)
                acc[i][j] = __builtin_amdgcn_mfma_f32_16x16x32_bf16(af[i], bfv[j], acc[i][j], 0, 0, 0);
    }

#pragma unroll
    for (int i = 0; i < 4; ++i) {
        const int cob = wr * 64 + i * 16 + lq * 4;
        float c2v[4];
#pragma unroll
        for (int r = 0; r < 4; ++r) c2v[r] = c2[(b << 7) + cob + r];
#pragma unroll
        for (int j = 0; j < 4; ++j) {
            const int px = n0 + wc * 64 + j * 16 + ll;
#pragma unroll
            for (int r = 0; r < 4; ++r) {
                const size_t oi = ((size_t)(b * 128 + cob + r) << 10) + px;
                t[oi] += acc[i][j][r] + c2v[r] + ybuf[oi];
            }
        }
    }
}

// ------------------------- fused LN2 + MLP via bf16 MFMA -------------------
__global__ __launch_bounds__(256) void mlp_mfma_kernel(
    float* __restrict__ t, const float* __restrict__ ln_g,
    const float* __restrict__ ln_b, const unsigned short* __restrict__ w1bf,
    const float* __restrict__ b1, const unsigned short* __restrict__ w2bf,
    const float* __restrict__ b2)
{
    __shared__ unsigned char lds[16384 + 65536];
    unsigned char* xnb = lds;
    unsigned char* hb = lds + 16384;

    const int tid = threadIdx.x;
    const int b = blockIdx.x >> 4;
    const int n0 = (blockIdx.x & 15) << 6;
    float* tb = t + ((size_t)b << 17) + n0;

    {
        const int px = tid >> 2, q = tid & 3;
        float v[32];
        float s = 0.f, sq = 0.f;
#pragma unroll
        for (int k = 0; k < 32; ++k) {
            float x = tb[((size_t)(q * 32 + k) << 10) + px];
            v[k] = x;
            s += x;
            sq += x * x;
        }
        s += __shfl_xor(s, 1); s += __shfl_xor(s, 2);
        sq += __shfl_xor(sq, 1); sq += __shfl_xor(sq, 2);
        const float mu = s * 0.0078125f;
        const float rstd = rsqrtf(sq * 0.0078125f - mu * mu + 1e-5f);
        const int sw = (px & 7) << 4;
#pragma unroll
        for (int cc = 0; cc < 4; ++cc) {
            u16x8 pk;
#pragma unroll
            for (int e = 0; e < 8; ++e) {
                int c = q * 32 + cc * 8 + e;
                float xv = (v[cc * 8 + e] - mu) * rstd * ln_g[c] + ln_b[c];
                pk[e] = f2bf(xv);
            }
            *(u16x8*)(xnb + px * 256 + ((q * 64 + cc * 16) ^ sw)) = pk;
        }
    }
    __syncthreads();

    const int wid = tid >> 6, lane = tid & 63;
    const int lr = lane & 15, lk = lane >> 4;

#pragma unroll 1
    for (int pass = 0; pass < 2; ++pass) {
        const int hidbase = (wid << 7) + (pass << 6);
        f32x4 acc[4][4];
#pragma unroll
        for (int i = 0; i < 4; ++i)
#pragma unroll
            for (int j = 0; j < 4; ++j)
#pragma unroll
                for (int r = 0; r < 4; ++r) acc[i][j][r] = 0.f;
#pragma unroll
        for (int kk = 0; kk < 4; ++kk) {
            bf16x8 af[4], bfr[4];
#pragma unroll
            for (int i = 0; i < 4; ++i)
                af[i] = *(const bf16x8*)(w1bf + (size_t)(hidbase + i * 16 + lr) * 128 + kk * 32 + lk * 8);
#pragma unroll
            for (int j = 0; j < 4; ++j) {
                const int px = j * 16 + lr;
                bfr[j] = *(const bf16x8*)(xnb + px * 256 + ((kk * 64 + lk * 16) ^ ((px & 7) << 4)));
            }
#pragma unroll
            for (int i = 0; i < 4; ++i)
#pragma unroll
                for (int j = 0; j < 4; ++j)
                    acc[i][j] = __builtin_amdgcn_mfma_f32_16x16x32_bf16(af[i], bfr[j], acc[i][j], 0, 0, 0);
        }
#pragma unroll
        for (int i = 0; i < 4; ++i) {
            const int hid0 = hidbase + i * 16 + lk * 4;
            float bi[4];
#pragma unroll
            for (int r = 0; r < 4; ++r) bi[r] = b1[hid0 + r];
#pragma unroll
            for (int j = 0; j < 4; ++j) {
                const int px = j * 16 + lr;
                u16x4 pk;
#pragma unroll
                for (int r = 0; r < 4; ++r) {
                    float x = acc[i][j][r] + bi[r];
                    float u = 1.5957691f * x * (1.f + 0.044715f * x * x);
                    float gv = x / (1.f + __expf(-u));
                    pk[r] = f2bf(gv);
                }
                *(u16x4*)(hb + px * 1024 + ((hid0 * 2) ^ ((px & 7) << 4))) = pk;
            }
        }
    }
    __syncthreads();

    f32x4 acc2[2][4];
#pragma unroll
    for (int i = 0; i < 2; ++i)
#pragma unroll
        for (int j = 0; j < 4; ++j)
#pragma unroll
            for (int r = 0; r < 4; ++r) acc2[i][j][r] = 0.f;
#pragma unroll 2
    for (int ks = 0; ks < 16; ++ks) {
        bf16x8 af[2], bfr[4];
#pragma unroll
        for (int i = 0; i < 2; ++i)
            af[i] = *(const bf16x8*)(w2bf + (size_t)((wid << 5) + i * 16 + lr) * 512 + ks * 32 + lk * 8);
#pragma unroll
        for (int j = 0; j < 4; ++j) {
            const int px = j * 16 + lr;
            bfr[j] = *(const bf16x8*)(hb + px * 1024 + ((ks * 64 + lk * 16) ^ ((px & 7) << 4)));
        }
#pragma unroll
        for (int i = 0; i < 2; ++i)
#pragma unroll
            for (int j = 0; j < 4; ++j)
                acc2[i][j] = __builtin_amdgcn_mfma_f32_16x16x32_bf16(af[i], bfr[j], acc2[i][j], 0, 0, 0);
    }
#pragma unroll
    for (int i = 0; i < 2; ++i) {
        const int cb = (wid << 5) + i * 16 + lk * 4;
        float b2v[4];
#pragma unroll
        for (int r = 0; r < 4; ++r) b2v[r] = b2[cb + r];
#pragma unroll
        for (int j = 0; j < 4; ++j) {
            const int px = j * 16 + lr;
#pragma unroll
            for (int r = 0; r < 4; ++r) {
                const size_t off = ((size_t)(cb + r) << 10) + px;
                tb[off] += acc2[i][j][r] + b2v[r];
            }
        }
    }
}

// ------------------------- flash SWSA via bf16 MFMA (+bf16 T out) ----------
__global__ __launch_bounds__(256) void swsa_mfma_kernel(
    const unsigned short* __restrict__ qT, const unsigned short* __restrict__ vbf,
    float* __restrict__ outp, unsigned short* __restrict__ outT, float fscale)
{
    __shared__ unsigned short K_lds[128 * 128];
    __shared__ unsigned short V_lds[128 * 128];
    const int tid = threadIdx.x;
    const int b = blockIdx.x >> 3;
    const int n0 = (blockIdx.x & 7) << 7;
    const int wid = tid >> 6, lane = tid & 63;
    const int lq = lane >> 4, ll = lane & 15;
    const unsigned short* qTb = qT + ((size_t)b << 17);
    const unsigned short* vb = vbf + ((size_t)b << 17);

    bf16x8 aq[2][4];
#pragma unroll
    for (int mi = 0; mi < 2; ++mi) {
        const int row = n0 + wid * 32 + mi * 16 + ll;
#pragma unroll
        for (int kk = 0; kk < 4; ++kk)
            aq[mi][kk] = *(const bf16x8*)(qTb + ((size_t)row << 7) + kk * 32 + lq * 8);
    }

    float mrun[8], lrun[8];
#pragma unroll
    for (int i = 0; i < 8; ++i) { mrun[i] = -INFINITY; lrun[i] = 0.f; }
    f32x4 yacc[2][8];
#pragma unroll
    for (int mi = 0; mi < 2; ++mi)
#pragma unroll
        for (int cj = 0; cj < 8; ++cj)
#pragma unroll
            for (int r = 0; r < 4; ++r) yacc[mi][cj][r] = 0.f;

#pragma unroll 1
    for (int mt = 0; mt < 8; ++mt) {
        const int m0 = mt << 7;
        for (int ch = tid; ch < 2048; ch += 256) {
            const int rr = ch >> 4, e0 = (ch & 15) << 3;
            const int sw = (rr & 7) << 3;
            *(u16x8*)&K_lds[rr * 128 + (e0 ^ sw)] =
                *(const u16x8*)(qTb + ((size_t)(m0 + rr) << 7) + e0);
            *(u16x8*)&V_lds[rr * 128 + (e0 ^ sw)] =
                *(const u16x8*)(vb + ((size_t)rr << 10) + m0 + e0);
        }
        __syncthreads();

        f32x4 sacc[2][8];
#pragma unroll
        for (int mi = 0; mi < 2; ++mi)
#pragma unroll
            for (int j = 0; j < 8; ++j)
#pragma unroll
                for (int r = 0; r < 4; ++r) sacc[mi][j][r] = 0.f;
#pragma unroll
        for (int j = 0; j < 8; ++j) {
            const int ml = j * 16 + ll;
            const int swk = (ml & 7) << 3;
            bf16x8 bk[4];
#pragma unroll
            for (int kk = 0; kk < 4; ++kk)
                bk[kk] = *(const bf16x8*)&K_lds[ml * 128 + ((kk * 32 + lq * 8) ^ swk)];
#pragma unroll
            for (int mi = 0; mi < 2; ++mi)
#pragma unroll
                for (int kk = 0; kk < 4; ++kk)
                    sacc[mi][j] = __builtin_amdgcn_mfma_f32_16x16x32_bf16(aq[mi][kk], bk[kk], sacc[mi][j], 0, 0, 0);
        }
        __syncthreads();

        float pmax[8];
#pragma unroll
        for (int i = 0; i < 8; ++i) pmax[i] = -INFINITY;
#pragma unroll
        for (int mi = 0; mi < 2; ++mi)
#pragma unroll
            for (int j = 0; j < 8; ++j)
#pragma unroll
                for (int r = 0; r < 4; ++r) {
                    float s = sacc[mi][j][r] * 0.08838834764831845f;
                    sacc[mi][j][r] = s;
                    pmax[mi * 4 + r] = fmaxf(pmax[mi * 4 + r], s);
                }
        float alpha[8], psum[8];
#pragma unroll
        for (int i = 0; i < 8; ++i) {
            float m = pmax[i];
            m = fmaxf(m, __shfl_xor(m, 1));
            m = fmaxf(m, __shfl_xor(m, 2));
            m = fmaxf(m, __shfl_xor(m, 4));
            m = fmaxf(m, __shfl_xor(m, 8));
            const float mn = fmaxf(mrun[i], m);
            alpha[i] = __expf(mrun[i] - mn);
            mrun[i] = mn;
            psum[i] = 0.f;
        }
#pragma unroll
        for (int mi = 0; mi < 2; ++mi)
#pragma unroll
            for (int r = 0; r < 4; ++r) {
                const int nbw = wid * 32 + mi * 16 + lq * 4 + r;
                const int sw = (nbw & 7) << 3;
                const float mn = mrun[mi * 4 + r];
                float ps = 0.f;
#pragma unroll
                for (int j = 0; j < 8; ++j) {
                    float p = __expf(sacc[mi][j][r] - mn);
                    ps += p;
                    K_lds[nbw * 128 + ((j * 16 + ll) ^ sw)] = f2bf(p);
                }
                psum[mi * 4 + r] += ps;
            }
#pragma unroll
        for (int i = 0; i < 8; ++i) {
            float s = psum[i];
            s += __shfl_xor(s, 1);
            s += __shfl_xor(s, 2);
            s += __shfl_xor(s, 4);
            s += __shfl_xor(s, 8);
            lrun[i] = lrun[i] * alpha[i] + s;
        }
#pragma unroll
        for (int mi = 0; mi < 2; ++mi)
#pragma unroll
            for (int cj = 0; cj < 8; ++cj)
#pragma unroll
                for (int r = 0; r < 4; ++r) yacc[mi][cj][r] *= alpha[mi * 4 + r];

        bf16x8 ap[2][4];
#pragma unroll
        for (int mi = 0; mi < 2; ++mi) {
            const int nb = wid * 32 + mi * 16 + ll;
            const int sw = (nb & 7) << 3;
#pragma unroll
            for (int mk = 0; mk < 4; ++mk)
                ap[mi][mk] = *(const bf16x8*)&K_lds[nb * 128 + ((mk * 32 + lq * 8) ^ sw)];
        }
#pragma unroll
        for (int cj = 0; cj < 8; ++cj) {
            const int cl = cj * 16 + ll;
            const int sw = (cl & 7) << 3;
            bf16x8 bv[4];
#pragma unroll
            for (int mk = 0; mk < 4; ++mk)
                bv[mk] = *(const bf16x8*)&V_lds[cl * 128 + ((mk * 32 + lq * 8) ^ sw)];
#pragma unroll
            for (int mi = 0; mi < 2; ++mi)
#pragma unroll
                for (int mk = 0; mk < 4; ++mk)
                    yacc[mi][cj] = __builtin_amdgcn_mfma_f32_16x16x32_bf16(ap[mi][mk], bv[mk], yacc[mi][cj], 0, 0, 0);
        }
        __syncthreads();
    }

#pragma unroll
    for (int mi = 0; mi < 2; ++mi) {
        const int nbase = n0 + wid * 32 + mi * 16 + lq * 4;
        float inv[4];
#pragma unroll
        for (int r = 0; r < 4; ++r) inv[r] = fscale / lrun[mi * 4 + r];
#pragma unroll
        for (int cj = 0; cj < 8; ++cj) {
            const int c = cj * 16 + ll;
            float4 o;
            o.x = yacc[mi][cj][0] * inv[0];
            o.y = yacc[mi][cj][1] * inv[1];
            o.z = yacc[mi][cj][2] * inv[2];
            o.w = yacc[mi][cj][3] * inv[3];
            *(float4*)(outp + ((size_t)(b * 128 + c) << 10) + nbase) = o;
            if (outT) {
                unsigned short* tb = outT + ((size_t)((b << 10) + nbase)) * 128 + c;
                tb[0] = f2bf(o.x);
                tb[128] = f2bf(o.y);
                tb[256] = f2bf(o.z);
                tb[384] = f2bf(o.w);
            }
        }
    }
}

// ------------------------- final: mean (stage 1) ---------------------------
__global__ __launch_bounds__(256) void mean_kernel(
    const float* __restrict__ xc, const float* __restrict__ xp,
    const float* __restrict__ lamuda, float* __restrict__ meanb)
{
    const int wid = threadIdx.x >> 6, lane = threadIdx.x & 63;
    const int row = (blockIdx.x << 2) + wid;
    const float lmd = 1.f / (1.f + __expf(-lamuda[0]));
    const float* a = xc + ((size_t)row << 10) + (lane << 2);
    const float* d = xp + ((size_t)row << 10) + (lane << 2);
    float s = 0.f;
#pragma unroll
    for (int i = 0; i < 4; ++i) {
        float4 va = *(const float4*)(a + (i << 8));
        float4 vd = *(const float4*)(d + (i << 8));
        s += lmd * (va.x + va.y + va.z + va.w) +
             (1.f - lmd) * (vd.x + vd.y + vd.z + vd.w);
    }
#pragma unroll
    for (int o = 1; o < 64; o <<= 1) s += __shfl_xor(s, o);
    if (lane == 0) meanb[row] = s * (1.f / 1024.f);
}

// ------------------------- final: fc (stage 2) -----------------------------
__global__ __launch_bounds__(256) void fc_kernel(
    const float* __restrict__ meanb, const float* __restrict__ fc_w,
    float* __restrict__ outp)
{
    const int idx = blockIdx.x * 256 + threadIdx.x;
    if (idx >= 512) return;
    const int b = idx >> 4, o = idx & 15;
    float s = 0.f;
#pragma unroll 4
    for (int c = 0; c < 128; ++c) s += fc_w[o * 128 + c] * meanb[b * 128 + c];
    outp[b * 16 + o] = s;
}

// ---------------------------------------------------------------------------
extern "C" void kernel_launch(void* const* d_in, const int* in_sizes, int n_in,
                              void* d_out, int out_size, void* d_ws, size_t ws_size,
                              hipStream_t stream)
{
    (void)in_sizes; (void)n_in; (void)out_size; (void)ws_size;

    const float* x       = (const float*)d_in[0];
    const float* ssfe_w  = (const float*)d_in[1];
    const float* ssfe_g  = (const float*)d_in[2];
    const float* ssfe_b  = (const float*)d_in[3];
    const float* cc_w    = (const float*)d_in[4];
    const float* cc_g    = (const float*)d_in[5];
    const float* cc_b    = (const float*)d_in[6];
    const float* ln1_g   = (const float*)d_in[7];
    const float* ln1_b   = (const float*)d_in[8];
    const float* qkv_w   = (const float*)d_in[9];
    const float* qkv_b   = (const float*)d_in[10];
    const float* gbn_g   = (const float*)d_in[11];
    const float* gbn_b   = (const float*)d_in[12];
    const float* qkv2_w  = (const float*)d_in[13];
    const float* qkv2_b  = (const float*)d_in[14];
    const float* ln2_g   = (const float*)d_in[15];
    const float* ln2_b   = (const float*)d_in[16];
    const float* mlp_w1  = (const float*)d_in[17];
    const float* mlp_b1  = (const float*)d_in[18];
    const float* mlp_w2  = (const float*)d_in[19];
    const float* mlp_b2  = (const float*)d_in[20];
    const float* cs_w    = (const float*)d_in[21];
    const float* cs_g    = (const float*)d_in[22];
    const float* cs_b    = (const float*)d_in[23];
    const float* lfe0_w  = (const float*)d_in[24];
    const float* lfe0_g  = (const float*)d_in[25];
    const float* lfe0_b  = (const float*)d_in[26];
    const float* s0_pi_w = (const float*)d_in[27];
    const float* s0_pi_b = (const float*)d_in[28];
    const float* s0_bn_g = (const float*)d_in[29];
    const float* s0_bn_b = (const float*)d_in[30];
    const float* s0_po_w = (const float*)d_in[31];
    const float* s0_po_b = (const float*)d_in[32];
    const float* lfe1_w  = (const float*)d_in[33];
    const float* lfe1_g  = (const float*)d_in[34];
    const float* lfe1_b  = (const float*)d_in[35];
    const float* s1_pi_w = (const float*)d_in[36];
    const float* s1_pi_b = (const float*)d_in[37];
    const float* s1_bn_g = (const float*)d_in[38];
    const float* s1_bn_b = (const float*)d_in[39];
    const float* s1_po_w = (const float*)d_in[40];
    const float* s1_po_b = (const float*)d_in[41];
    const float* lamuda  = (const float*)d_in[42];
    const float* fc_w    = (const float*)d_in[43];
    float* out = (float*)d_out;
    float* ws = (float*)d_ws;

    // workspace regions (floats)
    float* xs = ws;                    // scratch (wlfe1 weights)
    float* t  = ws + 4718592;          // (B,128,N) residual stream / xc
    float* P1 = ws + 8912896;          // (B,128,N)
    float* Qr = ws + 13107200;         // 12.58M floats, phase-overlaid
    float* P2 = ws + 25690112;         // (B,128,N)
    float* P3 = ws + 29884416;         // (B,128,N)

    // GISSA phase (Qr)
    unsigned short* curbf = (unsigned short*)Qr;               // (B,128,1024)
    unsigned short* curT  = (unsigned short*)(Qr + 2097152);   // (B,1024,128)
    unsigned short* yrbf  = (unsigned short*)(Qr + 4194304);   // (B,128,1024)
    unsigned short* yrT   = (unsigned short*)(Qr + 6291456);   // (B,1024,128)
    unsigned short* xsT   = (unsigned short*)(Qr + 8388608);   // (B,1024,160)
    float* ybuf = P2;                                          // (B,128,1024) fp32

    // swsa phase (Qr overlay)
    unsigned short* xpT   = (unsigned short*)Qr;               // cs->lfe0
    unsigned short* qT0   = (unsigned short*)Qr;               // pi0->swsa0/1
    unsigned short* v0    = (unsigned short*)(Qr + 2097152);
    unsigned short* yvT   = (unsigned short*)(Qr + 4194304);   // swsa0->po0
    unsigned short* v1    = (unsigned short*)(Qr + 4194304);   // pi1->swsa1
    unsigned short* xp3T  = (unsigned short*)(Qr + 6291456);   // po0->lfe1
    unsigned short* yv2T  = (unsigned short*)(Qr + 6291456);   // swsa1->po1
    unsigned short* xp2T  = (unsigned short*)(Qr + 8388608);   // lfe0->pi0
    unsigned short* xp4T  = (unsigned short*)(Qr + 8388608);   // lfe1->pi1

    // permanently-free Qr tail: packed 1x1+mlp weights + meanb
    unsigned short* linw  = (unsigned short*)(Qr + 11010048);  // 233472 u16
    unsigned short* wcc   = linw;                 // [128][160]
    unsigned short* wpi0  = linw + 20480;         // [256][128]
    unsigned short* wpi1  = linw + 53248;         // [128][128]
    unsigned short* wpo0  = linw + 69632;         // [128][128]
    unsigned short* wpo1  = linw + 86016;         // [128][128]
    unsigned short* w1bf  = linw + 102400;        // [512][128]
    unsigned short* w2bf  = linw + 167936;        // [128][512]
    float* meanb = Qr + 11200000;                 // 4096 floats

    // small mats in P3 (dead before po0 writes P3)
    float* Gbuf  = P3 + 1048576;
    float* Sbuf  = P3 + 1572864;
    unsigned short* M1bf = (unsigned short*)(P3 + 1576960);
    float* c1buf = P3 + 1839104;
    unsigned short* M2bf = (unsigned short*)(P3 + 1843200);
    float* c2buf = P3 + 2105344;

    unsigned short* wssfe = (unsigned short*)P3;             // 9*144*160
    unsigned short* wcs   = (unsigned short*)(P3 + 131072);  // 9*128*160
    unsigned short* wlfe0 = (unsigned short*)(P3 + 262144);  // 9*128*128
    unsigned short* wlfe1 = (unsigned short*)xs;             // 9*128*128

    const dim3 blk(256);

    prepack_convs<<<dim3((686592 + 255) / 256), blk, 0, stream>>>(
        ssfe_w, cs_w, lfe0_w, lfe1_w, wssfe, wcs, wlfe0, wlfe1);
    prepack_lins<<<dim3((233472 + 255) / 256), blk, 0, stream>>>(
        cc_w, s0_pi_w, s1_pi_w, s0_po_w, s1_po_w, mlp_w1, mlp_w2, linw);

    // xsT = cbr3(x, ssfe) (bf16 T only, pitch 160 zero-tailed)
    conv3x3_stg_kernel<160, 5, 3><<<dim3(32, 8, 3), blk, 0, stream>>>(
        x, 144, wssfe, ssfe_g, ssfe_b, nullptr, xsT, 144, 144);
    // t = cbr1(xs, cc)  [MFMA]
    lin_mfma_kernel<160><<<dim3(32, 8), blk, 0, stream>>>(
        xsT, wcc, nullptr, cc_g, cc_b, nullptr, t, nullptr, nullptr, 1);

    // ---- GISSA via Gram trick ----
    ln_kernel<<<dim3(128), blk, 0, stream>>>(t, ln1_g, ln1_b, curbf, curT);
    gram_kernel<<<dim3(128), blk, 0, stream>>>(curbf, Gbuf);
    sums_kernel<<<dim3(32), blk, 0, stream>>>(curbf, Sbuf);
    mats1_kernel<<<dim3(512), dim3(64), 0, stream>>>(Gbuf, Sbuf, qkv_w, qkv_b, gbn_g, gbn_b, M1bf, c1buf);
    apply1_mfma_kernel<<<dim3(256), blk, 0, stream>>>(curT, M1bf, c1buf, ybuf, yrbf, yrT);
    gram_kernel<<<dim3(128), blk, 0, stream>>>(yrbf, Gbuf);
    sums_kernel<<<dim3(32), blk, 0, stream>>>(yrbf, Sbuf);
    mats2_kernel<<<dim3(256), blk, 0, stream>>>(Gbuf, Sbuf, qkv2_w, qkv2_b, M2bf, c2buf);
    apply2_mfma_kernel<<<dim3(256), blk, 0, stream>>>(yrT, M2bf, c2buf, ybuf, t);

    // t += MLP(LN2(t))
    mlp_mfma_kernel<<<dim3(512), blk, 0, stream>>>(t, ln2_g, ln2_b, w1bf, mlp_b1, w2bf, mlp_b2);

    // xp = cbr3(xs, cs): LDS conv from xsT -> P1 fp32 + xpT bf16
    conv3x3_lds_kernel<160, 2><<<dim3(32, 8, 4), blk, 0, stream>>>(
        xsT, wcs, cs_g, cs_b, nullptr, P1, xpT, 128);
    // xp2 = cbr3(xp, lfe0) + xp -> P2 fp32 + xp2T bf16
    conv3x3_lds_kernel<128, 2><<<dim3(32, 8, 4), blk, 0, stream>>>(
        xpT, wlfe0, lfe0_g, lfe0_b, P1, P2, xp2T, 128);
    // pi0: q half -> qT0 (px-major), v half -> v0 (ch-major)  [MFMA x2]
    lin_mfma_kernel<128><<<dim3(32, 8), blk, 0, stream>>>(
        xp2T, wpi0, s0_pi_b, s0_bn_g, s0_bn_b, nullptr, nullptr, nullptr, qT0, 0);
    lin_mfma_kernel<128><<<dim3(32, 8), blk, 0, stream>>>(
        xp2T, wpi0 + (size_t)128 * 128, s0_pi_b + 128, s0_bn_g + 128, s0_bn_b + 128,
        nullptr, nullptr, v0, nullptr, 0);
    swsa_mfma_kernel<<<dim3(256), blk, 0, stream>>>(qT0, v0, P1, yvT, 1.0f);
    // xp3 = po0(yv) + xp2 -> P3 fp32 + xp3T bf16  [MFMA]
    lin_mfma_kernel<128><<<dim3(32, 8), blk, 0, stream>>>(
        yvT, wpo0, s0_po_b, nullptr, nullptr, P2, P3, nullptr, xp3T, 0);
    // xp4 = cbr3(xp3, lfe1) + xp3 -> P1 fp32 + xp4T bf16
    conv3x3_lds_kernel<128, 2><<<dim3(32, 8, 4), blk, 0, stream>>>(
        xp3T, wlfe1, lfe1_g, lfe1_b, P3, P1, xp4T, 128);
    // pi1 -> v1 (ch-major)  [MFMA]
    lin_mfma_kernel<128><<<dim3(32, 8), blk, 0, stream>>>(
        xp4T, wpi1, s1_pi_b, s1_bn_g, s1_bn_b, nullptr, nullptr, v1, nullptr, 0);
    swsa_mfma_kernel<<<dim3(256), blk, 0, stream>>>(qT0, v1, P2, yv2T, 0.08838834764831845f);
    // xp5 = po1(yv2) + xp4 -> P3  [MFMA]
    lin_mfma_kernel<128><<<dim3(32, 8), blk, 0, stream>>>(
        yv2T, wpo1, s1_po_b, nullptr, nullptr, P1, P3, nullptr, nullptr, 0);

    mean_kernel<<<dim3(1024), blk, 0, stream>>>(t, P3, lamuda, meanb);
    fc_kernel<<<dim3(2), blk, 0, stream>>>(meanb, fc_w, out);
}

// Round 9
// 580.066 us; speedup vs baseline: 8.0963x; 1.0941x over previous
//
#include <hip/hip_runtime.h>
#include <math.h>

// ---------------------------------------------------------------------------
// EATN forward. Layout: activations (B, C, N), N = 1024 contiguous.
// B=32, C=128 (144 stem), HEADS=16, HD=8.
// Round 9: swsa -> 512 blocks (64 q-rows) + XCD-local b-mapping + conflict-free
// P swizzle; lin_mfma -> 64-px blocks (grid 512).
// ---------------------------------------------------------------------------

static constexpr int NPIX = 1024;

typedef __attribute__((ext_vector_type(8))) short bf16x8;
typedef __attribute__((ext_vector_type(4))) float f32x4;
typedef __attribute__((ext_vector_type(8))) unsigned short u16x8;
typedef __attribute__((ext_vector_type(4))) unsigned short u16x4;

static __device__ __forceinline__ unsigned short f2bf(float f) {
    unsigned u = __builtin_bit_cast(unsigned, f);
    unsigned r = (u + 0x7fffu + ((u >> 16) & 1u)) >> 16;
    return (unsigned short)r;
}
static __device__ __forceinline__ float bf2f(unsigned short u) {
    unsigned v = ((unsigned)u) << 16;
    return __builtin_bit_cast(float, v);
}

// ------------------------- conv weight prepack (all 4, one launch) ---------
__global__ __launch_bounds__(256) void prepack_convs(
    const float* __restrict__ ssfe_w, const float* __restrict__ cs_w,
    const float* __restrict__ lfe0_w, const float* __restrict__ lfe1_w,
    unsigned short* __restrict__ wssfe, unsigned short* __restrict__ wcs,
    unsigned short* __restrict__ wlfe0, unsigned short* __restrict__ wlfe1)
{
    int idx = blockIdx.x * 256 + threadIdx.x;
    const float* src;
    unsigned short* dst;
    int k, Cout, CIN, CINP;
    if (idx < 207360) {
        src = ssfe_w; dst = wssfe; k = idx; Cout = 144; CIN = 144; CINP = 160;
    } else if (idx < 391680) {
        src = cs_w; dst = wcs; k = idx - 207360; Cout = 128; CIN = 144; CINP = 160;
    } else if (idx < 539136) {
        src = lfe0_w; dst = wlfe0; k = idx - 391680; Cout = 128; CIN = 128; CINP = 128;
    } else if (idx < 686592) {
        src = lfe1_w; dst = wlfe1; k = idx - 539136; Cout = 128; CIN = 128; CINP = 128;
    } else return;
    int ci = k % CINP;
    int rem = k / CINP;
    int co = rem % Cout;
    int tap = rem / Cout;
    float v = (ci < CIN) ? src[((size_t)co * CIN + ci) * 9 + tap] : 0.f;
    dst[k] = f2bf(v);
}

// ------------------------- 1x1 + mlp weights prepack (one launch) ----------
__global__ __launch_bounds__(256) void prepack_lins(
    const float* __restrict__ cc_w, const float* __restrict__ pi0_w,
    const float* __restrict__ pi1_w, const float* __restrict__ po0_w,
    const float* __restrict__ po1_w, const float* __restrict__ w1,
    const float* __restrict__ w2, unsigned short* __restrict__ o)
{
    int idx = blockIdx.x * 256 + threadIdx.x;
    if (idx >= 233472) return;
    float v;
    if (idx < 20480) {
        int ci = idx % 160, co = idx / 160;
        v = (ci < 144) ? cc_w[co * 144 + ci] : 0.f;
    } else if (idx < 53248) {
        v = pi0_w[idx - 20480];
    } else if (idx < 69632) {
        v = pi1_w[idx - 53248];
    } else if (idx < 86016) {
        v = po0_w[idx - 69632];
    } else if (idx < 102400) {
        v = po1_w[idx - 86016];
    } else if (idx < 167936) {
        v = w1[idx - 102400];
    } else {
        v = w2[idx - 167936];
    }
    o[idx] = f2bf(v);
}

// ------------------------- conv3x3, LDS-staged (ssfe, fp32 in) -------------
template <int CINP, int NCH, int M>
__global__ __launch_bounds__(256) void conv3x3_stg_kernel(
    const float* __restrict__ in, int CIN,
    const unsigned short* __restrict__ wrep,
    const float* __restrict__ g, const float* __restrict__ bb,
    float* __restrict__ out, unsigned short* __restrict__ outT,
    int Cout, int zcol)
{
    __shared__ unsigned short X[194 * 40];
    const int tid = threadIdx.x;
    const int b = blockIdx.x, gr = blockIdx.y, cg = blockIdx.z;
    const int co0 = cg * (M * 16);
    const int pbase = gr << 7;
    const int gbase = pbase - 33;
    const int wv = tid >> 6, lane = tid & 63;
    const int ll = lane & 15, lk = lane >> 4;
    const float* inb = in + ((size_t)b * CIN << 10);

    f32x4 acc[M][2];
#pragma unroll
    for (int i = 0; i < M; ++i)
#pragma unroll
        for (int j = 0; j < 2; ++j)
#pragma unroll
            for (int r = 0; r < 4; ++r) acc[i][j][r] = 0.f;

#pragma unroll 1
    for (int ch = 0; ch < NCH; ++ch) {
        const int c0 = ch << 5;
#pragma unroll 1
        for (int idx = tid; idx < 16 * 194; idx += 256) {
            const int ci2 = idx / 194;
            const int sp = idx - ci2 * 194;
            const int ci = c0 + ci2 * 2;
            const int gp = gbase + sp;
            const bool inr = (gp >= 0) & (gp < 1024);
            const float* p0 = inb + ((size_t)ci << 10);
            float a = (inr && ci < CIN) ? p0[gp] : 0.f;
            float c = (inr && (ci + 1) < CIN) ? p0[gp + 1024] : 0.f;
            *(unsigned*)&X[sp * 40 + ci2 * 2] =
                (unsigned)f2bf(a) | ((unsigned)f2bf(c) << 16);
        }
        __syncthreads();
#pragma unroll
        for (int tap = 0; tap < 9; ++tap) {
            const int soff = (tap / 3) * 32 + (tap % 3);
            const int dx = tap % 3;
            bf16x8 bfrag[2];
#pragma unroll
            for (int j = 0; j < 2; ++j) {
                const int p = wv * 32 + j * 16 + ll;
                bf16x8 v = *(const bf16x8*)&X[(p + soff) * 40 + lk * 8];
                const bool zed = (dx == 0 && j == 0 && ll == 0) ||
                                 (dx == 2 && j == 1 && ll == 15);
                if (zed) { bf16x8 z = {}; v = z; }
                bfrag[j] = v;
            }
            const unsigned short* wb =
                wrep + ((size_t)tap * Cout + co0) * CINP + c0 + lk * 8;
#pragma unroll
            for (int i = 0; i < M; ++i) {
                bf16x8 afr = *(const bf16x8*)(wb + (size_t)(i * 16 + ll) * CINP);
#pragma unroll
                for (int j = 0; j < 2; ++j)
                    acc[i][j] = __builtin_amdgcn_mfma_f32_16x16x32_bf16(
                        afr, bfrag[j], acc[i][j], 0, 0, 0);
            }
        }
        __syncthreads();
    }

#pragma unroll
    for (int i = 0; i < M; ++i) {
#pragma unroll
        for (int j = 0; j < 2; ++j) {
            const int px = pbase + wv * 32 + j * 16 + ll;
            u16x4 tp;
#pragma unroll
            for (int r = 0; r < 4; ++r) {
                const int co = co0 + i * 16 + lk * 4 + r;
                float v = fmaxf(acc[i][j][r] * g[co] + bb[co], 0.f);
                if (out) out[((size_t)(b * Cout + co) << 10) + px] = v;
                tp[r] = f2bf(v);
            }
            *(u16x4*)(outT + (((size_t)b << 10) + px) * CINP + co0 + i * 16 + lk * 4) = tp;
            if (cg == (int)gridDim.z - 1 && i == 0) {
                u16x4 z = {};
                *(u16x4*)(outT + (((size_t)b << 10) + px) * CINP + zcol + lk * 4) = z;
            }
        }
    }
}

// ------------------------- conv3x3, LDS-staged from bf16 xT ----------------
template <int CINP, int M>
__global__ __launch_bounds__(256) void conv3x3_lds_kernel(
    const unsigned short* __restrict__ xT,
    const unsigned short* __restrict__ wrep,
    const float* __restrict__ g, const float* __restrict__ bb,
    const float* __restrict__ res, float* __restrict__ out,
    unsigned short* __restrict__ outT, int Cout)
{
    constexpr int PITCH = CINP + 8;
    constexpr int NCHK = CINP / 8;
    __shared__ unsigned short X[194 * PITCH];
    const int tid = threadIdx.x;
    const int b = blockIdx.x, gr = blockIdx.y, cg = blockIdx.z;
    const int co0 = cg * (M * 16);
    const int pbase = gr << 7;
    const int gbase = pbase - 33;
    const int wv = tid >> 6, lane = tid & 63;
    const int ll = lane & 15, lq = lane >> 4;
    const unsigned short* xb = xT + ((size_t)b << 10) * CINP;

#pragma unroll 1
    for (int idx = tid; idx < 194 * NCHK; idx += 256) {
        const int row = idx / NCHK;
        const int chunk = idx - row * NCHK;
        const int gp = gbase + row;
        u16x8 v = {};
        if (gp >= 0 && gp < 1024)
            v = *(const u16x8*)(xb + (size_t)gp * CINP + chunk * 8);
        *(u16x8*)&X[row * PITCH + chunk * 8] = v;
    }
    __syncthreads();

    f32x4 acc[M][2];
#pragma unroll
    for (int i = 0; i < M; ++i)
#pragma unroll
        for (int j = 0; j < 2; ++j)
#pragma unroll
            for (int r = 0; r < 4; ++r) acc[i][j][r] = 0.f;

#pragma unroll
    for (int tap = 0; tap < 9; ++tap) {
        const int soff = (tap / 3) * 32 + (tap % 3);
        const int dx = tap % 3;
#pragma unroll
        for (int kc = 0; kc < CINP / 32; ++kc) {
            bf16x8 bfv[2];
#pragma unroll
            for (int j = 0; j < 2; ++j) {
                const int p = wv * 32 + j * 16 + ll;
                bf16x8 v = *(const bf16x8*)&X[(p + soff) * PITCH + kc * 32 + lq * 8];
                const bool zed = (dx == 0 && j == 0 && ll == 0) ||
                                 (dx == 2 && j == 1 && ll == 15);
                if (zed) { bf16x8 z = {}; v = z; }
                bfv[j] = v;
            }
            const unsigned short* wb =
                wrep + ((size_t)tap * Cout + co0) * CINP + kc * 32 + lq * 8;
#pragma unroll
            for (int i = 0; i < M; ++i) {
                bf16x8 af = *(const bf16x8*)(wb + (size_t)(i * 16 + ll) * CINP);
#pragma unroll
                for (int j = 0; j < 2; ++j)
                    acc[i][j] = __builtin_amdgcn_mfma_f32_16x16x32_bf16(
                        af, bfv[j], acc[i][j], 0, 0, 0);
            }
        }
    }

#pragma unroll
    for (int i = 0; i < M; ++i) {
#pragma unroll
        for (int j = 0; j < 2; ++j) {
            const int px = pbase + wv * 32 + j * 16 + ll;
            u16x4 tp;
#pragma unroll
            for (int r = 0; r < 4; ++r) {
                const int co = co0 + i * 16 + lq * 4 + r;
                float v = fmaxf(acc[i][j][r] * g[co] + bb[co], 0.f);
                const size_t oi = ((size_t)(b * Cout + co) << 10) + px;
                if (res) v += res[oi];
                out[oi] = v;
                tp[r] = f2bf(v);
            }
            if (outT)
                *(u16x4*)(outT + (((size_t)b << 10) + px) * 128 + co0 + i * 16 + lq * 4) = tp;
        }
    }
}

// ------------------------- unified 1x1 via bf16 MFMA (64-px blocks) --------
// grid (B, 16). Wave wid owns co rows wid*32..+32 x all 64 px.
template <int KP>
__global__ __launch_bounds__(256) void lin_mfma_kernel(
    const unsigned short* __restrict__ xT, const unsigned short* __restrict__ wbf,
    const float* __restrict__ bias0, const float* __restrict__ g,
    const float* __restrict__ bb, const float* __restrict__ res,
    float* __restrict__ outF, unsigned short* __restrict__ outBF,
    unsigned short* __restrict__ outT, int do_relu)
{
    const int tid = threadIdx.x;
    const int b = blockIdx.x;
    const int n0 = blockIdx.y << 6;
    const int wid = tid >> 6, lane = tid & 63;
    const int ll = lane & 15, lq = lane >> 4;
    const unsigned short* xb = xT + (size_t)((b << 10) + n0) * KP;

    f32x4 acc[2][4];
#pragma unroll
    for (int i = 0; i < 2; ++i)
#pragma unroll
        for (int j = 0; j < 4; ++j)
#pragma unroll
            for (int r = 0; r < 4; ++r) acc[i][j][r] = 0.f;

#pragma unroll
    for (int kk = 0; kk < KP / 32; ++kk) {
        bf16x8 af[2], bfv[4];
#pragma unroll
        for (int i = 0; i < 2; ++i)
            af[i] = *(const bf16x8*)(wbf + (size_t)(wid * 32 + i * 16 + ll) * KP + kk * 32 + lq * 8);
#pragma unroll
        for (int j = 0; j < 4; ++j)
            bfv[j] = *(const bf16x8*)(xb + (size_t)(j * 16 + ll) * KP + kk * 32 + lq * 8);
#pragma unroll
        for (int i = 0; i < 2; ++i)
#pragma unroll
            for (int j = 0; j < 4; ++j)
                acc[i][j] = __builtin_amdgcn_mfma_f32_16x16x32_bf16(af[i], bfv[j], acc[i][j], 0, 0, 0);
    }

#pragma unroll
    for (int i = 0; i < 2; ++i) {
        const int cob = wid * 32 + i * 16 + lq * 4;
        float b0v[4], gv[4], bv[4];
#pragma unroll
        for (int r = 0; r < 4; ++r) {
            b0v[r] = bias0 ? bias0[cob + r] : 0.f;
            gv[r] = g ? g[cob + r] : 1.f;
            bv[r] = g ? bb[cob + r] : 0.f;
        }
#pragma unroll
        for (int j = 0; j < 4; ++j) {
            const int px = n0 + j * 16 + ll;
            u16x4 tp;
#pragma unroll
            for (int r = 0; r < 4; ++r) {
                const int co = cob + r;
                float v = acc[i][j][r] + b0v[r];
                v = v * gv[r] + bv[r];
                if (do_relu) v = fmaxf(v, 0.f);
                const size_t oi = ((size_t)((b << 7) + co) << 10) + px;
                if (res) v += res[oi];
                if (outF) outF[oi] = v;
                unsigned short h = f2bf(v);
                if (outBF) outBF[oi] = h;
                tp[r] = h;
            }
            if (outT)
                *(u16x4*)(outT + ((size_t)((b << 10) + px)) * 128 + cob) = tp;
        }
    }
}

// ------------------------- LayerNorm -> bf16 (ch-major + px-major) ---------
__global__ __launch_bounds__(256) void ln_kernel(
    const float* __restrict__ in, const float* __restrict__ g,
    const float* __restrict__ bb, unsigned short* __restrict__ out_bf,
    unsigned short* __restrict__ outT)
{
    const int tid = threadIdx.x;
    const int b = blockIdx.x >> 2;
    const int n = ((blockIdx.x & 3) << 8) + tid;
    const float* ib = in + ((size_t)b << 17) + n;
    float s = 0.f, sq = 0.f;
#pragma unroll 8
    for (int c = 0; c < 128; ++c) {
        float v = ib[(size_t)c << 10];
        s += v;
        sq += v * v;
    }
    const float mu = s * 0.0078125f;
    const float r = rsqrtf(sq * 0.0078125f - mu * mu + 1e-5f);
    unsigned short* obf = out_bf + ((size_t)b << 17) + n;
    unsigned short* oT = outT + (((size_t)b << 10) + n) * 128;
#pragma unroll 2
    for (int c0 = 0; c0 < 128; c0 += 8) {
        u16x8 pk;
#pragma unroll
        for (int e = 0; e < 8; ++e) {
            const int c = c0 + e;
            float v = ib[(size_t)c << 10];
            float y = (v - mu) * r * g[c] + bb[c];
            unsigned short h = f2bf(y);
            obf[(size_t)c << 10] = h;
            pk[e] = h;
        }
        *(u16x8*)(oT + c0) = pk;
    }
}

// ------------------------- Gram matrix via bf16 MFMA -----------------------
__global__ __launch_bounds__(256) void gram_kernel(
    const unsigned short* __restrict__ Xbf, float* __restrict__ G)
{
    __shared__ unsigned short Xs[128 * 128];
    const int tid = threadIdx.x;
    const int b = blockIdx.x >> 2;
    const int rg = blockIdx.x & 3;
    const int wid = tid >> 6, lane = tid & 63;
    const int lq = lane >> 4, ll = lane & 15;
    const unsigned short* Xb = Xbf + ((size_t)b << 17);

    f32x4 acc[2][2];
#pragma unroll
    for (int mi = 0; mi < 2; ++mi)
#pragma unroll
        for (int ci = 0; ci < 2; ++ci)
#pragma unroll
            for (int r = 0; r < 4; ++r) acc[mi][ci][r] = 0.f;

#pragma unroll 1
    for (int nt = 0; nt < 8; ++nt) {
        const int n0 = nt << 7;
#pragma unroll
        for (int p = 0; p < 8; ++p) {
            const int ch = (p << 4) + (tid >> 4);
            const int seg = (tid & 15) << 3;
            *(u16x8*)&Xs[ch * 128 + (seg ^ ((ch & 7) << 3))] =
                *(const u16x8*)(Xb + ((size_t)ch << 10) + n0 + seg);
        }
        __syncthreads();
#pragma unroll
        for (int ks = 0; ks < 4; ++ks) {
            bf16x8 af[2], bf_[2];
#pragma unroll
            for (int mi = 0; mi < 2; ++mi) {
                const int ar = (rg << 5) + mi * 16 + ll;
                af[mi] = *(const bf16x8*)&Xs[ar * 128 + ((ks * 32 + lq * 8) ^ ((ar & 7) << 3))];
            }
#pragma unroll
            for (int ci = 0; ci < 2; ++ci) {
                const int br = (wid << 5) + ci * 16 + ll;
                bf_[ci] = *(const bf16x8*)&Xs[br * 128 + ((ks * 32 + lq * 8) ^ ((br & 7) << 3))];
            }
#pragma unroll
            for (int mi = 0; mi < 2; ++mi)
#pragma unroll
                for (int ci = 0; ci < 2; ++ci)
                    acc[mi][ci] = __builtin_amdgcn_mfma_f32_16x16x32_bf16(
                        af[mi], bf_[ci], acc[mi][ci], 0, 0, 0);
        }
        __syncthreads();
    }
    float* Gb = G + ((size_t)b << 14);
#pragma unroll
    for (int mi = 0; mi < 2; ++mi)
#pragma unroll
        for (int ci = 0; ci < 2; ++ci)
#pragma unroll
            for (int r = 0; r < 4; ++r) {
                const int row = (rg << 5) + mi * 16 + lq * 4 + r;
                const int col = (wid << 5) + ci * 16 + ll;
                Gb[row * 128 + col] = acc[mi][ci][r];
            }
}

// ------------------------- channel row-sums of bf16 tensor -----------------
__global__ __launch_bounds__(256) void sums_kernel(
    const unsigned short* __restrict__ Xbf, float* __restrict__ S)
{
    const int tid = threadIdx.x;
    const int b = blockIdx.x;
    const int ch = tid >> 1, half = tid & 1;
    const unsigned short* p = Xbf + ((size_t)b << 17) + ((size_t)ch << 10) + half * 512;
    float s = 0.f;
#pragma unroll 4
    for (int i = 0; i < 64; ++i) {
        u16x8 v = *(const u16x8*)(p + i * 8);
#pragma unroll
        for (int e = 0; e < 8; ++e) s += bf2f(v[e]);
    }
    s += __shfl_xor(s, 1);
    if (half == 0) S[(b << 7) + ch] = s;
}

// ------------------------- GISSA stage-1 matrices (bf16 M1) ----------------
__global__ __launch_bounds__(64) void mats1_kernel(
    const float* __restrict__ G, const float* __restrict__ S,
    const float* __restrict__ qkv_w, const float* __restrict__ qkv_b,
    const float* __restrict__ g, const float* __restrict__ bb,
    unsigned short* __restrict__ M1, float* __restrict__ c1)
{
    const int lane = threadIdx.x;
    const int b = blockIdx.x >> 4, h = blockIdx.x & 15;
    const float* Gb = G + ((size_t)b << 14);
    const float* Sb = S + (b << 7);
    const int d = lane >> 3, e = lane & 7;
    const int qch = h * 8 + d, kch = 128 + h * 8 + e;
    const int qoff = (qch / 24) * 8, koff = (kch / 24) * 8;
    float wq[8], wk[8];
#pragma unroll
    for (int i = 0; i < 8; ++i) {
        wq[i] = qkv_w[qch * 8 + i];
        wk[i] = qkv_w[kch * 8 + i];
    }
    float s = 0.f;
#pragma unroll
    for (int i = 0; i < 8; ++i) {
        float gu = 0.f;
#pragma unroll
        for (int j = 0; j < 8; ++j) gu += Gb[(qoff + i) * 128 + koff + j] * wk[j];
        s += wq[i] * gu;
    }
    const float bq = qkv_b[qch], bk = qkv_b[kch];
    float swk = 0.f, swq = 0.f;
#pragma unroll
    for (int j = 0; j < 8; ++j) { swk += wk[j] * Sb[koff + j]; swq += wq[j] * Sb[qoff + j]; }
    s += bq * swk + bk * swq + 1024.f * bq * bk;
    s *= 0.35355339059327373f;
    float a = (s > 0.f) ? sqrtf(s + 1e-5f) : ((s < 0.f) ? -sqrtf(1e-5f - s) : 0.f);
    float mx = a;
    mx = fmaxf(mx, __shfl_xor(mx, 1));
    mx = fmaxf(mx, __shfl_xor(mx, 2));
    mx = fmaxf(mx, __shfl_xor(mx, 4));
    float p = __expf(a - mx);
    float den = p;
    den += __shfl_xor(den, 1);
    den += __shfl_xor(den, 2);
    den += __shfl_xor(den, 4);
    const float A = p / den;

    const int l = e;
    const int cp = d * 16 + h;
    float row[16];
#pragma unroll
    for (int j = 0; j < 16; ++j) row[j] = 0.f;
    float cacc = 0.f;
#pragma unroll
    for (int e2 = 0; e2 < 8; ++e2) {
        const float Ae = __shfl(A, d * 8 + e2);
        const int vch = 256 + h * 8 + e2;
        const int voff = (vch / 24) * 8;
        cacc += Ae * qkv_b[vch];
        if ((voff >> 4) == l) {
            const int base = voff & 15;
#pragma unroll
            for (int j = 0; j < 8; ++j) row[base + j] += Ae * qkv_w[vch * 8 + j];
        }
    }
    const int idc = h * 8 + d;
    if ((idc >> 4) == l) row[idc & 15] += 1.f;
    const float gg = g[cp];
    unsigned short* mrow = M1 + ((size_t)b << 14) + cp * 128 + l * 16;
#pragma unroll
    for (int j = 0; j < 16; ++j) mrow[j] = f2bf(gg * row[j]);
    if (l == 0) c1[(b << 7) + cp] = gg * cacc + bb[cp];
}

// ------------------------- GISSA stage-2 matrices (bf16 M2) ----------------
__global__ __launch_bounds__(256) void mats2_kernel(
    const float* __restrict__ G, const float* __restrict__ S,
    const float* __restrict__ qkv2_w, const float* __restrict__ qkv2_b,
    unsigned short* __restrict__ M2, float* __restrict__ c2)
{
    const int tid = threadIdx.x;
    const int b = blockIdx.x >> 3, d = blockIdx.x & 7;
    const float* Gb = G + ((size_t)b << 14);
    const float* Sb = S + (b << 7);
    const int h = tid >> 4, gq = tid & 15;
    const int q2ch = d * 16 + h, k2ch = 128 + d * 16 + gq;
    const int qoff = (q2ch / 48) * 16, koff = (k2ch / 48) * 16;
    float wq[16], wk[16];
#pragma unroll
    for (int i = 0; i < 16; ++i) {
        wq[i] = qkv2_w[q2ch * 16 + i];
        wk[i] = qkv2_w[k2ch * 16 + i];
    }
    float s = 0.f;
#pragma unroll
    for (int i = 0; i < 16; ++i) {
        float gu = 0.f;
#pragma unroll
        for (int j = 0; j < 16; ++j) gu += Gb[(qoff + i) * 128 + koff + j] * wk[j];
        s += wq[i] * gu;
    }
    const float bq = qkv2_b[q2ch], bk = qkv2_b[k2ch];
    float swk = 0.f, swq = 0.f;
#pragma unroll
    for (int j = 0; j < 16; ++j) { swk += wk[j] * Sb[koff + j]; swq += wq[j] * Sb[qoff + j]; }
    s += bq * swk + bk * swq + 1024.f * bq * bk;
    s *= 0.25f;
    float a = (s > 0.f) ? sqrtf(s + 1e-5f) : ((s < 0.f) ? -sqrtf(1e-5f - s) : 0.f);
    float mx = a;
    mx = fmaxf(mx, __shfl_xor(mx, 1));
    mx = fmaxf(mx, __shfl_xor(mx, 2));
    mx = fmaxf(mx, __shfl_xor(mx, 4));
    mx = fmaxf(mx, __shfl_xor(mx, 8));
    float p = __expf(a - mx);
    float den = p;
    den += __shfl_xor(den, 1);
    den += __shfl_xor(den, 2);
    den += __shfl_xor(den, 4);
    den += __shfl_xor(den, 8);
    const float A2 = p / den;

    const int l = gq;
    float row[8];
#pragma unroll
    for (int j = 0; j < 8; ++j) row[j] = 0.f;
    float cacc = 0.f;
#pragma unroll
    for (int g2 = 0; g2 < 16; ++g2) {
        const float Ag = __shfl(A2, (tid & 48) + g2);
        const int v2ch = 256 + d * 16 + g2;
        const int voff = (v2ch / 48) * 16;
        cacc += Ag * qkv2_b[v2ch];
        if ((l >> 1) == (voff >> 4)) {
            const int base = (l & 1) * 8;
#pragma unroll
            for (int j = 0; j < 8; ++j) row[j] += Ag * qkv2_w[v2ch * 16 + base + j];
        }
    }
    const int c = h * 8 + d;
    unsigned short* mrow = M2 + ((size_t)b << 14) + c * 128 + l * 8;
#pragma unroll
    for (int j = 0; j < 8; ++j) mrow[j] = f2bf(row[j]);
    if (l == 0) c2[(b << 7) + c] = cacc;
}

// ------------------------- apply1: y = M1 x + c1 (MFMA) --------------------
__global__ __launch_bounds__(256) void apply1_mfma_kernel(
    const unsigned short* __restrict__ curT, const unsigned short* __restrict__ M1bf,
    const float* __restrict__ c1, float* __restrict__ ybuf,
    unsigned short* __restrict__ yrbf, unsigned short* __restrict__ yrT)
{
    const int tid = threadIdx.x;
    const int b = blockIdx.x >> 3;
    const int n0 = (blockIdx.x & 7) << 7;
    const int wid = tid >> 6, lane = tid & 63;
    const int wr = wid >> 1, wc = wid & 1;
    const int ll = lane & 15, lq = lane >> 4;
    const unsigned short* Mb = M1bf + ((size_t)b << 14);
    const unsigned short* xb = curT + (((size_t)b << 10) + n0 + wc * 64) * 128;

    f32x4 acc[4][4];
#pragma unroll
    for (int i = 0; i < 4; ++i)
#pragma unroll
        for (int j = 0; j < 4; ++j)
#pragma unroll
            for (int r = 0; r < 4; ++r) acc[i][j][r] = 0.f;

#pragma unroll
    for (int kk = 0; kk < 4; ++kk) {
        bf16x8 af[4], bfv[4];
#pragma unroll
        for (int i = 0; i < 4; ++i)
            af[i] = *(const bf16x8*)(Mb + (size_t)(wr * 64 + i * 16 + ll) * 128 + kk * 32 + lq * 8);
#pragma unroll
        for (int j = 0; j < 4; ++j)
            bfv[j] = *(const bf16x8*)(xb + (size_t)(j * 16 + ll) * 128 + kk * 32 + lq * 8);
#pragma unroll
        for (int i = 0; i < 4; ++i)
#pragma unroll
            for (int j = 0; j < 4; ++j)
                acc[i][j] = __builtin_amdgcn_mfma_f32_16x16x32_bf16(af[i], bfv[j], acc[i][j], 0, 0, 0);
    }

#pragma unroll
    for (int i = 0; i < 4; ++i) {
        const int cob = wr * 64 + i * 16 + lq * 4;
        float c1v[4];
#pragma unroll
        for (int r = 0; r < 4; ++r) c1v[r] = c1[(b << 7) + cob + r];
#pragma unroll
        for (int j = 0; j < 4; ++j) {
            const int px = n0 + wc * 64 + j * 16 + ll;
            u16x4 tp;
#pragma unroll
            for (int r = 0; r < 4; ++r) {
                const int co = cob + r;
                const float v = acc[i][j][r] + c1v[r];
                const size_t oi = ((size_t)(b * 128 + co) << 10) + px;
                ybuf[oi] = v;
                const unsigned short h = f2bf(fmaxf(v, 0.f));
                yrbf[oi] = h;
                tp[r] = h;
            }
            *(u16x4*)(yrT + (((size_t)b << 10) + px) * 128 + cob) = tp;
        }
    }
}

// ------------------------- apply2: t += M2 relu(y) + c2 + y (MFMA) ---------
__global__ __launch_bounds__(256) void apply2_mfma_kernel(
    const unsigned short* __restrict__ yrT, const unsigned short* __restrict__ M2bf,
    const float* __restrict__ c2, const float* __restrict__ ybuf,
    float* __restrict__ t)
{
    const int tid = threadIdx.x;
    const int b = blockIdx.x >> 3;
    const int n0 = (blockIdx.x & 7) << 7;
    const int wid = tid >> 6, lane = tid & 63;
    const int wr = wid >> 1, wc = wid & 1;
    const int ll = lane & 15, lq = lane >> 4;
    const unsigned short* Mb = M2bf + ((size_t)b << 14);
    const unsigned short* xb = yrT + (((size_t)b << 10) + n0 + wc * 64) * 128;

    f32x4 acc[4][4];
#pragma unroll
    for (int i = 0; i < 4; ++i)
#pragma unroll
        for (int j = 0; j < 4; ++j)
#pragma unroll
            for (int r = 0; r < 4; ++r) acc[i][j][r] = 0.f;

#pragma unroll
    for (int kk = 0; kk < 4; ++kk) {
        bf16x8 af[4], bfv[4];
#pragma unroll
        for (int i = 0; i < 4; ++i)
            af[i] = *(const bf16x8*)(Mb + (size_t)(wr * 64 + i * 16 + ll) * 128 + kk * 32 + lq * 8);
#pragma unroll
        for (int j = 0; j < 4; ++j)
            bfv[j] = *(const bf16x8*)(xb + (size_t)(j * 16 + ll) * 128 + kk * 32 + lq * 8);
#pragma unroll
        for (int i = 0; i < 4; ++i)
#pragma unroll
            for (int j = 0; j < 4; ++j)
                acc[i][j] = __builtin_amdgcn_mfma_f32_16x16x32_bf16(af[i], bfv[j], acc[i][j], 0, 0, 0);
    }

#pragma unroll
    for (int i = 0; i < 4; ++i) {
        const int cob = wr * 64 + i * 16 + lq * 4;
        float c2v[4];
#pragma unroll
        for (int r = 0; r < 4; ++r) c2v[r] = c2[(b << 7) + cob + r];
#pragma unroll
        for (int j = 0; j < 4; ++j) {
            const int px = n0 + wc * 64 + j * 16 + ll;
#pragma unroll
            for (int r = 0; r < 4; ++r) {
                const size_t oi = ((size_t)(b * 128 + cob + r) << 10) + px;
                t[oi] += acc[i][j][r] + c2v[r] + ybuf[oi];
            }
        }
    }
}

// ------------------------- fused LN2 + MLP via bf16 MFMA -------------------
__global__ __launch_bounds__(256) void mlp_mfma_kernel(
    float* __restrict__ t, const float* __restrict__ ln_g,
    const float* __restrict__ ln_b, const unsigned short* __restrict__ w1bf,
    const float* __restrict__ b1, const unsigned short* __restrict__ w2bf,
    const float* __restrict__ b2)
{
    __shared__ unsigned char lds[16384 + 65536];
    unsigned char* xnb = lds;
    unsigned char* hb = lds + 16384;

    const int tid = threadIdx.x;
    const int b = blockIdx.x >> 4;
    const int n0 = (blockIdx.x & 15) << 6;
    float* tb = t + ((size_t)b << 17) + n0;

    {
        const int px = tid >> 2, q = tid & 3;
        float v[32];
        float s = 0.f, sq = 0.f;
#pragma unroll
        for (int k = 0; k < 32; ++k) {
            float x = tb[((size_t)(q * 32 + k) << 10) + px];
            v[k] = x;
            s += x;
            sq += x * x;
        }
        s += __shfl_xor(s, 1); s += __shfl_xor(s, 2);
        sq += __shfl_xor(sq, 1); sq += __shfl_xor(sq, 2);
        const float mu = s * 0.0078125f;
        const float rstd = rsqrtf(sq * 0.0078125f - mu * mu + 1e-5f);
        const int sw = (px & 7) << 4;
#pragma unroll
        for (int cc = 0; cc < 4; ++cc) {
            u16x8 pk;
#pragma unroll
            for (int e = 0; e < 8; ++e) {
                int c = q * 32 + cc * 8 + e;
                float xv = (v[cc * 8 + e] - mu) * rstd * ln_g[c] + ln_b[c];
                pk[e] = f2bf(xv);
            }
            *(u16x8*)(xnb + px * 256 + ((q * 64 + cc * 16) ^ sw)) = pk;
        }
    }
    __syncthreads();

    const int wid = tid >> 6, lane = tid & 63;
    const int lr = lane & 15, lk = lane >> 4;

#pragma unroll 1
    for (int pass = 0; pass < 2; ++pass) {
        const int hidbase = (wid << 7) + (pass << 6);
        f32x4 acc[4][4];
#pragma unroll
        for (int i = 0; i < 4; ++i)
#pragma unroll
            for (int j = 0; j < 4; ++j)
#pragma unroll
                for (int r = 0; r < 4; ++r) acc[i][j][r] = 0.f;
#pragma unroll
        for (int kk = 0; kk < 4; ++kk) {
            bf16x8 af[4], bfr[4];
#pragma unroll
            for (int i = 0; i < 4; ++i)
                af[i] = *(const bf16x8*)(w1bf + (size_t)(hidbase + i * 16 + lr) * 128 + kk * 32 + lk * 8);
#pragma unroll
            for (int j = 0; j < 4; ++j) {
                const int px = j * 16 + lr;
                bfr[j] = *(const bf16x8*)(xnb + px * 256 + ((kk * 64 + lk * 16) ^ ((px & 7) << 4)));
            }
#pragma unroll
            for (int i = 0; i < 4; ++i)
#pragma unroll
                for (int j = 0; j < 4; ++j)
                    acc[i][j] = __builtin_amdgcn_mfma_f32_16x16x32_bf16(af[i], bfr[j], acc[i][j], 0, 0, 0);
        }
#pragma unroll
        for (int i = 0; i < 4; ++i) {
            const int hid0 = hidbase + i * 16 + lk * 4;
            float bi[4];
#pragma unroll
            for (int r = 0; r < 4; ++r) bi[r] = b1[hid0 + r];
#pragma unroll
            for (int j = 0; j < 4; ++j) {
                const int px = j * 16 + lr;
                u16x4 pk;
#pragma unroll
                for (int r = 0; r < 4; ++r) {
                    float x = acc[i][j][r] + bi[r];
                    float u = 1.5957691f * x * (1.f + 0.044715f * x * x);
                    float gv = x / (1.f + __expf(-u));
                    pk[r] = f2bf(gv);
                }
                *(u16x4*)(hb + px * 1024 + ((hid0 * 2) ^ ((px & 7) << 4))) = pk;
            }
        }
    }
    __syncthreads();

    f32x4 acc2[2][4];
#pragma unroll
    for (int i = 0; i < 2; ++i)
#pragma unroll
        for (int j = 0; j < 4; ++j)
#pragma unroll
            for (int r = 0; r < 4; ++r) acc2[i][j][r] = 0.f;
#pragma unroll 2
    for (int ks = 0; ks < 16; ++ks) {
        bf16x8 af[2], bfr[4];
#pragma unroll
        for (int i = 0; i < 2; ++i)
            af[i] = *(const bf16x8*)(w2bf + (size_t)((wid << 5) + i * 16 + lr) * 512 + ks * 32 + lk * 8);
#pragma unroll
        for (int j = 0; j < 4; ++j) {
            const int px = j * 16 + lr;
            bfr[j] = *(const bf16x8*)(hb + px * 1024 + ((ks * 64 + lk * 16) ^ ((px & 7) << 4)));
        }
#pragma unroll
        for (int i = 0; i < 2; ++i)
#pragma unroll
            for (int j = 0; j < 4; ++j)
                acc2[i][j] = __builtin_amdgcn_mfma_f32_16x16x32_bf16(af[i], bfr[j], acc2[i][j], 0, 0, 0);
    }
#pragma unroll
    for (int i = 0; i < 2; ++i) {
        const int cb = (wid << 5) + i * 16 + lk * 4;
        float b2v[4];
#pragma unroll
        for (int r = 0; r < 4; ++r) b2v[r] = b2[cb + r];
#pragma unroll
        for (int j = 0; j < 4; ++j) {
            const int px = j * 16 + lr;
#pragma unroll
            for (int r = 0; r < 4; ++r) {
                const size_t off = ((size_t)(cb + r) << 10) + px;
                tb[off] += acc2[i][j][r] + b2v[r];
            }
        }
    }
}

// ------------------------- flash SWSA via bf16 MFMA ------------------------
// 64 q-rows per block; grid.x = 512 with b = idx&31 (XCD-local), nblk = idx>>5.
__global__ __launch_bounds__(256) void swsa_mfma_kernel(
    const unsigned short* __restrict__ qT, const unsigned short* __restrict__ vbf,
    float* __restrict__ outp, unsigned short* __restrict__ outT, float fscale)
{
    __shared__ unsigned short K_lds[128 * 128];   // K tile; rows 0..63 reused for P
    __shared__ unsigned short V_lds[128 * 128];
    const int tid = threadIdx.x;
    const int b = blockIdx.x & 31;
    const int n0 = (blockIdx.x >> 5) << 6;
    const int wid = tid >> 6, lane = tid & 63;
    const int lq = lane >> 4, ll = lane & 15;
    const unsigned short* qTb = qT + ((size_t)b << 17);
    const unsigned short* vb = vbf + ((size_t)b << 17);

    bf16x8 aq[4];
    {
        const int row = n0 + wid * 16 + ll;
#pragma unroll
        for (int kk = 0; kk < 4; ++kk)
            aq[kk] = *(const bf16x8*)(qTb + ((size_t)row << 7) + kk * 32 + lq * 8);
    }

    float mrun[4], lrun[4];
#pragma unroll
    for (int i = 0; i < 4; ++i) { mrun[i] = -INFINITY; lrun[i] = 0.f; }
    f32x4 yacc[8];
#pragma unroll
    for (int cj = 0; cj < 8; ++cj)
#pragma unroll
        for (int r = 0; r < 4; ++r) yacc[cj][r] = 0.f;

#pragma unroll 1
    for (int mt = 0; mt < 8; ++mt) {
        const int m0 = mt << 7;
        for (int ch = tid; ch < 2048; ch += 256) {
            const int rr = ch >> 4, e0 = (ch & 15) << 3;
            const int sw = (rr & 7) << 3;
            *(u16x8*)&K_lds[rr * 128 + (e0 ^ sw)] =
                *(const u16x8*)(qTb + ((size_t)(m0 + rr) << 7) + e0);
            *(u16x8*)&V_lds[rr * 128 + (e0 ^ sw)] =
                *(const u16x8*)(vb + ((size_t)rr << 10) + m0 + e0);
        }
        __syncthreads();

        // QK^T: sacc[j] = D[n][m], n = this wave's 16 rows
        f32x4 sacc[8];
#pragma unroll
        for (int j = 0; j < 8; ++j)
#pragma unroll
            for (int r = 0; r < 4; ++r) sacc[j][r] = 0.f;
#pragma unroll
        for (int j = 0; j < 8; ++j) {
            const int ml = j * 16 + ll;
            const int swk = (ml & 7) << 3;
#pragma unroll
            for (int kk = 0; kk < 4; ++kk) {
                bf16x8 bk = *(const bf16x8*)&K_lds[ml * 128 + ((kk * 32 + lq * 8) ^ swk)];
                sacc[j] = __builtin_amdgcn_mfma_f32_16x16x32_bf16(aq[kk], bk, sacc[j], 0, 0, 0);
            }
        }
        __syncthreads();   // K reads done; rows 0..63 become P

        float pmax[4];
#pragma unroll
        for (int i = 0; i < 4; ++i) pmax[i] = -INFINITY;
#pragma unroll
        for (int j = 0; j < 8; ++j)
#pragma unroll
            for (int r = 0; r < 4; ++r) {
                float s = sacc[j][r] * 0.08838834764831845f;
                sacc[j][r] = s;
                pmax[r] = fmaxf(pmax[r], s);
            }
        float alpha[4];
#pragma unroll
        for (int i = 0; i < 4; ++i) {
            float m = pmax[i];
            m = fmaxf(m, __shfl_xor(m, 1));
            m = fmaxf(m, __shfl_xor(m, 2));
            m = fmaxf(m, __shfl_xor(m, 4));
            m = fmaxf(m, __shfl_xor(m, 8));
            const float mn = fmaxf(mrun[i], m);
            alpha[i] = __expf(mrun[i] - mn);
            mrun[i] = mn;
        }
        // P write: row nbw, conflict-free swizzle sw4 = ((nbw>>2)&3)<<4
        float psum[4];
#pragma unroll
        for (int r = 0; r < 4; ++r) {
            const int nbw = wid * 16 + lq * 4 + r;
            const int sw4 = ((nbw >> 2) & 3) << 4;
            const float mn = mrun[r];
            float ps = 0.f;
#pragma unroll
            for (int j = 0; j < 8; ++j) {
                float p = __expf(sacc[j][r] - mn);
                ps += p;
                K_lds[nbw * 128 + ((j * 16 + ll) ^ sw4)] = f2bf(p);
            }
            psum[r] = ps;
        }
#pragma unroll
        for (int i = 0; i < 4; ++i) {
            float s = psum[i];
            s += __shfl_xor(s, 1);
            s += __shfl_xor(s, 2);
            s += __shfl_xor(s, 4);
            s += __shfl_xor(s, 8);
            lrun[i] = lrun[i] * alpha[i] + s;
        }
#pragma unroll
        for (int cj = 0; cj < 8; ++cj)
#pragma unroll
            for (int r = 0; r < 4; ++r) yacc[cj][r] *= alpha[r];

        // PV: A = P (own wave rows, sw4 swizzle), B = V^T
        bf16x8 ap[4];
        {
            const int nb = wid * 16 + ll;
            const int sw4 = ((nb >> 2) & 3) << 4;
#pragma unroll
            for (int mk = 0; mk < 4; ++mk)
                ap[mk] = *(const bf16x8*)&K_lds[nb * 128 + ((mk * 32 + lq * 8) ^ sw4)];
        }
#pragma unroll
        for (int cj = 0; cj < 8; ++cj) {
            const int cl = cj * 16 + ll;
            const int sw = (cl & 7) << 3;
#pragma unroll
            for (int mk = 0; mk < 4; ++mk) {
                bf16x8 bv = *(const bf16x8*)&V_lds[cl * 128 + ((mk * 32 + lq * 8) ^ sw)];
                yacc[cj] = __builtin_amdgcn_mfma_f32_16x16x32_bf16(ap[mk], bv, yacc[cj], 0, 0, 0);
            }
        }
        __syncthreads();
    }

    const int nbase = n0 + wid * 16 + lq * 4;
    float inv[4];
#pragma unroll
    for (int r = 0; r < 4; ++r) inv[r] = fscale / lrun[r];
#pragma unroll
    for (int cj = 0; cj < 8; ++cj) {
        const int c = cj * 16 + ll;
        float4 o;
        o.x = yacc[cj][0] * inv[0];
        o.y = yacc[cj][1] * inv[1];
        o.z = yacc[cj][2] * inv[2];
        o.w = yacc[cj][3] * inv[3];
        *(float4*)(outp + ((size_t)(b * 128 + c) << 10) + nbase) = o;
        if (outT) {
            unsigned short* tb = outT + ((size_t)((b << 10) + nbase)) * 128 + c;
            tb[0] = f2bf(o.x);
            tb[128] = f2bf(o.y);
            tb[256] = f2bf(o.z);
            tb[384] = f2bf(o.w);
        }
    }
}

// ------------------------- final: mean (stage 1) ---------------------------
__global__ __launch_bounds__(256) void mean_kernel(
    const float* __restrict__ xc, const float* __restrict__ xp,
    const float* __restrict__ lamuda, float* __restrict__ meanb)
{
    const int wid = threadIdx.x >> 6, lane = threadIdx.x & 63;
    const int row = (blockIdx.x << 2) + wid;
    const float lmd = 1.f / (1.f + __expf(-lamuda[0]));
    const float* a = xc + ((size_t)row << 10) + (lane << 2);
    const float* d = xp + ((size_t)row << 10) + (lane << 2);
    float s = 0.f;
#pragma unroll
    for (int i = 0; i < 4; ++i) {
        float4 va = *(const float4*)(a + (i << 8));
        float4 vd = *(const float4*)(d + (i << 8));
        s += lmd * (va.x + va.y + va.z + va.w) +
             (1.f - lmd) * (vd.x + vd.y + vd.z + vd.w);
    }
#pragma unroll
    for (int o = 1; o < 64; o <<= 1) s += __shfl_xor(s, o);
    if (lane == 0) meanb[row] = s * (1.f / 1024.f);
}

// ------------------------- final: fc (stage 2) -----------------------------
__global__ __launch_bounds__(256) void fc_kernel(
    const float* __restrict__ meanb, const float* __restrict__ fc_w,
    float* __restrict__ outp)
{
    const int idx = blockIdx.x * 256 + threadIdx.x;
    if (idx >= 512) return;
    const int b = idx >> 4, o = idx & 15;
    float s = 0.f;
#pragma unroll 4
    for (int c = 0; c < 128; ++c) s += fc_w[o * 128 + c] * meanb[b * 128 + c];
    outp[b * 16 + o] = s;
}

// ---------------------------------------------------------------------------
extern "C" void kernel_launch(void* const* d_in, const int* in_sizes, int n_in,
                              void* d_out, int out_size, void* d_ws, size_t ws_size,
                              hipStream_t stream)
{
    (void)in_sizes; (void)n_in; (void)out_size; (void)ws_size;

    const float* x       = (const float*)d_in[0];
    const float* ssfe_w  = (const float*)d_in[1];
    const float* ssfe_g  = (const float*)d_in[2];
    const float* ssfe_b  = (const float*)d_in[3];
    const float* cc_w    = (const float*)d_in[4];
    const float* cc_g    = (const float*)d_in[5];
    const float* cc_b    = (const float*)d_in[6];
    const float* ln1_g   = (const float*)d_in[7];
    const float* ln1_b   = (const float*)d_in[8];
    const float* qkv_w   = (const float*)d_in[9];
    const float* qkv_b   = (const float*)d_in[10];
    const float* gbn_g   = (const float*)d_in[11];
    const float* gbn_b   = (const float*)d_in[12];
    const float* qkv2_w  = (const float*)d_in[13];
    const float* qkv2_b  = (const float*)d_in[14];
    const float* ln2_g   = (const float*)d_in[15];
    const float* ln2_b   = (const float*)d_in[16];
    const float* mlp_w1  = (const float*)d_in[17];
    const float* mlp_b1  = (const float*)d_in[18];
    const float* mlp_w2  = (const float*)d_in[19];
    const float* mlp_b2  = (const float*)d_in[20];
    const float* cs_w    = (const float*)d_in[21];
    const float* cs_g    = (const float*)d_in[22];
    const float* cs_b    = (const float*)d_in[23];
    const float* lfe0_w  = (const float*)d_in[24];
    const float* lfe0_g  = (const float*)d_in[25];
    const float* lfe0_b  = (const float*)d_in[26];
    const float* s0_pi_w = (const float*)d_in[27];
    const float* s0_pi_b = (const float*)d_in[28];
    const float* s0_bn_g = (const float*)d_in[29];
    const float* s0_bn_b = (const float*)d_in[30];
    const float* s0_po_w = (const float*)d_in[31];
    const float* s0_po_b = (const float*)d_in[32];
    const float* lfe1_w  = (const float*)d_in[33];
    const float* lfe1_g  = (const float*)d_in[34];
    const float* lfe1_b  = (const float*)d_in[35];
    const float* s1_pi_w = (const float*)d_in[36];
    const float* s1_pi_b = (const float*)d_in[37];
    const float* s1_bn_g = (const float*)d_in[38];
    const float* s1_bn_b = (const float*)d_in[39];
    const float* s1_po_w = (const float*)d_in[40];
    const float* s1_po_b = (const float*)d_in[41];
    const float* lamuda  = (const float*)d_in[42];
    const float* fc_w    = (const float*)d_in[43];
    float* out = (float*)d_out;
    float* ws = (float*)d_ws;

    // workspace regions (floats)
    float* xs = ws;                    // scratch (wlfe1 weights)
    float* t  = ws + 4718592;          // (B,128,N) residual stream / xc
    float* P1 = ws + 8912896;          // (B,128,N)
    float* Qr = ws + 13107200;         // 12.58M floats, phase-overlaid
    float* P2 = ws + 25690112;         // (B,128,N)
    float* P3 = ws + 29884416;         // (B,128,N)

    // GISSA phase (Qr)
    unsigned short* curbf = (unsigned short*)Qr;               // (B,128,1024)
    unsigned short* curT  = (unsigned short*)(Qr + 2097152);   // (B,1024,128)
    unsigned short* yrbf  = (unsigned short*)(Qr + 4194304);   // (B,128,1024)
    unsigned short* yrT   = (unsigned short*)(Qr + 6291456);   // (B,1024,128)
    unsigned short* xsT   = (unsigned short*)(Qr + 8388608);   // (B,1024,160)
    float* ybuf = P2;                                          // (B,128,1024) fp32

    // swsa phase (Qr overlay)
    unsigned short* xpT   = (unsigned short*)Qr;               // cs->lfe0
    unsigned short* qT0   = (unsigned short*)Qr;               // pi0->swsa0/1
    unsigned short* v0    = (unsigned short*)(Qr + 2097152);
    unsigned short* yvT   = (unsigned short*)(Qr + 4194304);   // swsa0->po0
    unsigned short* v1    = (unsigned short*)(Qr + 4194304);   // pi1->swsa1
    unsigned short* xp3T  = (unsigned short*)(Qr + 6291456);   // po0->lfe1
    unsigned short* yv2T  = (unsigned short*)(Qr + 6291456);   // swsa1->po1
    unsigned short* xp2T  = (unsigned short*)(Qr + 8388608);   // lfe0->pi0
    unsigned short* xp4T  = (unsigned short*)(Qr + 8388608);   // lfe1->pi1

    // permanently-free Qr tail: packed 1x1+mlp weights + meanb
    unsigned short* linw  = (unsigned short*)(Qr + 11010048);  // 233472 u16
    unsigned short* wcc   = linw;                 // [128][160]
    unsigned short* wpi0  = linw + 20480;         // [256][128]
    unsigned short* wpi1  = linw + 53248;         // [128][128]
    unsigned short* wpo0  = linw + 69632;         // [128][128]
    unsigned short* wpo1  = linw + 86016;         // [128][128]
    unsigned short* w1bf  = linw + 102400;        // [512][128]
    unsigned short* w2bf  = linw + 167936;        // [128][512]
    float* meanb = Qr + 11200000;                 // 4096 floats

    // small mats in P3 (dead before po0 writes P3)
    float* Gbuf  = P3 + 1048576;
    float* Sbuf  = P3 + 1572864;
    unsigned short* M1bf = (unsigned short*)(P3 + 1576960);
    float* c1buf = P3 + 1839104;
    unsigned short* M2bf = (unsigned short*)(P3 + 1843200);
    float* c2buf = P3 + 2105344;

    unsigned short* wssfe = (unsigned short*)P3;             // 9*144*160
    unsigned short* wcs   = (unsigned short*)(P3 + 131072);  // 9*128*160
    unsigned short* wlfe0 = (unsigned short*)(P3 + 262144);  // 9*128*128
    unsigned short* wlfe1 = (unsigned short*)xs;             // 9*128*128

    const dim3 blk(256);

    prepack_convs<<<dim3((686592 + 255) / 256), blk, 0, stream>>>(
        ssfe_w, cs_w, lfe0_w, lfe1_w, wssfe, wcs, wlfe0, wlfe1);
    prepack_lins<<<dim3((233472 + 255) / 256), blk, 0, stream>>>(
        cc_w, s0_pi_w, s1_pi_w, s0_po_w, s1_po_w, mlp_w1, mlp_w2, linw);

    conv3x3_stg_kernel<160, 5, 3><<<dim3(32, 8, 3), blk, 0, stream>>>(
        x, 144, wssfe, ssfe_g, ssfe_b, nullptr, xsT, 144, 144);
    lin_mfma_kernel<160><<<dim3(32, 16), blk, 0, stream>>>(
        xsT, wcc, nullptr, cc_g, cc_b, nullptr, t, nullptr, nullptr, 1);

    // ---- GISSA via Gram trick ----
    ln_kernel<<<dim3(128), blk, 0, stream>>>(t, ln1_g, ln1_b, curbf, curT);
    gram_kernel<<<dim3(128), blk, 0, stream>>>(curbf, Gbuf);
    sums_kernel<<<dim3(32), blk, 0, stream>>>(curbf, Sbuf);
    mats1_kernel<<<dim3(512), dim3(64), 0, stream>>>(Gbuf, Sbuf, qkv_w, qkv_b, gbn_g, gbn_b, M1bf, c1buf);
    apply1_mfma_kernel<<<dim3(256), blk, 0, stream>>>(curT, M1bf, c1buf, ybuf, yrbf, yrT);
    gram_kernel<<<dim3(128), blk, 0, stream>>>(yrbf, Gbuf);
    sums_kernel<<<dim3(32), blk, 0, stream>>>(yrbf, Sbuf);
    mats2_kernel<<<dim3(256), blk, 0, stream>>>(Gbuf, Sbuf, qkv2_w, qkv2_b, M2bf, c2buf);
    apply2_mfma_kernel<<<dim3(256), blk, 0, stream>>>(yrT, M2bf, c2buf, ybuf, t);

    mlp_mfma_kernel<<<dim3(512), blk, 0, stream>>>(t, ln2_g, ln2_b, w1bf, mlp_b1, w2bf, mlp_b2);

    conv3x3_lds_kernel<160, 2><<<dim3(32, 8, 4), blk, 0, stream>>>(
        xsT, wcs, cs_g, cs_b, nullptr, P1, xpT, 128);
    conv3x3_lds_kernel<128, 2><<<dim3(32, 8, 4), blk, 0, stream>>>(
        xpT, wlfe0, lfe0_g, lfe0_b, P1, P2, xp2T, 128);
    lin_mfma_kernel<128><<<dim3(32, 16), blk, 0, stream>>>(
        xp2T, wpi0, s0_pi_b, s0_bn_g, s0_bn_b, nullptr, nullptr, nullptr, qT0, 0);
    lin_mfma_kernel<128><<<dim3(32, 16), blk, 0, stream>>>(
        xp2T, wpi0 + (size_t)128 * 128, s0_pi_b + 128, s0_bn_g + 128, s0_bn_b + 128,
        nullptr, nullptr, v0, nullptr, 0);
    swsa_mfma_kernel<<<dim3(512), blk, 0, stream>>>(qT0, v0, P1, yvT, 1.0f);
    lin_mfma_kernel<128><<<dim3(32, 16), blk, 0, stream>>>(
        yvT, wpo0, s0_po_b, nullptr, nullptr, P2, P3, nullptr, xp3T, 0);
    conv3x3_lds_kernel<128, 2><<<dim3(32, 8, 4), blk, 0, stream>>>(
        xp3T, wlfe1, lfe1_g, lfe1_b, P3, P1, xp4T, 128);
    lin_mfma_kernel<128><<<dim3(32, 16), blk, 0, stream>>>(
        xp4T, wpi1, s1_pi_b, s1_bn_g, s1_bn_b, nullptr, nullptr, v1, nullptr, 0);
    swsa_mfma_kernel<<<dim3(512), blk, 0, stream>>>(qT0, v1, P2, yv2T, 0.08838834764831845f);
    lin_mfma_kernel<128><<<dim3(32, 16), blk, 0, stream>>>(
        yv2T, wpo1, s1_po_b, nullptr, nullptr, P1, P3, nullptr, nullptr, 0);

    mean_kernel<<<dim3(1024), blk, 0, stream>>>(t, P3, lamuda, meanb);
    fc_kernel<<<dim3(2), blk, 0, stream>>>(meanb, fc_w, out);
}

// Round 10
// 457.376 us; speedup vs baseline: 10.2681x; 1.2682x over previous
//
#include <hip/hip_runtime.h>
#include <math.h>

// ---------------------------------------------------------------------------
// EATN forward. Layout: activations (B, C, N), N = 1024 contiguous.
// B=32, C=128 (144 stem), HEADS=16, HD=8.
// Round 10: xp-branch goes all-bf16 (residuals read from *T buffers; dead fp32
// outputs dropped); conv3x3 restructured to 64px x 128co blocks (no cg
// re-staging, 3-4 blocks/CU).
// ---------------------------------------------------------------------------

static constexpr int NPIX = 1024;

typedef __attribute__((ext_vector_type(8))) short bf16x8;
typedef __attribute__((ext_vector_type(4))) float f32x4;
typedef __attribute__((ext_vector_type(8))) unsigned short u16x8;
typedef __attribute__((ext_vector_type(4))) unsigned short u16x4;

static __device__ __forceinline__ unsigned short f2bf(float f) {
    unsigned u = __builtin_bit_cast(unsigned, f);
    unsigned r = (u + 0x7fffu + ((u >> 16) & 1u)) >> 16;
    return (unsigned short)r;
}
static __device__ __forceinline__ float bf2f(unsigned short u) {
    unsigned v = ((unsigned)u) << 16;
    return __builtin_bit_cast(float, v);
}

// ------------------------- conv weight prepack (all 4, one launch) ---------
__global__ __launch_bounds__(256) void prepack_convs(
    const float* __restrict__ ssfe_w, const float* __restrict__ cs_w,
    const float* __restrict__ lfe0_w, const float* __restrict__ lfe1_w,
    unsigned short* __restrict__ wssfe, unsigned short* __restrict__ wcs,
    unsigned short* __restrict__ wlfe0, unsigned short* __restrict__ wlfe1)
{
    int idx = blockIdx.x * 256 + threadIdx.x;
    const float* src;
    unsigned short* dst;
    int k, Cout, CIN, CINP;
    if (idx < 207360) {
        src = ssfe_w; dst = wssfe; k = idx; Cout = 144; CIN = 144; CINP = 160;
    } else if (idx < 391680) {
        src = cs_w; dst = wcs; k = idx - 207360; Cout = 128; CIN = 144; CINP = 160;
    } else if (idx < 539136) {
        src = lfe0_w; dst = wlfe0; k = idx - 391680; Cout = 128; CIN = 128; CINP = 128;
    } else if (idx < 686592) {
        src = lfe1_w; dst = wlfe1; k = idx - 539136; Cout = 128; CIN = 128; CINP = 128;
    } else return;
    int ci = k % CINP;
    int rem = k / CINP;
    int co = rem % Cout;
    int tap = rem / Cout;
    float v = (ci < CIN) ? src[((size_t)co * CIN + ci) * 9 + tap] : 0.f;
    dst[k] = f2bf(v);
}

// ------------------------- 1x1 + mlp weights prepack (one launch) ----------
__global__ __launch_bounds__(256) void prepack_lins(
    const float* __restrict__ cc_w, const float* __restrict__ pi0_w,
    const float* __restrict__ pi1_w, const float* __restrict__ po0_w,
    const float* __restrict__ po1_w, const float* __restrict__ w1,
    const float* __restrict__ w2, unsigned short* __restrict__ o)
{
    int idx = blockIdx.x * 256 + threadIdx.x;
    if (idx >= 233472) return;
    float v;
    if (idx < 20480) {
        int ci = idx % 160, co = idx / 160;
        v = (ci < 144) ? cc_w[co * 144 + ci] : 0.f;
    } else if (idx < 53248) {
        v = pi0_w[idx - 20480];
    } else if (idx < 69632) {
        v = pi1_w[idx - 53248];
    } else if (idx < 86016) {
        v = po0_w[idx - 69632];
    } else if (idx < 102400) {
        v = po1_w[idx - 86016];
    } else if (idx < 167936) {
        v = w1[idx - 102400];
    } else {
        v = w2[idx - 167936];
    }
    o[idx] = f2bf(v);
}

// ------------------------- conv3x3, LDS-staged (ssfe, fp32 in) -------------
template <int CINP, int NCH, int M>
__global__ __launch_bounds__(256) void conv3x3_stg_kernel(
    const float* __restrict__ in, int CIN,
    const unsigned short* __restrict__ wrep,
    const float* __restrict__ g, const float* __restrict__ bb,
    unsigned short* __restrict__ outT, int Cout, int zcol)
{
    __shared__ unsigned short X[194 * 40];
    const int tid = threadIdx.x;
    const int b = blockIdx.x, gr = blockIdx.y, cg = blockIdx.z;
    const int co0 = cg * (M * 16);
    const int pbase = gr << 7;
    const int gbase = pbase - 33;
    const int wv = tid >> 6, lane = tid & 63;
    const int ll = lane & 15, lk = lane >> 4;
    const float* inb = in + ((size_t)b * CIN << 10);

    f32x4 acc[M][2];
#pragma unroll
    for (int i = 0; i < M; ++i)
#pragma unroll
        for (int j = 0; j < 2; ++j)
#pragma unroll
            for (int r = 0; r < 4; ++r) acc[i][j][r] = 0.f;

#pragma unroll 1
    for (int ch = 0; ch < NCH; ++ch) {
        const int c0 = ch << 5;
#pragma unroll 1
        for (int idx = tid; idx < 16 * 194; idx += 256) {
            const int ci2 = idx / 194;
            const int sp = idx - ci2 * 194;
            const int ci = c0 + ci2 * 2;
            const int gp = gbase + sp;
            const bool inr = (gp >= 0) & (gp < 1024);
            const float* p0 = inb + ((size_t)ci << 10);
            float a = (inr && ci < CIN) ? p0[gp] : 0.f;
            float c = (inr && (ci + 1) < CIN) ? p0[gp + 1024] : 0.f;
            *(unsigned*)&X[sp * 40 + ci2 * 2] =
                (unsigned)f2bf(a) | ((unsigned)f2bf(c) << 16);
        }
        __syncthreads();
#pragma unroll
        for (int tap = 0; tap < 9; ++tap) {
            const int soff = (tap / 3) * 32 + (tap % 3);
            const int dx = tap % 3;
            bf16x8 bfrag[2];
#pragma unroll
            for (int j = 0; j < 2; ++j) {
                const int p = wv * 32 + j * 16 + ll;
                bf16x8 v = *(const bf16x8*)&X[(p + soff) * 40 + lk * 8];
                const bool zed = (dx == 0 && j == 0 && ll == 0) ||
                                 (dx == 2 && j == 1 && ll == 15);
                if (zed) { bf16x8 z = {}; v = z; }
                bfrag[j] = v;
            }
            const unsigned short* wb =
                wrep + ((size_t)tap * Cout + co0) * CINP + c0 + lk * 8;
#pragma unroll
            for (int i = 0; i < M; ++i) {
                bf16x8 afr = *(const bf16x8*)(wb + (size_t)(i * 16 + ll) * CINP);
#pragma unroll
                for (int j = 0; j < 2; ++j)
                    acc[i][j] = __builtin_amdgcn_mfma_f32_16x16x32_bf16(
                        afr, bfrag[j], acc[i][j], 0, 0, 0);
            }
        }
        __syncthreads();
    }

#pragma unroll
    for (int i = 0; i < M; ++i) {
#pragma unroll
        for (int j = 0; j < 2; ++j) {
            const int px = pbase + wv * 32 + j * 16 + ll;
            u16x4 tp;
#pragma unroll
            for (int r = 0; r < 4; ++r) {
                const int co = co0 + i * 16 + lk * 4 + r;
                float v = fmaxf(acc[i][j][r] * g[co] + bb[co], 0.f);
                tp[r] = f2bf(v);
            }
            *(u16x4*)(outT + (((size_t)b << 10) + px) * CINP + co0 + i * 16 + lk * 4) = tp;
            if (cg == (int)gridDim.z - 1 && i == 0) {
                u16x4 z = {};
                *(u16x4*)(outT + (((size_t)b << 10) + px) * CINP + zcol + lk * 4) = z;
            }
        }
    }
}

// ------------------------- conv3x3 bf16->bf16, 64px x 128co blocks ---------
// xT/resT/outT: (B,1024,*) bf16 px-major (pitch CINP in / 128 out).
// Block: (b, 64 px). 4 waves x 32 co. out = relu(conv*g+b) [+resT].
template <int CINP>
__global__ __launch_bounds__(256) void conv3x3_lds_kernel(
    const unsigned short* __restrict__ xT,
    const unsigned short* __restrict__ wrep,
    const float* __restrict__ g, const float* __restrict__ bb,
    const unsigned short* __restrict__ resT,
    unsigned short* __restrict__ outT, int Cout)
{
    constexpr int PITCH = CINP + 8;
    constexpr int NCHK = CINP / 8;
    __shared__ unsigned short X[130 * PITCH];
    const int tid = threadIdx.x;
    const int b = blockIdx.x, gr = blockIdx.y;
    const int pbase = gr << 6;
    const int gbase = pbase - 33;
    const int wid = tid >> 6, lane = tid & 63;
    const int ll = lane & 15, lq = lane >> 4;
    const int co0w = wid << 5;
    const unsigned short* xb = xT + ((size_t)b << 10) * CINP;

#pragma unroll 1
    for (int idx = tid; idx < 130 * NCHK; idx += 256) {
        const int row = idx / NCHK;
        const int chunk = idx - row * NCHK;
        const int gp = gbase + row;
        u16x8 v = {};
        if (gp >= 0 && gp < 1024)
            v = *(const u16x8*)(xb + (size_t)gp * CINP + chunk * 8);
        *(u16x8*)&X[row * PITCH + chunk * 8] = v;
    }
    __syncthreads();

    f32x4 acc[2][4];
#pragma unroll
    for (int i = 0; i < 2; ++i)
#pragma unroll
        for (int j = 0; j < 4; ++j)
#pragma unroll
            for (int r = 0; r < 4; ++r) acc[i][j][r] = 0.f;

#pragma unroll
    for (int tap = 0; tap < 9; ++tap) {
        const int soff = (tap / 3) * 32 + (tap % 3);
        const int dx = tap % 3;
#pragma unroll
        for (int kc = 0; kc < CINP / 32; ++kc) {
            bf16x8 bfv[4];
#pragma unroll
            for (int j = 0; j < 4; ++j) {
                const int p = j * 16 + ll;
                bf16x8 v = *(const bf16x8*)&X[(p + soff) * PITCH + kc * 32 + lq * 8];
                const bool zed = (dx == 0 && (j & 1) == 0 && ll == 0) ||
                                 (dx == 2 && (j & 1) == 1 && ll == 15);
                if (zed) { bf16x8 z = {}; v = z; }
                bfv[j] = v;
            }
            const unsigned short* wb =
                wrep + ((size_t)tap * Cout + co0w) * CINP + kc * 32 + lq * 8;
#pragma unroll
            for (int i = 0; i < 2; ++i) {
                bf16x8 af = *(const bf16x8*)(wb + (size_t)(i * 16 + ll) * CINP);
#pragma unroll
                for (int j = 0; j < 4; ++j)
                    acc[i][j] = __builtin_amdgcn_mfma_f32_16x16x32_bf16(
                        af, bfv[j], acc[i][j], 0, 0, 0);
            }
        }
    }

#pragma unroll
    for (int i = 0; i < 2; ++i) {
        const int cob = co0w + i * 16 + lq * 4;
        float gv[4], bv[4];
#pragma unroll
        for (int r = 0; r < 4; ++r) { gv[r] = g[cob + r]; bv[r] = bb[cob + r]; }
#pragma unroll
        for (int j = 0; j < 4; ++j) {
            const int px = pbase + j * 16 + ll;
            const size_t rowT = ((size_t)((b << 10) + px)) << 7;
            u16x4 rv = {};
            if (resT) rv = *(const u16x4*)(resT + rowT + cob);
            u16x4 tp;
#pragma unroll
            for (int r = 0; r < 4; ++r) {
                float v = fmaxf(acc[i][j][r] * gv[r] + bv[r], 0.f);
                if (resT) v += bf2f(rv[r]);
                tp[r] = f2bf(v);
            }
            *(u16x4*)(outT + rowT + cob) = tp;
        }
    }
}

// ------------------------- unified 1x1 via bf16 MFMA (64-px blocks) --------
// resT: optional bf16 px-major residual.
template <int KP>
__global__ __launch_bounds__(256) void lin_mfma_kernel(
    const unsigned short* __restrict__ xT, const unsigned short* __restrict__ wbf,
    const float* __restrict__ bias0, const float* __restrict__ g,
    const float* __restrict__ bb, const unsigned short* __restrict__ resT,
    float* __restrict__ outF, unsigned short* __restrict__ outBF,
    unsigned short* __restrict__ outT, int do_relu)
{
    const int tid = threadIdx.x;
    const int b = blockIdx.x;
    const int n0 = blockIdx.y << 6;
    const int wid = tid >> 6, lane = tid & 63;
    const int ll = lane & 15, lq = lane >> 4;
    const unsigned short* xb = xT + (size_t)((b << 10) + n0) * KP;

    f32x4 acc[2][4];
#pragma unroll
    for (int i = 0; i < 2; ++i)
#pragma unroll
        for (int j = 0; j < 4; ++j)
#pragma unroll
            for (int r = 0; r < 4; ++r) acc[i][j][r] = 0.f;

#pragma unroll
    for (int kk = 0; kk < KP / 32; ++kk) {
        bf16x8 af[2], bfv[4];
#pragma unroll
        for (int i = 0; i < 2; ++i)
            af[i] = *(const bf16x8*)(wbf + (size_t)(wid * 32 + i * 16 + ll) * KP + kk * 32 + lq * 8);
#pragma unroll
        for (int j = 0; j < 4; ++j)
            bfv[j] = *(const bf16x8*)(xb + (size_t)(j * 16 + ll) * KP + kk * 32 + lq * 8);
#pragma unroll
        for (int i = 0; i < 2; ++i)
#pragma unroll
            for (int j = 0; j < 4; ++j)
                acc[i][j] = __builtin_amdgcn_mfma_f32_16x16x32_bf16(af[i], bfv[j], acc[i][j], 0, 0, 0);
    }

#pragma unroll
    for (int i = 0; i < 2; ++i) {
        const int cob = wid * 32 + i * 16 + lq * 4;
        float b0v[4], gv[4], bv[4];
#pragma unroll
        for (int r = 0; r < 4; ++r) {
            b0v[r] = bias0 ? bias0[cob + r] : 0.f;
            gv[r] = g ? g[cob + r] : 1.f;
            bv[r] = g ? bb[cob + r] : 0.f;
        }
#pragma unroll
        for (int j = 0; j < 4; ++j) {
            const int px = n0 + j * 16 + ll;
            const size_t rowT = ((size_t)((b << 10) + px)) << 7;
            u16x4 rv = {};
            if (resT) rv = *(const u16x4*)(resT + rowT + cob);
            u16x4 tp;
#pragma unroll
            for (int r = 0; r < 4; ++r) {
                const int co = cob + r;
                float v = acc[i][j][r] + b0v[r];
                v = v * gv[r] + bv[r];
                if (do_relu) v = fmaxf(v, 0.f);
                if (resT) v += bf2f(rv[r]);
                if (outF) outF[((size_t)((b << 7) + co) << 10) + px] = v;
                unsigned short h = f2bf(v);
                if (outBF) outBF[((size_t)((b << 7) + co) << 10) + px] = h;
                tp[r] = h;
            }
            if (outT) *(u16x4*)(outT + rowT + cob) = tp;
        }
    }
}

// ------------------------- LayerNorm -> bf16 (ch-major + px-major) ---------
__global__ __launch_bounds__(256) void ln_kernel(
    const float* __restrict__ in, const float* __restrict__ g,
    const float* __restrict__ bb, unsigned short* __restrict__ out_bf,
    unsigned short* __restrict__ outT)
{
    const int tid = threadIdx.x;
    const int b = blockIdx.x >> 2;
    const int n = ((blockIdx.x & 3) << 8) + tid;
    const float* ib = in + ((size_t)b << 17) + n;
    float s = 0.f, sq = 0.f;
#pragma unroll 8
    for (int c = 0; c < 128; ++c) {
        float v = ib[(size_t)c << 10];
        s += v;
        sq += v * v;
    }
    const float mu = s * 0.0078125f;
    const float r = rsqrtf(sq * 0.0078125f - mu * mu + 1e-5f);
    unsigned short* obf = out_bf + ((size_t)b << 17) + n;
    unsigned short* oT = outT + (((size_t)b << 10) + n) * 128;
#pragma unroll 2
    for (int c0 = 0; c0 < 128; c0 += 8) {
        u16x8 pk;
#pragma unroll
        for (int e = 0; e < 8; ++e) {
            const int c = c0 + e;
            float v = ib[(size_t)c << 10];
            float y = (v - mu) * r * g[c] + bb[c];
            unsigned short h = f2bf(y);
            obf[(size_t)c << 10] = h;
            pk[e] = h;
        }
        *(u16x8*)(oT + c0) = pk;
    }
}

// ------------------------- Gram matrix via bf16 MFMA -----------------------
__global__ __launch_bounds__(256) void gram_kernel(
    const unsigned short* __restrict__ Xbf, float* __restrict__ G)
{
    __shared__ unsigned short Xs[128 * 128];
    const int tid = threadIdx.x;
    const int b = blockIdx.x >> 2;
    const int rg = blockIdx.x & 3;
    const int wid = tid >> 6, lane = tid & 63;
    const int lq = lane >> 4, ll = lane & 15;
    const unsigned short* Xb = Xbf + ((size_t)b << 17);

    f32x4 acc[2][2];
#pragma unroll
    for (int mi = 0; mi < 2; ++mi)
#pragma unroll
        for (int ci = 0; ci < 2; ++ci)
#pragma unroll
            for (int r = 0; r < 4; ++r) acc[mi][ci][r] = 0.f;

#pragma unroll 1
    for (int nt = 0; nt < 8; ++nt) {
        const int n0 = nt << 7;
#pragma unroll
        for (int p = 0; p < 8; ++p) {
            const int ch = (p << 4) + (tid >> 4);
            const int seg = (tid & 15) << 3;
            *(u16x8*)&Xs[ch * 128 + (seg ^ ((ch & 7) << 3))] =
                *(const u16x8*)(Xb + ((size_t)ch << 10) + n0 + seg);
        }
        __syncthreads();
#pragma unroll
        for (int ks = 0; ks < 4; ++ks) {
            bf16x8 af[2], bf_[2];
#pragma unroll
            for (int mi = 0; mi < 2; ++mi) {
                const int ar = (rg << 5) + mi * 16 + ll;
                af[mi] = *(const bf16x8*)&Xs[ar * 128 + ((ks * 32 + lq * 8) ^ ((ar & 7) << 3))];
            }
#pragma unroll
            for (int ci = 0; ci < 2; ++ci) {
                const int br = (wid << 5) + ci * 16 + ll;
                bf_[ci] = *(const bf16x8*)&Xs[br * 128 + ((ks * 32 + lq * 8) ^ ((br & 7) << 3))];
            }
#pragma unroll
            for (int mi = 0; mi < 2; ++mi)
#pragma unroll
                for (int ci = 0; ci < 2; ++ci)
                    acc[mi][ci] = __builtin_amdgcn_mfma_f32_16x16x32_bf16(
                        af[mi], bf_[ci], acc[mi][ci], 0, 0, 0);
        }
        __syncthreads();
    }
    float* Gb = G + ((size_t)b << 14);
#pragma unroll
    for (int mi = 0; mi < 2; ++mi)
#pragma unroll
        for (int ci = 0; ci < 2; ++ci)
#pragma unroll
            for (int r = 0; r < 4; ++r) {
                const int row = (rg << 5) + mi * 16 + lq * 4 + r;
                const int col = (wid << 5) + ci * 16 + ll;
                Gb[row * 128 + col] = acc[mi][ci][r];
            }
}

// ------------------------- channel row-sums of bf16 tensor -----------------
__global__ __launch_bounds__(256) void sums_kernel(
    const unsigned short* __restrict__ Xbf, float* __restrict__ S)
{
    const int tid = threadIdx.x;
    const int b = blockIdx.x;
    const int ch = tid >> 1, half = tid & 1;
    const unsigned short* p = Xbf + ((size_t)b << 17) + ((size_t)ch << 10) + half * 512;
    float s = 0.f;
#pragma unroll 4
    for (int i = 0; i < 64; ++i) {
        u16x8 v = *(const u16x8*)(p + i * 8);
#pragma unroll
        for (int e = 0; e < 8; ++e) s += bf2f(v[e]);
    }
    s += __shfl_xor(s, 1);
    if (half == 0) S[(b << 7) + ch] = s;
}

// ------------------------- GISSA stage-1 matrices (bf16 M1) ----------------
__global__ __launch_bounds__(64) void mats1_kernel(
    const float* __restrict__ G, const float* __restrict__ S,
    const float* __restrict__ qkv_w, const float* __restrict__ qkv_b,
    const float* __restrict__ g, const float* __restrict__ bb,
    unsigned short* __restrict__ M1, float* __restrict__ c1)
{
    const int lane = threadIdx.x;
    const int b = blockIdx.x >> 4, h = blockIdx.x & 15;
    const float* Gb = G + ((size_t)b << 14);
    const float* Sb = S + (b << 7);
    const int d = lane >> 3, e = lane & 7;
    const int qch = h * 8 + d, kch = 128 + h * 8 + e;
    const int qoff = (qch / 24) * 8, koff = (kch / 24) * 8;
    float wq[8], wk[8];
#pragma unroll
    for (int i = 0; i < 8; ++i) {
        wq[i] = qkv_w[qch * 8 + i];
        wk[i] = qkv_w[kch * 8 + i];
    }
    float s = 0.f;
#pragma unroll
    for (int i = 0; i < 8; ++i) {
        float gu = 0.f;
#pragma unroll
        for (int j = 0; j < 8; ++j) gu += Gb[(qoff + i) * 128 + koff + j] * wk[j];
        s += wq[i] * gu;
    }
    const float bq = qkv_b[qch], bk = qkv_b[kch];
    float swk = 0.f, swq = 0.f;
#pragma unroll
    for (int j = 0; j < 8; ++j) { swk += wk[j] * Sb[koff + j]; swq += wq[j] * Sb[qoff + j]; }
    s += bq * swk + bk * swq + 1024.f * bq * bk;
    s *= 0.35355339059327373f;
    float a = (s > 0.f) ? sqrtf(s + 1e-5f) : ((s < 0.f) ? -sqrtf(1e-5f - s) : 0.f);
    float mx = a;
    mx = fmaxf(mx, __shfl_xor(mx, 1));
    mx = fmaxf(mx, __shfl_xor(mx, 2));
    mx = fmaxf(mx, __shfl_xor(mx, 4));
    float p = __expf(a - mx);
    float den = p;
    den += __shfl_xor(den, 1);
    den += __shfl_xor(den, 2);
    den += __shfl_xor(den, 4);
    const float A = p / den;

    const int l = e;
    const int cp = d * 16 + h;
    float row[16];
#pragma unroll
    for (int j = 0; j < 16; ++j) row[j] = 0.f;
    float cacc = 0.f;
#pragma unroll
    for (int e2 = 0; e2 < 8; ++e2) {
        const float Ae = __shfl(A, d * 8 + e2);
        const int vch = 256 + h * 8 + e2;
        const int voff = (vch / 24) * 8;
        cacc += Ae * qkv_b[vch];
        if ((voff >> 4) == l) {
            const int base = voff & 15;
#pragma unroll
            for (int j = 0; j < 8; ++j) row[base + j] += Ae * qkv_w[vch * 8 + j];
        }
    }
    const int idc = h * 8 + d;
    if ((idc >> 4) == l) row[idc & 15] += 1.f;
    const float gg = g[cp];
    unsigned short* mrow = M1 + ((size_t)b << 14) + cp * 128 + l * 16;
#pragma unroll
    for (int j = 0; j < 16; ++j) mrow[j] = f2bf(gg * row[j]);
    if (l == 0) c1[(b << 7) + cp] = gg * cacc + bb[cp];
}

// ------------------------- GISSA stage-2 matrices (bf16 M2) ----------------
__global__ __launch_bounds__(256) void mats2_kernel(
    const float* __restrict__ G, const float* __restrict__ S,
    const float* __restrict__ qkv2_w, const float* __restrict__ qkv2_b,
    unsigned short* __restrict__ M2, float* __restrict__ c2)
{
    const int tid = threadIdx.x;
    const int b = blockIdx.x >> 3, d = blockIdx.x & 7;
    const float* Gb = G + ((size_t)b << 14);
    const float* Sb = S + (b << 7);
    const int h = tid >> 4, gq = tid & 15;
    const int q2ch = d * 16 + h, k2ch = 128 + d * 16 + gq;
    const int qoff = (q2ch / 48) * 16, koff = (k2ch / 48) * 16;
    float wq[16], wk[16];
#pragma unroll
    for (int i = 0; i < 16; ++i) {
        wq[i] = qkv2_w[q2ch * 16 + i];
        wk[i] = qkv2_w[k2ch * 16 + i];
    }
    float s = 0.f;
#pragma unroll
    for (int i = 0; i < 16; ++i) {
        float gu = 0.f;
#pragma unroll
        for (int j = 0; j < 16; ++j) gu += Gb[(qoff + i) * 128 + koff + j] * wk[j];
        s += wq[i] * gu;
    }
    const float bq = qkv2_b[q2ch], bk = qkv2_b[k2ch];
    float swk = 0.f, swq = 0.f;
#pragma unroll
    for (int j = 0; j < 16; ++j) { swk += wk[j] * Sb[koff + j]; swq += wq[j] * Sb[qoff + j]; }
    s += bq * swk + bk * swq + 1024.f * bq * bk;
    s *= 0.25f;
    float a = (s > 0.f) ? sqrtf(s + 1e-5f) : ((s < 0.f) ? -sqrtf(1e-5f - s) : 0.f);
    float mx = a;
    mx = fmaxf(mx, __shfl_xor(mx, 1));
    mx = fmaxf(mx, __shfl_xor(mx, 2));
    mx = fmaxf(mx, __shfl_xor(mx, 4));
    mx = fmaxf(mx, __shfl_xor(mx, 8));
    float p = __expf(a - mx);
    float den = p;
    den += __shfl_xor(den, 1);
    den += __shfl_xor(den, 2);
    den += __shfl_xor(den, 4);
    den += __shfl_xor(den, 8);
    const float A2 = p / den;

    const int l = gq;
    float row[8];
#pragma unroll
    for (int j = 0; j < 8; ++j) row[j] = 0.f;
    float cacc = 0.f;
#pragma unroll
    for (int g2 = 0; g2 < 16; ++g2) {
        const float Ag = __shfl(A2, (tid & 48) + g2);
        const int v2ch = 256 + d * 16 + g2;
        const int voff = (v2ch / 48) * 16;
        cacc += Ag * qkv2_b[v2ch];
        if ((l >> 1) == (voff >> 4)) {
            const int base = (l & 1) * 8;
#pragma unroll
            for (int j = 0; j < 8; ++j) row[j] += Ag * qkv2_w[v2ch * 16 + base + j];
        }
    }
    const int c = h * 8 + d;
    unsigned short* mrow = M2 + ((size_t)b << 14) + c * 128 + l * 8;
#pragma unroll
    for (int j = 0; j < 8; ++j) mrow[j] = f2bf(row[j]);
    if (l == 0) c2[(b << 7) + c] = cacc;
}

// ------------------------- apply1: y = M1 x + c1 (MFMA) --------------------
__global__ __launch_bounds__(256) void apply1_mfma_kernel(
    const unsigned short* __restrict__ curT, const unsigned short* __restrict__ M1bf,
    const float* __restrict__ c1, float* __restrict__ ybuf,
    unsigned short* __restrict__ yrbf, unsigned short* __restrict__ yrT)
{
    const int tid = threadIdx.x;
    const int b = blockIdx.x >> 3;
    const int n0 = (blockIdx.x & 7) << 7;
    const int wid = tid >> 6, lane = tid & 63;
    const int wr = wid >> 1, wc = wid & 1;
    const int ll = lane & 15, lq = lane >> 4;
    const unsigned short* Mb = M1bf + ((size_t)b << 14);
    const unsigned short* xb = curT + (((size_t)b << 10) + n0 + wc * 64) * 128;

    f32x4 acc[4][4];
#pragma unroll
    for (int i = 0; i < 4; ++i)
#pragma unroll
        for (int j = 0; j < 4; ++j)
#pragma unroll
            for (int r = 0; r < 4; ++r) acc[i][j][r] = 0.f;

#pragma unroll
    for (int kk = 0; kk < 4; ++kk) {
        bf16x8 af[4], bfv[4];
#pragma unroll
        for (int i = 0; i < 4; ++i)
            af[i] = *(const bf16x8*)(Mb + (size_t)(wr * 64 + i * 16 + ll) * 128 + kk * 32 + lq * 8);
#pragma unroll
        for (int j = 0; j < 4; ++j)
            bfv[j] = *(const bf16x8*)(xb + (size_t)(j * 16 + ll) * 128 + kk * 32 + lq * 8);
#pragma unroll
        for (int i = 0; i < 4; ++i)
#pragma unroll
            for (int j = 0; j < 4; ++j)
                acc[i][j] = __builtin_amdgcn_mfma_f32_16x16x32_bf16(af[i], bfv[j], acc[i][j], 0, 0, 0);
    }

#pragma unroll
    for (int i = 0; i < 4; ++i) {
        const int cob = wr * 64 + i * 16 + lq * 4;
        float c1v[4];
#pragma unroll
        for (int r = 0; r < 4; ++r) c1v[r] = c1[(b << 7) + cob + r];
#pragma unroll
        for (int j = 0; j < 4; ++j) {
            const int px = n0 + wc * 64 + j * 16 + ll;
            u16x4 tp;
#pragma unroll
            for (int r = 0; r < 4; ++r) {
                const int co = cob + r;
                const float v = acc[i][j][r] + c1v[r];
                const size_t oi = ((size_t)(b * 128 + co) << 10) + px;
                ybuf[oi] = v;
                const unsigned short h = f2bf(fmaxf(v, 0.f));
                yrbf[oi] = h;
                tp[r] = h;
            }
            *(u16x4*)(yrT + (((size_t)b << 10) + px) * 128 + cob) = tp;
        }
    }
}

// ------------------------- apply2: t += M2 relu(y) + c2 + y (MFMA) ---------
__global__ __launch_bounds__(256) void apply2_mfma_kernel(
    const unsigned short* __restrict__ yrT, const unsigned short* __restrict__ M2bf,
    const float* __restrict__ c2, const float* __restrict__ ybuf,
    float* __restrict__ t)
{
    const int tid = threadIdx.x;
    const int b = blockIdx.x >> 3;
    const int n0 = (blockIdx.x & 7) << 7;
    const int wid = tid >> 6, lane = tid & 63;
    const int wr = wid >> 1, wc = wid & 1;
    const int ll = lane & 15, lq = lane >> 4;
    const unsigned short* Mb = M2bf + ((size_t)b << 14);
    const unsigned short* xb = yrT + (((size_t)b << 10) + n0 + wc * 64) * 128;

    f32x4 acc[4][4];
#pragma unroll
    for (int i = 0; i < 4; ++i)
#pragma unroll
        for (int j = 0; j < 4; ++j)
#pragma unroll
            for (int r = 0; r < 4; ++r) acc[i][j][r] = 0.f;

#pragma unroll
    for (int kk = 0; kk < 4; ++kk) {
        bf16x8 af[4], bfv[4];
#pragma unroll
        for (int i = 0; i < 4; ++i)
            af[i] = *(const bf16x8*)(Mb + (size_t)(wr * 64 + i * 16 + ll) * 128 + kk * 32 + lq * 8);
#pragma unroll
        for (int j = 0; j < 4; ++j)
            bfv[j] = *(const bf16x8*)(xb + (size_t)(j * 16 + ll) * 128 + kk * 32 + lq * 8);
#pragma unroll
        for (int i = 0; i < 4; ++i)
#pragma unroll
            for (int j = 0; j < 4; ++j)
                acc[i][j] = __builtin_amdgcn_mfma_f32_16x16x32_bf16(af[i], bfv[j], acc[i][j], 0, 0, 0);
    }

#pragma unroll
    for (int i = 0; i < 4; ++i) {
        const int cob = wr * 64 + i * 16 + lq * 4;
        float c2v[4];
#pragma unroll
        for (int r = 0; r < 4; ++r) c2v[r] = c2[(b << 7) + cob + r];
#pragma unroll
        for (int j = 0; j < 4; ++j) {
            const int px = n0 + wc * 64 + j * 16 + ll;
#pragma unroll
            for (int r = 0; r < 4; ++r) {
                const size_t oi = ((size_t)(b * 128 + cob + r) << 10) + px;
                t[oi] += acc[i][j][r] + c2v[r] + ybuf[oi];
            }
        }
    }
}

// ------------------------- fused LN2 + MLP via bf16 MFMA -------------------
__global__ __launch_bounds__(256) void mlp_mfma_kernel(
    float* __restrict__ t, const float* __restrict__ ln_g,
    const float* __restrict__ ln_b, const unsigned short* __restrict__ w1bf,
    const float* __restrict__ b1, const unsigned short* __restrict__ w2bf,
    const float* __restrict__ b2)
{
    __shared__ unsigned char lds[16384 + 65536];
    unsigned char* xnb = lds;
    unsigned char* hb = lds + 16384;

    const int tid = threadIdx.x;
    const int b = blockIdx.x >> 4;
    const int n0 = (blockIdx.x & 15) << 6;
    float* tb = t + ((size_t)b << 17) + n0;

    {
        const int px = tid >> 2, q = tid & 3;
        float v[32];
        float s = 0.f, sq = 0.f;
#pragma unroll
        for (int k = 0; k < 32; ++k) {
            float x = tb[((size_t)(q * 32 + k) << 10) + px];
            v[k] = x;
            s += x;
            sq += x * x;
        }
        s += __shfl_xor(s, 1); s += __shfl_xor(s, 2);
        sq += __shfl_xor(sq, 1); sq += __shfl_xor(sq, 2);
        const float mu = s * 0.0078125f;
        const float rstd = rsqrtf(sq * 0.0078125f - mu * mu + 1e-5f);
        const int sw = (px & 7) << 4;
#pragma unroll
        for (int cc = 0; cc < 4; ++cc) {
            u16x8 pk;
#pragma unroll
            for (int e = 0; e < 8; ++e) {
                int c = q * 32 + cc * 8 + e;
                float xv = (v[cc * 8 + e] - mu) * rstd * ln_g[c] + ln_b[c];
                pk[e] = f2bf(xv);
            }
            *(u16x8*)(xnb + px * 256 + ((q * 64 + cc * 16) ^ sw)) = pk;
        }
    }
    __syncthreads();

    const int wid = tid >> 6, lane = tid & 63;
    const int lr = lane & 15, lk = lane >> 4;

#pragma unroll 1
    for (int pass = 0; pass < 2; ++pass) {
        const int hidbase = (wid << 7) + (pass << 6);
        f32x4 acc[4][4];
#pragma unroll
        for (int i = 0; i < 4; ++i)
#pragma unroll
            for (int j = 0; j < 4; ++j)
#pragma unroll
                for (int r = 0; r < 4; ++r) acc[i][j][r] = 0.f;
#pragma unroll
        for (int kk = 0; kk < 4; ++kk) {
            bf16x8 af[4], bfr[4];
#pragma unroll
            for (int i = 0; i < 4; ++i)
                af[i] = *(const bf16x8*)(w1bf + (size_t)(hidbase + i * 16 + lr) * 128 + kk * 32 + lk * 8);
#pragma unroll
            for (int j = 0; j < 4; ++j) {
                const int px = j * 16 + lr;
                bfr[j] = *(const bf16x8*)(xnb + px * 256 + ((kk * 64 + lk * 16) ^ ((px & 7) << 4)));
            }
#pragma unroll
            for (int i = 0; i < 4; ++i)
#pragma unroll
                for (int j = 0; j < 4; ++j)
                    acc[i][j] = __builtin_amdgcn_mfma_f32_16x16x32_bf16(af[i], bfr[j], acc[i][j], 0, 0, 0);
        }
#pragma unroll
        for (int i = 0; i < 4; ++i) {
            const int hid0 = hidbase + i * 16 + lk * 4;
            float bi[4];
#pragma unroll
            for (int r = 0; r < 4; ++r) bi[r] = b1[hid0 + r];
#pragma unroll
            for (int j = 0; j < 4; ++j) {
                const int px = j * 16 + lr;
                u16x4 pk;
#pragma unroll
                for (int r = 0; r < 4; ++r) {
                    float x = acc[i][j][r] + bi[r];
                    float u = 1.5957691f * x * (1.f + 0.044715f * x * x);
                    float gv = x / (1.f + __expf(-u));
                    pk[r] = f2bf(gv);
                }
                *(u16x4*)(hb + px * 1024 + ((hid0 * 2) ^ ((px & 7) << 4))) = pk;
            }
        }
    }
    __syncthreads();

    f32x4 acc2[2][4];
#pragma unroll
    for (int i = 0; i < 2; ++i)
#pragma unroll
        for (int j = 0; j < 4; ++j)
#pragma unroll
            for (int r = 0; r < 4; ++r) acc2[i][j][r] = 0.f;
#pragma unroll 2
    for (int ks = 0; ks < 16; ++ks) {
        bf16x8 af[2], bfr[4];
#pragma unroll
        for (int i = 0; i < 2; ++i)
            af[i] = *(const bf16x8*)(w2bf + (size_t)((wid << 5) + i * 16 + lr) * 512 + ks * 32 + lk * 8);
#pragma unroll
        for (int j = 0; j < 4; ++j) {
            const int px = j * 16 + lr;
            bfr[j] = *(const bf16x8*)(hb + px * 1024 + ((ks * 64 + lk * 16) ^ ((px & 7) << 4)));
        }
#pragma unroll
        for (int i = 0; i < 2; ++i)
#pragma unroll
            for (int j = 0; j < 4; ++j)
                acc2[i][j] = __builtin_amdgcn_mfma_f32_16x16x32_bf16(af[i], bfr[j], acc2[i][j], 0, 0, 0);
    }
#pragma unroll
    for (int i = 0; i < 2; ++i) {
        const int cb = (wid << 5) + i * 16 + lk * 4;
        float b2v[4];
#pragma unroll
        for (int r = 0; r < 4; ++r) b2v[r] = b2[cb + r];
#pragma unroll
        for (int j = 0; j < 4; ++j) {
            const int px = j * 16 + lr;
#pragma unroll
            for (int r = 0; r < 4; ++r) {
                const size_t off = ((size_t)(cb + r) << 10) + px;
                tb[off] += acc2[i][j][r] + b2v[r];
            }
        }
    }
}

// ------------------------- flash SWSA via bf16 MFMA ------------------------
// 64 q-rows per block; grid.x = 512, b = idx&31 (XCD-local). fp32 out optional.
__global__ __launch_bounds__(256) void swsa_mfma_kernel(
    const unsigned short* __restrict__ qT, const unsigned short* __restrict__ vbf,
    float* __restrict__ outp, unsigned short* __restrict__ outT, float fscale)
{
    __shared__ unsigned short K_lds[128 * 128];
    __shared__ unsigned short V_lds[128 * 128];
    const int tid = threadIdx.x;
    const int b = blockIdx.x & 31;
    const int n0 = (blockIdx.x >> 5) << 6;
    const int wid = tid >> 6, lane = tid & 63;
    const int lq = lane >> 4, ll = lane & 15;
    const unsigned short* qTb = qT + ((size_t)b << 17);
    const unsigned short* vb = vbf + ((size_t)b << 17);

    bf16x8 aq[4];
    {
        const int row = n0 + wid * 16 + ll;
#pragma unroll
        for (int kk = 0; kk < 4; ++kk)
            aq[kk] = *(const bf16x8*)(qTb + ((size_t)row << 7) + kk * 32 + lq * 8);
    }

    float mrun[4], lrun[4];
#pragma unroll
    for (int i = 0; i < 4; ++i) { mrun[i] = -INFINITY; lrun[i] = 0.f; }
    f32x4 yacc[8];
#pragma unroll
    for (int cj = 0; cj < 8; ++cj)
#pragma unroll
        for (int r = 0; r < 4; ++r) yacc[cj][r] = 0.f;

#pragma unroll 1
    for (int mt = 0; mt < 8; ++mt) {
        const int m0 = mt << 7;
        for (int ch = tid; ch < 2048; ch += 256) {
            const int rr = ch >> 4, e0 = (ch & 15) << 3;
            const int sw = (rr & 7) << 3;
            *(u16x8*)&K_lds[rr * 128 + (e0 ^ sw)] =
                *(const u16x8*)(qTb + ((size_t)(m0 + rr) << 7) + e0);
            *(u16x8*)&V_lds[rr * 128 + (e0 ^ sw)] =
                *(const u16x8*)(vb + ((size_t)rr << 10) + m0 + e0);
        }
        __syncthreads();

        f32x4 sacc[8];
#pragma unroll
        for (int j = 0; j < 8; ++j)
#pragma unroll
            for (int r = 0; r < 4; ++r) sacc[j][r] = 0.f;
#pragma unroll
        for (int j = 0; j < 8; ++j) {
            const int ml = j * 16 + ll;
            const int swk = (ml & 7) << 3;
#pragma unroll
            for (int kk = 0; kk < 4; ++kk) {
                bf16x8 bk = *(const bf16x8*)&K_lds[ml * 128 + ((kk * 32 + lq * 8) ^ swk)];
                sacc[j] = __builtin_amdgcn_mfma_f32_16x16x32_bf16(aq[kk], bk, sacc[j], 0, 0, 0);
            }
        }
        __syncthreads();

        float pmax[4];
#pragma unroll
        for (int i = 0; i < 4; ++i) pmax[i] = -INFINITY;
#pragma unroll
        for (int j = 0; j < 8; ++j)
#pragma unroll
            for (int r = 0; r < 4; ++r) {
                float s = sacc[j][r] * 0.08838834764831845f;
                sacc[j][r] = s;
                pmax[r] = fmaxf(pmax[r], s);
            }
        float alpha[4];
#pragma unroll
        for (int i = 0; i < 4; ++i) {
            float m = pmax[i];
            m = fmaxf(m, __shfl_xor(m, 1));
            m = fmaxf(m, __shfl_xor(m, 2));
            m = fmaxf(m, __shfl_xor(m, 4));
            m = fmaxf(m, __shfl_xor(m, 8));
            const float mn = fmaxf(mrun[i], m);
            alpha[i] = __expf(mrun[i] - mn);
            mrun[i] = mn;
        }
        float psum[4];
#pragma unroll
        for (int r = 0; r < 4; ++r) {
            const int nbw = wid * 16 + lq * 4 + r;
            const int sw4 = ((nbw >> 2) & 3) << 4;
            const float mn = mrun[r];
            float ps = 0.f;
#pragma unroll
            for (int j = 0; j < 8; ++j) {
                float p = __expf(sacc[j][r] - mn);
                ps += p;
                K_lds[nbw * 128 + ((j * 16 + ll) ^ sw4)] = f2bf(p);
            }
            psum[r] = ps;
        }
#pragma unroll
        for (int i = 0; i < 4; ++i) {
            float s = psum[i];
            s += __shfl_xor(s, 1);
            s += __shfl_xor(s, 2);
            s += __shfl_xor(s, 4);
            s += __shfl_xor(s, 8);
            lrun[i] = lrun[i] * alpha[i] + s;
        }
#pragma unroll
        for (int cj = 0; cj < 8; ++cj)
#pragma unroll
            for (int r = 0; r < 4; ++r) yacc[cj][r] *= alpha[r];

        bf16x8 ap[4];
        {
            const int nb = wid * 16 + ll;
            const int sw4 = ((nb >> 2) & 3) << 4;
#pragma unroll
            for (int mk = 0; mk < 4; ++mk)
                ap[mk] = *(const bf16x8*)&K_lds[nb * 128 + ((mk * 32 + lq * 8) ^ sw4)];
        }
#pragma unroll
        for (int cj = 0; cj < 8; ++cj) {
            const int cl = cj * 16 + ll;
            const int sw = (cl & 7) << 3;
#pragma unroll
            for (int mk = 0; mk < 4; ++mk) {
                bf16x8 bv = *(const bf16x8*)&V_lds[cl * 128 + ((mk * 32 + lq * 8) ^ sw)];
                yacc[cj] = __builtin_amdgcn_mfma_f32_16x16x32_bf16(ap[mk], bv, yacc[cj], 0, 0, 0);
            }
        }
        __syncthreads();
    }

    const int nbase = n0 + wid * 16 + lq * 4;
    float inv[4];
#pragma unroll
    for (int r = 0; r < 4; ++r) inv[r] = fscale / lrun[r];
#pragma unroll
    for (int cj = 0; cj < 8; ++cj) {
        const int c = cj * 16 + ll;
        float4 o;
        o.x = yacc[cj][0] * inv[0];
        o.y = yacc[cj][1] * inv[1];
        o.z = yacc[cj][2] * inv[2];
        o.w = yacc[cj][3] * inv[3];
        if (outp)
            *(float4*)(outp + ((size_t)(b * 128 + c) << 10) + nbase) = o;
        if (outT) {
            unsigned short* tb = outT + ((size_t)((b << 10) + nbase)) * 128 + c;
            tb[0] = f2bf(o.x);
            tb[128] = f2bf(o.y);
            tb[256] = f2bf(o.z);
            tb[384] = f2bf(o.w);
        }
    }
}

// ------------------------- final: mean (stage 1) ---------------------------
__global__ __launch_bounds__(256) void mean_kernel(
    const float* __restrict__ xc, const float* __restrict__ xp,
    const float* __restrict__ lamuda, float* __restrict__ meanb)
{
    const int wid = threadIdx.x >> 6, lane = threadIdx.x & 63;
    const int row = (blockIdx.x << 2) + wid;
    const float lmd = 1.f / (1.f + __expf(-lamuda[0]));
    const float* a = xc + ((size_t)row << 10) + (lane << 2);
    const float* d = xp + ((size_t)row << 10) + (lane << 2);
    float s = 0.f;
#pragma unroll
    for (int i = 0; i < 4; ++i) {
        float4 va = *(const float4*)(a + (i << 8));
        float4 vd = *(const float4*)(d + (i << 8));
        s += lmd * (va.x + va.y + va.z + va.w) +
             (1.f - lmd) * (vd.x + vd.y + vd.z + vd.w);
    }
#pragma unroll
    for (int o = 1; o < 64; o <<= 1) s += __shfl_xor(s, o);
    if (lane == 0) meanb[row] = s * (1.f / 1024.f);
}

// ------------------------- final: fc (stage 2) -----------------------------
__global__ __launch_bounds__(256) void fc_kernel(
    const float* __restrict__ meanb, const float* __restrict__ fc_w,
    float* __restrict__ outp)
{
    const int idx = blockIdx.x * 256 + threadIdx.x;
    if (idx >= 512) return;
    const int b = idx >> 4, o = idx & 15;
    float s = 0.f;
#pragma unroll 4
    for (int c = 0; c < 128; ++c) s += fc_w[o * 128 + c] * meanb[b * 128 + c];
    outp[b * 16 + o] = s;
}

// ---------------------------------------------------------------------------
extern "C" void kernel_launch(void* const* d_in, const int* in_sizes, int n_in,
                              void* d_out, int out_size, void* d_ws, size_t ws_size,
                              hipStream_t stream)
{
    (void)in_sizes; (void)n_in; (void)out_size; (void)ws_size;

    const float* x       = (const float*)d_in[0];
    const float* ssfe_w  = (const float*)d_in[1];
    const float* ssfe_g  = (const float*)d_in[2];
    const float* ssfe_b  = (const float*)d_in[3];
    const float* cc_w    = (const float*)d_in[4];
    const float* cc_g    = (const float*)d_in[5];
    const float* cc_b    = (const float*)d_in[6];
    const float* ln1_g   = (const float*)d_in[7];
    const float* ln1_b   = (const float*)d_in[8];
    const float* qkv_w   = (const float*)d_in[9];
    const float* qkv_b   = (const float*)d_in[10];
    const float* gbn_g   = (const float*)d_in[11];
    const float* gbn_b   = (const float*)d_in[12];
    const float* qkv2_w  = (const float*)d_in[13];
    const float* qkv2_b  = (const float*)d_in[14];
    const float* ln2_g   = (const float*)d_in[15];
    const float* ln2_b   = (const float*)d_in[16];
    const float* mlp_w1  = (const float*)d_in[17];
    const float* mlp_b1  = (const float*)d_in[18];
    const float* mlp_w2  = (const float*)d_in[19];
    const float* mlp_b2  = (const float*)d_in[20];
    const float* cs_w    = (const float*)d_in[21];
    const float* cs_g    = (const float*)d_in[22];
    const float* cs_b    = (const float*)d_in[23];
    const float* lfe0_w  = (const float*)d_in[24];
    const float* lfe0_g  = (const float*)d_in[25];
    const float* lfe0_b  = (const float*)d_in[26];
    const float* s0_pi_w = (const float*)d_in[27];
    const float* s0_pi_b = (const float*)d_in[28];
    const float* s0_bn_g = (const float*)d_in[29];
    const float* s0_bn_b = (const float*)d_in[30];
    const float* s0_po_w = (const float*)d_in[31];
    const float* s0_po_b = (const float*)d_in[32];
    const float* lfe1_w  = (const float*)d_in[33];
    const float* lfe1_g  = (const float*)d_in[34];
    const float* lfe1_b  = (const float*)d_in[35];
    const float* s1_pi_w = (const float*)d_in[36];
    const float* s1_pi_b = (const float*)d_in[37];
    const float* s1_bn_g = (const float*)d_in[38];
    const float* s1_bn_b = (const float*)d_in[39];
    const float* s1_po_w = (const float*)d_in[40];
    const float* s1_po_b = (const float*)d_in[41];
    const float* lamuda  = (const float*)d_in[42];
    const float* fc_w    = (const float*)d_in[43];
    float* out = (float*)d_out;
    float* ws = (float*)d_ws;

    // workspace regions (floats)
    float* xs = ws;                    // scratch (wlfe1 weights)
    float* t  = ws + 4718592;          // (B,128,N) residual stream / xc
    float* P1 = ws + 8912896;          // (B,128,N)
    float* Qr = ws + 13107200;         // 12.58M floats, phase-overlaid
    float* P2 = ws + 25690112;         // (B,128,N)
    float* P3 = ws + 29884416;         // (B,128,N)

    // GISSA phase (Qr)
    unsigned short* curbf = (unsigned short*)Qr;               // (B,128,1024)
    unsigned short* curT  = (unsigned short*)(Qr + 2097152);   // (B,1024,128)
    unsigned short* yrbf  = (unsigned short*)(Qr + 4194304);   // (B,128,1024)
    unsigned short* yrT   = (unsigned short*)(Qr + 6291456);   // (B,1024,128)
    unsigned short* xsT   = (unsigned short*)(Qr + 8388608);   // (B,1024,160)
    float* ybuf = P2;                                          // (B,128,1024) fp32

    // swsa phase (Qr overlay)
    unsigned short* xpT   = (unsigned short*)Qr;               // cs->lfe0 (+res)
    unsigned short* qT0   = (unsigned short*)Qr;               // pi0->swsa0/1
    unsigned short* v0    = (unsigned short*)(Qr + 2097152);
    unsigned short* yvT   = (unsigned short*)(Qr + 4194304);   // swsa0->po0
    unsigned short* v1    = (unsigned short*)(Qr + 4194304);   // pi1->swsa1
    unsigned short* xp3T  = (unsigned short*)(Qr + 6291456);   // po0->lfe1 (+res)
    unsigned short* yv2T  = (unsigned short*)(Qr + 6291456);   // swsa1->po1
    unsigned short* xp2T  = (unsigned short*)(Qr + 8388608);   // lfe0->pi0,po0-res
    unsigned short* xp4T  = (unsigned short*)(Qr + 8388608);   // lfe1->pi1,po1-res

    // permanently-free Qr tail: packed 1x1+mlp weights + meanb
    unsigned short* linw  = (unsigned short*)(Qr + 11010048);  // 233472 u16
    unsigned short* wcc   = linw;                 // [128][160]
    unsigned short* wpi0  = linw + 20480;         // [256][128]
    unsigned short* wpi1  = linw + 53248;         // [128][128]
    unsigned short* wpo0  = linw + 69632;         // [128][128]
    unsigned short* wpo1  = linw + 86016;         // [128][128]
    unsigned short* w1bf  = linw + 102400;        // [512][128]
    unsigned short* w2bf  = linw + 167936;        // [128][512]
    float* meanb = Qr + 11200000;                 // 4096 floats

    // small mats in P3 (dead before po1 writes P3)
    float* Gbuf  = P3 + 1048576;
    float* Sbuf  = P3 + 1572864;
    unsigned short* M1bf = (unsigned short*)(P3 + 1576960);
    float* c1buf = P3 + 1839104;
    unsigned short* M2bf = (unsigned short*)(P3 + 1843200);
    float* c2buf = P3 + 2105344;

    unsigned short* wssfe = (unsigned short*)P3;             // 9*144*160
    unsigned short* wcs   = (unsigned short*)(P3 + 131072);  // 9*128*160
    unsigned short* wlfe0 = (unsigned short*)(P3 + 262144);  // 9*128*128
    unsigned short* wlfe1 = (unsigned short*)xs;             // 9*128*128

    const dim3 blk(256);

    prepack_convs<<<dim3((686592 + 255) / 256), blk, 0, stream>>>(
        ssfe_w, cs_w, lfe0_w, lfe1_w, wssfe, wcs, wlfe0, wlfe1);
    prepack_lins<<<dim3((233472 + 255) / 256), blk, 0, stream>>>(
        cc_w, s0_pi_w, s1_pi_w, s0_po_w, s1_po_w, mlp_w1, mlp_w2, linw);

    conv3x3_stg_kernel<160, 5, 3><<<dim3(32, 8, 3), blk, 0, stream>>>(
        x, 144, wssfe, ssfe_g, ssfe_b, xsT, 144, 144);
    lin_mfma_kernel<160><<<dim3(32, 16), blk, 0, stream>>>(
        xsT, wcc, nullptr, cc_g, cc_b, nullptr, t, nullptr, nullptr, 1);

    // ---- GISSA via Gram trick ----
    ln_kernel<<<dim3(128), blk, 0, stream>>>(t, ln1_g, ln1_b, curbf, curT);
    gram_kernel<<<dim3(128), blk, 0, stream>>>(curbf, Gbuf);
    sums_kernel<<<dim3(32), blk, 0, stream>>>(curbf, Sbuf);
    mats1_kernel<<<dim3(512), dim3(64), 0, stream>>>(Gbuf, Sbuf, qkv_w, qkv_b, gbn_g, gbn_b, M1bf, c1buf);
    apply1_mfma_kernel<<<dim3(256), blk, 0, stream>>>(curT, M1bf, c1buf, ybuf, yrbf, yrT);
    gram_kernel<<<dim3(128), blk, 0, stream>>>(yrbf, Gbuf);
    sums_kernel<<<dim3(32), blk, 0, stream>>>(yrbf, Sbuf);
    mats2_kernel<<<dim3(256), blk, 0, stream>>>(Gbuf, Sbuf, qkv2_w, qkv2_b, M2bf, c2buf);
    apply2_mfma_kernel<<<dim3(256), blk, 0, stream>>>(yrT, M2bf, c2buf, ybuf, t);

    mlp_mfma_kernel<<<dim3(512), blk, 0, stream>>>(t, ln2_g, ln2_b, w1bf, mlp_b1, w2bf, mlp_b2);

    // ---- xp branch, all-bf16 ----
    // xpT = cbr3(xsT, cs)
    conv3x3_lds_kernel<160><<<dim3(32, 16), blk, 0, stream>>>(
        xsT, wcs, cs_g, cs_b, nullptr, xpT, 128);
    // xp2T = cbr3(xpT, lfe0) + xpT
    conv3x3_lds_kernel<128><<<dim3(32, 16), blk, 0, stream>>>(
        xpT, wlfe0, lfe0_g, lfe0_b, xpT, xp2T, 128);
    // pi0: q -> qT0, v -> v0
    lin_mfma_kernel<128><<<dim3(32, 16), blk, 0, stream>>>(
        xp2T, wpi0, s0_pi_b, s0_bn_g, s0_bn_b, nullptr, nullptr, nullptr, qT0, 0);
    lin_mfma_kernel<128><<<dim3(32, 16), blk, 0, stream>>>(
        xp2T, wpi0 + (size_t)128 * 128, s0_pi_b + 128, s0_bn_g + 128, s0_bn_b + 128,
        nullptr, nullptr, v0, nullptr, 0);
    swsa_mfma_kernel<<<dim3(512), blk, 0, stream>>>(qT0, v0, nullptr, yvT, 1.0f);
    // xp3T = po0(yvT) + xp2T
    lin_mfma_kernel<128><<<dim3(32, 16), blk, 0, stream>>>(
        yvT, wpo0, s0_po_b, nullptr, nullptr, xp2T, nullptr, nullptr, xp3T, 0);
    // xp4T = cbr3(xp3T, lfe1) + xp3T
    conv3x3_lds_kernel<128><<<dim3(32, 16), blk, 0, stream>>>(
        xp3T, wlfe1, lfe1_g, lfe1_b, xp3T, xp4T, 128);
    // pi1 -> v1
    lin_mfma_kernel<128><<<dim3(32, 16), blk, 0, stream>>>(
        xp4T, wpi1, s1_pi_b, s1_bn_g, s1_bn_b, nullptr, nullptr, v1, nullptr, 0);
    swsa_mfma_kernel<<<dim3(512), blk, 0, stream>>>(qT0, v1, nullptr, yv2T, 0.08838834764831845f);
    // xp5 (fp32, P3) = po1(yv2T) + xp4T
    lin_mfma_kernel<128><<<dim3(32, 16), blk, 0, stream>>>(
        yv2T, wpo1, s1_po_b, nullptr, nullptr, xp4T, P3, nullptr, nullptr, 0);

    mean_kernel<<<dim3(1024), blk, 0, stream>>>(t, P3, lamuda, meanb);
    fc_kernel<<<dim3(2), blk, 0, stream>>>(meanb, fc_w, out);
}